// Round 1
// baseline (10644.021 us; speedup 1.0000x reference)
//
#include <hip/hip_runtime.h>
#include <math.h>

// Problem constants
#define BB 4
#define CM 128      // d_model
#define DI 256      // d_inner
#define NS 16       // d_state
#define RK 8        // dt_rank
#define KD 4        // K directions
#define HH 64
#define WW 128      // interleaved width
#define LL 8192     // HH*WW

__device__ __forceinline__ float sigmoidf_(float x){ return 1.f/(1.f+__expf(-x)); }
__device__ __forceinline__ float siluf_(float x){ return x*sigmoidf_(x); }
__device__ __forceinline__ float softplusf_(float x){
  if (x > 20.f) return x;
  if (x < -20.f) return __expf(x);
  return log1pf(__expf(x));
}
__device__ __forceinline__ float geluf_(float x){ return 0.5f*x*(1.f+erff(x*0.70710678118654752f)); }
__device__ __forceinline__ float waveReduceSum(float v){
  for (int o=32;o>0;o>>=1) v += __shfl_xor(v,o,64);
  return v;
}

// ---------------- CT build: interleave x1/x2 -> channel-first (B,128,L) ----------------
__global__ void k_build_ct(const float* __restrict__ x1, const float* __restrict__ x2,
                           float* __restrict__ ct){
  int idx = blockIdx.x*256 + threadIdx.x;          // < 4*128*8192
  int p = idx & (LL-1); int c = (idx>>13) & 127; int b = idx>>20;
  int hh = p>>7, ww = p&127;
  const float* src = (ww&1) ? x2 : x1;
  ct[idx] = src[(((size_t)b*CM + c)*HH + hh)*64 + (ww>>1)];
}

// ---------------- Generic tiled f32 GEMM over tokens ----------------
// C[m,n] = epi( sum_k A[m,k]*W[n,k] + bias[n] ), per-batch (grid.z), M=8192 rows/batch.
// atrans: A stored K-major per batch: A[k*8192 + m]
// epi: 0 plain, 1 +resid, 2 gelu, 3 split (n<256 -> C, else C2)
__global__ void k_gemm(const float* __restrict__ A, const float* __restrict__ W,
                       const float* __restrict__ bias, const float* __restrict__ resid,
                       float* __restrict__ C, float* __restrict__ C2,
                       int N, int Kd, int epi, int atrans){
  const int L = LL;
  int b = blockIdx.z;
  const float* Ab = A + (size_t)b*L*Kd;
  int m0 = blockIdx.y*32, n0 = blockIdx.x*32;
  __shared__ float As[32][33], Ws[32][33];
  int tx = threadIdx.x, ty = threadIdx.y, t = ty*16+tx;
  float a00=0.f,a01=0.f,a10=0.f,a11=0.f;
  for (int k0=0;k0<Kd;k0+=32){
    for (int i=t;i<1024;i+=256){
      if (atrans){ int mm=i&31, kk=i>>5; As[mm][kk] = Ab[(size_t)(k0+kk)*L + m0+mm]; }
      else       { int r=i>>5, c=i&31;   As[r][c]  = Ab[(size_t)(m0+r)*Kd + k0+c]; }
      int r=i>>5, c=i&31;
      Ws[r][c] = W[(size_t)(n0+r)*Kd + k0+c];
    }
    __syncthreads();
#pragma unroll
    for (int kk=0;kk<32;kk++){
      float x0=As[ty][kk], x1=As[ty+16][kk];
      float w0=Ws[tx][kk], w1=Ws[tx+16][kk];
      a00 += x0*w0; a01 += x0*w1; a10 += x1*w0; a11 += x1*w1;
    }
    __syncthreads();
  }
  size_t outb = (size_t)b*L;
#define EMIT(mm,nn,vv) { \
    int m_ = (mm), n_ = (nn); float v_ = (vv); \
    if (bias) v_ += bias[n_]; \
    if (epi==2) v_ = geluf_(v_); \
    if (epi==1) v_ += resid[(outb+m_)*(size_t)N + n_]; \
    if (epi==3){ if (n_<256) C[(outb+m_)*256+n_]=v_; else C2[(outb+m_)*256+(n_-256)]=v_; } \
    else C[(outb+m_)*(size_t)N + n_] = v_; }
  EMIT(m0+ty,    n0+tx,    a00);
  EMIT(m0+ty,    n0+tx+16, a01);
  EMIT(m0+ty+16, n0+tx,    a10);
  EMIT(m0+ty+16, n0+tx+16, a11);
#undef EMIT
}

// ---------------- LayerNorm over 128 channels ----------------
__global__ void k_ln128(const float* __restrict__ X, const float* __restrict__ g,
                        const float* __restrict__ bt, float* __restrict__ O){
  int tok = blockIdx.x, tid = threadIdx.x;
  float x = X[(size_t)tok*128 + tid];
  float s  = waveReduceSum(x);
  float s2 = waveReduceSum(x*x);
  __shared__ float a[2], a2[2];
  if ((tid&63)==0){ a[tid>>6]=s; a2[tid>>6]=s2; }
  __syncthreads();
  float mean = (a[0]+a[1])*(1.f/128.f);
  float var  = (a2[0]+a2[1])*(1.f/128.f) - mean*mean;
  float r = rsqrtf(var + 1e-5f);
  O[(size_t)tok*128+tid] = (x-mean)*r*g[tid] + bt[tid];
}

// ---------------- Depthwise 3x3 + bias + SiLU, channel-last (B,L,256) ----------------
__global__ void k_dwconv(const float* __restrict__ Xp, const float* __restrict__ w,
                         const float* __restrict__ bias, float* __restrict__ O){
  int tok = blockIdx.x; int d = threadIdx.x;
  int b = tok >> 13; int p = tok & (LL-1); int hh = p>>7, ww = p&127;
  float acc = bias[d];
#pragma unroll
  for (int dy=0;dy<3;dy++){
    int yy = hh+dy-1; if (yy<0||yy>=HH) continue;
#pragma unroll
    for (int dx=0;dx<3;dx++){
      int xx = ww+dx-1; if (xx<0||xx>=WW) continue;
      acc += Xp[((size_t)b*LL + yy*WW + xx)*256 + d] * w[d*9 + dy*3 + dx];
    }
  }
  O[(size_t)tok*256 + d] = siluf_(acc);
}

// ---------------- x_proj: per-token 4x40 projections, written in scan order ----------------
__global__ void k_xdbl(const float* __restrict__ Xpa, const float* __restrict__ xpw,
                       float* __restrict__ DBC){
  __shared__ float U[16][256];
  int tid = threadIdx.x;
  int blk = blockIdx.x;              // B*L/16 = 2048
  int b = blk >> 9;
  int p0 = (blk & 511) << 4;
  for (int i=tid;i<16*256;i+=256){ int tt=i>>8, d=i&255;
    U[tt][d] = Xpa[((size_t)b*LL + p0+tt)*256 + d]; }
  __syncthreads();
  if (tid < 160){
    int k = tid/40, c = tid%40;
    const float* wr = xpw + ((size_t)k*40 + c)*256;
    float acc[16];
#pragma unroll
    for (int tt=0;tt<16;tt++) acc[tt]=0.f;
    for (int d=0;d<256;d++){
      float wv = wr[d];
#pragma unroll
      for (int tt=0;tt<16;tt++) acc[tt] += U[tt][d]*wv;
    }
    for (int tt=0;tt<16;tt++){
      int p = p0+tt; int hh=p>>7, ww=p&127;
      int t;
      if      (k==0) t = p;
      else if (k==1) t = (ww<<6)|hh;
      else if (k==2) t = LL-1-p;
      else           t = LL-1-((ww<<6)|hh);
      DBC[(((size_t)(b*KD+k))*LL + t)*40 + c] = acc[tt];
    }
  }
}

// ---------------- Selective scan: 16 lanes (states) per (b,k,d) group ----------------
__global__ void k_scan(const float* __restrict__ DBC, const float* __restrict__ Xpa,
                       const float* __restrict__ dtw_all, const float* __restrict__ dtb_all,
                       const float* __restrict__ A_logs, const float* __restrict__ Ds,
                       float* __restrict__ Y){
  int tid = threadIdx.x;
  int gid = blockIdx.x*16 + (tid>>4);   // 0..4095 : (b,k,d)
  int n = tid & 15;
  int b = gid >> 10;
  int k = (gid >> 8) & 3;
  int d = gid & 255;
  int kd = k*256+d;
  float dtw[8];
#pragma unroll
  for (int r=0;r<8;r++) dtw[r] = dtw_all[kd*8+r];
  float dtb  = dtb_all[kd];
  float Aval = -__expf(A_logs[kd*16+n]);
  float Dval = Ds[kd];
  const float* dbc = DBC + ((size_t)(b*KD+k))*LL*40;
  const float* xp  = Xpa + (size_t)b*LL*256 + d;
  float* yp        = Y   + (size_t)b*LL*256 + d;
  float h = 0.f;
  for (int t=0;t<LL;t++){
    int p;
    if      (k==0) p = t;
    else if (k==1) p = ((t&63)<<7) | (t>>6);
    else if (k==2) p = LL-1-t;
    else { int j = LL-1-t; p = ((j&63)<<7) | (j>>6); }
    const float* row = dbc + (size_t)t*40;
    float dsum = dtb;
#pragma unroll
    for (int r=0;r<8;r++) dsum += row[r]*dtw[r];
    float delta = softplusf_(dsum);
    float u  = xp[(size_t)p*256];
    float Bn = row[8+n], Cn = row[24+n];
    h = __expf(delta*Aval)*h + (delta*u)*Bn;
    float yi = h*Cn;
    yi += __shfl_xor(yi,1,64);
    yi += __shfl_xor(yi,2,64);
    yi += __shfl_xor(yi,4,64);
    yi += __shfl_xor(yi,8,64);
    if (n==0) atomicAdd(yp + (size_t)p*256, yi + u*Dval);
  }
}

// ---------------- Out-norm (LN 256) * SiLU(z) ----------------
__global__ void k_gate(const float* __restrict__ Y, const float* __restrict__ Z,
                       const float* __restrict__ g, const float* __restrict__ bt,
                       float* __restrict__ G){
  int tok = blockIdx.x, tid = threadIdx.x;
  float y = Y[(size_t)tok*256+tid];
  float s  = waveReduceSum(y);
  float s2 = waveReduceSum(y*y);
  __shared__ float a[4], a2[4];
  if ((tid&63)==0){ a[tid>>6]=s; a2[tid>>6]=s2; }
  __syncthreads();
  float mean = (a[0]+a[1]+a[2]+a[3])*(1.f/256.f);
  float var  = (a2[0]+a2[1]+a2[2]+a2[3])*(1.f/256.f) - mean*mean;
  float r = rsqrtf(var+1e-5f);
  float ln = (y-mean)*r*g[tid]+bt[tid];
  float z  = Z[(size_t)tok*256+tid];
  G[(size_t)tok*256+tid] = ln * siluf_(z);
}

// ---------------- De-interleave: X0 (B,L,128) -> x1f/x2f (B,128,64,64) ----------------
__global__ void k_deint(const float* __restrict__ X, float* __restrict__ o1, float* __restrict__ o2){
  int idx = blockIdx.x*256 + threadIdx.x;   // < 4*128*64*64
  int j = idx & 63; int y = (idx>>6)&63; int c = (idx>>12)&127; int b = idx>>19;
  o1[idx] = X[((size_t)b*LL + y*WW + 2*j  )*128 + c];
  o2[idx] = X[((size_t)b*LL + y*WW + 2*j+1)*128 + c];
}

// ---------------- 3x3 conv (128->128) + BN (+res) + ReLU ----------------
__global__ void k_conv3(const float* __restrict__ in, const float* __restrict__ w9,
                        const float* __restrict__ g, const float* __restrict__ bb2,
                        const float* __restrict__ mm2, const float* __restrict__ vv2,
                        const float* __restrict__ res, float* __restrict__ out){
  int x = threadIdx.x;            // 0..63
  int cosub = threadIdx.y;        // 0..3
  int co = blockIdx.x*4 + cosub;
  int y = blockIdx.y; int b = blockIdx.z;
  __shared__ float S[3][66];
  float acc = 0.f;
  for (int ci=0; ci<128; ci++){
    int t = cosub*64 + x;
    for (int i=t;i<198;i+=256){
      int dy = i/66, xx = i%66; int yy = y + dy - 1; int xs = xx - 1;
      float v = 0.f;
      if (yy>=0 && yy<64 && xs>=0 && xs<64)
        v = in[(((size_t)b*128+ci)*64+yy)*64+xs];
      S[dy][xx] = v;
    }
    __syncthreads();
    const float* wr = w9 + ((size_t)co*128 + ci)*9;
#pragma unroll
    for (int dy=0;dy<3;dy++){
      acc += S[dy][x]*wr[dy*3+0] + S[dy][x+1]*wr[dy*3+1] + S[dy][x+2]*wr[dy*3+2];
    }
    __syncthreads();
  }
  float s = g[co]*rsqrtf(vv2[co]+1e-5f);
  float v = acc*s + (bb2[co] - mm2[co]*s);
  if (res) v += res[(((size_t)b*128+co)*64+y)*64+x];
  out[(((size_t)b*128+co)*64+y)*64+x] = fmaxf(v, 0.f);
}

extern "C" void kernel_launch(void* const* d_in, const int* in_sizes, int n_in,
                              void* d_out, int out_size, void* d_ws, size_t ws_size,
                              hipStream_t stream){
  const float* x1        = (const float*)d_in[0];
  const float* x2        = (const float*)d_in[1];
  const float* conv_in_w = (const float*)d_in[2];
  const float* conv_in_b = (const float*)d_in[3];
  const float* ln1_g     = (const float*)d_in[4];
  const float* ln1_b     = (const float*)d_in[5];
  const float* in_proj_w = (const float*)d_in[6];
  const float* dw_w      = (const float*)d_in[7];
  const float* dw_b      = (const float*)d_in[8];
  const float* x_proj_w  = (const float*)d_in[9];
  const float* dt_proj_w = (const float*)d_in[10];
  const float* dt_proj_b = (const float*)d_in[11];
  const float* A_logs    = (const float*)d_in[12];
  const float* Ds        = (const float*)d_in[13];
  const float* onorm_g   = (const float*)d_in[14];
  const float* onorm_b   = (const float*)d_in[15];
  const float* out_proj_w= (const float*)d_in[16];
  const float* ln2_g     = (const float*)d_in[17];
  const float* ln2_b     = (const float*)d_in[18];
  const float* mlp_w1    = (const float*)d_in[19];
  const float* mlp_b1    = (const float*)d_in[20];
  const float* mlp_w2    = (const float*)d_in[21];
  const float* mlp_b2    = (const float*)d_in[22];
  const float* rb1_w     = (const float*)d_in[23];
  const float* bn1_g     = (const float*)d_in[24];
  const float* bn1_b     = (const float*)d_in[25];
  const float* bn1_m     = (const float*)d_in[26];
  const float* bn1_v     = (const float*)d_in[27];
  const float* rb2_w     = (const float*)d_in[28];
  const float* bn2_g     = (const float*)d_in[29];
  const float* bn2_b     = (const float*)d_in[30];
  const float* bn2_m     = (const float*)d_in[31];
  const float* bn2_v     = (const float*)d_in[32];

  float* ws = (float*)d_ws;
  const size_t FM = 262144; // floats per MiB
  // Aliased workspace layout (peak 148 MiB):
  float* X0  = ws + 0;        // 0-16   residual stream (B,L,128)
  float* Ln  = ws + 16*FM;    // 16-32  LN out (reused), later x1f region
  float* Yb  = ws + 16*FM;    // 16-48  scan accumulator (over Ln+first half of Ab; timing disjoint)
  float* Ab  = ws + 32*FM;    // 32-64  xp pre-conv (B,L,256)
  float* Zb  = ws + 64*FM;    // 64-96  z
  float* Xpa = ws + 96*FM;    // 96-128 post-dw-silu (B,L,256)
  float* CT  = ws + 96*FM;    // alias (used before Xpa)
  float* Gb  = ws + 96*FM;    // alias (used after Xpa dead)
  float* DBC = ws + 128*FM;   // 128-148 (B,K,L,40)
  float* H1  = ws + 32*FM;    // 32-96  MLP hidden (B,L,512)
  float* x1f = ws + 16*FM;    // 16-24
  float* x2f = ws + 24*FM;    // 24-32
  float* tmpc= ws + 32*FM;    // 32-40
  float* out = (float*)d_out;

  dim3 bgemm(16,16);
  // 1. interleave -> CT (channel-first)
  k_build_ct<<<16384,256,0,stream>>>(x1,x2,CT);
  // 2. conv_in 1x1: X0 = CT^T @ conv_in_w^T + b
  k_gemm<<<dim3(4,256,BB),bgemm,0,stream>>>(CT, conv_in_w, conv_in_b, nullptr, X0, nullptr, 128,128,0,1);
  // 3. LN1
  k_ln128<<<BB*LL,128,0,stream>>>(X0, ln1_g, ln1_b, Ln);
  // 4. in_proj (512) -> split xp(Ab) / z(Zb)
  k_gemm<<<dim3(16,256,BB),bgemm,0,stream>>>(Ln, in_proj_w, nullptr, nullptr, Ab, Zb, 512,128,3,0);
  // 5. depthwise 3x3 + silu
  k_dwconv<<<BB*LL,256,0,stream>>>(Ab, dw_w, dw_b, Xpa);
  // 6. zero scan accumulator
  hipMemsetAsync(Yb, 0, (size_t)32*1024*1024, stream);
  // 7. x_proj -> DBC (dts/B/C in scan order)
  k_xdbl<<<2048,256,0,stream>>>(Xpa, x_proj_w, DBC);
  // 8. selective scan (4 directions), atomic accumulate into Yb
  k_scan<<<256,256,0,stream>>>(DBC, Xpa, dt_proj_w, dt_proj_b, A_logs, Ds, Yb);
  // 9. out-norm * silu(z) -> Gb
  k_gate<<<BB*LL,256,0,stream>>>(Yb, Zb, onorm_g, onorm_b, Gb);
  // 10. out_proj + residual -> X0
  k_gemm<<<dim3(4,256,BB),bgemm,0,stream>>>(Gb, out_proj_w, nullptr, X0, X0, nullptr, 128,256,1,0);
  // 11. LN2
  k_ln128<<<BB*LL,128,0,stream>>>(X0, ln2_g, ln2_b, Ln);
  // 12. MLP1 gelu -> H1
  k_gemm<<<dim3(16,256,BB),bgemm,0,stream>>>(Ln, mlp_w1, mlp_b1, nullptr, H1, nullptr, 512,128,2,0);
  // 13. MLP2 + residual -> X0
  k_gemm<<<dim3(4,256,BB),bgemm,0,stream>>>(H1, mlp_w2, mlp_b2, X0, X0, nullptr, 128,512,1,0);
  // 14. de-interleave
  k_deint<<<8192,256,0,stream>>>(X0, x1f, x2f);
  // 15-18. resblocks
  k_conv3<<<dim3(32,64,BB),dim3(64,4),0,stream>>>(x1f, rb1_w, bn1_g,bn1_b,bn1_m,bn1_v, nullptr, tmpc);
  k_conv3<<<dim3(32,64,BB),dim3(64,4),0,stream>>>(tmpc, rb2_w, bn2_g,bn2_b,bn2_m,bn2_v, x1f, out);
  k_conv3<<<dim3(32,64,BB),dim3(64,4),0,stream>>>(x2f, rb1_w, bn1_g,bn1_b,bn1_m,bn1_v, nullptr, tmpc);
  k_conv3<<<dim3(32,64,BB),dim3(64,4),0,stream>>>(tmpc, rb2_w, bn2_g,bn2_b,bn2_m,bn2_v, x2f, out + (size_t)2097152);
}

// Round 2
// 6619.019 us; speedup vs baseline: 1.6081x; 1.6081x over previous
//
#include <hip/hip_runtime.h>
#include <math.h>

// Problem constants
#define BB 4
#define CM 128      // d_model
#define DI 256      // d_inner
#define NS 16       // d_state
#define RK 8        // dt_rank
#define KD 4        // K directions
#define HH 64
#define WW 128      // interleaved width
#define LL 8192     // HH*WW
#define NC 16       // scan chunks per sequence
#define CH 512      // chunk length (NC*CH == LL)

__device__ __forceinline__ float sigmoidf_(float x){ return 1.f/(1.f+__expf(-x)); }
__device__ __forceinline__ float siluf_(float x){ return x*sigmoidf_(x); }
__device__ __forceinline__ float softplusf_(float x){
  if (x > 20.f) return x;
  if (x < -20.f) return __expf(x);
  return log1pf(__expf(x));
}
__device__ __forceinline__ float geluf_(float x){ return 0.5f*x*(1.f+erff(x*0.70710678118654752f)); }
__device__ __forceinline__ float waveReduceSum(float v){
  for (int o=32;o>0;o>>=1) v += __shfl_xor(v,o,64);
  return v;
}
__device__ __forceinline__ int scan_pos(int t, int k){
  if      (k==0) return t;
  else if (k==1) return ((t&63)<<7) | (t>>6);
  else if (k==2) return LL-1-t;
  else { int j = LL-1-t; return ((j&63)<<7) | (j>>6); }
}

// ---------------- CT build: interleave x1/x2 -> channel-first (B,128,L) ----------------
__global__ void k_build_ct(const float* __restrict__ x1, const float* __restrict__ x2,
                           float* __restrict__ ct){
  int idx = blockIdx.x*256 + threadIdx.x;          // < 4*128*8192
  int p = idx & (LL-1); int c = (idx>>13) & 127; int b = idx>>20;
  int hh = p>>7, ww = p&127;
  const float* src = (ww&1) ? x2 : x1;
  ct[idx] = src[(((size_t)b*CM + c)*HH + hh)*64 + (ww>>1)];
}

// ---------------- Generic tiled f32 GEMM over tokens ----------------
__global__ void k_gemm(const float* __restrict__ A, const float* __restrict__ W,
                       const float* __restrict__ bias, const float* __restrict__ resid,
                       float* __restrict__ C, float* __restrict__ C2,
                       int N, int Kd, int epi, int atrans){
  const int L = LL;
  int b = blockIdx.z;
  const float* Ab = A + (size_t)b*L*Kd;
  int m0 = blockIdx.y*32, n0 = blockIdx.x*32;
  __shared__ float As[32][33], Ws[32][33];
  int tx = threadIdx.x, ty = threadIdx.y, t = ty*16+tx;
  float a00=0.f,a01=0.f,a10=0.f,a11=0.f;
  for (int k0=0;k0<Kd;k0+=32){
    for (int i=t;i<1024;i+=256){
      if (atrans){ int mm=i&31, kk=i>>5; As[mm][kk] = Ab[(size_t)(k0+kk)*L + m0+mm]; }
      else       { int r=i>>5, c=i&31;   As[r][c]  = Ab[(size_t)(m0+r)*Kd + k0+c]; }
      int r=i>>5, c=i&31;
      Ws[r][c] = W[(size_t)(n0+r)*Kd + k0+c];
    }
    __syncthreads();
#pragma unroll
    for (int kk=0;kk<32;kk++){
      float x0=As[ty][kk], x1=As[ty+16][kk];
      float w0=Ws[tx][kk], w1=Ws[tx+16][kk];
      a00 += x0*w0; a01 += x0*w1; a10 += x1*w0; a11 += x1*w1;
    }
    __syncthreads();
  }
  size_t outb = (size_t)b*L;
#define EMIT(mm,nn,vv) { \
    int m_ = (mm), n_ = (nn); float v_ = (vv); \
    if (bias) v_ += bias[n_]; \
    if (epi==2) v_ = geluf_(v_); \
    if (epi==1) v_ += resid[(outb+m_)*(size_t)N + n_]; \
    if (epi==3){ if (n_<256) C[(outb+m_)*256+n_]=v_; else C2[(outb+m_)*256+(n_-256)]=v_; } \
    else C[(outb+m_)*(size_t)N + n_] = v_; }
  EMIT(m0+ty,    n0+tx,    a00);
  EMIT(m0+ty,    n0+tx+16, a01);
  EMIT(m0+ty+16, n0+tx,    a10);
  EMIT(m0+ty+16, n0+tx+16, a11);
#undef EMIT
}

// ---------------- LayerNorm over 128 channels ----------------
__global__ void k_ln128(const float* __restrict__ X, const float* __restrict__ g,
                        const float* __restrict__ bt, float* __restrict__ O){
  int tok = blockIdx.x, tid = threadIdx.x;
  float x = X[(size_t)tok*128 + tid];
  float s  = waveReduceSum(x);
  float s2 = waveReduceSum(x*x);
  __shared__ float a[2], a2[2];
  if ((tid&63)==0){ a[tid>>6]=s; a2[tid>>6]=s2; }
  __syncthreads();
  float mean = (a[0]+a[1])*(1.f/128.f);
  float var  = (a2[0]+a2[1])*(1.f/128.f) - mean*mean;
  float r = rsqrtf(var + 1e-5f);
  O[(size_t)tok*128+tid] = (x-mean)*r*g[tid] + bt[tid];
}

// ---------------- Depthwise 3x3 + bias + SiLU, channel-last (B,L,256) ----------------
__global__ void k_dwconv(const float* __restrict__ Xp, const float* __restrict__ w,
                         const float* __restrict__ bias, float* __restrict__ O){
  int tok = blockIdx.x; int d = threadIdx.x;
  int b = tok >> 13; int p = tok & (LL-1); int hh = p>>7, ww = p&127;
  float acc = bias[d];
#pragma unroll
  for (int dy=0;dy<3;dy++){
    int yy = hh+dy-1; if (yy<0||yy>=HH) continue;
#pragma unroll
    for (int dx=0;dx<3;dx++){
      int xx = ww+dx-1; if (xx<0||xx>=WW) continue;
      acc += Xp[((size_t)b*LL + yy*WW + xx)*256 + d] * w[d*9 + dy*3 + dx];
    }
  }
  O[(size_t)tok*256 + d] = siluf_(acc);
}

// ---------------- x_proj: per-token 4x40 projections, written in scan order ----------------
__global__ void k_xdbl(const float* __restrict__ Xpa, const float* __restrict__ xpw,
                       float* __restrict__ DBC){
  __shared__ float U[16][256];
  int tid = threadIdx.x;
  int blk = blockIdx.x;              // B*L/16 = 2048
  int b = blk >> 9;
  int p0 = (blk & 511) << 4;
  for (int i=tid;i<16*256;i+=256){ int tt=i>>8, d=i&255;
    U[tt][d] = Xpa[((size_t)b*LL + p0+tt)*256 + d]; }
  __syncthreads();
  if (tid < 160){
    int k = tid/40, c = tid%40;
    const float* wr = xpw + ((size_t)k*40 + c)*256;
    float acc[16];
#pragma unroll
    for (int tt=0;tt<16;tt++) acc[tt]=0.f;
    for (int d=0;d<256;d++){
      float wv = wr[d];
#pragma unroll
      for (int tt=0;tt<16;tt++) acc[tt] += U[tt][d]*wv;
    }
    for (int tt=0;tt<16;tt++){
      int p = p0+tt; int hh=p>>7, ww=p&127;
      int t;
      if      (k==0) t = p;
      else if (k==1) t = (ww<<6)|hh;
      else if (k==2) t = LL-1-p;
      else           t = LL-1-((ww<<6)|hh);
      DBC[(((size_t)(b*KD+k))*LL + t)*40 + c] = acc[tt];
    }
  }
}

// ---------------- Chunked selective scan ----------------
// Pass A: per (b,k,d,chunk) group of 16 lanes: scan chunk from h=0,
//         store h_out[n] and sum of delta (scalar).
__global__ void k_scanA(const float* __restrict__ DBC, const float* __restrict__ Xpa,
                        const float* __restrict__ dtw_all, const float* __restrict__ dtb_all,
                        const float* __restrict__ A_logs,
                        float* __restrict__ Hout, float* __restrict__ Ssum){
  int tid = threadIdx.x;
  int gid = blockIdx.x*16 + (tid>>4);   // group: bkd*NC + c  (65536 total)
  int n = tid & 15;
  int c = gid & (NC-1);
  int bkd = gid >> 4;                    // log2(NC)=4
  int b = bkd >> 10;
  int k = (bkd >> 8) & 3;
  int d = bkd & 255;
  int kd = k*256+d;
  float dtw[8];
#pragma unroll
  for (int r=0;r<8;r++) dtw[r] = dtw_all[kd*8+r];
  float dtb  = dtb_all[kd];
  float Aval = -__expf(A_logs[kd*16+n]);
  const float* dbc = DBC + ((size_t)(b*KD+k))*LL*40;
  const float* xp  = Xpa + (size_t)b*LL*256 + d;
  float h = 0.f, S = 0.f;
  int t0 = c*CH;
  for (int i=0;i<CH;i++){
    int t = t0+i;
    int p = scan_pos(t,k);
    const float* row = dbc + (size_t)t*40;
    float dsum = dtb;
#pragma unroll
    for (int r=0;r<8;r++) dsum += row[r]*dtw[r];
    float delta = softplusf_(dsum);
    S += delta;
    float u  = xp[(size_t)p*256];
    float Bn = row[8+n];
    h = __expf(delta*Aval)*h + (delta*u)*Bn;
  }
  Hout[(size_t)gid*16+n] = h;
  if (n==0) Ssum[gid] = S;
}

// Pass B: serial over chunks, compute each chunk's starting state.
__global__ void k_scanB(const float* __restrict__ Ssum, const float* __restrict__ Hout,
                        const float* __restrict__ A_logs, float* __restrict__ Hstart){
  int idx = blockIdx.x*256 + threadIdx.x;  // bkd*16+n (65536)
  int n = idx & 15; int bkd = idx >> 4;
  int kd = ((bkd>>8)&3)*256 + (bkd&255);
  float Aval = -__expf(A_logs[kd*16+n]);
  float h = 0.f;
  for (int c=0;c<NC;c++){
    size_t g = (size_t)bkd*NC + c;
    Hstart[g*16+n] = h;
    h = __expf(Aval*Ssum[g])*h + Hout[g*16+n];
  }
}

// Pass C: re-scan chunk with correct h_start, emit y (atomic accumulate).
__global__ void k_scanC(const float* __restrict__ DBC, const float* __restrict__ Xpa,
                        const float* __restrict__ dtw_all, const float* __restrict__ dtb_all,
                        const float* __restrict__ A_logs, const float* __restrict__ Ds,
                        const float* __restrict__ Hstart, float* __restrict__ Y){
  int tid = threadIdx.x;
  int gid = blockIdx.x*16 + (tid>>4);
  int n = tid & 15;
  int c = gid & (NC-1);
  int bkd = gid >> 4;
  int b = bkd >> 10;
  int k = (bkd >> 8) & 3;
  int d = bkd & 255;
  int kd = k*256+d;
  float dtw[8];
#pragma unroll
  for (int r=0;r<8;r++) dtw[r] = dtw_all[kd*8+r];
  float dtb  = dtb_all[kd];
  float Aval = -__expf(A_logs[kd*16+n]);
  float Dval = Ds[kd];
  const float* dbc = DBC + ((size_t)(b*KD+k))*LL*40;
  const float* xp  = Xpa + (size_t)b*LL*256 + d;
  float* yp        = Y   + (size_t)b*LL*256 + d;
  float h = Hstart[(size_t)gid*16+n];
  int t0 = c*CH;
  for (int i=0;i<CH;i++){
    int t = t0+i;
    int p = scan_pos(t,k);
    const float* row = dbc + (size_t)t*40;
    float dsum = dtb;
#pragma unroll
    for (int r=0;r<8;r++) dsum += row[r]*dtw[r];
    float delta = softplusf_(dsum);
    float u  = xp[(size_t)p*256];
    float Bn = row[8+n], Cn = row[24+n];
    h = __expf(delta*Aval)*h + (delta*u)*Bn;
    float yi = h*Cn;
    yi += __shfl_xor(yi,1,64);
    yi += __shfl_xor(yi,2,64);
    yi += __shfl_xor(yi,4,64);
    yi += __shfl_xor(yi,8,64);
    if (n==0) atomicAdd(yp + (size_t)p*256, yi + u*Dval);
  }
}

// ---------------- Out-norm (LN 256) * SiLU(z) ----------------
__global__ void k_gate(const float* __restrict__ Y, const float* __restrict__ Z,
                       const float* __restrict__ g, const float* __restrict__ bt,
                       float* __restrict__ G){
  int tok = blockIdx.x, tid = threadIdx.x;
  float y = Y[(size_t)tok*256+tid];
  float s  = waveReduceSum(y);
  float s2 = waveReduceSum(y*y);
  __shared__ float a[4], a2[4];
  if ((tid&63)==0){ a[tid>>6]=s; a2[tid>>6]=s2; }
  __syncthreads();
  float mean = (a[0]+a[1]+a[2]+a[3])*(1.f/256.f);
  float var  = (a2[0]+a2[1]+a2[2]+a2[3])*(1.f/256.f) - mean*mean;
  float r = rsqrtf(var+1e-5f);
  float ln = (y-mean)*r*g[tid]+bt[tid];
  float z  = Z[(size_t)tok*256+tid];
  G[(size_t)tok*256+tid] = ln * siluf_(z);
}

// ---------------- De-interleave: X0 (B,L,128) -> x1f/x2f (B,128,64,64) ----------------
__global__ void k_deint(const float* __restrict__ X, float* __restrict__ o1, float* __restrict__ o2){
  int idx = blockIdx.x*256 + threadIdx.x;   // < 4*128*64*64
  int j = idx & 63; int y = (idx>>6)&63; int c = (idx>>12)&127; int b = idx>>19;
  o1[idx] = X[((size_t)b*LL + y*WW + 2*j  )*128 + c];
  o2[idx] = X[((size_t)b*LL + y*WW + 2*j+1)*128 + c];
}

// ---------------- 3x3 conv (128->128) + BN (+res) + ReLU ----------------
__global__ void k_conv3(const float* __restrict__ in, const float* __restrict__ w9,
                        const float* __restrict__ g, const float* __restrict__ bb2,
                        const float* __restrict__ mm2, const float* __restrict__ vv2,
                        const float* __restrict__ res, float* __restrict__ out){
  int x = threadIdx.x;            // 0..63
  int cosub = threadIdx.y;        // 0..3
  int co = blockIdx.x*4 + cosub;
  int y = blockIdx.y; int b = blockIdx.z;
  __shared__ float S[3][66];
  float acc = 0.f;
  for (int ci=0; ci<128; ci++){
    int t = cosub*64 + x;
    for (int i=t;i<198;i+=256){
      int dy = i/66, xx = i%66; int yy = y + dy - 1; int xs = xx - 1;
      float v = 0.f;
      if (yy>=0 && yy<64 && xs>=0 && xs<64)
        v = in[(((size_t)b*128+ci)*64+yy)*64+xs];
      S[dy][xx] = v;
    }
    __syncthreads();
    const float* wr = w9 + ((size_t)co*128 + ci)*9;
#pragma unroll
    for (int dy=0;dy<3;dy++){
      acc += S[dy][x]*wr[dy*3+0] + S[dy][x+1]*wr[dy*3+1] + S[dy][x+2]*wr[dy*3+2];
    }
    __syncthreads();
  }
  float s = g[co]*rsqrtf(vv2[co]+1e-5f);
  float v = acc*s + (bb2[co] - mm2[co]*s);
  if (res) v += res[(((size_t)b*128+co)*64+y)*64+x];
  out[(((size_t)b*128+co)*64+y)*64+x] = fmaxf(v, 0.f);
}

extern "C" void kernel_launch(void* const* d_in, const int* in_sizes, int n_in,
                              void* d_out, int out_size, void* d_ws, size_t ws_size,
                              hipStream_t stream){
  const float* x1        = (const float*)d_in[0];
  const float* x2        = (const float*)d_in[1];
  const float* conv_in_w = (const float*)d_in[2];
  const float* conv_in_b = (const float*)d_in[3];
  const float* ln1_g     = (const float*)d_in[4];
  const float* ln1_b     = (const float*)d_in[5];
  const float* in_proj_w = (const float*)d_in[6];
  const float* dw_w      = (const float*)d_in[7];
  const float* dw_b      = (const float*)d_in[8];
  const float* x_proj_w  = (const float*)d_in[9];
  const float* dt_proj_w = (const float*)d_in[10];
  const float* dt_proj_b = (const float*)d_in[11];
  const float* A_logs    = (const float*)d_in[12];
  const float* Ds        = (const float*)d_in[13];
  const float* onorm_g   = (const float*)d_in[14];
  const float* onorm_b   = (const float*)d_in[15];
  const float* out_proj_w= (const float*)d_in[16];
  const float* ln2_g     = (const float*)d_in[17];
  const float* ln2_b     = (const float*)d_in[18];
  const float* mlp_w1    = (const float*)d_in[19];
  const float* mlp_b1    = (const float*)d_in[20];
  const float* mlp_w2    = (const float*)d_in[21];
  const float* mlp_b2    = (const float*)d_in[22];
  const float* rb1_w     = (const float*)d_in[23];
  const float* bn1_g     = (const float*)d_in[24];
  const float* bn1_b     = (const float*)d_in[25];
  const float* bn1_m     = (const float*)d_in[26];
  const float* bn1_v     = (const float*)d_in[27];
  const float* rb2_w     = (const float*)d_in[28];
  const float* bn2_g     = (const float*)d_in[29];
  const float* bn2_b     = (const float*)d_in[30];
  const float* bn2_m     = (const float*)d_in[31];
  const float* bn2_v     = (const float*)d_in[32];

  float* ws = (float*)d_ws;
  const size_t FM = 262144; // floats per MiB
  // Aliased workspace layout (peak 148 MiB):
  float* X0  = ws + 0;        // 0-16   residual stream (B,L,128)
  float* Ln  = ws + 16*FM;    // 16-32  LN out (reused), later x1f region
  float* Yb  = ws + 16*FM;    // 16-48  scan accumulator
  float* Ab  = ws + 32*FM;    // 32-64  xp pre-conv (B,L,256); upper half free during scan
  float* Zb  = ws + 64*FM;    // 64-96  z
  float* Xpa = ws + 96*FM;    // 96-128 post-dw-silu (B,L,256)
  float* CT  = ws + 96*FM;    // alias (used before Xpa)
  float* Gb  = ws + 96*FM;    // alias (used after Xpa dead)
  float* DBC = ws + 128*FM;   // 128-148 (B,K,L,40)
  float* H1  = ws + 32*FM;    // 32-96  MLP hidden (B,L,512)
  float* x1f = ws + 16*FM;    // 16-24
  float* x2f = ws + 24*FM;    // 24-32
  float* tmpc= ws + 32*FM;    // 32-40
  // scan scratch in dead 48-64 MiB region:
  float* Hout  = ws + 48*FM;  // 4 MiB (65536*16 f)
  float* Hstart= ws + 52*FM;  // 4 MiB
  float* Ssum  = ws + 56*FM;  // 0.25 MiB
  float* out = (float*)d_out;

  dim3 bgemm(16,16);
  // 1. interleave -> CT (channel-first)
  k_build_ct<<<16384,256,0,stream>>>(x1,x2,CT);
  // 2. conv_in 1x1
  k_gemm<<<dim3(4,256,BB),bgemm,0,stream>>>(CT, conv_in_w, conv_in_b, nullptr, X0, nullptr, 128,128,0,1);
  // 3. LN1
  k_ln128<<<BB*LL,128,0,stream>>>(X0, ln1_g, ln1_b, Ln);
  // 4. in_proj (512) -> split xp(Ab) / z(Zb)
  k_gemm<<<dim3(16,256,BB),bgemm,0,stream>>>(Ln, in_proj_w, nullptr, nullptr, Ab, Zb, 512,128,3,0);
  // 5. depthwise 3x3 + silu
  k_dwconv<<<BB*LL,256,0,stream>>>(Ab, dw_w, dw_b, Xpa);
  // 6. zero scan accumulator
  hipMemsetAsync(Yb, 0, (size_t)32*1024*1024, stream);
  // 7. x_proj -> DBC (dts/B/C in scan order)
  k_xdbl<<<2048,256,0,stream>>>(Xpa, x_proj_w, DBC);
  // 8. chunked selective scan (4 directions)
  k_scanA<<<4096,256,0,stream>>>(DBC, Xpa, dt_proj_w, dt_proj_b, A_logs, Hout, Ssum);
  k_scanB<<<256,256,0,stream>>>(Ssum, Hout, A_logs, Hstart);
  k_scanC<<<4096,256,0,stream>>>(DBC, Xpa, dt_proj_w, dt_proj_b, A_logs, Ds, Hstart, Yb);
  // 9. out-norm * silu(z) -> Gb
  k_gate<<<BB*LL,256,0,stream>>>(Yb, Zb, onorm_g, onorm_b, Gb);
  // 10. out_proj + residual -> X0
  k_gemm<<<dim3(4,256,BB),bgemm,0,stream>>>(Gb, out_proj_w, nullptr, X0, X0, nullptr, 128,256,1,0);
  // 11. LN2
  k_ln128<<<BB*LL,128,0,stream>>>(X0, ln2_g, ln2_b, Ln);
  // 12. MLP1 gelu -> H1
  k_gemm<<<dim3(16,256,BB),bgemm,0,stream>>>(Ln, mlp_w1, mlp_b1, nullptr, H1, nullptr, 512,128,2,0);
  // 13. MLP2 + residual -> X0
  k_gemm<<<dim3(4,256,BB),bgemm,0,stream>>>(H1, mlp_w2, mlp_b2, X0, X0, nullptr, 128,512,1,0);
  // 14. de-interleave
  k_deint<<<8192,256,0,stream>>>(X0, x1f, x2f);
  // 15-18. resblocks
  k_conv3<<<dim3(32,64,BB),dim3(64,4),0,stream>>>(x1f, rb1_w, bn1_g,bn1_b,bn1_m,bn1_v, nullptr, tmpc);
  k_conv3<<<dim3(32,64,BB),dim3(64,4),0,stream>>>(tmpc, rb2_w, bn2_g,bn2_b,bn2_m,bn2_v, x1f, out);
  k_conv3<<<dim3(32,64,BB),dim3(64,4),0,stream>>>(x2f, rb1_w, bn1_g,bn1_b,bn1_m,bn1_v, nullptr, tmpc);
  k_conv3<<<dim3(32,64,BB),dim3(64,4),0,stream>>>(tmpc, rb2_w, bn2_g,bn2_b,bn2_m,bn2_v, x2f, out + (size_t)2097152);
}

// Round 3
// 3091.358 us; speedup vs baseline: 3.4432x; 2.1411x over previous
//
#include <hip/hip_runtime.h>
#include <math.h>

// Problem constants
#define BB 4
#define CM 128      // d_model
#define DI 256      // d_inner
#define NS 16       // d_state
#define RK 8        // dt_rank
#define KD 4        // K directions
#define HH 64
#define WW 128      // interleaved width
#define LL 8192     // HH*WW
#define NC 16       // scan chunks per sequence
#define CH 512      // chunk length (NC*CH == LL)

typedef unsigned short ushortt;
typedef unsigned int uintt;

__device__ __forceinline__ float sigmoidf_(float x){ return 1.f/(1.f+__expf(-x)); }
__device__ __forceinline__ float siluf_(float x){ return x*sigmoidf_(x); }
__device__ __forceinline__ float softplusf_(float x){
  if (x > 20.f) return x;
  if (x < -20.f) return __expf(x);
  return log1pf(__expf(x));
}
__device__ __forceinline__ float geluf_(float x){ return 0.5f*x*(1.f+erff(x*0.70710678118654752f)); }
__device__ __forceinline__ float waveReduceSum(float v){
  for (int o=32;o>0;o>>=1) v += __shfl_xor(v,o,64);
  return v;
}
__device__ __forceinline__ ushortt f2bf(float f){
  uintt u = __float_as_uint(f);
  uintt r = (u + 0x7fffu + ((u>>16)&1u)) >> 16;
  return (ushortt)r;
}
__device__ __forceinline__ float bf2f(ushortt s){
  return __uint_as_float(((uintt)s)<<16);
}
template<int CTRL>
__device__ __forceinline__ float dppadd(float x){
  int r = __builtin_amdgcn_update_dpp(0, __float_as_int(x), CTRL, 0xF, 0xF, true);
  return x + __int_as_float(r);
}
// full sum over each 16-lane row; result on all lanes
__device__ __forceinline__ float rowsum16(float x){
  x = dppadd<0x121>(x);  // row_ror:1
  x = dppadd<0x122>(x);  // row_ror:2
  x = dppadd<0x124>(x);  // row_ror:4
  x = dppadd<0x128>(x);  // row_ror:8
  return x;
}
__device__ __forceinline__ int scan_pos(int t, int k){
  if      (k==0) return t;
  else if (k==1) return ((t&63)<<7) | (t>>6);
  else if (k==2) return LL-1-t;
  else { int j = LL-1-t; return ((j&63)<<7) | (j>>6); }
}

// ---------------- CT build: interleave x1/x2 -> channel-first (B,128,L) ----------------
__global__ void k_build_ct(const float* __restrict__ x1, const float* __restrict__ x2,
                           float* __restrict__ ct){
  int idx = blockIdx.x*256 + threadIdx.x;          // < 4*128*8192
  int p = idx & (LL-1); int c = (idx>>13) & 127; int b = idx>>20;
  int hh = p>>7, ww = p&127;
  const float* src = (ww&1) ? x2 : x1;
  ct[idx] = src[(((size_t)b*CM + c)*HH + hh)*64 + (ww>>1)];
}

// ---------------- Generic tiled f32 GEMM over tokens ----------------
// epi: 0 plain, 1 +resid, 2 gelu, 3 split (n<256 -> C f32, else Zc bf16)
// abf: A is bf16 (row-major path only)
__global__ void k_gemm(const float* __restrict__ A, const float* __restrict__ W,
                       const float* __restrict__ bias, const float* __restrict__ resid,
                       float* __restrict__ C, ushortt* __restrict__ Zc,
                       int N, int Kd, int epi, int atrans, int abf){
  const int L = LL;
  int b = blockIdx.z;
  const float*  Ab = A + (size_t)b*L*Kd;
  const ushortt* Au = (const ushortt*)A + (size_t)b*L*Kd;
  int m0 = blockIdx.y*32, n0 = blockIdx.x*32;
  __shared__ float As[32][33], Ws[32][33];
  int tx = threadIdx.x, ty = threadIdx.y, t = ty*16+tx;
  float a00=0.f,a01=0.f,a10=0.f,a11=0.f;
  for (int k0=0;k0<Kd;k0+=32){
    for (int i=t;i<1024;i+=256){
      if (atrans){ int mm=i&31, kk=i>>5; As[mm][kk] = Ab[(size_t)(k0+kk)*L + m0+mm]; }
      else       { int r=i>>5, c=i&31;
                   As[r][c] = abf ? bf2f(Au[(size_t)(m0+r)*Kd + k0+c])
                                  : Ab[(size_t)(m0+r)*Kd + k0+c]; }
      int r=i>>5, c=i&31;
      Ws[r][c] = W[(size_t)(n0+r)*Kd + k0+c];
    }
    __syncthreads();
#pragma unroll
    for (int kk=0;kk<32;kk++){
      float x0=As[ty][kk], x1=As[ty+16][kk];
      float w0=Ws[tx][kk], w1=Ws[tx+16][kk];
      a00 += x0*w0; a01 += x0*w1; a10 += x1*w0; a11 += x1*w1;
    }
    __syncthreads();
  }
  size_t outb = (size_t)b*L;
#define EMIT(mm,nn,vv) { \
    int m_ = (mm), n_ = (nn); float v_ = (vv); \
    if (bias) v_ += bias[n_]; \
    if (epi==2) v_ = geluf_(v_); \
    if (epi==1) v_ += resid[(outb+m_)*(size_t)N + n_]; \
    if (epi==3){ if (n_<256) C[(outb+m_)*256+n_]=v_; else Zc[(outb+m_)*256+(n_-256)]=f2bf(v_); } \
    else C[(outb+m_)*(size_t)N + n_] = v_; }
  EMIT(m0+ty,    n0+tx,    a00);
  EMIT(m0+ty,    n0+tx+16, a01);
  EMIT(m0+ty+16, n0+tx,    a10);
  EMIT(m0+ty+16, n0+tx+16, a11);
#undef EMIT
}

// ---------------- LayerNorm over 128 channels ----------------
__global__ void k_ln128(const float* __restrict__ X, const float* __restrict__ g,
                        const float* __restrict__ bt, float* __restrict__ O){
  int tok = blockIdx.x, tid = threadIdx.x;
  float x = X[(size_t)tok*128 + tid];
  float s  = waveReduceSum(x);
  float s2 = waveReduceSum(x*x);
  __shared__ float a[2], a2[2];
  if ((tid&63)==0){ a[tid>>6]=s; a2[tid>>6]=s2; }
  __syncthreads();
  float mean = (a[0]+a[1])*(1.f/128.f);
  float var  = (a2[0]+a2[1])*(1.f/128.f) - mean*mean;
  float r = rsqrtf(var + 1e-5f);
  O[(size_t)tok*128+tid] = (x-mean)*r*g[tid] + bt[tid];
}

// ---------------- Depthwise 3x3 + bias + SiLU, channel-last (B,L,256) ----------------
__global__ void k_dwconv(const float* __restrict__ Xp, const float* __restrict__ w,
                         const float* __restrict__ bias, float* __restrict__ O){
  int tok = blockIdx.x; int d = threadIdx.x;
  int b = tok >> 13; int p = tok & (LL-1); int hh = p>>7, ww = p&127;
  float acc = bias[d];
#pragma unroll
  for (int dy=0;dy<3;dy++){
    int yy = hh+dy-1; if (yy<0||yy>=HH) continue;
#pragma unroll
    for (int dx=0;dx<3;dx++){
      int xx = ww+dx-1; if (xx<0||xx>=WW) continue;
      acc += Xp[((size_t)b*LL + yy*WW + xx)*256 + d] * w[d*9 + dy*3 + dx];
    }
  }
  O[(size_t)tok*256 + d] = siluf_(acc);
}

// ---------------- x_proj: per-token 4x40 projections, written in scan order ----------------
// DBC row layout (96B per (b,k,t)): [0..31] 8x f32 dts; [32+4j] bf16 B_j (low), C_j (high)
__global__ void k_xdbl(const float* __restrict__ Xpa, const float* __restrict__ xpw,
                       char* __restrict__ DBCb){
  __shared__ float U[16][256];
  int tid = threadIdx.x;
  int blk = blockIdx.x;              // B*L/16 = 2048
  int b = blk >> 9;
  int p0 = (blk & 511) << 4;
  for (int i=tid;i<16*256;i+=256){ int tt=i>>8, d=i&255;
    U[tt][d] = Xpa[((size_t)b*LL + p0+tt)*256 + d]; }
  __syncthreads();
  if (tid < 160){
    int k = tid/40, c = tid%40;
    const float* wr = xpw + ((size_t)k*40 + c)*256;
    float acc[16];
#pragma unroll
    for (int tt=0;tt<16;tt++) acc[tt]=0.f;
    for (int d=0;d<256;d++){
      float wv = wr[d];
#pragma unroll
      for (int tt=0;tt<16;tt++) acc[tt] += U[tt][d]*wv;
    }
    for (int tt=0;tt<16;tt++){
      int p = p0+tt; int hh=p>>7, ww=p&127;
      int t;
      if      (k==0) t = p;
      else if (k==1) t = (ww<<6)|hh;
      else if (k==2) t = LL-1-p;
      else           t = LL-1-((ww<<6)|hh);
      char* rowp = DBCb + ((size_t)(b*KD+k)*LL + t)*96;
      if (c < 8)       *(float*)(rowp + 4*c) = acc[tt];
      else if (c < 24) *(ushortt*)(rowp + 32 + 4*(c-8))  = f2bf(acc[tt]);
      else             *(ushortt*)(rowp + 34 + 4*(c-24)) = f2bf(acc[tt]);
    }
  }
}

// ---------------- Chunked selective scan ----------------
// Pass A: per (bkd, chunk): scan from h=0, store h_out and sum(delta).
__global__ void k_scanA(const char* __restrict__ DBCb, const float* __restrict__ Xpa,
                        const float* __restrict__ dtw_all, const float* __restrict__ dtb_all,
                        const float* __restrict__ A_logs,
                        float* __restrict__ Hbuf, float* __restrict__ Ssum){
  __shared__ float2 sdd[16][16];
  int tid = threadIdx.x;
  int grp = tid >> 4, lane = tid & 15;
  int gid = blockIdx.x*16 + grp;       // bkd*16 + c
  int c = gid & 15;
  int bkd = gid >> 4;
  int b = bkd >> 10, k = (bkd>>8)&3, d = bkd & 255;
  int kd = k*256+d;
  float dtw[8];
  { const float4* w4 = (const float4*)(dtw_all + (size_t)kd*8);
    float4 w0 = w4[0], w1 = w4[1];
    dtw[0]=w0.x; dtw[1]=w0.y; dtw[2]=w0.z; dtw[3]=w0.w;
    dtw[4]=w1.x; dtw[5]=w1.y; dtw[6]=w1.z; dtw[7]=w1.w; }
  float dtb  = dtb_all[kd];
  float Aval = -__expf(A_logs[(size_t)kd*16+lane]);
  const char* dbc = DBCb + (size_t)(b*KD+k)*LL*96;
  const float* xp = Xpa + ((size_t)b*LL)*256 + d;
  float h = 0.f, Sacc = 0.f;
  int t0 = c*CH;
  for (int blk=0; blk<CH/16; ++blk){
    int tb = t0 + blk*16;
    int tme = tb + lane;
    const char* rowme = dbc + (size_t)tme*96;
    float4 q0 = *(const float4*)rowme;
    float4 q1 = *(const float4*)(rowme+16);
    float dsum = dtb + q0.x*dtw[0] + q0.y*dtw[1] + q0.z*dtw[2] + q0.w*dtw[3]
                     + q1.x*dtw[4] + q1.y*dtw[5] + q1.z*dtw[6] + q1.w*dtw[7];
    float delta = softplusf_(dsum);
    int pme = scan_pos(tme, k);
    float u = xp[(size_t)pme*256];
    sdd[grp][lane] = make_float2(delta, delta*u);
    Sacc += rowsum16(delta);
    const char* rowB = dbc + (size_t)tb*96 + 32 + 4*lane;
#pragma unroll
    for (int i=0;i<16;i++){
      float2 dd = sdd[grp][i];
      uintt w = *(const uintt*)(rowB + 96*i);
      float Bn = __uint_as_float(w<<16);
      float e = __expf(dd.x * Aval);
      h = e*h + dd.y*Bn;
    }
  }
  Hbuf[(size_t)gid*16 + lane] = h;
  if (lane==0) Ssum[gid] = Sacc;
}

// Pass B: serial over chunks; converts Hbuf (h_out) to h_start in place.
__global__ void k_scanB(const float* __restrict__ Ssum, float* __restrict__ Hbuf,
                        const float* __restrict__ A_logs){
  int idx = blockIdx.x*256 + threadIdx.x;  // bkd*16+n (65536)
  int n = idx & 15; int bkd = idx >> 4;
  int kd = ((bkd>>8)&3)*256 + (bkd&255);
  float Aval = -__expf(A_logs[(size_t)kd*16+n]);
  float h = 0.f;
  for (int c=0;c<NC;c++){
    size_t g = (size_t)bkd*NC + c;
    float hout = Hbuf[g*16+n];
    Hbuf[g*16+n] = h;
    h = __expf(Aval*Ssum[g])*h + hout;
  }
}

// Pass C: re-scan chunk with correct h_start, write y (bf16, scan order [b][d][t]).
__global__ void k_scanC(const char* __restrict__ DBCb, const float* __restrict__ Xpa,
                        const float* __restrict__ dtw_all, const float* __restrict__ dtb_all,
                        const float* __restrict__ A_logs, const float* __restrict__ Hbuf,
                        ushortt* __restrict__ Y0, ushortt* __restrict__ Y1,
                        ushortt* __restrict__ Y2, ushortt* __restrict__ Y3){
  __shared__ float2 sdd[16][16];
  int tid = threadIdx.x;
  int grp = tid >> 4, lane = tid & 15;
  int gid = blockIdx.x*16 + grp;
  int c = gid & 15;
  int bkd = gid >> 4;
  int b = bkd >> 10, k = (bkd>>8)&3, d = bkd & 255;
  int kd = k*256+d;
  float dtw[8];
  { const float4* w4 = (const float4*)(dtw_all + (size_t)kd*8);
    float4 w0 = w4[0], w1 = w4[1];
    dtw[0]=w0.x; dtw[1]=w0.y; dtw[2]=w0.z; dtw[3]=w0.w;
    dtw[4]=w1.x; dtw[5]=w1.y; dtw[6]=w1.z; dtw[7]=w1.w; }
  float dtb  = dtb_all[kd];
  float Aval = -__expf(A_logs[(size_t)kd*16+lane]);
  const char* dbc = DBCb + (size_t)(b*KD+k)*LL*96;
  const float* xp = Xpa + ((size_t)b*LL)*256 + d;
  ushortt* Yk = (k==0?Y0 : k==1?Y1 : k==2?Y2 : Y3) + ((size_t)b*256 + d)*LL;
  float h = Hbuf[(size_t)gid*16 + lane];
  int t0 = c*CH;
  for (int blk=0; blk<CH/16; ++blk){
    int tb = t0 + blk*16;
    int tme = tb + lane;
    const char* rowme = dbc + (size_t)tme*96;
    float4 q0 = *(const float4*)rowme;
    float4 q1 = *(const float4*)(rowme+16);
    float dsum = dtb + q0.x*dtw[0] + q0.y*dtw[1] + q0.z*dtw[2] + q0.w*dtw[3]
                     + q1.x*dtw[4] + q1.y*dtw[5] + q1.z*dtw[6] + q1.w*dtw[7];
    float delta = softplusf_(dsum);
    int pme = scan_pos(tme, k);
    float u = xp[(size_t)pme*256];
    sdd[grp][lane] = make_float2(delta, delta*u);
    const char* rowB = dbc + (size_t)tb*96 + 32 + 4*lane;
    float myY = 0.f;
#pragma unroll
    for (int i=0;i<16;i++){
      float2 dd = sdd[grp][i];
      uintt w = *(const uintt*)(rowB + 96*i);
      float Bn = __uint_as_float(w<<16);
      float Cn = __uint_as_float(w & 0xffff0000u);
      float e = __expf(dd.x * Aval);
      h = e*h + dd.y*Bn;
      float y = h*Cn;
      y = rowsum16(y);
      if (lane == i) myY = y;
    }
    Yk[tme] = f2bf(myY);
  }
}

// ---------------- Gate: gather Y0..Y3 + u*sum(D), LN256, *silu(z) ----------------
// Tile: one hh row, 32 ww, all 256 d. Zg holds z (bf16) in, gated out (bf16).
__global__ void k_gate2(const ushortt* __restrict__ Y0, const ushortt* __restrict__ Y1,
                        const ushortt* __restrict__ Y2, const ushortt* __restrict__ Y3,
                        const float* __restrict__ Xpa, const float* __restrict__ Ds,
                        ushortt* __restrict__ Zg,
                        const float* __restrict__ g, const float* __restrict__ bt){
  __shared__ float ysum[32][257];
  __shared__ float Dl[256];
  int tid = threadIdx.x;
  int wwb = blockIdx.x;      // 0..3
  int hh  = blockIdx.y;      // 0..63
  int b   = blockIdx.z;
  if (tid < 256) Dl[tid] = Ds[tid] + Ds[256+tid] + Ds[512+tid] + Ds[768+tid];
  int ww0 = wwb*32;
  // phase 1: gather 4 direction outputs
  for (int it=0; it<32; ++it){
    int idx = it*256 + tid;
    int d = idx >> 5, tl = idx & 31;
    int ww = ww0 + tl;
    int p  = hh*128 + ww;
    size_t base = ((size_t)b*256 + d) << 13;
    int t1 = ww*64 + hh;
    float v = bf2f(Y0[base + p]) + bf2f(Y2[base + (LL-1) - p])
            + bf2f(Y1[base + t1]) + bf2f(Y3[base + (LL-1) - t1]);
    ysum[tl][d] = v;
  }
  __syncthreads();
  // phase 2: += Dsum*u
  for (int tl=0; tl<32; ++tl){
    int d = tid;
    if (d < 256){
      int p = hh*128 + ww0 + tl;
      float u = Xpa[(((size_t)b<<13) + p)*256 + d];
      ysum[tl][d] += Dl[d]*u;
    }
  }
  __syncthreads();
  // phase 3: LN + silu(z) gate (8 tokens per wave)
  int wave = tid >> 6, lane = tid & 63;
  for (int tk = wave*8; tk < wave*8+8; ++tk){
    float v0 = ysum[tk][lane], v1 = ysum[tk][lane+64];
    float v2 = ysum[tk][lane+128], v3 = ysum[tk][lane+192];
    float s  = waveReduceSum(v0+v1+v2+v3);
    float s2 = waveReduceSum(v0*v0+v1*v1+v2*v2+v3*v3);
    float mean = s*(1.f/256.f);
    float var  = s2*(1.f/256.f) - mean*mean;
    float r = rsqrtf(var + 1e-5f);
    int p = hh*128 + ww0 + tk;
    size_t zb = (((size_t)b<<13) + p) << 8;
#pragma unroll
    for (int j=0;j<4;j++){
      int d = lane + 64*j;
      float ln = (ysum[tk][d]-mean)*r*g[d] + bt[d];
      float z = bf2f(Zg[zb + d]);
      Zg[zb + d] = f2bf(ln * siluf_(z));
    }
  }
}

// ---------------- De-interleave: X0 (B,L,128) -> x1f/x2f (B,128,64,64) ----------------
__global__ void k_deint(const float* __restrict__ X, float* __restrict__ o1, float* __restrict__ o2){
  int idx = blockIdx.x*256 + threadIdx.x;   // < 4*128*64*64
  int j = idx & 63; int y = (idx>>6)&63; int c = (idx>>12)&127; int b = idx>>19;
  o1[idx] = X[((size_t)b*LL + y*WW + 2*j  )*128 + c];
  o2[idx] = X[((size_t)b*LL + y*WW + 2*j+1)*128 + c];
}

// ---------------- 3x3 conv (128->128) + BN (+res) + ReLU ----------------
__global__ void k_conv3(const float* __restrict__ in, const float* __restrict__ w9,
                        const float* __restrict__ g, const float* __restrict__ bb2,
                        const float* __restrict__ mm2, const float* __restrict__ vv2,
                        const float* __restrict__ res, float* __restrict__ out){
  int x = threadIdx.x;            // 0..63
  int cosub = threadIdx.y;        // 0..3
  int co = blockIdx.x*4 + cosub;
  int y = blockIdx.y; int b = blockIdx.z;
  __shared__ float S[3][66];
  float acc = 0.f;
  for (int ci=0; ci<128; ci++){
    int t = cosub*64 + x;
    for (int i=t;i<198;i+=256){
      int dy = i/66, xx = i%66; int yy = y + dy - 1; int xs = xx - 1;
      float v = 0.f;
      if (yy>=0 && yy<64 && xs>=0 && xs<64)
        v = in[(((size_t)b*128+ci)*64+yy)*64+xs];
      S[dy][xx] = v;
    }
    __syncthreads();
    const float* wr = w9 + ((size_t)co*128 + ci)*9;
#pragma unroll
    for (int dy=0;dy<3;dy++){
      acc += S[dy][x]*wr[dy*3+0] + S[dy][x+1]*wr[dy*3+1] + S[dy][x+2]*wr[dy*3+2];
    }
    __syncthreads();
  }
  float s = g[co]*rsqrtf(vv2[co]+1e-5f);
  float v = acc*s + (bb2[co] - mm2[co]*s);
  if (res) v += res[(((size_t)b*128+co)*64+y)*64+x];
  out[(((size_t)b*128+co)*64+y)*64+x] = fmaxf(v, 0.f);
}

extern "C" void kernel_launch(void* const* d_in, const int* in_sizes, int n_in,
                              void* d_out, int out_size, void* d_ws, size_t ws_size,
                              hipStream_t stream){
  const float* x1        = (const float*)d_in[0];
  const float* x2        = (const float*)d_in[1];
  const float* conv_in_w = (const float*)d_in[2];
  const float* conv_in_b = (const float*)d_in[3];
  const float* ln1_g     = (const float*)d_in[4];
  const float* ln1_b     = (const float*)d_in[5];
  const float* in_proj_w = (const float*)d_in[6];
  const float* dw_w      = (const float*)d_in[7];
  const float* dw_b      = (const float*)d_in[8];
  const float* x_proj_w  = (const float*)d_in[9];
  const float* dt_proj_w = (const float*)d_in[10];
  const float* dt_proj_b = (const float*)d_in[11];
  const float* A_logs    = (const float*)d_in[12];
  const float* Ds        = (const float*)d_in[13];
  const float* onorm_g   = (const float*)d_in[14];
  const float* onorm_b   = (const float*)d_in[15];
  const float* out_proj_w= (const float*)d_in[16];
  const float* ln2_g     = (const float*)d_in[17];
  const float* ln2_b     = (const float*)d_in[18];
  const float* mlp_w1    = (const float*)d_in[19];
  const float* mlp_b1    = (const float*)d_in[20];
  const float* mlp_w2    = (const float*)d_in[21];
  const float* mlp_b2    = (const float*)d_in[22];
  const float* rb1_w     = (const float*)d_in[23];
  const float* bn1_g     = (const float*)d_in[24];
  const float* bn1_b     = (const float*)d_in[25];
  const float* bn1_m     = (const float*)d_in[26];
  const float* bn1_v     = (const float*)d_in[27];
  const float* rb2_w     = (const float*)d_in[28];
  const float* bn2_g     = (const float*)d_in[29];
  const float* bn2_b     = (const float*)d_in[30];
  const float* bn2_m     = (const float*)d_in[31];
  const float* bn2_v     = (const float*)d_in[32];

  float* ws = (float*)d_ws;
  char*  wsB = (char*)d_ws;
  const size_t FM = 262144;            // floats per MiB
  const size_t MB = 1048576;           // bytes per MiB
  // Workspace layout (peak 148 MiB, same as prior passing rounds):
  float*  X0   = ws;                   // 0-16   residual stream (B,L,128) f32
  float*  Xpa  = ws + 16*FM;           // 16-48  post-dw-silu u (B,L,256) f32
  char*   DBCb = wsB + 48*MB;          // 48-61  (B,K,L) rows of 96B
  ushortt* Zg  = (ushortt*)(wsB + 61*MB); // 61-77 z / gated (B,L,256) bf16
  ushortt* Y0  = (ushortt*)(wsB + 77*MB);  // 77-93
  ushortt* Y1  = (ushortt*)(wsB + 93*MB);  // 93-109
  ushortt* Y2  = (ushortt*)(wsB + 109*MB); // 109-125
  ushortt* Y3  = (ushortt*)(wsB + 125*MB); // 125-141
  float*  Hbuf = ws + 141*FM;          // 141-145 (65536*16 f32)
  float*  Ssum = ws + 145*FM;          // 145-145.25
  // time-disjoint aliases:
  float*  CT   = ws + 77*FM;           // 77-109  (dead after conv_in)
  float*  Abuf = ws + 77*FM;           // 77-109  pre-dw xp (dead after dwconv)
  float*  Ln1  = ws + 109*FM;          // 109-125 (dead after in_proj)
  float*  Ln2  = ws + 80*FM;           // 80-96   (post-mamba)
  float*  H1   = ws + 16*FM;           // 16-80   MLP hidden (B,L,512) f32
  float*  x1f  = ws + 16*FM;           // 16-24
  float*  x2f  = ws + 24*FM;           // 24-32
  float*  tmpc = ws + 32*FM;           // 32-40
  float*  out  = (float*)d_out;

  dim3 bgemm(16,16);
  // 1. interleave -> CT (channel-first)
  k_build_ct<<<16384,256,0,stream>>>(x1,x2,CT);
  // 2. conv_in 1x1
  k_gemm<<<dim3(4,256,BB),bgemm,0,stream>>>(CT, conv_in_w, conv_in_b, nullptr, X0, nullptr, 128,128,0,1,0);
  // 3. LN1
  k_ln128<<<BB*LL,128,0,stream>>>(X0, ln1_g, ln1_b, Ln1);
  // 4. in_proj (512) -> split xp(Abuf f32) / z(Zg bf16)
  k_gemm<<<dim3(16,256,BB),bgemm,0,stream>>>(Ln1, in_proj_w, nullptr, nullptr, Abuf, Zg, 512,128,3,0,0);
  // 5. depthwise 3x3 + silu -> Xpa
  k_dwconv<<<BB*LL,256,0,stream>>>(Abuf, dw_w, dw_b, Xpa);
  // 6. x_proj -> DBC (dts f32 + B/C bf16, scan order)
  k_xdbl<<<2048,256,0,stream>>>(Xpa, x_proj_w, DBCb);
  // 7. chunked selective scan
  k_scanA<<<4096,256,0,stream>>>(DBCb, Xpa, dt_proj_w, dt_proj_b, A_logs, Hbuf, Ssum);
  k_scanB<<<256,256,0,stream>>>(Ssum, Hbuf, A_logs);
  k_scanC<<<4096,256,0,stream>>>(DBCb, Xpa, dt_proj_w, dt_proj_b, A_logs, Hbuf, Y0,Y1,Y2,Y3);
  // 8. gate: gather + LN + silu(z) -> Zg (in place)
  k_gate2<<<dim3(4,64,BB),256,0,stream>>>(Y0,Y1,Y2,Y3, Xpa, Ds, Zg, onorm_g, onorm_b);
  // 9. out_proj (bf16 A) + residual -> X0
  k_gemm<<<dim3(4,256,BB),bgemm,0,stream>>>((const float*)Zg, out_proj_w, nullptr, X0, X0, nullptr, 128,256,1,0,1);
  // 10. LN2
  k_ln128<<<BB*LL,128,0,stream>>>(X0, ln2_g, ln2_b, Ln2);
  // 11. MLP1 gelu -> H1
  k_gemm<<<dim3(16,256,BB),bgemm,0,stream>>>(Ln2, mlp_w1, mlp_b1, nullptr, H1, nullptr, 512,128,2,0,0);
  // 12. MLP2 + residual -> X0
  k_gemm<<<dim3(4,256,BB),bgemm,0,stream>>>(H1, mlp_w2, mlp_b2, X0, X0, nullptr, 128,512,1,0,0);
  // 13. de-interleave
  k_deint<<<8192,256,0,stream>>>(X0, x1f, x2f);
  // 14-17. resblocks
  k_conv3<<<dim3(32,64,BB),dim3(64,4),0,stream>>>(x1f, rb1_w, bn1_g,bn1_b,bn1_m,bn1_v, nullptr, tmpc);
  k_conv3<<<dim3(32,64,BB),dim3(64,4),0,stream>>>(tmpc, rb2_w, bn2_g,bn2_b,bn2_m,bn2_v, x1f, out);
  k_conv3<<<dim3(32,64,BB),dim3(64,4),0,stream>>>(x2f, rb1_w, bn1_g,bn1_b,bn1_m,bn1_v, nullptr, tmpc);
  k_conv3<<<dim3(32,64,BB),dim3(64,4),0,stream>>>(tmpc, rb2_w, bn2_g,bn2_b,bn2_m,bn2_v, x2f, out + (size_t)2097152);
}

// Round 4
// 1500.257 us; speedup vs baseline: 7.0948x; 2.0606x over previous
//
#include <hip/hip_runtime.h>
#include <math.h>

// Problem constants
#define BB 4
#define CM 128      // d_model
#define DI 256      // d_inner
#define NS 16       // d_state
#define RK 8        // dt_rank
#define KD 4        // K directions
#define HH 64
#define WW 128      // interleaved width
#define LL 8192     // HH*WW
#define NC 16       // scan chunks per sequence
#define CH 512      // chunk length (NC*CH == LL)

typedef unsigned short ushortt;
typedef unsigned int uintt;
typedef __attribute__((ext_vector_type(8))) __bf16 bf16x8;
typedef __attribute__((ext_vector_type(4))) float f32x4;

__device__ __forceinline__ float sigmoidf_(float x){ return 1.f/(1.f+__expf(-x)); }
__device__ __forceinline__ float siluf_(float x){ return x*sigmoidf_(x); }
__device__ __forceinline__ float softplusf_(float x){
  if (x > 20.f) return x;
  if (x < -20.f) return __expf(x);
  return log1pf(__expf(x));
}
__device__ __forceinline__ float geluf_(float x){ return 0.5f*x*(1.f+erff(x*0.70710678118654752f)); }
__device__ __forceinline__ float waveReduceSum(float v){
  for (int o=32;o>0;o>>=1) v += __shfl_xor(v,o,64);
  return v;
}
__device__ __forceinline__ ushortt f2bf(float f){
  uintt u = __float_as_uint(f);
  uintt r = (u + 0x7fffu + ((u>>16)&1u)) >> 16;
  return (ushortt)r;
}
__device__ __forceinline__ float bf2f(ushortt s){
  return __uint_as_float(((uintt)s)<<16);
}
template<int CTRL>
__device__ __forceinline__ float dppadd(float x){
  int r = __builtin_amdgcn_update_dpp(0, __float_as_int(x), CTRL, 0xF, 0xF, true);
  return x + __int_as_float(r);
}
// full sum over each 16-lane row; result on all lanes
__device__ __forceinline__ float rowsum16(float x){
  x = dppadd<0x121>(x);  // row_ror:1
  x = dppadd<0x122>(x);  // row_ror:2
  x = dppadd<0x124>(x);  // row_ror:4
  x = dppadd<0x128>(x);  // row_ror:8
  return x;
}
__device__ __forceinline__ int scan_pos(int t, int k){
  if      (k==0) return t;
  else if (k==1) return ((t&63)<<7) | (t>>6);
  else if (k==2) return LL-1-t;
  else { int j = LL-1-t; return ((j&63)<<7) | (j>>6); }
}

// ---------------- weight conversions ----------------
__global__ void k_tobf(const float* __restrict__ s, ushortt* __restrict__ d, int n){
  int i = blockIdx.x*256 + threadIdx.x;
  if (i < n) d[i] = f2bf(s[i]);
}
// rb weights (co,ci,3,3) f32 -> (tap,co,ci) bf16
__global__ void k_wrb(const float* __restrict__ src, ushortt* __restrict__ dst){
  int i = blockIdx.x*256 + threadIdx.x;  // < 147456
  if (i >= 147456) return;
  int ci = i & 127, co = (i>>7)&127, tap = i>>14;
  dst[i] = f2bf(src[(size_t)(co*128+ci)*9 + tap]);
}

// ---------------- CT build: interleave x1/x2 -> token-major bf16 (B*L, 128) ----------------
__global__ void k_build_ct2(const float* __restrict__ x1, const float* __restrict__ x2,
                            ushortt* __restrict__ CT){
  __shared__ ushortt Tl[64][136];
  int tid = threadIdx.x;
  int p0 = (blockIdx.x & 127) * 64;
  int b  = blockIdx.x >> 7;
  int j = tid & 63;
  int p = p0 + j; int hh = p>>7, ww = p&127, w2 = ww>>1;
  const float* src = (ww&1) ? x2 : x1;
  const float* sp = src + ((size_t)b*128*64 + hh)*64 + w2;
  for (int c0 = tid>>6; c0 < 128; c0 += 4)
    Tl[j][c0] = f2bf(sp[(size_t)c0*4096]);
  __syncthreads();
  int c = tid & 127; int rh = tid >> 7;
  for (int r = rh; r < 64; r += 2)
    CT[((size_t)b*LL + p0 + r)*128 + c] = Tl[r][c];
}

// ---------------- MFMA token GEMM ----------------
// A: [32768][K] bf16, W: [N][K] bf16; grid (N/64, 512), block 256 (4 waves).
// EPI 0: (+bias) f32 C ; 1: (+bias)+resid f32 C ; 2: +bias,gelu -> bf16 C2 (stride 512)
// EPI 3: split n<256 -> f32 C (stride 256), else bf16 C2 (stride 256)
template<int EPI>
__global__ void k_mgemm(const ushortt* __restrict__ A, const ushortt* __restrict__ W,
                        const float* __restrict__ bias, const float* __restrict__ resid,
                        float* __restrict__ C, ushortt* __restrict__ C2, int N, int K){
  int n0 = blockIdx.x*64, m0 = blockIdx.y*64;
  int wv = threadIdx.x>>6, l = threadIdx.x&63;
  int ar = l&15, kg = l>>4;
  int mw = m0 + wv*16;
  f32x4 acc[4];
#pragma unroll
  for (int i=0;i<4;i++){ acc[i][0]=0.f; acc[i][1]=0.f; acc[i][2]=0.f; acc[i][3]=0.f; }
  const ushortt* Ap = A + (size_t)(mw+ar)*K + kg*8;
  const ushortt* Wp = W + (size_t)(n0+ar)*K + kg*8;
  for (int k0=0; k0<K; k0+=32){
    bf16x8 af = *(const bf16x8*)(Ap + k0);
#pragma unroll
    for (int nf=0; nf<4; ++nf){
      bf16x8 bfv = *(const bf16x8*)(Wp + (size_t)nf*16*K + k0);
      acc[nf] = __builtin_amdgcn_mfma_f32_16x16x32_bf16(af, bfv, acc[nf], 0,0,0);
    }
  }
#pragma unroll
  for (int nf=0;nf<4;nf++){
    int n = n0 + nf*16 + ar;
#pragma unroll
    for (int r=0;r<4;r++){
      int m = mw + kg*4 + r;
      float v = acc[nf][r];
      if (EPI==0 || EPI==1){
        if (bias) v += bias[n];
        if (EPI==1) v += resid[(size_t)m*N + n];
        C[(size_t)m*N + n] = v;
      } else if (EPI==2){
        v += bias[n];
        C2[(size_t)m*512 + n] = f2bf(geluf_(v));
      } else {
        if (n < 256) C[(size_t)m*256 + n] = v;
        else         C2[(size_t)m*256 + (n-256)] = f2bf(v);
      }
    }
  }
}

// ---------------- LayerNorm over 128 channels -> bf16 ----------------
__global__ void k_ln128b(const float* __restrict__ X, const float* __restrict__ g,
                         const float* __restrict__ bt, ushortt* __restrict__ O){
  int tok = blockIdx.x, tid = threadIdx.x;
  float x = X[(size_t)tok*128 + tid];
  float s  = waveReduceSum(x);
  float s2 = waveReduceSum(x*x);
  __shared__ float a[2], a2[2];
  if ((tid&63)==0){ a[tid>>6]=s; a2[tid>>6]=s2; }
  __syncthreads();
  float mean = (a[0]+a[1])*(1.f/128.f);
  float var  = (a2[0]+a2[1])*(1.f/128.f) - mean*mean;
  float r = rsqrtf(var + 1e-5f);
  O[(size_t)tok*128+tid] = f2bf((x-mean)*r*g[tid] + bt[tid]);
}

// ---------------- Depthwise 3x3 + bias + SiLU, channel-last (B,L,256) ----------------
__global__ void k_dwconv(const float* __restrict__ Xp, const float* __restrict__ w,
                         const float* __restrict__ bias, float* __restrict__ O){
  int tok = blockIdx.x; int d = threadIdx.x;
  int b = tok >> 13; int p = tok & (LL-1); int hh = p>>7, ww = p&127;
  float acc = bias[d];
#pragma unroll
  for (int dy=0;dy<3;dy++){
    int yy = hh+dy-1; if (yy<0||yy>=HH) continue;
#pragma unroll
    for (int dx=0;dx<3;dx++){
      int xx = ww+dx-1; if (xx<0||xx>=WW) continue;
      acc += Xp[((size_t)b*LL + yy*WW + xx)*256 + d] * w[d*9 + dy*3 + dx];
    }
  }
  O[(size_t)tok*256 + d] = siluf_(acc);
}

// ---------------- x_proj: per-token 4x40 projections, written in scan order ----------------
// DBC row layout (96B per (b,k,t)): [0..31] 8x f32 dts; [32+4j] bf16 B_j (low), C_j (high)
__global__ void k_xdbl(const float* __restrict__ Xpa, const float* __restrict__ xpw,
                       char* __restrict__ DBCb){
  __shared__ float U[16][256];
  int tid = threadIdx.x;
  int blk = blockIdx.x;              // B*L/16 = 2048
  int b = blk >> 9;
  int p0 = (blk & 511) << 4;
  for (int i=tid;i<16*256;i+=256){ int tt=i>>8, d=i&255;
    U[tt][d] = Xpa[((size_t)b*LL + p0+tt)*256 + d]; }
  __syncthreads();
  if (tid < 160){
    int k = tid/40, c = tid%40;
    const float* wr = xpw + ((size_t)k*40 + c)*256;
    float acc[16];
#pragma unroll
    for (int tt=0;tt<16;tt++) acc[tt]=0.f;
    for (int d=0;d<256;d++){
      float wv = wr[d];
#pragma unroll
      for (int tt=0;tt<16;tt++) acc[tt] += U[tt][d]*wv;
    }
    for (int tt=0;tt<16;tt++){
      int p = p0+tt; int hh=p>>7, ww=p&127;
      int t;
      if      (k==0) t = p;
      else if (k==1) t = (ww<<6)|hh;
      else if (k==2) t = LL-1-p;
      else           t = LL-1-((ww<<6)|hh);
      char* rowp = DBCb + ((size_t)(b*KD+k)*LL + t)*96;
      if (c < 8)       *(float*)(rowp + 4*c) = acc[tt];
      else if (c < 24) *(ushortt*)(rowp + 32 + 4*(c-8))  = f2bf(acc[tt]);
      else             *(ushortt*)(rowp + 34 + 4*(c-24)) = f2bf(acc[tt]);
    }
  }
}

// ---------------- Chunked selective scan ----------------
__global__ void k_scanA(const char* __restrict__ DBCb, const float* __restrict__ Xpa,
                        const float* __restrict__ dtw_all, const float* __restrict__ dtb_all,
                        const float* __restrict__ A_logs,
                        float* __restrict__ Hbuf, float* __restrict__ Ssum){
  __shared__ float2 sdd[16][16];
  int tid = threadIdx.x;
  int grp = tid >> 4, lane = tid & 15;
  int gid = blockIdx.x*16 + grp;       // bkd*16 + c
  int c = gid & 15;
  int bkd = gid >> 4;
  int b = bkd >> 10, k = (bkd>>8)&3, d = bkd & 255;
  int kd = k*256+d;
  float dtw[8];
  { const float4* w4 = (const float4*)(dtw_all + (size_t)kd*8);
    float4 w0 = w4[0], w1 = w4[1];
    dtw[0]=w0.x; dtw[1]=w0.y; dtw[2]=w0.z; dtw[3]=w0.w;
    dtw[4]=w1.x; dtw[5]=w1.y; dtw[6]=w1.z; dtw[7]=w1.w; }
  float dtb  = dtb_all[kd];
  float Aval = -__expf(A_logs[(size_t)kd*16+lane]);
  const char* dbc = DBCb + (size_t)(b*KD+k)*LL*96;
  const float* xp = Xpa + ((size_t)b*LL)*256 + d;
  float h = 0.f, Sacc = 0.f;
  int t0 = c*CH;
  for (int blk=0; blk<CH/16; ++blk){
    int tb = t0 + blk*16;
    int tme = tb + lane;
    const char* rowme = dbc + (size_t)tme*96;
    float4 q0 = *(const float4*)rowme;
    float4 q1 = *(const float4*)(rowme+16);
    float dsum = dtb + q0.x*dtw[0] + q0.y*dtw[1] + q0.z*dtw[2] + q0.w*dtw[3]
                     + q1.x*dtw[4] + q1.y*dtw[5] + q1.z*dtw[6] + q1.w*dtw[7];
    float delta = softplusf_(dsum);
    int pme = scan_pos(tme, k);
    float u = xp[(size_t)pme*256];
    sdd[grp][lane] = make_float2(delta, delta*u);
    Sacc += rowsum16(delta);
    const char* rowB = dbc + (size_t)tb*96 + 32 + 4*lane;
#pragma unroll
    for (int i=0;i<16;i++){
      float2 dd = sdd[grp][i];
      uintt w = *(const uintt*)(rowB + 96*i);
      float Bn = __uint_as_float(w<<16);
      float e = __expf(dd.x * Aval);
      h = e*h + dd.y*Bn;
    }
  }
  Hbuf[(size_t)gid*16 + lane] = h;
  if (lane==0) Ssum[gid] = Sacc;
}

__global__ void k_scanB(const float* __restrict__ Ssum, float* __restrict__ Hbuf,
                        const float* __restrict__ A_logs){
  int idx = blockIdx.x*256 + threadIdx.x;  // bkd*16+n (65536)
  int n = idx & 15; int bkd = idx >> 4;
  int kd = ((bkd>>8)&3)*256 + (bkd&255);
  float Aval = -__expf(A_logs[(size_t)kd*16+n]);
  float h = 0.f;
  for (int c=0;c<NC;c++){
    size_t g = (size_t)bkd*NC + c;
    float hout = Hbuf[g*16+n];
    Hbuf[g*16+n] = h;
    h = __expf(Aval*Ssum[g])*h + hout;
  }
}

__global__ void k_scanC(const char* __restrict__ DBCb, const float* __restrict__ Xpa,
                        const float* __restrict__ dtw_all, const float* __restrict__ dtb_all,
                        const float* __restrict__ A_logs, const float* __restrict__ Hbuf,
                        ushortt* __restrict__ Y0, ushortt* __restrict__ Y1,
                        ushortt* __restrict__ Y2, ushortt* __restrict__ Y3){
  __shared__ float2 sdd[16][16];
  int tid = threadIdx.x;
  int grp = tid >> 4, lane = tid & 15;
  int gid = blockIdx.x*16 + grp;
  int c = gid & 15;
  int bkd = gid >> 4;
  int b = bkd >> 10, k = (bkd>>8)&3, d = bkd & 255;
  int kd = k*256+d;
  float dtw[8];
  { const float4* w4 = (const float4*)(dtw_all + (size_t)kd*8);
    float4 w0 = w4[0], w1 = w4[1];
    dtw[0]=w0.x; dtw[1]=w0.y; dtw[2]=w0.z; dtw[3]=w0.w;
    dtw[4]=w1.x; dtw[5]=w1.y; dtw[6]=w1.z; dtw[7]=w1.w; }
  float dtb  = dtb_all[kd];
  float Aval = -__expf(A_logs[(size_t)kd*16+lane]);
  float Dval = 0.f; (void)Dval;
  const char* dbc = DBCb + (size_t)(b*KD+k)*LL*96;
  const float* xp = Xpa + ((size_t)b*LL)*256 + d;
  ushortt* Yk = (k==0?Y0 : k==1?Y1 : k==2?Y2 : Y3) + ((size_t)b*256 + d)*LL;
  float h = Hbuf[(size_t)gid*16 + lane];
  int t0 = c*CH;
  for (int blk=0; blk<CH/16; ++blk){
    int tb = t0 + blk*16;
    int tme = tb + lane;
    const char* rowme = dbc + (size_t)tme*96;
    float4 q0 = *(const float4*)rowme;
    float4 q1 = *(const float4*)(rowme+16);
    float dsum = dtb + q0.x*dtw[0] + q0.y*dtw[1] + q0.z*dtw[2] + q0.w*dtw[3]
                     + q1.x*dtw[4] + q1.y*dtw[5] + q1.z*dtw[6] + q1.w*dtw[7];
    float delta = softplusf_(dsum);
    int pme = scan_pos(tme, k);
    float u = xp[(size_t)pme*256];
    sdd[grp][lane] = make_float2(delta, delta*u);
    const char* rowB = dbc + (size_t)tb*96 + 32 + 4*lane;
    float myY = 0.f;
#pragma unroll
    for (int i=0;i<16;i++){
      float2 dd = sdd[grp][i];
      uintt w = *(const uintt*)(rowB + 96*i);
      float Bn = __uint_as_float(w<<16);
      float Cn = __uint_as_float(w & 0xffff0000u);
      float e = __expf(dd.x * Aval);
      h = e*h + dd.y*Bn;
      float y = h*Cn;
      y = rowsum16(y);
      if (lane == i) myY = y;
    }
    Yk[tme] = f2bf(myY);
  }
}

// ---------------- Gate: gather Y0..Y3 + u*sum(D), LN256, *silu(z) ----------------
__global__ void k_gate2(const ushortt* __restrict__ Y0, const ushortt* __restrict__ Y1,
                        const ushortt* __restrict__ Y2, const ushortt* __restrict__ Y3,
                        const float* __restrict__ Xpa, const float* __restrict__ Ds,
                        ushortt* __restrict__ Zg,
                        const float* __restrict__ g, const float* __restrict__ bt){
  __shared__ float ysum[32][257];
  __shared__ float Dl[256];
  int tid = threadIdx.x;
  int wwb = blockIdx.x;      // 0..3
  int hh  = blockIdx.y;      // 0..63
  int b   = blockIdx.z;
  if (tid < 256) Dl[tid] = Ds[tid] + Ds[256+tid] + Ds[512+tid] + Ds[768+tid];
  int ww0 = wwb*32;
  for (int it=0; it<32; ++it){
    int idx = it*256 + tid;
    int d = idx >> 5, tl = idx & 31;
    int ww = ww0 + tl;
    int p  = hh*128 + ww;
    size_t base = ((size_t)b*256 + d) << 13;
    int t1 = ww*64 + hh;
    float v = bf2f(Y0[base + p]) + bf2f(Y2[base + (LL-1) - p])
            + bf2f(Y1[base + t1]) + bf2f(Y3[base + (LL-1) - t1]);
    ysum[tl][d] = v;
  }
  __syncthreads();
  for (int tl=0; tl<32; ++tl){
    int d = tid;
    if (d < 256){
      int p = hh*128 + ww0 + tl;
      float u = Xpa[(((size_t)b<<13) + p)*256 + d];
      ysum[tl][d] += Dl[d]*u;
    }
  }
  __syncthreads();
  int wave = tid >> 6, lane = tid & 63;
  for (int tk = wave*8; tk < wave*8+8; ++tk){
    float v0 = ysum[tk][lane], v1 = ysum[tk][lane+64];
    float v2 = ysum[tk][lane+128], v3 = ysum[tk][lane+192];
    float s  = waveReduceSum(v0+v1+v2+v3);
    float s2 = waveReduceSum(v0*v0+v1*v1+v2*v2+v3*v3);
    float mean = s*(1.f/256.f);
    float var  = s2*(1.f/256.f) - mean*mean;
    float r = rsqrtf(var + 1e-5f);
    int p = hh*128 + ww0 + tk;
    size_t zb = (((size_t)b<<13) + p) << 8;
#pragma unroll
    for (int j=0;j<4;j++){
      int d = lane + 64*j;
      float ln = (ysum[tk][d]-mean)*r*g[d] + bt[d];
      float z = bf2f(Zg[zb + d]);
      Zg[zb + d] = f2bf(ln * siluf_(z));
    }
  }
}

// ---------------- De-interleave -> padded bf16 conv input + f32 residual ----------------
// P: [8][66][66][128] bf16 (img = im2*4+b), R: [8][64][64][128] f32
__global__ void k_deint2(const float* __restrict__ X, ushortt* __restrict__ P,
                         float* __restrict__ R){
  int c = threadIdx.x & 127;
  int xh = threadIdx.x >> 7;
  int x = blockIdx.x*2 + xh;
  int y = blockIdx.y; int b = blockIdx.z;
#pragma unroll
  for (int im2=0; im2<2; ++im2){
    int ww = 2*x + im2;
    float v = X[((size_t)b*LL + y*128 + ww)*128 + c];
    int im = im2*4 + b;
    P[(((size_t)im*66 + y+1)*66 + x+1)*128 + c] = f2bf(v);
    R[(((size_t)im*64 + y)*64 + x)*128 + c] = v;
  }
}

// ---------------- MFMA 3x3 conv 128->128 + BN (+res) + ReLU ----------------
// I: [8][66][66][128] bf16 padded; Wt: [9][128][128] bf16.
// grid (2 co-halves, 64 y, 8 img), block 256 (4 waves, each 16 x-positions).
// FINAL=0: BN+ReLU -> padded bf16 Op. FINAL=1: BN+res+ReLU -> f32 Of (img-major NCHW).
template<int FINAL>
__global__ void k_mconv(const ushortt* __restrict__ I, const ushortt* __restrict__ Wt,
                        const float* __restrict__ g, const float* __restrict__ bb,
                        const float* __restrict__ mn, const float* __restrict__ vv,
                        const float* __restrict__ R, ushortt* __restrict__ Op,
                        float* __restrict__ Of){
  int nh = blockIdx.x;
  int y  = blockIdx.y;
  int im = blockIdx.z;
  int wv = threadIdx.x>>6, l = threadIdx.x&63;
  int ar = l&15, kg = l>>4;
  int x0 = wv*16;
  f32x4 acc[4];
#pragma unroll
  for (int i=0;i<4;i++){ acc[i][0]=0.f; acc[i][1]=0.f; acc[i][2]=0.f; acc[i][3]=0.f; }
  const ushortt* Ibase = I + (((size_t)im*66 + y)*66 + x0 + ar)*128 + kg*8;
  const ushortt* Wbase = Wt + (size_t)(nh*64 + ar)*128 + kg*8;
#pragma unroll
  for (int tap=0; tap<9; ++tap){
    int dy = tap/3, dx = tap - dy*3;
    const ushortt* Ir = Ibase + ((size_t)dy*66 + dx)*128;
    const ushortt* Wr = Wbase + (size_t)tap*16384;
#pragma unroll
    for (int kc=0;kc<4;kc++){
      bf16x8 af = *(const bf16x8*)(Ir + kc*32);
#pragma unroll
      for (int nf=0;nf<4;nf++){
        bf16x8 bfv = *(const bf16x8*)(Wr + (size_t)nf*16*128 + kc*32);
        acc[nf] = __builtin_amdgcn_mfma_f32_16x16x32_bf16(af, bfv, acc[nf], 0,0,0);
      }
    }
  }
#pragma unroll
  for (int nf=0;nf<4;nf++){
    int co = nh*64 + nf*16 + ar;
    float s  = g[co]*rsqrtf(vv[co]+1e-5f);
    float sh = bb[co] - mn[co]*s;
#pragma unroll
    for (int r=0;r<4;r++){
      int x = x0 + kg*4 + r;
      float v = acc[nf][r]*s + sh;
      if (FINAL){
        v += R[(((size_t)im*64 + y)*64 + x)*128 + co];
        v = fmaxf(v, 0.f);
        Of[(((size_t)im*128 + co)*64 + y)*64 + x] = v;
      } else {
        v = fmaxf(v, 0.f);
        Op[(((size_t)im*66 + (y+1))*66 + (x+1))*128 + co] = f2bf(v);
      }
    }
  }
}

extern "C" void kernel_launch(void* const* d_in, const int* in_sizes, int n_in,
                              void* d_out, int out_size, void* d_ws, size_t ws_size,
                              hipStream_t stream){
  const float* x1        = (const float*)d_in[0];
  const float* x2        = (const float*)d_in[1];
  const float* conv_in_w = (const float*)d_in[2];
  const float* conv_in_b = (const float*)d_in[3];
  const float* ln1_g     = (const float*)d_in[4];
  const float* ln1_b     = (const float*)d_in[5];
  const float* in_proj_w = (const float*)d_in[6];
  const float* dw_w      = (const float*)d_in[7];
  const float* dw_b      = (const float*)d_in[8];
  const float* x_proj_w  = (const float*)d_in[9];
  const float* dt_proj_w = (const float*)d_in[10];
  const float* dt_proj_b = (const float*)d_in[11];
  const float* A_logs    = (const float*)d_in[12];
  const float* Ds        = (const float*)d_in[13];
  const float* onorm_g   = (const float*)d_in[14];
  const float* onorm_b   = (const float*)d_in[15];
  const float* out_proj_w= (const float*)d_in[16];
  const float* ln2_g     = (const float*)d_in[17];
  const float* ln2_b     = (const float*)d_in[18];
  const float* mlp_w1    = (const float*)d_in[19];
  const float* mlp_b1    = (const float*)d_in[20];
  const float* mlp_w2    = (const float*)d_in[21];
  const float* mlp_b2    = (const float*)d_in[22];
  const float* rb1_w     = (const float*)d_in[23];
  const float* bn1_g     = (const float*)d_in[24];
  const float* bn1_b     = (const float*)d_in[25];
  const float* bn1_m     = (const float*)d_in[26];
  const float* bn1_v     = (const float*)d_in[27];
  const float* rb2_w     = (const float*)d_in[28];
  const float* bn2_g     = (const float*)d_in[29];
  const float* bn2_b     = (const float*)d_in[30];
  const float* bn2_m     = (const float*)d_in[31];
  const float* bn2_v     = (const float*)d_in[32];

  float* ws = (float*)d_ws;
  char*  wsB = (char*)d_ws;
  const size_t FM = 262144;            // floats per MiB
  const size_t MB = 1048576;           // bytes per MiB
  // Workspace layout (peak 147.1 MiB; <= 148 MiB proven available):
  float*   X0   = ws;                          // 0-16    residual stream (B,L,128) f32
  float*   Xpa  = ws + 16*FM;                  // 16-48   u post-dw-silu (B,L,256) f32
  char*    DBCb = wsB + 48*MB;                 // 48-61   scan rows 96B
  ushortt* Zg   = (ushortt*)(wsB + 61*MB);     // 61-77   z / gated bf16
  ushortt* Y0   = (ushortt*)(wsB + 77*MB);     // 77-93
  ushortt* Y1   = (ushortt*)(wsB + 93*MB);     // 93-109
  ushortt* Y2   = (ushortt*)(wsB + 109*MB);    // 109-125
  ushortt* Y3   = (ushortt*)(wsB + 125*MB);    // 125-141
  float*   Hbuf = ws + 141*FM;                 // 141-145
  float*   Ssum = ws + 145*FM;                 // 145-145.25
  // time-disjoint aliases:
  ushortt* CT   = (ushortt*)(wsB + 77*MB);     // steps 1-2 (over Y0)
  ushortt* Lnb  = (ushortt*)(wsB + 85*MB);     // steps 3-4 (over Y0 2nd half)
  float*   Abuf = ws + 93*FM;                  // steps 4-5 (over Y1,Y2) xp pre-dw f32
  ushortt* Ln2b = (ushortt*)(wsB + 77*MB);     // steps 10-11 (Y0 dead)
  ushortt* H1   = (ushortt*)(wsB + 16*MB);     // steps 11-12 (Xpa dead) [32768][512] bf16
  ushortt* P    = (ushortt*)(wsB + 16*MB);     // step 13+ padded conv input [8][66][66][128]
  ushortt* T    = (ushortt*)(wsB + 25*MB);     // conv1 out padded
  float*   R    = (float*)(wsB + 34*MB);       // 34-50 residual [8][64][64][128] f32
  // bf16 weights (persistent, never aliased):
  ushortt* cw  = (ushortt*)(wsB + 146*MB);           // 32 KB
  ushortt* ipw = (ushortt*)(wsB + 146*MB + 32*1024); // 128 KB
  ushortt* opw = (ushortt*)(wsB + 146*MB + 160*1024);// 64 KB
  ushortt* m1w = (ushortt*)(wsB + 146*MB + 224*1024);// 128 KB
  ushortt* m2w = (ushortt*)(wsB + 146*MB + 352*1024);// 128 KB
  ushortt* rw1 = (ushortt*)(wsB + 146*MB + 480*1024);// 288 KB
  ushortt* rw2 = (ushortt*)(wsB + 146*MB + 768*1024);// 288 KB
  float* out = (float*)d_out;

  // 0. weight conversions
  k_tobf<<<64, 256,0,stream>>>(conv_in_w, cw, 16384);
  k_tobf<<<256,256,0,stream>>>(in_proj_w, ipw, 65536);
  k_tobf<<<128,256,0,stream>>>(out_proj_w, opw, 32768);
  k_tobf<<<256,256,0,stream>>>(mlp_w1, m1w, 65536);
  k_tobf<<<256,256,0,stream>>>(mlp_w2, m2w, 65536);
  k_wrb<<<576,256,0,stream>>>(rb1_w, rw1);
  k_wrb<<<576,256,0,stream>>>(rb2_w, rw2);
  // 1. interleave -> CT bf16 token-major
  k_build_ct2<<<512,256,0,stream>>>(x1,x2,CT);
  // 2. conv_in 1x1 (bias) -> X0 f32
  k_mgemm<0><<<dim3(2,512),256,0,stream>>>(CT, cw, conv_in_b, nullptr, X0, nullptr, 128,128);
  // 3. LN1 -> bf16
  k_ln128b<<<BB*LL,128,0,stream>>>(X0, ln1_g, ln1_b, Lnb);
  // 4. in_proj (512) -> split xp(Abuf f32) / z(Zg bf16)
  k_mgemm<3><<<dim3(8,512),256,0,stream>>>(Lnb, ipw, nullptr, nullptr, Abuf, Zg, 512,128);
  // 5. depthwise 3x3 + silu -> Xpa
  k_dwconv<<<BB*LL,256,0,stream>>>(Abuf, dw_w, dw_b, Xpa);
  // 6. x_proj -> DBC
  k_xdbl<<<2048,256,0,stream>>>(Xpa, x_proj_w, DBCb);
  // 7. chunked selective scan
  k_scanA<<<4096,256,0,stream>>>(DBCb, Xpa, dt_proj_w, dt_proj_b, A_logs, Hbuf, Ssum);
  k_scanB<<<256,256,0,stream>>>(Ssum, Hbuf, A_logs);
  k_scanC<<<4096,256,0,stream>>>(DBCb, Xpa, dt_proj_w, dt_proj_b, A_logs, Hbuf, Y0,Y1,Y2,Y3);
  // 8. gate
  k_gate2<<<dim3(4,64,BB),256,0,stream>>>(Y0,Y1,Y2,Y3, Xpa, Ds, Zg, onorm_g, onorm_b);
  // 9. out_proj + residual -> X0
  k_mgemm<1><<<dim3(2,512),256,0,stream>>>(Zg, opw, nullptr, X0, X0, nullptr, 128,256);
  // 10. LN2 -> bf16
  k_ln128b<<<BB*LL,128,0,stream>>>(X0, ln2_g, ln2_b, Ln2b);
  // 11. MLP1 gelu -> H1 bf16
  k_mgemm<2><<<dim3(8,512),256,0,stream>>>(Ln2b, m1w, mlp_b1, nullptr, nullptr, H1, 512,128);
  // 12. MLP2 + bias + residual -> X0
  k_mgemm<1><<<dim3(2,512),256,0,stream>>>(H1, m2w, mlp_b2, X0, X0, nullptr, 128,512);
  // 13. zero padded conv buffers (P and T), then de-interleave
  hipMemsetAsync(wsB + 16*MB, 0, 18*MB, stream);
  k_deint2<<<dim3(32,64,BB),256,0,stream>>>(X0, P, R);
  // 14-15. resblocks (both images batched, img = im2*4 + b)
  k_mconv<0><<<dim3(2,64,8),256,0,stream>>>(P, rw1, bn1_g,bn1_b,bn1_m,bn1_v, nullptr, T, nullptr);
  k_mconv<1><<<dim3(2,64,8),256,0,stream>>>(T, rw2, bn2_g,bn2_b,bn2_m,bn2_v, R, nullptr, out);
}

// Round 6
// 1170.887 us; speedup vs baseline: 9.0906x; 1.2813x over previous
//
#include <hip/hip_runtime.h>
#include <math.h>

// Problem constants
#define BB 4
#define CM 128      // d_model
#define DI 256      // d_inner
#define NS 16       // d_state
#define RK 8        // dt_rank
#define KD 4        // K directions
#define HH 64
#define WW 128      // interleaved width
#define LL 8192     // HH*WW
#define NC 16       // scan chunks per sequence
#define CH 512      // chunk length (NC*CH == LL)

typedef unsigned short ushortt;
typedef unsigned int uintt;
typedef __attribute__((ext_vector_type(8))) __bf16 bf16x8;
typedef __attribute__((ext_vector_type(4))) float f32x4;

__device__ __forceinline__ void lds_fence(){
  asm volatile("" ::: "memory");
  __builtin_amdgcn_sched_barrier(0);
}

__device__ __forceinline__ float sigmoidf_(float x){ return 1.f/(1.f+__expf(-x)); }
__device__ __forceinline__ float siluf_(float x){ return x*sigmoidf_(x); }
__device__ __forceinline__ float softplusf_(float x){
  if (x > 20.f) return x;
  if (x < -20.f) return __expf(x);
  return log1pf(__expf(x));
}
__device__ __forceinline__ float geluf_(float x){ return 0.5f*x*(1.f+erff(x*0.70710678118654752f)); }
__device__ __forceinline__ float waveReduceSum(float v){
  for (int o=32;o>0;o>>=1) v += __shfl_xor(v,o,64);
  return v;
}
__device__ __forceinline__ ushortt f2bf(float f){
  uintt u = __float_as_uint(f);
  uintt r = (u + 0x7fffu + ((u>>16)&1u)) >> 16;
  return (ushortt)r;
}
__device__ __forceinline__ float bf2f(ushortt s){
  return __uint_as_float(((uintt)s)<<16);
}
template<int CTRL>
__device__ __forceinline__ float dppadd(float x){
  int r = __builtin_amdgcn_update_dpp(0, __float_as_int(x), CTRL, 0xF, 0xF, true);
  return x + __int_as_float(r);
}
// full sum over each 16-lane row; result on all lanes
__device__ __forceinline__ float rowsum16(float x){
  x = dppadd<0x121>(x);  // row_ror:1
  x = dppadd<0x122>(x);  // row_ror:2
  x = dppadd<0x124>(x);  // row_ror:4
  x = dppadd<0x128>(x);  // row_ror:8
  return x;
}

// ---------------- weight conversions ----------------
__global__ void k_tobf(const float* __restrict__ s, ushortt* __restrict__ d, int n){
  int i = blockIdx.x*256 + threadIdx.x;
  if (i < n) d[i] = f2bf(s[i]);
}
// rb weights (co,ci,3,3) f32 -> (tap,co,ci) bf16
__global__ void k_wrb(const float* __restrict__ src, ushortt* __restrict__ dst){
  int i = blockIdx.x*256 + threadIdx.x;  // < 147456
  if (i >= 147456) return;
  int ci = i & 127, co = (i>>7)&127, tap = i>>14;
  dst[i] = f2bf(src[(size_t)(co*128+ci)*9 + tap]);
}

// ---------------- CT build: interleave x1/x2 -> token-major bf16 (B*L, 128) ----------------
__global__ void k_build_ct2(const float* __restrict__ x1, const float* __restrict__ x2,
                            ushortt* __restrict__ CT){
  __shared__ ushortt Tl[64][136];
  int tid = threadIdx.x;
  int p0 = (blockIdx.x & 127) * 64;
  int b  = blockIdx.x >> 7;
  int j = tid & 63;
  int p = p0 + j; int hh = p>>7, ww = p&127, w2 = ww>>1;
  const float* src = (ww&1) ? x2 : x1;
  const float* sp = src + ((size_t)b*128*64 + hh)*64 + w2;
  for (int c0 = tid>>6; c0 < 128; c0 += 4)
    Tl[j][c0] = f2bf(sp[(size_t)c0*4096]);
  __syncthreads();
  int c = tid & 127; int rh = tid >> 7;
  for (int r = rh; r < 64; r += 2)
    CT[((size_t)b*LL + p0 + r)*128 + c] = Tl[r][c];
}

// ---------------- MFMA token GEMM ----------------
// A: [32768][K] bf16, W: [N][K] bf16; grid (N/64, 512), block 256 (4 waves).
// EPI 0: (+bias) f32 C ; 1: (+bias)+resid f32 C ; 2: +bias,gelu -> bf16 C2 (stride 512)
// EPI 3: split n<256 -> f32 C (stride 256), else bf16 C2 (stride 256)
template<int EPI>
__global__ void k_mgemm(const ushortt* __restrict__ A, const ushortt* __restrict__ W,
                        const float* __restrict__ bias, const float* __restrict__ resid,
                        float* __restrict__ C, ushortt* __restrict__ C2, int N, int K){
  int n0 = blockIdx.x*64, m0 = blockIdx.y*64;
  int wv = threadIdx.x>>6, l = threadIdx.x&63;
  int ar = l&15, kg = l>>4;
  int mw = m0 + wv*16;
  f32x4 acc[4];
#pragma unroll
  for (int i=0;i<4;i++){ acc[i][0]=0.f; acc[i][1]=0.f; acc[i][2]=0.f; acc[i][3]=0.f; }
  const ushortt* Ap = A + (size_t)(mw+ar)*K + kg*8;
  const ushortt* Wp = W + (size_t)(n0+ar)*K + kg*8;
  for (int k0=0; k0<K; k0+=32){
    bf16x8 af = *(const bf16x8*)(Ap + k0);
#pragma unroll
    for (int nf=0; nf<4; ++nf){
      bf16x8 bfv = *(const bf16x8*)(Wp + (size_t)nf*16*K + k0);
      acc[nf] = __builtin_amdgcn_mfma_f32_16x16x32_bf16(af, bfv, acc[nf], 0,0,0);
    }
  }
#pragma unroll
  for (int nf=0;nf<4;nf++){
    int n = n0 + nf*16 + ar;
#pragma unroll
    for (int r=0;r<4;r++){
      int m = mw + kg*4 + r;
      float v = acc[nf][r];
      if (EPI==0 || EPI==1){
        if (bias) v += bias[n];
        if (EPI==1) v += resid[(size_t)m*N + n];
        C[(size_t)m*N + n] = v;
      } else if (EPI==2){
        v += bias[n];
        C2[(size_t)m*512 + n] = f2bf(geluf_(v));
      } else {
        if (n < 256) C[(size_t)m*256 + n] = v;
        else         C2[(size_t)m*256 + (n-256)] = f2bf(v);
      }
    }
  }
}

// ---------------- LayerNorm over 128 channels -> bf16 ----------------
__global__ void k_ln128b(const float* __restrict__ X, const float* __restrict__ g,
                         const float* __restrict__ bt, ushortt* __restrict__ O){
  int tok = blockIdx.x, tid = threadIdx.x;
  float x = X[(size_t)tok*128 + tid];
  float s  = waveReduceSum(x);
  float s2 = waveReduceSum(x*x);
  __shared__ float a[2], a2[2];
  if ((tid&63)==0){ a[tid>>6]=s; a2[tid>>6]=s2; }
  __syncthreads();
  float mean = (a[0]+a[1])*(1.f/128.f);
  float var  = (a2[0]+a2[1])*(1.f/128.f) - mean*mean;
  float r = rsqrtf(var + 1e-5f);
  O[(size_t)tok*128+tid] = f2bf((x-mean)*r*g[tid] + bt[tid]);
}

// ---------------- Depthwise 3x3 + bias + SiLU, channel-last (B,L,256) -> bf16 ----------------
__global__ void k_dwconv(const float* __restrict__ Xp, const float* __restrict__ w,
                         const float* __restrict__ bias, ushortt* __restrict__ O){
  int tok = blockIdx.x; int d = threadIdx.x;
  int b = tok >> 13; int p = tok & (LL-1); int hh = p>>7, ww = p&127;
  float acc = bias[d];
#pragma unroll
  for (int dy=0;dy<3;dy++){
    int yy = hh+dy-1; if (yy<0||yy>=HH) continue;
#pragma unroll
    for (int dx=0;dx<3;dx++){
      int xx = ww+dx-1; if (xx<0||xx>=WW) continue;
      acc += Xp[((size_t)b*LL + yy*WW + xx)*256 + d] * w[d*9 + dy*3 + dx];
    }
  }
  O[(size_t)tok*256 + d] = f2bf(siluf_(acc));
}

// ---------------- transposes: Xpab[b][p][d] -> Xpt0[b][d][raster p] ----------------
__global__ void k_xt0(const ushortt* __restrict__ Xpab, ushortt* __restrict__ Xpt0){
  __shared__ ushortt Tl[64][68];
  int b = blockIdx.z, d0 = blockIdx.y*64, p0 = blockIdx.x*64;
  int di = threadIdx.x&63, q = threadIdx.x>>6;
  for (int k2=0;k2<16;k2++){ int pi = q*16 + k2;
    Tl[pi][di] = Xpab[((size_t)b*LL + p0+pi)*256 + d0+di]; }
  __syncthreads();
  for (int k2=0;k2<16;k2++){ int dr = q*16 + k2;
    Xpt0[((size_t)(b*256 + d0+dr))*LL + p0+di] = Tl[di][dr]; }
}
// ---------------- Xpab -> Xpt1[b][d][colmajor t1 = ww*64+hh] ----------------
__global__ void k_xt1(const ushortt* __restrict__ Xpab, ushortt* __restrict__ Xpt1){
  __shared__ ushortt Tl[64][68];
  int b = blockIdx.z, d0 = blockIdx.y*64, ww = blockIdx.x;
  int di = threadIdx.x&63, q = threadIdx.x>>6;
  for (int k2=0;k2<16;k2++){ int hh = q*16 + k2;
    Tl[hh][di] = Xpab[((size_t)b*LL + hh*128 + ww)*256 + d0+di]; }
  __syncthreads();
  for (int k2=0;k2<16;k2++){ int dr = q*16 + k2;
    Xpt1[((size_t)(b*256 + d0+dr))*LL + ww*64 + di] = Tl[di][dr]; }
}

// ---------------- x_proj: per-token 4x40 projections, written in scan order ----------------
// DBC row layout (96B per (b,k,t)): [0..31] 8x f32 dts; [32+4j] bf16 B_j (low), C_j (high)
__global__ void k_xdbl(const ushortt* __restrict__ Xpab, const float* __restrict__ xpw,
                       char* __restrict__ DBCb){
  __shared__ float U[16][256];
  int tid = threadIdx.x;
  int blk = blockIdx.x;              // B*L/16 = 2048
  int b = blk >> 9;
  int p0 = (blk & 511) << 4;
  for (int i=tid;i<16*256;i+=256){ int tt=i>>8, d=i&255;
    U[tt][d] = bf2f(Xpab[((size_t)b*LL + p0+tt)*256 + d]); }
  __syncthreads();
  if (tid < 160){
    int k = tid/40, c = tid%40;
    const float* wr = xpw + ((size_t)k*40 + c)*256;
    float acc[16];
#pragma unroll
    for (int tt=0;tt<16;tt++) acc[tt]=0.f;
    for (int d=0;d<256;d++){
      float wv = wr[d];
#pragma unroll
      for (int tt=0;tt<16;tt++) acc[tt] += U[tt][d]*wv;
    }
    for (int tt=0;tt<16;tt++){
      int p = p0+tt; int hh=p>>7, ww=p&127;
      int t;
      if      (k==0) t = p;
      else if (k==1) t = (ww<<6)|hh;
      else if (k==2) t = LL-1-p;
      else           t = LL-1-((ww<<6)|hh);
      char* rowp = DBCb + ((size_t)(b*KD+k)*LL + t)*96;
      if (c < 8)       *(float*)(rowp + 4*c) = acc[tt];
      else if (c < 24) *(ushortt*)(rowp + 32 + 4*(c-8))  = f2bf(acc[tt]);
      else             *(ushortt*)(rowp + 34 + 4*(c-24)) = f2bf(acc[tt]);
    }
  }
}

// ---------------- Chunked selective scan ----------------
// Pass A: per (bkd, chunk): scan from h=0, store h_out and sum(delta).
__global__ void k_scanA(const char* __restrict__ DBCb,
                        const ushortt* __restrict__ Xpt0, const ushortt* __restrict__ Xpt1,
                        const float* __restrict__ dtw_all, const float* __restrict__ dtb_all,
                        const float* __restrict__ A_logs,
                        float* __restrict__ Hbuf, float* __restrict__ Ssum){
  __shared__ float2 sdd[16][16];
  int tid = threadIdx.x;
  int grp = tid >> 4, lane = tid & 15;
  int gid = blockIdx.x*16 + grp;       // bkd*16 + c
  int c = gid & 15;
  int bkd = gid >> 4;
  int b = bkd >> 10, k = (bkd>>8)&3, d = bkd & 255;
  int kd = k*256+d;
  float dtw[8];
  { const float4* w4 = (const float4*)(dtw_all + (size_t)kd*8);
    float4 w0 = w4[0], w1 = w4[1];
    dtw[0]=w0.x; dtw[1]=w0.y; dtw[2]=w0.z; dtw[3]=w0.w;
    dtw[4]=w1.x; dtw[5]=w1.y; dtw[6]=w1.z; dtw[7]=w1.w; }
  float dtb  = dtb_all[kd];
  float Aval = -__expf(A_logs[(size_t)kd*16+lane]);
  const char* dbc = DBCb + (size_t)(b*KD+k)*LL*96;
  const ushortt* Up = ((k&1)?Xpt1:Xpt0) + ((size_t)(b*256+d))*LL;
  float h = 0.f, Sacc = 0.f;
  int t0 = c*CH;
  for (int blk=0; blk<CH/16; ++blk){
    int tb = t0 + blk*16;
    int tme = tb + lane;
    const char* rowme = dbc + (size_t)tme*96;
    float4 q0 = *(const float4*)rowme;
    float4 q1 = *(const float4*)(rowme+16);
    float dsum = dtb + q0.x*dtw[0] + q0.y*dtw[1] + q0.z*dtw[2] + q0.w*dtw[3]
                     + q1.x*dtw[4] + q1.y*dtw[5] + q1.z*dtw[6] + q1.w*dtw[7];
    float delta = softplusf_(dsum);
    int ui = (k<2) ? tme : (LL-1-tme);
    float u = bf2f(Up[ui]);
    sdd[grp][lane] = make_float2(delta, delta*u);
    lds_fence();             // order sdd write vs cross-lane reads below
    Sacc += rowsum16(delta);
    const char* rowB = dbc + (size_t)tb*96 + 32 + 4*lane;
#pragma unroll
    for (int i=0;i<16;i++){
      float2 dd = sdd[grp][i];
      uintt w = *(const uintt*)(rowB + 96*i);
      float Bn = __uint_as_float(w<<16);
      float e = __expf(dd.x * Aval);
      h = e*h + dd.y*Bn;
    }
    lds_fence();             // order sdd reads vs next block's write
  }
  Hbuf[(size_t)gid*16 + lane] = h;
  if (lane==0) Ssum[gid] = Sacc;
}

// Pass B: serial over chunks; converts Hbuf (h_out) to h_start in place.
__global__ void k_scanB(const float* __restrict__ Ssum, float* __restrict__ Hbuf,
                        const float* __restrict__ A_logs){
  int idx = blockIdx.x*256 + threadIdx.x;  // bkd*16+n (65536)
  int n = idx & 15; int bkd = idx >> 4;
  int kd = ((bkd>>8)&3)*256 + (bkd&255);
  float Aval = -__expf(A_logs[(size_t)kd*16+n]);
  float h = 0.f;
  for (int c=0;c<NC;c++){
    size_t g = (size_t)bkd*NC + c;
    float hout = Hbuf[g*16+n];
    Hbuf[g*16+n] = h;
    h = __expf(Aval*Ssum[g])*h + hout;
  }
}

// Pass C: re-scan chunk with correct h_start, write y (bf16, scan order [b][d][t]).
__global__ void k_scanC(const char* __restrict__ DBCb,
                        const ushortt* __restrict__ Xpt0, const ushortt* __restrict__ Xpt1,
                        const float* __restrict__ dtw_all, const float* __restrict__ dtb_all,
                        const float* __restrict__ A_logs, const float* __restrict__ Hbuf,
                        ushortt* __restrict__ Y0, ushortt* __restrict__ Y1,
                        ushortt* __restrict__ Y2, ushortt* __restrict__ Y3){
  __shared__ float2 sdd[16][16];
  __shared__ float yt[16][16][17];   // [grp][step][state], +1 pad
  int tid = threadIdx.x;
  int grp = tid >> 4, lane = tid & 15;
  int gid = blockIdx.x*16 + grp;
  int c = gid & 15;
  int bkd = gid >> 4;
  int b = bkd >> 10, k = (bkd>>8)&3, d = bkd & 255;
  int kd = k*256+d;
  float dtw[8];
  { const float4* w4 = (const float4*)(dtw_all + (size_t)kd*8);
    float4 w0 = w4[0], w1 = w4[1];
    dtw[0]=w0.x; dtw[1]=w0.y; dtw[2]=w0.z; dtw[3]=w0.w;
    dtw[4]=w1.x; dtw[5]=w1.y; dtw[6]=w1.z; dtw[7]=w1.w; }
  float dtb  = dtb_all[kd];
  float Aval = -__expf(A_logs[(size_t)kd*16+lane]);
  const char* dbc = DBCb + (size_t)(b*KD+k)*LL*96;
  const ushortt* Up = ((k&1)?Xpt1:Xpt0) + ((size_t)(b*256+d))*LL;
  ushortt* Yk = (k==0?Y0 : k==1?Y1 : k==2?Y2 : Y3) + ((size_t)b*256 + d)*LL;
  float h = Hbuf[(size_t)gid*16 + lane];
  int t0 = c*CH;
  for (int blk=0; blk<CH/16; ++blk){
    int tb = t0 + blk*16;
    int tme = tb + lane;
    const char* rowme = dbc + (size_t)tme*96;
    float4 q0 = *(const float4*)rowme;
    float4 q1 = *(const float4*)(rowme+16);
    float dsum = dtb + q0.x*dtw[0] + q0.y*dtw[1] + q0.z*dtw[2] + q0.w*dtw[3]
                     + q1.x*dtw[4] + q1.y*dtw[5] + q1.z*dtw[6] + q1.w*dtw[7];
    float delta = softplusf_(dsum);
    int ui = (k<2) ? tme : (LL-1-tme);
    float u = bf2f(Up[ui]);
    sdd[grp][lane] = make_float2(delta, delta*u);
    lds_fence();             // order sdd write vs cross-lane reads below
    const char* rowB = dbc + (size_t)tb*96 + 32 + 4*lane;
#pragma unroll
    for (int i=0;i<16;i++){
      float2 dd = sdd[grp][i];
      uintt w = *(const uintt*)(rowB + 96*i);
      float Bn = __uint_as_float(w<<16);
      float Cn = __uint_as_float(w & 0xffff0000u);
      float e = __expf(dd.x * Aval);
      h = e*h + dd.y*Bn;
      yt[grp][i][lane] = h*Cn;
    }
    lds_fence();             // order yt writes vs cross-lane yt reads
    float acc = 0.f;
#pragma unroll
    for (int n=0;n<16;n++) acc += yt[grp][lane][n];
    Yk[tme] = f2bf(acc);
    lds_fence();             // order yt reads vs next block's yt writes
  }
}

// ---------------- Gate: gather Y0..Y3 + u*sum(D), LN256, *silu(z) ----------------
__global__ void k_gate2(const ushortt* __restrict__ Y0, const ushortt* __restrict__ Y1,
                        const ushortt* __restrict__ Y2, const ushortt* __restrict__ Y3,
                        const ushortt* __restrict__ Xpt0, const float* __restrict__ Ds,
                        ushortt* __restrict__ Zg,
                        const float* __restrict__ g, const float* __restrict__ bt){
  __shared__ float ysum[32][257];
  __shared__ float Dl[256];
  int tid = threadIdx.x;
  int wwb = blockIdx.x;      // 0..3
  int hh  = blockIdx.y;      // 0..63
  int b   = blockIdx.z;
  if (tid < 256) Dl[tid] = Ds[tid] + Ds[256+tid] + Ds[512+tid] + Ds[768+tid];
  int ww0 = wwb*32;
  for (int it=0; it<32; ++it){
    int idx = it*256 + tid;
    int d = idx >> 5, tl = idx & 31;
    int ww = ww0 + tl;
    int p  = hh*128 + ww;
    size_t base = ((size_t)b*256 + d) << 13;
    int t1 = ww*64 + hh;
    float v = bf2f(Y0[base + p]) + bf2f(Y2[base + (LL-1) - p])
            + bf2f(Y1[base + t1]) + bf2f(Y3[base + (LL-1) - t1]);
    ysum[tl][d] = v;
  }
  __syncthreads();
  {
    int d = tid;
    if (d < 256){
      size_t ub = (((size_t)b*256 + d) << 13) + hh*128 + ww0;
      for (int tl=0; tl<32; ++tl){
        float u = bf2f(Xpt0[ub + tl]);
        ysum[tl][d] += Dl[d]*u;
      }
    }
  }
  __syncthreads();
  int wave = tid >> 6, lane = tid & 63;
  for (int tk = wave*8; tk < wave*8+8; ++tk){
    float v0 = ysum[tk][lane], v1 = ysum[tk][lane+64];
    float v2 = ysum[tk][lane+128], v3 = ysum[tk][lane+192];
    float s  = waveReduceSum(v0+v1+v2+v3);
    float s2 = waveReduceSum(v0*v0+v1*v1+v2*v2+v3*v3);
    float mean = s*(1.f/256.f);
    float var  = s2*(1.f/256.f) - mean*mean;
    float r = rsqrtf(var + 1e-5f);
    int p = hh*128 + ww0 + tk;
    size_t zb = (((size_t)b<<13) + p) << 8;
#pragma unroll
    for (int j=0;j<4;j++){
      int dd = lane + 64*j;
      float ln = (ysum[tk][dd]-mean)*r*g[dd] + bt[dd];
      float z = bf2f(Zg[zb + dd]);
      Zg[zb + dd] = f2bf(ln * siluf_(z));
    }
  }
}

// ---------------- De-interleave -> padded bf16 conv input + f32 residual ----------------
// P: [8][66][66][128] bf16 (img = im2*4+b), R: [8][64][64][128] f32
__global__ void k_deint2(const float* __restrict__ X, ushortt* __restrict__ P,
                         float* __restrict__ R){
  int c = threadIdx.x & 127;
  int xh = threadIdx.x >> 7;
  int x = blockIdx.x*2 + xh;
  int y = blockIdx.y; int b = blockIdx.z;
#pragma unroll
  for (int im2=0; im2<2; ++im2){
    int ww = 2*x + im2;
    float v = X[((size_t)b*LL + y*128 + ww)*128 + c];
    int im = im2*4 + b;
    P[(((size_t)im*66 + y+1)*66 + x+1)*128 + c] = f2bf(v);
    R[(((size_t)im*64 + y)*64 + x)*128 + c] = v;
  }
}

// ---------------- MFMA 3x3 conv 128->128 + BN (+res) + ReLU ----------------
template<int FINAL>
__global__ void k_mconv(const ushortt* __restrict__ I, const ushortt* __restrict__ Wt,
                        const float* __restrict__ g, const float* __restrict__ bb,
                        const float* __restrict__ mn, const float* __restrict__ vv,
                        const float* __restrict__ R, ushortt* __restrict__ Op,
                        float* __restrict__ Of){
  int nh = blockIdx.x;
  int y  = blockIdx.y;
  int im = blockIdx.z;
  int wv = threadIdx.x>>6, l = threadIdx.x&63;
  int ar = l&15, kg = l>>4;
  int x0 = wv*16;
  f32x4 acc[4];
#pragma unroll
  for (int i=0;i<4;i++){ acc[i][0]=0.f; acc[i][1]=0.f; acc[i][2]=0.f; acc[i][3]=0.f; }
  const ushortt* Ibase = I + (((size_t)im*66 + y)*66 + x0 + ar)*128 + kg*8;
  const ushortt* Wbase = Wt + (size_t)(nh*64 + ar)*128 + kg*8;
#pragma unroll
  for (int tap=0; tap<9; ++tap){
    int dy = tap/3, dx = tap - dy*3;
    const ushortt* Ir = Ibase + ((size_t)dy*66 + dx)*128;
    const ushortt* Wr = Wbase + (size_t)tap*16384;
#pragma unroll
    for (int kc=0;kc<4;kc++){
      bf16x8 af = *(const bf16x8*)(Ir + kc*32);
#pragma unroll
      for (int nf=0;nf<4;nf++){
        bf16x8 bfv = *(const bf16x8*)(Wr + (size_t)nf*16*128 + kc*32);
        acc[nf] = __builtin_amdgcn_mfma_f32_16x16x32_bf16(af, bfv, acc[nf], 0,0,0);
      }
    }
  }
#pragma unroll
  for (int nf=0;nf<4;nf++){
    int co = nh*64 + nf*16 + ar;
    float s  = g[co]*rsqrtf(vv[co]+1e-5f);
    float sh = bb[co] - mn[co]*s;
#pragma unroll
    for (int r=0;r<4;r++){
      int x = x0 + kg*4 + r;
      float v = acc[nf][r]*s + sh;
      if (FINAL){
        v += R[(((size_t)im*64 + y)*64 + x)*128 + co];
        v = fmaxf(v, 0.f);
        Of[(((size_t)im*128 + co)*64 + y)*64 + x] = v;
      } else {
        v = fmaxf(v, 0.f);
        Op[(((size_t)im*66 + (y+1))*66 + (x+1))*128 + co] = f2bf(v);
      }
    }
  }
}

extern "C" void kernel_launch(void* const* d_in, const int* in_sizes, int n_in,
                              void* d_out, int out_size, void* d_ws, size_t ws_size,
                              hipStream_t stream){
  const float* x1        = (const float*)d_in[0];
  const float* x2        = (const float*)d_in[1];
  const float* conv_in_w = (const float*)d_in[2];
  const float* conv_in_b = (const float*)d_in[3];
  const float* ln1_g     = (const float*)d_in[4];
  const float* ln1_b     = (const float*)d_in[5];
  const float* in_proj_w = (const float*)d_in[6];
  const float* dw_w      = (const float*)d_in[7];
  const float* dw_b      = (const float*)d_in[8];
  const float* x_proj_w  = (const float*)d_in[9];
  const float* dt_proj_w = (const float*)d_in[10];
  const float* dt_proj_b = (const float*)d_in[11];
  const float* A_logs    = (const float*)d_in[12];
  const float* Ds        = (const float*)d_in[13];
  const float* onorm_g   = (const float*)d_in[14];
  const float* onorm_b   = (const float*)d_in[15];
  const float* out_proj_w= (const float*)d_in[16];
  const float* ln2_g     = (const float*)d_in[17];
  const float* ln2_b     = (const float*)d_in[18];
  const float* mlp_w1    = (const float*)d_in[19];
  const float* mlp_b1    = (const float*)d_in[20];
  const float* mlp_w2    = (const float*)d_in[21];
  const float* mlp_b2    = (const float*)d_in[22];
  const float* rb1_w     = (const float*)d_in[23];
  const float* bn1_g     = (const float*)d_in[24];
  const float* bn1_b     = (const float*)d_in[25];
  const float* bn1_m     = (const float*)d_in[26];
  const float* bn1_v     = (const float*)d_in[27];
  const float* rb2_w     = (const float*)d_in[28];
  const float* bn2_g     = (const float*)d_in[29];
  const float* bn2_b     = (const float*)d_in[30];
  const float* bn2_m     = (const float*)d_in[31];
  const float* bn2_v     = (const float*)d_in[32];

  float* ws = (float*)d_ws;
  char*  wsB = (char*)d_ws;
  const size_t FM = 262144;            // floats per MiB
  const size_t MB = 1048576;           // bytes per MiB
  // Workspace layout (peak 147.1 MiB, proven available):
  float*   X0   = ws;                          // 0-16    residual stream (B,L,128) f32
  ushortt* Xpab = (ushortt*)(wsB + 16*MB);     // 16-32   u post-dw-silu (B,L,256) bf16
  ushortt* Xpt0 = (ushortt*)(wsB + 32*MB);     // 32-48   u raster-order [b][d][p]
  ushortt* Xpt1 = (ushortt*)(wsB + 48*MB);     // 48-64   u colmajor-order [b][d][t1]
  char*    DBCb = wsB + 64*MB;                 // 64-77   scan rows 96B
  ushortt* Zg   = (ushortt*)(wsB + 77*MB);     // 77-93   z / gated bf16
  ushortt* Y0   = (ushortt*)(wsB + 93*MB);     // 93-109
  ushortt* Y1   = (ushortt*)(wsB + 109*MB);    // 109-125
  ushortt* Y2   = (ushortt*)(wsB + 125*MB);    // 125-141
  ushortt* Y3   = Xpab;                        // alias (Xpab dead before scanC)
  float*   Hbuf = ws + 141*FM;                 // 141-145
  float*   Ssum = ws + 145*FM;                 // 145-145.25
  // time-disjoint aliases:
  ushortt* CT   = (ushortt*)(wsB + 93*MB);     // steps 1-2 (over Y0)
  ushortt* Lnb  = (ushortt*)(wsB + 101*MB);    // steps 3-4 (over Y0 2nd half)
  float*   Abuf = ws + 109*FM;                 // steps 4-5 (over Y1,Y2) xp pre-dw f32
  ushortt* Ln2b = (ushortt*)(wsB + 93*MB);     // steps 10-11 (Y0 dead)
  ushortt* H1   = (ushortt*)(wsB + 109*MB);    // steps 11-12 (Y1,Y2 dead)
  ushortt* P    = (ushortt*)(wsB + 16*MB);     // step 13+ padded conv input [8][66][66][128]
  ushortt* T    = (ushortt*)(wsB + 25*MB);     // conv1 out padded
  float*   R    = (float*)(wsB + 34*MB);       // 34-51 residual [8][64][64][128] f32
  // bf16 weights (persistent, never aliased):
  ushortt* cw  = (ushortt*)(wsB + 146*MB);           // 32 KB
  ushortt* ipw = (ushortt*)(wsB + 146*MB + 32*1024); // 128 KB
  ushortt* opw = (ushortt*)(wsB + 146*MB + 160*1024);// 64 KB
  ushortt* m1w = (ushortt*)(wsB + 146*MB + 224*1024);// 128 KB
  ushortt* m2w = (ushortt*)(wsB + 146*MB + 352*1024);// 128 KB
  ushortt* rw1 = (ushortt*)(wsB + 146*MB + 480*1024);// 288 KB
  ushortt* rw2 = (ushortt*)(wsB + 146*MB + 768*1024);// 288 KB
  float* out = (float*)d_out;

  // 0. weight conversions
  k_tobf<<<64, 256,0,stream>>>(conv_in_w, cw, 16384);
  k_tobf<<<256,256,0,stream>>>(in_proj_w, ipw, 65536);
  k_tobf<<<128,256,0,stream>>>(out_proj_w, opw, 32768);
  k_tobf<<<256,256,0,stream>>>(mlp_w1, m1w, 65536);
  k_tobf<<<256,256,0,stream>>>(mlp_w2, m2w, 65536);
  k_wrb<<<576,256,0,stream>>>(rb1_w, rw1);
  k_wrb<<<576,256,0,stream>>>(rb2_w, rw2);
  // 1. interleave -> CT bf16 token-major
  k_build_ct2<<<512,256,0,stream>>>(x1,x2,CT);
  // 2. conv_in 1x1 (bias) -> X0 f32
  k_mgemm<0><<<dim3(2,512),256,0,stream>>>(CT, cw, conv_in_b, nullptr, X0, nullptr, 128,128);
  // 3. LN1 -> bf16
  k_ln128b<<<BB*LL,128,0,stream>>>(X0, ln1_g, ln1_b, Lnb);
  // 4. in_proj (512) -> split xp(Abuf f32) / z(Zg bf16)
  k_mgemm<3><<<dim3(8,512),256,0,stream>>>(Lnb, ipw, nullptr, nullptr, Abuf, Zg, 512,128);
  // 5. depthwise 3x3 + silu -> Xpab bf16
  k_dwconv<<<BB*LL,256,0,stream>>>(Abuf, dw_w, dw_b, Xpab);
  // 5b. direction-ordered u copies
  k_xt0<<<dim3(128,4,BB),256,0,stream>>>(Xpab, Xpt0);
  k_xt1<<<dim3(128,4,BB),256,0,stream>>>(Xpab, Xpt1);
  // 6. x_proj -> DBC
  k_xdbl<<<2048,256,0,stream>>>(Xpab, x_proj_w, DBCb);
  // 7. chunked selective scan
  k_scanA<<<4096,256,0,stream>>>(DBCb, Xpt0, Xpt1, dt_proj_w, dt_proj_b, A_logs, Hbuf, Ssum);
  k_scanB<<<256,256,0,stream>>>(Ssum, Hbuf, A_logs);
  k_scanC<<<4096,256,0,stream>>>(DBCb, Xpt0, Xpt1, dt_proj_w, dt_proj_b, A_logs, Hbuf, Y0,Y1,Y2,Y3);
  // 8. gate
  k_gate2<<<dim3(4,64,BB),256,0,stream>>>(Y0,Y1,Y2,Y3, Xpt0, Ds, Zg, onorm_g, onorm_b);
  // 9. out_proj + residual -> X0
  k_mgemm<1><<<dim3(2,512),256,0,stream>>>(Zg, opw, nullptr, X0, X0, nullptr, 128,256);
  // 10. LN2 -> bf16
  k_ln128b<<<BB*LL,128,0,stream>>>(X0, ln2_g, ln2_b, Ln2b);
  // 11. MLP1 gelu -> H1 bf16
  k_mgemm<2><<<dim3(8,512),256,0,stream>>>(Ln2b, m1w, mlp_b1, nullptr, nullptr, H1, 512,128);
  // 12. MLP2 + bias + residual -> X0
  k_mgemm<1><<<dim3(2,512),256,0,stream>>>(H1, m2w, mlp_b2, X0, X0, nullptr, 128,512);
  // 13. zero padded conv buffers (P and T), then de-interleave
  hipMemsetAsync(wsB + 16*MB, 0, 18*MB, stream);
  k_deint2<<<dim3(32,64,BB),256,0,stream>>>(X0, P, R);
  // 14-15. resblocks (both images batched, img = im2*4 + b)
  k_mconv<0><<<dim3(2,64,8),256,0,stream>>>(P, rw1, bn1_g,bn1_b,bn1_m,bn1_v, nullptr, T, nullptr);
  k_mconv<1><<<dim3(2,64,8),256,0,stream>>>(T, rw2, bn2_g,bn2_b,bn2_m,bn2_v, R, nullptr, out);
}

// Round 7
// 935.711 us; speedup vs baseline: 11.3753x; 1.2513x over previous
//
#include <hip/hip_runtime.h>
#include <math.h>

// Problem constants
#define BB 4
#define CM 128      // d_model
#define DI 256      // d_inner
#define NS 16       // d_state
#define RK 8        // dt_rank
#define KD 4        // K directions
#define HH 64
#define WW 128      // interleaved width
#define LL 8192     // HH*WW
#define NC 16       // scan chunks per sequence
#define CH 512      // chunk length (NC*CH == LL)

typedef unsigned short ushortt;
typedef unsigned int uintt;
typedef __attribute__((ext_vector_type(8))) __bf16 bf16x8;
typedef __attribute__((ext_vector_type(4))) float f32x4;

__device__ __forceinline__ void lds_fence(){
  asm volatile("" ::: "memory");
  __builtin_amdgcn_sched_barrier(0);
}

__device__ __forceinline__ float sigmoidf_(float x){ return 1.f/(1.f+__expf(-x)); }
__device__ __forceinline__ float siluf_(float x){ return x*sigmoidf_(x); }
__device__ __forceinline__ float softplusf_(float x){
  if (x > 20.f) return x;
  if (x < -20.f) return __expf(x);
  return log1pf(__expf(x));
}
__device__ __forceinline__ float geluf_(float x){ return 0.5f*x*(1.f+erff(x*0.70710678118654752f)); }
__device__ __forceinline__ float waveReduceSum(float v){
  for (int o=32;o>0;o>>=1) v += __shfl_xor(v,o,64);
  return v;
}
__device__ __forceinline__ ushortt f2bf(float f){
  uintt u = __float_as_uint(f);
  uintt r = (u + 0x7fffu + ((u>>16)&1u)) >> 16;
  return (ushortt)r;
}
__device__ __forceinline__ float bf2f(ushortt s){
  return __uint_as_float(((uintt)s)<<16);
}
template<int CTRL>
__device__ __forceinline__ float dppadd(float x){
  int r = __builtin_amdgcn_update_dpp(0, __float_as_int(x), CTRL, 0xF, 0xF, true);
  return x + __int_as_float(r);
}
// full sum over each 16-lane row; result on all lanes
__device__ __forceinline__ float rowsum16(float x){
  x = dppadd<0x121>(x);  // row_ror:1
  x = dppadd<0x122>(x);  // row_ror:2
  x = dppadd<0x124>(x);  // row_ror:4
  x = dppadd<0x128>(x);  // row_ror:8
  return x;
}

// ---------------- merged weight conversions (1 launch) ----------------
__global__ void k_wall(const float* __restrict__ cw_s, ushortt* __restrict__ cw_d,
                       const float* __restrict__ ip_s, ushortt* __restrict__ ip_d,
                       const float* __restrict__ op_s, ushortt* __restrict__ op_d,
                       const float* __restrict__ m1_s, ushortt* __restrict__ m1_d,
                       const float* __restrict__ m2_s, ushortt* __restrict__ m2_d,
                       const float* __restrict__ r1_s, ushortt* __restrict__ r1_d,
                       const float* __restrict__ r2_s, ushortt* __restrict__ r2_d){
  int i = blockIdx.x*256 + threadIdx.x;
  if (i < 16384){ cw_d[i] = f2bf(cw_s[i]); return; }
  i -= 16384;
  if (i < 65536){ ip_d[i] = f2bf(ip_s[i]); return; }
  i -= 65536;
  if (i < 32768){ op_d[i] = f2bf(op_s[i]); return; }
  i -= 32768;
  if (i < 65536){ m1_d[i] = f2bf(m1_s[i]); return; }
  i -= 65536;
  if (i < 65536){ m2_d[i] = f2bf(m2_s[i]); return; }
  i -= 65536;
  if (i < 147456){ int ci=i&127, co=(i>>7)&127, tap=i>>14;
    r1_d[i]=f2bf(r1_s[(size_t)(co*128+ci)*9+tap]); return; }
  i -= 147456;
  if (i < 147456){ int ci=i&127, co=(i>>7)&127, tap=i>>14;
    r2_d[i]=f2bf(r2_s[(size_t)(co*128+ci)*9+tap]); }
}

// ---------------- CT build: interleave x1/x2 -> token-major bf16 (B*L, 128) ----------------
__global__ void k_build_ct2(const float* __restrict__ x1, const float* __restrict__ x2,
                            ushortt* __restrict__ CT){
  __shared__ ushortt Tl[64][136];
  int tid = threadIdx.x;
  int p0 = (blockIdx.x & 127) * 64;
  int b  = blockIdx.x >> 7;
  int j = tid & 63;
  int p = p0 + j; int hh = p>>7, ww = p&127, w2 = ww>>1;
  const float* src = (ww&1) ? x2 : x1;
  const float* sp = src + ((size_t)b*128*64 + hh)*64 + w2;
  for (int c0 = tid>>6; c0 < 128; c0 += 4)
    Tl[j][c0] = f2bf(sp[(size_t)c0*4096]);
  __syncthreads();
  int c = tid & 127; int rh = tid >> 7;
  for (int r = rh; r < 64; r += 2)
    CT[((size_t)b*LL + p0 + r)*128 + c] = Tl[r][c];
}

// ---------------- MFMA token GEMM ----------------
// A: [32768][K] bf16, W: [N][K] bf16; grid (N/64, 512), block 256 (4 waves).
// EPI 0: (+bias) f32 C ; 1: (+bias)+resid f32 C ; 2: +bias,gelu -> bf16 C2 (stride 512)
// EPI 3: split n<256 -> f32 C (stride 256), else bf16 C2 (stride 256)
template<int EPI>
__global__ void k_mgemm(const ushortt* __restrict__ A, const ushortt* __restrict__ W,
                        const float* __restrict__ bias, const float* __restrict__ resid,
                        float* __restrict__ C, ushortt* __restrict__ C2, int N, int K){
  int n0 = blockIdx.x*64, m0 = blockIdx.y*64;
  int wv = threadIdx.x>>6, l = threadIdx.x&63;
  int ar = l&15, kg = l>>4;
  int mw = m0 + wv*16;
  f32x4 acc[4];
#pragma unroll
  for (int i=0;i<4;i++){ acc[i][0]=0.f; acc[i][1]=0.f; acc[i][2]=0.f; acc[i][3]=0.f; }
  const ushortt* Ap = A + (size_t)(mw+ar)*K + kg*8;
  const ushortt* Wp = W + (size_t)(n0+ar)*K + kg*8;
  for (int k0=0; k0<K; k0+=32){
    bf16x8 af = *(const bf16x8*)(Ap + k0);
#pragma unroll
    for (int nf=0; nf<4; ++nf){
      bf16x8 bfv = *(const bf16x8*)(Wp + (size_t)nf*16*K + k0);
      acc[nf] = __builtin_amdgcn_mfma_f32_16x16x32_bf16(af, bfv, acc[nf], 0,0,0);
    }
  }
#pragma unroll
  for (int nf=0;nf<4;nf++){
    int n = n0 + nf*16 + ar;
#pragma unroll
    for (int r=0;r<4;r++){
      int m = mw + kg*4 + r;
      float v = acc[nf][r];
      if (EPI==0 || EPI==1){
        if (bias) v += bias[n];
        if (EPI==1) v += resid[(size_t)m*N + n];
        C[(size_t)m*N + n] = v;
      } else if (EPI==2){
        v += bias[n];
        C2[(size_t)m*512 + n] = f2bf(geluf_(v));
      } else {
        if (n < 256) C[(size_t)m*256 + n] = v;
        else         C2[(size_t)m*256 + (n-256)] = f2bf(v);
      }
    }
  }
}

// ---------------- LayerNorm over 128 channels -> bf16 ----------------
__global__ void k_ln128b(const float* __restrict__ X, const float* __restrict__ g,
                         const float* __restrict__ bt, ushortt* __restrict__ O){
  int tok = blockIdx.x, tid = threadIdx.x;
  float x = X[(size_t)tok*128 + tid];
  float s  = waveReduceSum(x);
  float s2 = waveReduceSum(x*x);
  __shared__ float a[2], a2[2];
  if ((tid&63)==0){ a[tid>>6]=s; a2[tid>>6]=s2; }
  __syncthreads();
  float mean = (a[0]+a[1])*(1.f/128.f);
  float var  = (a2[0]+a2[1])*(1.f/128.f) - mean*mean;
  float r = rsqrtf(var + 1e-5f);
  O[(size_t)tok*128+tid] = f2bf((x-mean)*r*g[tid] + bt[tid]);
}

// ---------------- Depthwise 3x3 + bias + SiLU, channel-last (B,L,256) -> bf16 ----------------
__global__ void k_dwconv(const float* __restrict__ Xp, const float* __restrict__ w,
                         const float* __restrict__ bias, ushortt* __restrict__ O){
  int tok = blockIdx.x; int d = threadIdx.x;
  int b = tok >> 13; int p = tok & (LL-1); int hh = p>>7, ww = p&127;
  float acc = bias[d];
#pragma unroll
  for (int dy=0;dy<3;dy++){
    int yy = hh+dy-1; if (yy<0||yy>=HH) continue;
#pragma unroll
    for (int dx=0;dx<3;dx++){
      int xx = ww+dx-1; if (xx<0||xx>=WW) continue;
      acc += Xp[((size_t)b*LL + yy*WW + xx)*256 + d] * w[d*9 + dy*3 + dx];
    }
  }
  O[(size_t)tok*256 + d] = f2bf(siluf_(acc));
}

// ---------------- merged transposes: Xpab[b][p][d] -> Xpt0 (raster) / Xpt1 (colmajor) ----------------
__global__ void k_xtm(const ushortt* __restrict__ Xpab, ushortt* __restrict__ Xpt0,
                      ushortt* __restrict__ Xpt1){
  __shared__ ushortt Tl[64][68];
  int zb = blockIdx.z; int b = zb >> 1; int mode = zb & 1;
  int d0 = blockIdx.y*64;
  int di = threadIdx.x&63, q = threadIdx.x>>6;
  if (mode == 0){
    int p0 = blockIdx.x*64;
    for (int k2=0;k2<16;k2++){ int pi = q*16 + k2;
      Tl[pi][di] = Xpab[((size_t)b*LL + p0+pi)*256 + d0+di]; }
    __syncthreads();
    for (int k2=0;k2<16;k2++){ int dr = q*16 + k2;
      Xpt0[((size_t)(b*256 + d0+dr))*LL + p0+di] = Tl[di][dr]; }
  } else {
    int ww = blockIdx.x;
    for (int k2=0;k2<16;k2++){ int hh = q*16 + k2;
      Tl[hh][di] = Xpab[((size_t)b*LL + hh*128 + ww)*256 + d0+di]; }
    __syncthreads();
    for (int k2=0;k2<16;k2++){ int dr = q*16 + k2;
      Xpt1[((size_t)(b*256 + d0+dr))*LL + ww*64 + di] = Tl[di][dr]; }
  }
}

// ---------------- x_proj: per-token 4x40 projections, written in scan order ----------------
// DBC row layout (96B per (b,k,t)): [0..31] 8x f32 dts; [32+4j] bf16 B_j (low), C_j (high)
__global__ void k_xdbl(const ushortt* __restrict__ Xpab, const float* __restrict__ xpw,
                       char* __restrict__ DBCb){
  __shared__ float U[16][256];
  int tid = threadIdx.x;
  int blk = blockIdx.x;              // B*L/16 = 2048
  int b = blk >> 9;
  int p0 = (blk & 511) << 4;
  for (int i=tid;i<16*256;i+=256){ int tt=i>>8, d=i&255;
    U[tt][d] = bf2f(Xpab[((size_t)b*LL + p0+tt)*256 + d]); }
  __syncthreads();
  if (tid < 160){
    int k = tid/40, c = tid%40;
    const float* wr = xpw + ((size_t)k*40 + c)*256;
    float acc[16];
#pragma unroll
    for (int tt=0;tt<16;tt++) acc[tt]=0.f;
    for (int d=0;d<256;d++){
      float wv = wr[d];
#pragma unroll
      for (int tt=0;tt<16;tt++) acc[tt] += U[tt][d]*wv;
    }
    for (int tt=0;tt<16;tt++){
      int p = p0+tt; int hh=p>>7, ww=p&127;
      int t;
      if      (k==0) t = p;
      else if (k==1) t = (ww<<6)|hh;
      else if (k==2) t = LL-1-p;
      else           t = LL-1-((ww<<6)|hh);
      char* rowp = DBCb + ((size_t)(b*KD+k)*LL + t)*96;
      if (c < 8)       *(float*)(rowp + 4*c) = acc[tt];
      else if (c < 24) *(ushortt*)(rowp + 32 + 4*(c-8))  = f2bf(acc[tt]);
      else             *(ushortt*)(rowp + 34 + 4*(c-24)) = f2bf(acc[tt]);
    }
  }
}

// ---------------- Merged scan pass: from h=0, write y_local + h_out + sum(delta) ----------------
__global__ void k_scanM(const char* __restrict__ DBCb,
                        const ushortt* __restrict__ Xpt0, const ushortt* __restrict__ Xpt1,
                        const float* __restrict__ dtw_all, const float* __restrict__ dtb_all,
                        const float* __restrict__ A_logs,
                        float* __restrict__ Hbuf, float* __restrict__ Ssum,
                        ushortt* __restrict__ Y0, ushortt* __restrict__ Y1,
                        ushortt* __restrict__ Y2, ushortt* __restrict__ Y3){
  __shared__ float2 sdd[16][16];
  __shared__ float yt[16][16][17];   // [grp][step][state], +1 pad
  int tid = threadIdx.x;
  int grp = tid >> 4, lane = tid & 15;
  int gid = blockIdx.x*16 + grp;
  int c = gid & 15;
  int bkd = gid >> 4;
  int b = bkd >> 10, k = (bkd>>8)&3, d = bkd & 255;
  int kd = k*256+d;
  float dtw[8];
  { const float4* w4 = (const float4*)(dtw_all + (size_t)kd*8);
    float4 w0 = w4[0], w1 = w4[1];
    dtw[0]=w0.x; dtw[1]=w0.y; dtw[2]=w0.z; dtw[3]=w0.w;
    dtw[4]=w1.x; dtw[5]=w1.y; dtw[6]=w1.z; dtw[7]=w1.w; }
  float dtb  = dtb_all[kd];
  float Aval = -__expf(A_logs[(size_t)kd*16+lane]);
  const char* dbc = DBCb + (size_t)(b*KD+k)*LL*96;
  const ushortt* Up = ((k&1)?Xpt1:Xpt0) + ((size_t)(b*256+d))*LL;
  ushortt* Yk = (k==0?Y0 : k==1?Y1 : k==2?Y2 : Y3) + ((size_t)b*256 + d)*LL;
  float h = 0.f, Sacc = 0.f;
  int t0 = c*CH;
  for (int blk=0; blk<CH/16; ++blk){
    int tb = t0 + blk*16;
    int tme = tb + lane;
    const char* rowme = dbc + (size_t)tme*96;
    float4 q0 = *(const float4*)rowme;
    float4 q1 = *(const float4*)(rowme+16);
    float dsum = dtb + q0.x*dtw[0] + q0.y*dtw[1] + q0.z*dtw[2] + q0.w*dtw[3]
                     + q1.x*dtw[4] + q1.y*dtw[5] + q1.z*dtw[6] + q1.w*dtw[7];
    float delta = softplusf_(dsum);
    Sacc += delta;
    int ui = (k<2) ? tme : (LL-1-tme);
    float u = bf2f(Up[ui]);
    sdd[grp][lane] = make_float2(delta, delta*u);
    lds_fence();             // order sdd write vs cross-lane reads below
    const char* rowB = dbc + (size_t)tb*96 + 32 + 4*lane;
#pragma unroll
    for (int i=0;i<16;i++){
      float2 dd = sdd[grp][i];
      uintt w = *(const uintt*)(rowB + 96*i);
      float Bn = __uint_as_float(w<<16);
      float Cn = __uint_as_float(w & 0xffff0000u);
      float e = __expf(dd.x * Aval);
      h = e*h + dd.y*Bn;
      yt[grp][i][lane] = h*Cn;
    }
    lds_fence();             // order yt writes vs cross-lane yt reads
    float acc = 0.f;
#pragma unroll
    for (int n=0;n<16;n++) acc += yt[grp][lane][n];
    Yk[tme] = f2bf(acc);
    lds_fence();             // order yt reads vs next block's yt writes
  }
  Hbuf[(size_t)gid*16 + lane] = h;
  float Stot = rowsum16(Sacc);
  if (lane==0) Ssum[gid] = Stot;
}

// Pass B: serial over chunks; converts Hbuf (h_out) to h_start in place.
__global__ void k_scanB(const float* __restrict__ Ssum, float* __restrict__ Hbuf,
                        const float* __restrict__ A_logs){
  int idx = blockIdx.x*256 + threadIdx.x;  // bkd*16+n (65536)
  int n = idx & 15; int bkd = idx >> 4;
  int kd = ((bkd>>8)&3)*256 + (bkd&255);
  float Aval = -__expf(A_logs[(size_t)kd*16+n]);
  float h = 0.f;
  for (int c=0;c<NC;c++){
    size_t g = (size_t)bkd*NC + c;
    float hout = Hbuf[g*16+n];
    Hbuf[g*16+n] = h;
    h = __expf(Aval*Ssum[g])*h + hout;
  }
}

// Pass C': correction sweep. y(t) += sum_n C_n(t) * exp(A_n * S_incl(t)) * h0_n.
// lane = step owner; early-exit once decay kills remaining contributions.
__global__ void k_corr(const char* __restrict__ DBCb,
                       const float* __restrict__ dtw_all, const float* __restrict__ dtb_all,
                       const float* __restrict__ Hbuf,
                       ushortt* __restrict__ Y0, ushortt* __restrict__ Y1,
                       ushortt* __restrict__ Y2, ushortt* __restrict__ Y3){
  int tid = threadIdx.x;
  int grp = tid >> 4, lane = tid & 15;
  int gid = blockIdx.x*16 + grp;
  int c = gid & 15;
  if (c == 0) return;                 // h0 == 0 exactly
  int bkd = gid >> 4;
  int b = bkd >> 10, k = (bkd>>8)&3, d = bkd & 255;
  int kd = k*256+d;
  float h0[16];
  float hmax = 0.f;
#pragma unroll
  for (int n=0;n<16;n++){
    h0[n] = Hbuf[(size_t)gid*16 + n];
    hmax = fmaxf(hmax, fabsf(h0[n]));
  }
  float Sexit = 14.f + __logf(fmaxf(hmax, 1e-30f));
  if (0.f > Sexit) return;            // h0 negligible
  float dtw[8];
  { const float4* w4 = (const float4*)(dtw_all + (size_t)kd*8);
    float4 w0 = w4[0], w1 = w4[1];
    dtw[0]=w0.x; dtw[1]=w0.y; dtw[2]=w0.z; dtw[3]=w0.w;
    dtw[4]=w1.x; dtw[5]=w1.y; dtw[6]=w1.z; dtw[7]=w1.w; }
  float dtb  = dtb_all[kd];
  const char* dbc = DBCb + (size_t)(b*KD+k)*LL*96;
  ushortt* Yk = (k==0?Y0 : k==1?Y1 : k==2?Y2 : Y3) + ((size_t)b*256 + d)*LL;
  float S0 = 0.f;
  int t0 = c*CH;
  for (int blk=0; blk<CH/16; ++blk){
    int tme = t0 + blk*16 + lane;
    const char* rowme = dbc + (size_t)tme*96;
    float4 q0 = *(const float4*)rowme;
    float4 q1 = *(const float4*)(rowme+16);
    float dsum = dtb + q0.x*dtw[0] + q0.y*dtw[1] + q0.z*dtw[2] + q0.w*dtw[3]
                     + q1.x*dtw[4] + q1.y*dtw[5] + q1.z*dtw[6] + q1.w*dtw[7];
    float delta = softplusf_(dsum);
    // inclusive prefix sum over the 16-lane group
    float pre = delta;
#pragma unroll
    for (int o=1;o<16;o<<=1){
      float t = __shfl_up(pre, o, 16);
      if (lane >= o) pre += t;
    }
    float S = S0 + pre;
    float E = __expf(-S);
    // load C_0..15 of my step (high halves of 16 dwords at +32)
    const uint4* cr = (const uint4*)(rowme + 32);
    uint4 w0 = cr[0], w1 = cr[1], w2 = cr[2], w3 = cr[3];
    float p = E, acc = 0.f;
    uintt wd[16] = {w0.x,w0.y,w0.z,w0.w, w1.x,w1.y,w1.z,w1.w,
                    w2.x,w2.y,w2.z,w2.w, w3.x,w3.y,w3.z,w3.w};
#pragma unroll
    for (int n=0;n<16;n++){
      float Cn = __uint_as_float(wd[n] & 0xffff0000u);
      acc += Cn * h0[n] * p;
      p *= E;
    }
    float yv = bf2f(Yk[tme]);
    Yk[tme] = f2bf(yv + acc);
    S0 = __shfl(S, 15, 16);           // block total carry
    if (S0 > Sexit) break;            // uniform across group
  }
}

// ---------------- Gate: gather Y0..Y3 + u*sum(D), LN256, *silu(z) ----------------
__global__ void k_gate2(const ushortt* __restrict__ Y0, const ushortt* __restrict__ Y1,
                        const ushortt* __restrict__ Y2, const ushortt* __restrict__ Y3,
                        const ushortt* __restrict__ Xpt0, const float* __restrict__ Ds,
                        ushortt* __restrict__ Zg,
                        const float* __restrict__ g, const float* __restrict__ bt){
  __shared__ float ysum[32][257];
  __shared__ float Dl[256];
  int tid = threadIdx.x;
  int wwb = blockIdx.x;      // 0..3
  int hh  = blockIdx.y;      // 0..63
  int b   = blockIdx.z;
  if (tid < 256) Dl[tid] = Ds[tid] + Ds[256+tid] + Ds[512+tid] + Ds[768+tid];
  int ww0 = wwb*32;
  for (int it=0; it<32; ++it){
    int idx = it*256 + tid;
    int d = idx >> 5, tl = idx & 31;
    int ww = ww0 + tl;
    int p  = hh*128 + ww;
    size_t base = ((size_t)b*256 + d) << 13;
    int t1 = ww*64 + hh;
    float v = bf2f(Y0[base + p]) + bf2f(Y2[base + (LL-1) - p])
            + bf2f(Y1[base + t1]) + bf2f(Y3[base + (LL-1) - t1]);
    ysum[tl][d] = v;
  }
  __syncthreads();
  {
    int d = tid;
    if (d < 256){
      size_t ub = (((size_t)b*256 + d) << 13) + hh*128 + ww0;
      for (int tl=0; tl<32; ++tl){
        float u = bf2f(Xpt0[ub + tl]);
        ysum[tl][d] += Dl[d]*u;
      }
    }
  }
  __syncthreads();
  int wave = tid >> 6, lane = tid & 63;
  for (int tk = wave*8; tk < wave*8+8; ++tk){
    float v0 = ysum[tk][lane], v1 = ysum[tk][lane+64];
    float v2 = ysum[tk][lane+128], v3 = ysum[tk][lane+192];
    float s  = waveReduceSum(v0+v1+v2+v3);
    float s2 = waveReduceSum(v0*v0+v1*v1+v2*v2+v3*v3);
    float mean = s*(1.f/256.f);
    float var  = s2*(1.f/256.f) - mean*mean;
    float r = rsqrtf(var + 1e-5f);
    int p = hh*128 + ww0 + tk;
    size_t zb = (((size_t)b<<13) + p) << 8;
#pragma unroll
    for (int j=0;j<4;j++){
      int dd = lane + 64*j;
      float ln = (ysum[tk][dd]-mean)*r*g[dd] + bt[dd];
      float z = bf2f(Zg[zb + dd]);
      Zg[zb + dd] = f2bf(ln * siluf_(z));
    }
  }
}

// ---------------- De-interleave -> padded bf16 conv input + f32 residual ----------------
// P: [8][66][66][128] bf16 (img = im2*4+b), R: [8][64][64][128] f32
__global__ void k_deint2(const float* __restrict__ X, ushortt* __restrict__ P,
                         float* __restrict__ R){
  int c = threadIdx.x & 127;
  int xh = threadIdx.x >> 7;
  int x = blockIdx.x*2 + xh;
  int y = blockIdx.y; int b = blockIdx.z;
#pragma unroll
  for (int im2=0; im2<2; ++im2){
    int ww = 2*x + im2;
    float v = X[((size_t)b*LL + y*128 + ww)*128 + c];
    int im = im2*4 + b;
    P[(((size_t)im*66 + y+1)*66 + x+1)*128 + c] = f2bf(v);
    R[(((size_t)im*64 + y)*64 + x)*128 + c] = v;
  }
}

// ---------------- MFMA 3x3 conv 128->128 + BN (+res) + ReLU ----------------
template<int FINAL>
__global__ void k_mconv(const ushortt* __restrict__ I, const ushortt* __restrict__ Wt,
                        const float* __restrict__ g, const float* __restrict__ bb,
                        const float* __restrict__ mn, const float* __restrict__ vv,
                        const float* __restrict__ R, ushortt* __restrict__ Op,
                        float* __restrict__ Of){
  int nh = blockIdx.x;
  int y  = blockIdx.y;
  int im = blockIdx.z;
  int wv = threadIdx.x>>6, l = threadIdx.x&63;
  int ar = l&15, kg = l>>4;
  int x0 = wv*16;
  f32x4 acc[4];
#pragma unroll
  for (int i=0;i<4;i++){ acc[i][0]=0.f; acc[i][1]=0.f; acc[i][2]=0.f; acc[i][3]=0.f; }
  const ushortt* Ibase = I + (((size_t)im*66 + y)*66 + x0 + ar)*128 + kg*8;
  const ushortt* Wbase = Wt + (size_t)(nh*64 + ar)*128 + kg*8;
#pragma unroll
  for (int tap=0; tap<9; ++tap){
    int dy = tap/3, dx = tap - dy*3;
    const ushortt* Ir = Ibase + ((size_t)dy*66 + dx)*128;
    const ushortt* Wr = Wbase + (size_t)tap*16384;
#pragma unroll
    for (int kc=0;kc<4;kc++){
      bf16x8 af = *(const bf16x8*)(Ir + kc*32);
#pragma unroll
      for (int nf=0;nf<4;nf++){
        bf16x8 bfv = *(const bf16x8*)(Wr + (size_t)nf*16*128 + kc*32);
        acc[nf] = __builtin_amdgcn_mfma_f32_16x16x32_bf16(af, bfv, acc[nf], 0,0,0);
      }
    }
  }
#pragma unroll
  for (int nf=0;nf<4;nf++){
    int co = nh*64 + nf*16 + ar;
    float s  = g[co]*rsqrtf(vv[co]+1e-5f);
    float sh = bb[co] - mn[co]*s;
#pragma unroll
    for (int r=0;r<4;r++){
      int x = x0 + kg*4 + r;
      float v = acc[nf][r]*s + sh;
      if (FINAL){
        v += R[(((size_t)im*64 + y)*64 + x)*128 + co];
        v = fmaxf(v, 0.f);
        Of[(((size_t)im*128 + co)*64 + y)*64 + x] = v;
      } else {
        v = fmaxf(v, 0.f);
        Op[(((size_t)im*66 + (y+1))*66 + (x+1))*128 + co] = f2bf(v);
      }
    }
  }
}

extern "C" void kernel_launch(void* const* d_in, const int* in_sizes, int n_in,
                              void* d_out, int out_size, void* d_ws, size_t ws_size,
                              hipStream_t stream){
  const float* x1        = (const float*)d_in[0];
  const float* x2        = (const float*)d_in[1];
  const float* conv_in_w = (const float*)d_in[2];
  const float* conv_in_b = (const float*)d_in[3];
  const float* ln1_g     = (const float*)d_in[4];
  const float* ln1_b     = (const float*)d_in[5];
  const float* in_proj_w = (const float*)d_in[6];
  const float* dw_w      = (const float*)d_in[7];
  const float* dw_b      = (const float*)d_in[8];
  const float* x_proj_w  = (const float*)d_in[9];
  const float* dt_proj_w = (const float*)d_in[10];
  const float* dt_proj_b = (const float*)d_in[11];
  const float* A_logs    = (const float*)d_in[12];
  const float* Ds        = (const float*)d_in[13];
  const float* onorm_g   = (const float*)d_in[14];
  const float* onorm_b   = (const float*)d_in[15];
  const float* out_proj_w= (const float*)d_in[16];
  const float* ln2_g     = (const float*)d_in[17];
  const float* ln2_b     = (const float*)d_in[18];
  const float* mlp_w1    = (const float*)d_in[19];
  const float* mlp_b1    = (const float*)d_in[20];
  const float* mlp_w2    = (const float*)d_in[21];
  const float* mlp_b2    = (const float*)d_in[22];
  const float* rb1_w     = (const float*)d_in[23];
  const float* bn1_g     = (const float*)d_in[24];
  const float* bn1_b     = (const float*)d_in[25];
  const float* bn1_m     = (const float*)d_in[26];
  const float* bn1_v     = (const float*)d_in[27];
  const float* rb2_w     = (const float*)d_in[28];
  const float* bn2_g     = (const float*)d_in[29];
  const float* bn2_b     = (const float*)d_in[30];
  const float* bn2_m     = (const float*)d_in[31];
  const float* bn2_v     = (const float*)d_in[32];

  float* ws = (float*)d_ws;
  char*  wsB = (char*)d_ws;
  const size_t FM = 262144;            // floats per MiB
  const size_t MB = 1048576;           // bytes per MiB
  // Workspace layout (peak 147.1 MiB, proven available):
  float*   X0   = ws;                          // 0-16    residual stream (B,L,128) f32
  ushortt* Xpab = (ushortt*)(wsB + 16*MB);     // 16-32   u post-dw-silu (B,L,256) bf16
  ushortt* Xpt0 = (ushortt*)(wsB + 32*MB);     // 32-48   u raster-order [b][d][p]
  ushortt* Xpt1 = (ushortt*)(wsB + 48*MB);     // 48-64   u colmajor-order [b][d][t1]
  char*    DBCb = wsB + 64*MB;                 // 64-77   scan rows 96B
  ushortt* Zg   = (ushortt*)(wsB + 77*MB);     // 77-93   z / gated bf16
  ushortt* Y0   = (ushortt*)(wsB + 93*MB);     // 93-109
  ushortt* Y1   = (ushortt*)(wsB + 109*MB);    // 109-125
  ushortt* Y2   = (ushortt*)(wsB + 125*MB);    // 125-141
  ushortt* Y3   = Xpab;                        // alias (Xpab dead before scanM)
  float*   Hbuf = ws + 141*FM;                 // 141-145
  float*   Ssum = ws + 145*FM;                 // 145-145.25
  // time-disjoint aliases:
  ushortt* CT   = (ushortt*)(wsB + 93*MB);     // steps 1-2 (over Y0)
  ushortt* Lnb  = (ushortt*)(wsB + 101*MB);    // steps 3-4 (over Y0 2nd half)
  float*   Abuf = ws + 109*FM;                 // steps 4-5 (over Y1,Y2) xp pre-dw f32
  ushortt* Ln2b = (ushortt*)(wsB + 93*MB);     // steps 10-11 (Y0 dead)
  ushortt* H1   = (ushortt*)(wsB + 109*MB);    // steps 11-12 (Y1,Y2 dead)
  ushortt* P    = (ushortt*)(wsB + 16*MB);     // step 13+ padded conv input [8][66][66][128]
  ushortt* T    = (ushortt*)(wsB + 25*MB);     // conv1 out padded
  float*   R    = (float*)(wsB + 34*MB);       // 34-51 residual [8][64][64][128] f32
  // bf16 weights (persistent, never aliased):
  ushortt* cw  = (ushortt*)(wsB + 146*MB);           // 32 KB
  ushortt* ipw = (ushortt*)(wsB + 146*MB + 32*1024); // 128 KB
  ushortt* opw = (ushortt*)(wsB + 146*MB + 160*1024);// 64 KB
  ushortt* m1w = (ushortt*)(wsB + 146*MB + 224*1024);// 128 KB
  ushortt* m2w = (ushortt*)(wsB + 146*MB + 352*1024);// 128 KB
  ushortt* rw1 = (ushortt*)(wsB + 146*MB + 480*1024);// 288 KB
  ushortt* rw2 = (ushortt*)(wsB + 146*MB + 768*1024);// 288 KB
  float* out = (float*)d_out;

  // 0. all weight conversions (one launch)
  k_wall<<<2112,256,0,stream>>>(conv_in_w,cw, in_proj_w,ipw, out_proj_w,opw,
                                mlp_w1,m1w, mlp_w2,m2w, rb1_w,rw1, rb2_w,rw2);
  // 1. interleave -> CT bf16 token-major
  k_build_ct2<<<512,256,0,stream>>>(x1,x2,CT);
  // 2. conv_in 1x1 (bias) -> X0 f32
  k_mgemm<0><<<dim3(2,512),256,0,stream>>>(CT, cw, conv_in_b, nullptr, X0, nullptr, 128,128);
  // 3. LN1 -> bf16
  k_ln128b<<<BB*LL,128,0,stream>>>(X0, ln1_g, ln1_b, Lnb);
  // 4. in_proj (512) -> split xp(Abuf f32) / z(Zg bf16)
  k_mgemm<3><<<dim3(8,512),256,0,stream>>>(Lnb, ipw, nullptr, nullptr, Abuf, Zg, 512,128);
  // 5. depthwise 3x3 + silu -> Xpab bf16
  k_dwconv<<<BB*LL,256,0,stream>>>(Abuf, dw_w, dw_b, Xpab);
  // 5b. direction-ordered u copies (merged)
  k_xtm<<<dim3(128,4,2*BB),256,0,stream>>>(Xpab, Xpt0, Xpt1);
  // 6. x_proj -> DBC
  k_xdbl<<<2048,256,0,stream>>>(Xpab, x_proj_w, DBCb);
  // 7. chunked selective scan: merged main pass + chain + correction
  k_scanM<<<4096,256,0,stream>>>(DBCb, Xpt0, Xpt1, dt_proj_w, dt_proj_b, A_logs,
                                 Hbuf, Ssum, Y0,Y1,Y2,Y3);
  k_scanB<<<256,256,0,stream>>>(Ssum, Hbuf, A_logs);
  k_corr<<<4096,256,0,stream>>>(DBCb, dt_proj_w, dt_proj_b, Hbuf, Y0,Y1,Y2,Y3);
  // 8. gate
  k_gate2<<<dim3(4,64,BB),256,0,stream>>>(Y0,Y1,Y2,Y3, Xpt0, Ds, Zg, onorm_g, onorm_b);
  // 9. out_proj + residual -> X0
  k_mgemm<1><<<dim3(2,512),256,0,stream>>>(Zg, opw, nullptr, X0, X0, nullptr, 128,256);
  // 10. LN2 -> bf16
  k_ln128b<<<BB*LL,128,0,stream>>>(X0, ln2_g, ln2_b, Ln2b);
  // 11. MLP1 gelu -> H1 bf16
  k_mgemm<2><<<dim3(8,512),256,0,stream>>>(Ln2b, m1w, mlp_b1, nullptr, nullptr, H1, 512,128);
  // 12. MLP2 + bias + residual -> X0
  k_mgemm<1><<<dim3(2,512),256,0,stream>>>(H1, m2w, mlp_b2, X0, X0, nullptr, 128,512);
  // 13. zero padded conv buffers (P and T), then de-interleave
  hipMemsetAsync(wsB + 16*MB, 0, 18*MB, stream);
  k_deint2<<<dim3(32,64,BB),256,0,stream>>>(X0, P, R);
  // 14-15. resblocks (both images batched, img = im2*4 + b)
  k_mconv<0><<<dim3(2,64,8),256,0,stream>>>(P, rw1, bn1_g,bn1_b,bn1_m,bn1_v, nullptr, T, nullptr);
  k_mconv<1><<<dim3(2,64,8),256,0,stream>>>(T, rw2, bn2_g,bn2_b,bn2_m,bn2_v, R, nullptr, out);
}

// Round 8
// 890.396 us; speedup vs baseline: 11.9543x; 1.0509x over previous
//
#include <hip/hip_runtime.h>
#include <math.h>

// Problem constants
#define BB 4
#define CM 128      // d_model
#define DI 256      // d_inner
#define NS 16       // d_state
#define RK 8        // dt_rank
#define KD 4        // K directions
#define HH 64
#define WW 128      // interleaved width
#define LL 8192     // HH*WW
#define NC 16       // scan chunks per sequence
#define CH 512      // chunk length (NC*CH == LL)

typedef unsigned short ushortt;
typedef unsigned int uintt;
typedef __attribute__((ext_vector_type(8))) __bf16 bf16x8;
typedef __attribute__((ext_vector_type(4))) float f32x4;

__device__ __forceinline__ void lds_fence(){
  asm volatile("" ::: "memory");
  __builtin_amdgcn_sched_barrier(0);
}

__device__ __forceinline__ float sigmoidf_(float x){ return 1.f/(1.f+__expf(-x)); }
__device__ __forceinline__ float siluf_(float x){ return x*sigmoidf_(x); }
__device__ __forceinline__ float softplusf_(float x){
  float r = __logf(1.f + __expf(x));   // fast path, no libcall
  return (x > 20.f) ? x : r;
}
__device__ __forceinline__ float geluf_(float x){ return 0.5f*x*(1.f+erff(x*0.70710678118654752f)); }
__device__ __forceinline__ float waveReduceSum(float v){
  for (int o=32;o>0;o>>=1) v += __shfl_xor(v,o,64);
  return v;
}
__device__ __forceinline__ ushortt f2bf(float f){
  uintt u = __float_as_uint(f);
  uintt r = (u + 0x7fffu + ((u>>16)&1u)) >> 16;
  return (ushortt)r;
}
__device__ __forceinline__ float bf2f(ushortt s){
  return __uint_as_float(((uintt)s)<<16);
}
template<int CTRL>
__device__ __forceinline__ float dppadd(float x){
  int r = __builtin_amdgcn_update_dpp(0, __float_as_int(x), CTRL, 0xF, 0xF, true);
  return x + __int_as_float(r);
}
// full sum over each 16-lane row; result on all lanes
__device__ __forceinline__ float rowsum16(float x){
  x = dppadd<0x121>(x);  // row_ror:1
  x = dppadd<0x122>(x);  // row_ror:2
  x = dppadd<0x124>(x);  // row_ror:4
  x = dppadd<0x128>(x);  // row_ror:8
  return x;
}

// ---------------- merged weight conversions (1 launch) ----------------
__global__ void k_wall(const float* __restrict__ cw_s, ushortt* __restrict__ cw_d,
                       const float* __restrict__ ip_s, ushortt* __restrict__ ip_d,
                       const float* __restrict__ op_s, ushortt* __restrict__ op_d,
                       const float* __restrict__ m1_s, ushortt* __restrict__ m1_d,
                       const float* __restrict__ m2_s, ushortt* __restrict__ m2_d,
                       const float* __restrict__ r1_s, ushortt* __restrict__ r1_d,
                       const float* __restrict__ r2_s, ushortt* __restrict__ r2_d){
  int i = blockIdx.x*256 + threadIdx.x;
  if (i < 16384){ cw_d[i] = f2bf(cw_s[i]); return; }
  i -= 16384;
  if (i < 65536){ ip_d[i] = f2bf(ip_s[i]); return; }
  i -= 65536;
  if (i < 32768){ op_d[i] = f2bf(op_s[i]); return; }
  i -= 32768;
  if (i < 65536){ m1_d[i] = f2bf(m1_s[i]); return; }
  i -= 65536;
  if (i < 65536){ m2_d[i] = f2bf(m2_s[i]); return; }
  i -= 65536;
  if (i < 147456){ int ci=i&127, co=(i>>7)&127, tap=i>>14;
    r1_d[i]=f2bf(r1_s[(size_t)(co*128+ci)*9+tap]); return; }
  i -= 147456;
  if (i < 147456){ int ci=i&127, co=(i>>7)&127, tap=i>>14;
    r2_d[i]=f2bf(r2_s[(size_t)(co*128+ci)*9+tap]); }
}

// ---------------- CT build: interleave x1/x2 -> token-major bf16 (B*L, 128) ----------------
__global__ void k_build_ct2(const float* __restrict__ x1, const float* __restrict__ x2,
                            ushortt* __restrict__ CT){
  __shared__ ushortt Tl[64][136];
  int tid = threadIdx.x;
  int p0 = (blockIdx.x & 127) * 64;
  int b  = blockIdx.x >> 7;
  int j = tid & 63;
  int p = p0 + j; int hh = p>>7, ww = p&127, w2 = ww>>1;
  const float* src = (ww&1) ? x2 : x1;
  const float* sp = src + ((size_t)b*128*64 + hh)*64 + w2;
  for (int c0 = tid>>6; c0 < 128; c0 += 4)
    Tl[j][c0] = f2bf(sp[(size_t)c0*4096]);
  __syncthreads();
  int c = tid & 127; int rh = tid >> 7;
  for (int r = rh; r < 64; r += 2)
    CT[((size_t)b*LL + p0 + r)*128 + c] = Tl[r][c];
}

// ---------------- MFMA token GEMM ----------------
// A: [32768][K] bf16, W: [N][K] bf16; grid (N/64, 512), block 256 (4 waves).
// EPI 0: (+bias) f32 C ; 1: (+bias)+resid f32 C ; 2: +bias,gelu -> bf16 C2 (stride 512)
// EPI 3: split n<256 -> f32 C (stride 256), else bf16 C2 (stride 256)
// EPI 4: +bias+resid -> fused de-interleave: P (padded bf16) + R (f32), N=128
template<int EPI>
__global__ void k_mgemm(const ushortt* __restrict__ A, const ushortt* __restrict__ W,
                        const float* __restrict__ bias, const float* __restrict__ resid,
                        float* __restrict__ C, ushortt* __restrict__ C2,
                        ushortt* __restrict__ Pp, float* __restrict__ Rp, int N, int K){
  int n0 = blockIdx.x*64, m0 = blockIdx.y*64;
  int wv = threadIdx.x>>6, l = threadIdx.x&63;
  int ar = l&15, kg = l>>4;
  int mw = m0 + wv*16;
  f32x4 acc[4];
#pragma unroll
  for (int i=0;i<4;i++){ acc[i][0]=0.f; acc[i][1]=0.f; acc[i][2]=0.f; acc[i][3]=0.f; }
  const ushortt* Ap = A + (size_t)(mw+ar)*K + kg*8;
  const ushortt* Wp = W + (size_t)(n0+ar)*K + kg*8;
  for (int k0=0; k0<K; k0+=32){
    bf16x8 af = *(const bf16x8*)(Ap + k0);
#pragma unroll
    for (int nf=0; nf<4; ++nf){
      bf16x8 bfv = *(const bf16x8*)(Wp + (size_t)nf*16*K + k0);
      acc[nf] = __builtin_amdgcn_mfma_f32_16x16x32_bf16(af, bfv, acc[nf], 0,0,0);
    }
  }
#pragma unroll
  for (int nf=0;nf<4;nf++){
    int n = n0 + nf*16 + ar;
#pragma unroll
    for (int r=0;r<4;r++){
      int m = mw + kg*4 + r;
      float v = acc[nf][r];
      if (EPI==0 || EPI==1){
        if (bias) v += bias[n];
        if (EPI==1) v += resid[(size_t)m*N + n];
        C[(size_t)m*N + n] = v;
      } else if (EPI==2){
        v += bias[n];
        C2[(size_t)m*512 + n] = f2bf(geluf_(v));
      } else if (EPI==3){
        if (n < 256) C[(size_t)m*256 + n] = v;
        else         C2[(size_t)m*256 + (n-256)] = f2bf(v);
      } else { // EPI==4
        v += bias[n];
        v += resid[(size_t)m*128 + n];
        int bq = m >> 13; int pq = m & 8191; int yq = pq >> 7; int wq = pq & 127;
        int im = (wq&1)*4 + bq; int xq = wq>>1;
        Pp[(((size_t)im*66 + yq+1)*66 + xq+1)*128 + n] = f2bf(v);
        Rp[(((size_t)im*64 + yq)*64 + xq)*128 + n] = v;
      }
    }
  }
}

// ---------------- LayerNorm over 128 channels -> bf16 ----------------
__global__ void k_ln128b(const float* __restrict__ X, const float* __restrict__ g,
                         const float* __restrict__ bt, ushortt* __restrict__ O){
  int tok = blockIdx.x, tid = threadIdx.x;
  float x = X[(size_t)tok*128 + tid];
  float s  = waveReduceSum(x);
  float s2 = waveReduceSum(x*x);
  __shared__ float a[2], a2[2];
  if ((tid&63)==0){ a[tid>>6]=s; a2[tid>>6]=s2; }
  __syncthreads();
  float mean = (a[0]+a[1])*(1.f/128.f);
  float var  = (a2[0]+a2[1])*(1.f/128.f) - mean*mean;
  float r = rsqrtf(var + 1e-5f);
  O[(size_t)tok*128+tid] = f2bf((x-mean)*r*g[tid] + bt[tid]);
}

// ---------------- Depthwise 3x3 + bias + SiLU, channel-last (B,L,256) -> bf16 ----------------
__global__ void k_dwconv(const float* __restrict__ Xp, const float* __restrict__ w,
                         const float* __restrict__ bias, ushortt* __restrict__ O){
  int tok = blockIdx.x; int d = threadIdx.x;
  int b = tok >> 13; int p = tok & (LL-1); int hh = p>>7, ww = p&127;
  float acc = bias[d];
#pragma unroll
  for (int dy=0;dy<3;dy++){
    int yy = hh+dy-1; if (yy<0||yy>=HH) continue;
#pragma unroll
    for (int dx=0;dx<3;dx++){
      int xx = ww+dx-1; if (xx<0||xx>=WW) continue;
      acc += Xp[((size_t)b*LL + yy*WW + xx)*256 + d] * w[d*9 + dy*3 + dx];
    }
  }
  O[(size_t)tok*256 + d] = f2bf(siluf_(acc));
}

// ---------------- merged transposes: Xpab[b][p][d] -> Xpt0 (raster) / Xpt1 (colmajor) ----------------
__global__ void k_xtm(const ushortt* __restrict__ Xpab, ushortt* __restrict__ Xpt0,
                      ushortt* __restrict__ Xpt1){
  __shared__ ushortt Tl[64][68];
  int zb = blockIdx.z; int b = zb >> 1; int mode = zb & 1;
  int d0 = blockIdx.y*64;
  int di = threadIdx.x&63, q = threadIdx.x>>6;
  if (mode == 0){
    int p0 = blockIdx.x*64;
    for (int k2=0;k2<16;k2++){ int pi = q*16 + k2;
      Tl[pi][di] = Xpab[((size_t)b*LL + p0+pi)*256 + d0+di]; }
    __syncthreads();
    for (int k2=0;k2<16;k2++){ int dr = q*16 + k2;
      Xpt0[((size_t)(b*256 + d0+dr))*LL + p0+di] = Tl[di][dr]; }
  } else {
    int ww = blockIdx.x;
    for (int k2=0;k2<16;k2++){ int hh = q*16 + k2;
      Tl[hh][di] = Xpab[((size_t)b*LL + hh*128 + ww)*256 + d0+di]; }
    __syncthreads();
    for (int k2=0;k2<16;k2++){ int dr = q*16 + k2;
      Xpt1[((size_t)(b*256 + d0+dr))*LL + ww*64 + di] = Tl[di][dr]; }
  }
}

// ---------------- x_proj: per-token 4x40 projections, written in scan order ----------------
// DBC row layout (96B per (b,k,t)): [0..31] 8x f32 dts; [32+4j] bf16 B_j (low), C_j (high)
__global__ void k_xdbl(const ushortt* __restrict__ Xpab, const float* __restrict__ xpw,
                       char* __restrict__ DBCb){
  __shared__ float U[16][256];
  int tid = threadIdx.x;
  int blk = blockIdx.x;              // B*L/16 = 2048
  int b = blk >> 9;
  int p0 = (blk & 511) << 4;
  for (int i=tid;i<16*256;i+=256){ int tt=i>>8, d=i&255;
    U[tt][d] = bf2f(Xpab[((size_t)b*LL + p0+tt)*256 + d]); }
  __syncthreads();
  if (tid < 160){
    int k = tid/40, c = tid%40;
    const float* wr = xpw + ((size_t)k*40 + c)*256;
    float acc[16];
#pragma unroll
    for (int tt=0;tt<16;tt++) acc[tt]=0.f;
    for (int d=0;d<256;d++){
      float wv = wr[d];
#pragma unroll
      for (int tt=0;tt<16;tt++) acc[tt] += U[tt][d]*wv;
    }
    for (int tt=0;tt<16;tt++){
      int p = p0+tt; int hh=p>>7, ww=p&127;
      int t;
      if      (k==0) t = p;
      else if (k==1) t = (ww<<6)|hh;
      else if (k==2) t = LL-1-p;
      else           t = LL-1-((ww<<6)|hh);
      char* rowp = DBCb + ((size_t)(b*KD+k)*LL + t)*96;
      if (c < 8)       *(float*)(rowp + 4*c) = acc[tt];
      else if (c < 24) *(ushortt*)(rowp + 32 + 4*(c-8))  = f2bf(acc[tt]);
      else             *(ushortt*)(rowp + 34 + 4*(c-24)) = f2bf(acc[tt]);
    }
  }
}

// ---------------- Merged scan pass: from h=0, write y_local + h_out + sum(delta) ----------------
// 128 threads = 8 groups of 16 lanes; small LDS for full occupancy.
__global__ __launch_bounds__(128) void k_scanM(const char* __restrict__ DBCb,
                        const ushortt* __restrict__ Xpt0, const ushortt* __restrict__ Xpt1,
                        const float* __restrict__ dtw_all, const float* __restrict__ dtb_all,
                        const float* __restrict__ A_logs,
                        float* __restrict__ Hbuf, float* __restrict__ Ssum,
                        ushortt* __restrict__ Y0, ushortt* __restrict__ Y1,
                        ushortt* __restrict__ Y2, ushortt* __restrict__ Y3){
  __shared__ float2 sdd[8][16];
  __shared__ float yt[8][16][17];   // [grp][step][state], +1 pad
  int tid = threadIdx.x;
  int grp = tid >> 4, lane = tid & 15;
  int gid = blockIdx.x*8 + grp;
  int c = gid & 15;
  int bkd = gid >> 4;
  int b = bkd >> 10, k = (bkd>>8)&3, d = bkd & 255;
  int kd = k*256+d;
  float dtw[8];
  { const float4* w4 = (const float4*)(dtw_all + (size_t)kd*8);
    float4 w0 = w4[0], w1 = w4[1];
    dtw[0]=w0.x; dtw[1]=w0.y; dtw[2]=w0.z; dtw[3]=w0.w;
    dtw[4]=w1.x; dtw[5]=w1.y; dtw[6]=w1.z; dtw[7]=w1.w; }
  float dtb  = dtb_all[kd];
  float Aval = -__expf(A_logs[(size_t)kd*16+lane]);
  const char* dbc = DBCb + (size_t)(b*KD+k)*LL*96;
  const ushortt* Up = ((k&1)?Xpt1:Xpt0) + ((size_t)(b*256+d))*LL;
  ushortt* Yk = (k==0?Y0 : k==1?Y1 : k==2?Y2 : Y3) + ((size_t)b*256 + d)*LL;
  float h = 0.f, Sacc = 0.f;
  int t0 = c*CH;
  // prefetch block 0
  const char* row0 = dbc + (size_t)(t0+lane)*96;
  float4 q0 = *(const float4*)row0;
  float4 q1 = *(const float4*)(row0+16);
  ushortt ur = Up[(k<2) ? (t0+lane) : (LL-1-(t0+lane))];
  for (int blk=0; blk<CH/16; ++blk){
    int tb = t0 + blk*16;
    int tme = tb + lane;
    float4 c0 = q0, c1 = q1; ushortt cu = ur;
    if (blk+1 < CH/16){
      const char* rn = dbc + (size_t)(tme+16)*96;
      q0 = *(const float4*)rn;
      q1 = *(const float4*)(rn+16);
      ur = Up[(k<2) ? (tme+16) : (LL-1-(tme+16))];
    }
    float dsum = dtb + c0.x*dtw[0] + c0.y*dtw[1] + c0.z*dtw[2] + c0.w*dtw[3]
                     + c1.x*dtw[4] + c1.y*dtw[5] + c1.z*dtw[6] + c1.w*dtw[7];
    float delta = softplusf_(dsum);
    Sacc += delta;
    float u = bf2f(cu);
    sdd[grp][lane] = make_float2(delta, delta*u);
    lds_fence();             // order sdd write vs cross-lane reads below
    const char* rowB = dbc + (size_t)tb*96 + 32 + 4*lane;
#pragma unroll
    for (int i=0;i<16;i++){
      float2 dd = sdd[grp][i];
      uintt w = *(const uintt*)(rowB + 96*i);
      float Bn = __uint_as_float(w<<16);
      float Cn = __uint_as_float(w & 0xffff0000u);
      float e = __expf(dd.x * Aval);
      h = e*h + dd.y*Bn;
      yt[grp][i][lane] = h*Cn;
    }
    lds_fence();             // order yt writes vs cross-lane yt reads
    float acc = 0.f;
#pragma unroll
    for (int n=0;n<16;n++) acc += yt[grp][lane][n];
    Yk[tme] = f2bf(acc);
    lds_fence();             // order yt reads vs next block's yt writes
  }
  Hbuf[(size_t)gid*16 + lane] = h;
  float Stot = rowsum16(Sacc);
  if (lane==0) Ssum[gid] = Stot;
}

// Pass B: serial over chunks; converts Hbuf (h_out) to h_start in place.
__global__ void k_scanB(const float* __restrict__ Ssum, float* __restrict__ Hbuf,
                        const float* __restrict__ A_logs){
  int idx = blockIdx.x*256 + threadIdx.x;  // bkd*16+n (65536)
  int n = idx & 15; int bkd = idx >> 4;
  int kd = ((bkd>>8)&3)*256 + (bkd&255);
  float Aval = -__expf(A_logs[(size_t)kd*16+n]);
  float h = 0.f;
  for (int c=0;c<NC;c++){
    size_t g = (size_t)bkd*NC + c;
    float hout = Hbuf[g*16+n];
    Hbuf[g*16+n] = h;
    h = __expf(Aval*Ssum[g])*h + hout;
  }
}

// Pass C': correction sweep. y(t) += sum_n C_n(t) * exp(A_n * S_incl(t)) * h0_n.
// lane = step owner; early-exit once decay kills remaining contributions.
__global__ __launch_bounds__(128) void k_corr(const char* __restrict__ DBCb,
                       const float* __restrict__ dtw_all, const float* __restrict__ dtb_all,
                       const float* __restrict__ Hbuf,
                       ushortt* __restrict__ Y0, ushortt* __restrict__ Y1,
                       ushortt* __restrict__ Y2, ushortt* __restrict__ Y3){
  int tid = threadIdx.x;
  int grp = tid >> 4, lane = tid & 15;
  int gid = blockIdx.x*8 + grp;
  int c = gid & 15;
  if (c == 0) return;                 // h0 == 0 exactly
  int bkd = gid >> 4;
  int b = bkd >> 10, k = (bkd>>8)&3, d = bkd & 255;
  int kd = k*256+d;
  float h0[16];
  float hmax = 0.f;
#pragma unroll
  for (int n=0;n<16;n++){
    h0[n] = Hbuf[(size_t)gid*16 + n];
    hmax = fmaxf(hmax, fabsf(h0[n]));
  }
  float Sexit = 14.f + __logf(fmaxf(hmax, 1e-30f));
  if (0.f > Sexit) return;            // h0 negligible
  float dtw[8];
  { const float4* w4 = (const float4*)(dtw_all + (size_t)kd*8);
    float4 w0 = w4[0], w1 = w4[1];
    dtw[0]=w0.x; dtw[1]=w0.y; dtw[2]=w0.z; dtw[3]=w0.w;
    dtw[4]=w1.x; dtw[5]=w1.y; dtw[6]=w1.z; dtw[7]=w1.w; }
  float dtb  = dtb_all[kd];
  const char* dbc = DBCb + (size_t)(b*KD+k)*LL*96;
  ushortt* Yk = (k==0?Y0 : k==1?Y1 : k==2?Y2 : Y3) + ((size_t)b*256 + d)*LL;
  float S0 = 0.f;
  int t0 = c*CH;
  for (int blk=0; blk<CH/16; ++blk){
    int tme = t0 + blk*16 + lane;
    const char* rowme = dbc + (size_t)tme*96;
    float4 q0 = *(const float4*)rowme;
    float4 q1 = *(const float4*)(rowme+16);
    float dsum = dtb + q0.x*dtw[0] + q0.y*dtw[1] + q0.z*dtw[2] + q0.w*dtw[3]
                     + q1.x*dtw[4] + q1.y*dtw[5] + q1.z*dtw[6] + q1.w*dtw[7];
    float delta = softplusf_(dsum);
    // inclusive prefix sum over the 16-lane group
    float pre = delta;
#pragma unroll
    for (int o=1;o<16;o<<=1){
      float t = __shfl_up(pre, o, 16);
      if (lane >= o) pre += t;
    }
    float S = S0 + pre;
    float E = __expf(-S);
    // load C_0..15 of my step (high halves of 16 dwords at +32)
    const uint4* cr = (const uint4*)(rowme + 32);
    uint4 w0 = cr[0], w1 = cr[1], w2 = cr[2], w3 = cr[3];
    float p = E, acc = 0.f;
    uintt wd[16] = {w0.x,w0.y,w0.z,w0.w, w1.x,w1.y,w1.z,w1.w,
                    w2.x,w2.y,w2.z,w2.w, w3.x,w3.y,w3.z,w3.w};
#pragma unroll
    for (int n=0;n<16;n++){
      float Cn = __uint_as_float(wd[n] & 0xffff0000u);
      acc += Cn * h0[n] * p;
      p *= E;
    }
    float yv = bf2f(Yk[tme]);
    Yk[tme] = f2bf(yv + acc);
    S0 = __shfl(S, 15, 16);           // block total carry
    if (S0 > Sexit) break;            // uniform across group
  }
}

// ---------------- Gate: gather Y0..Y3 + u*sum(D), LN256, *silu(z) ----------------
__global__ void k_gate2(const ushortt* __restrict__ Y0, const ushortt* __restrict__ Y1,
                        const ushortt* __restrict__ Y2, const ushortt* __restrict__ Y3,
                        const ushortt* __restrict__ Xpt0, const float* __restrict__ Ds,
                        ushortt* __restrict__ Zg,
                        const float* __restrict__ g, const float* __restrict__ bt){
  __shared__ float ysum[32][257];
  __shared__ float Dl[256];
  int tid = threadIdx.x;
  int wwb = blockIdx.x;      // 0..3
  int hh  = blockIdx.y;      // 0..63
  int b   = blockIdx.z;
  if (tid < 256) Dl[tid] = Ds[tid] + Ds[256+tid] + Ds[512+tid] + Ds[768+tid];
  int ww0 = wwb*32;
  for (int it=0; it<32; ++it){
    int idx = it*256 + tid;
    int d = idx >> 5, tl = idx & 31;
    int ww = ww0 + tl;
    int p  = hh*128 + ww;
    size_t base = ((size_t)b*256 + d) << 13;
    int t1 = ww*64 + hh;
    float v = bf2f(Y0[base + p]) + bf2f(Y2[base + (LL-1) - p])
            + bf2f(Y1[base + t1]) + bf2f(Y3[base + (LL-1) - t1]);
    ysum[tl][d] = v;
  }
  __syncthreads();
  {
    int d = tid;
    if (d < 256){
      size_t ub = (((size_t)b*256 + d) << 13) + hh*128 + ww0;
      for (int tl=0; tl<32; ++tl){
        float u = bf2f(Xpt0[ub + tl]);
        ysum[tl][d] += Dl[d]*u;
      }
    }
  }
  __syncthreads();
  int wave = tid >> 6, lane = tid & 63;
  for (int tk = wave*8; tk < wave*8+8; ++tk){
    float v0 = ysum[tk][lane], v1 = ysum[tk][lane+64];
    float v2 = ysum[tk][lane+128], v3 = ysum[tk][lane+192];
    float s  = waveReduceSum(v0+v1+v2+v3);
    float s2 = waveReduceSum(v0*v0+v1*v1+v2*v2+v3*v3);
    float mean = s*(1.f/256.f);
    float var  = s2*(1.f/256.f) - mean*mean;
    float r = rsqrtf(var + 1e-5f);
    int p = hh*128 + ww0 + tk;
    size_t zb = (((size_t)b<<13) + p) << 8;
#pragma unroll
    for (int j=0;j<4;j++){
      int dd = lane + 64*j;
      float ln = (ysum[tk][dd]-mean)*r*g[dd] + bt[dd];
      float z = bf2f(Zg[zb + dd]);
      Zg[zb + dd] = f2bf(ln * siluf_(z));
    }
  }
}

// ---------------- MFMA 3x3 conv 128->128 + BN (+res) + ReLU ----------------
template<int FINAL>
__global__ void k_mconv(const ushortt* __restrict__ I, const ushortt* __restrict__ Wt,
                        const float* __restrict__ g, const float* __restrict__ bb,
                        const float* __restrict__ mn, const float* __restrict__ vv,
                        const float* __restrict__ R, ushortt* __restrict__ Op,
                        float* __restrict__ Of){
  int nh = blockIdx.x;
  int y  = blockIdx.y;
  int im = blockIdx.z;
  int wv = threadIdx.x>>6, l = threadIdx.x&63;
  int ar = l&15, kg = l>>4;
  int x0 = wv*16;
  f32x4 acc[4];
#pragma unroll
  for (int i=0;i<4;i++){ acc[i][0]=0.f; acc[i][1]=0.f; acc[i][2]=0.f; acc[i][3]=0.f; }
  const ushortt* Ibase = I + (((size_t)im*66 + y)*66 + x0 + ar)*128 + kg*8;
  const ushortt* Wbase = Wt + (size_t)(nh*64 + ar)*128 + kg*8;
#pragma unroll
  for (int tap=0; tap<9; ++tap){
    int dy = tap/3, dx = tap - dy*3;
    const ushortt* Ir = Ibase + ((size_t)dy*66 + dx)*128;
    const ushortt* Wr = Wbase + (size_t)tap*16384;
#pragma unroll
    for (int kc=0;kc<4;kc++){
      bf16x8 af = *(const bf16x8*)(Ir + kc*32);
#pragma unroll
      for (int nf=0;nf<4;nf++){
        bf16x8 bfv = *(const bf16x8*)(Wr + (size_t)nf*16*128 + kc*32);
        acc[nf] = __builtin_amdgcn_mfma_f32_16x16x32_bf16(af, bfv, acc[nf], 0,0,0);
      }
    }
  }
#pragma unroll
  for (int nf=0;nf<4;nf++){
    int co = nh*64 + nf*16 + ar;
    float s  = g[co]*rsqrtf(vv[co]+1e-5f);
    float sh = bb[co] - mn[co]*s;
#pragma unroll
    for (int r=0;r<4;r++){
      int x = x0 + kg*4 + r;
      float v = acc[nf][r]*s + sh;
      if (FINAL){
        v += R[(((size_t)im*64 + y)*64 + x)*128 + co];
        v = fmaxf(v, 0.f);
        Of[(((size_t)im*128 + co)*64 + y)*64 + x] = v;
      } else {
        v = fmaxf(v, 0.f);
        Op[(((size_t)im*66 + (y+1))*66 + (x+1))*128 + co] = f2bf(v);
      }
    }
  }
}

extern "C" void kernel_launch(void* const* d_in, const int* in_sizes, int n_in,
                              void* d_out, int out_size, void* d_ws, size_t ws_size,
                              hipStream_t stream){
  const float* x1        = (const float*)d_in[0];
  const float* x2        = (const float*)d_in[1];
  const float* conv_in_w = (const float*)d_in[2];
  const float* conv_in_b = (const float*)d_in[3];
  const float* ln1_g     = (const float*)d_in[4];
  const float* ln1_b     = (const float*)d_in[5];
  const float* in_proj_w = (const float*)d_in[6];
  const float* dw_w      = (const float*)d_in[7];
  const float* dw_b      = (const float*)d_in[8];
  const float* x_proj_w  = (const float*)d_in[9];
  const float* dt_proj_w = (const float*)d_in[10];
  const float* dt_proj_b = (const float*)d_in[11];
  const float* A_logs    = (const float*)d_in[12];
  const float* Ds        = (const float*)d_in[13];
  const float* onorm_g   = (const float*)d_in[14];
  const float* onorm_b   = (const float*)d_in[15];
  const float* out_proj_w= (const float*)d_in[16];
  const float* ln2_g     = (const float*)d_in[17];
  const float* ln2_b     = (const float*)d_in[18];
  const float* mlp_w1    = (const float*)d_in[19];
  const float* mlp_b1    = (const float*)d_in[20];
  const float* mlp_w2    = (const float*)d_in[21];
  const float* mlp_b2    = (const float*)d_in[22];
  const float* rb1_w     = (const float*)d_in[23];
  const float* bn1_g     = (const float*)d_in[24];
  const float* bn1_b     = (const float*)d_in[25];
  const float* bn1_m     = (const float*)d_in[26];
  const float* bn1_v     = (const float*)d_in[27];
  const float* rb2_w     = (const float*)d_in[28];
  const float* bn2_g     = (const float*)d_in[29];
  const float* bn2_b     = (const float*)d_in[30];
  const float* bn2_m     = (const float*)d_in[31];
  const float* bn2_v     = (const float*)d_in[32];

  float* ws = (float*)d_ws;
  char*  wsB = (char*)d_ws;
  const size_t FM = 262144;            // floats per MiB
  const size_t MB = 1048576;           // bytes per MiB
  // Workspace layout (peak 147.1 MiB, proven available):
  float*   X0   = ws;                          // 0-16    residual stream (B,L,128) f32
  ushortt* Xpab = (ushortt*)(wsB + 16*MB);     // 16-32   u post-dw-silu (B,L,256) bf16
  ushortt* Xpt0 = (ushortt*)(wsB + 32*MB);     // 32-48   u raster-order [b][d][p]
  ushortt* Xpt1 = (ushortt*)(wsB + 48*MB);     // 48-64   u colmajor-order [b][d][t1]
  char*    DBCb = wsB + 64*MB;                 // 64-77   scan rows 96B
  ushortt* Zg   = (ushortt*)(wsB + 77*MB);     // 77-93   z / gated bf16
  ushortt* Y0   = (ushortt*)(wsB + 93*MB);     // 93-109
  ushortt* Y1   = (ushortt*)(wsB + 109*MB);    // 109-125
  ushortt* Y2   = (ushortt*)(wsB + 125*MB);    // 125-141
  ushortt* Y3   = Xpab;                        // alias (Xpab dead before scanM)
  float*   Hbuf = ws + 141*FM;                 // 141-145
  float*   Ssum = ws + 145*FM;                 // 145-145.25
  // time-disjoint aliases:
  ushortt* CT   = (ushortt*)(wsB + 93*MB);     // steps 1-2 (over Y0)
  ushortt* Lnb  = (ushortt*)(wsB + 101*MB);    // steps 3-4 (over Y0 2nd half)
  float*   Abuf = ws + 109*FM;                 // steps 4-5 (over Y1,Y2) xp pre-dw f32
  ushortt* Ln2b = (ushortt*)(wsB + 93*MB);     // steps 10-11 (Y0 dead)
  ushortt* H1   = (ushortt*)(wsB + 109*MB);    // steps 11-12 (Y1,Y2 dead)
  ushortt* P    = (ushortt*)(wsB + 16*MB);     // step 12+ padded conv input [8][66][66][128]
  ushortt* T    = (ushortt*)(wsB + 25*MB);     // conv1 out padded
  float*   R    = (float*)(wsB + 34*MB);       // 34-51 residual [8][64][64][128] f32
  // bf16 weights (persistent, never aliased):
  ushortt* cw  = (ushortt*)(wsB + 146*MB);           // 32 KB
  ushortt* ipw = (ushortt*)(wsB + 146*MB + 32*1024); // 128 KB
  ushortt* opw = (ushortt*)(wsB + 146*MB + 160*1024);// 64 KB
  ushortt* m1w = (ushortt*)(wsB + 146*MB + 224*1024);// 128 KB
  ushortt* m2w = (ushortt*)(wsB + 146*MB + 352*1024);// 128 KB
  ushortt* rw1 = (ushortt*)(wsB + 146*MB + 480*1024);// 288 KB
  ushortt* rw2 = (ushortt*)(wsB + 146*MB + 768*1024);// 288 KB
  float* out = (float*)d_out;

  // 0. all weight conversions (one launch)
  k_wall<<<2112,256,0,stream>>>(conv_in_w,cw, in_proj_w,ipw, out_proj_w,opw,
                                mlp_w1,m1w, mlp_w2,m2w, rb1_w,rw1, rb2_w,rw2);
  // 1. interleave -> CT bf16 token-major
  k_build_ct2<<<512,256,0,stream>>>(x1,x2,CT);
  // 2. conv_in 1x1 (bias) -> X0 f32
  k_mgemm<0><<<dim3(2,512),256,0,stream>>>(CT, cw, conv_in_b, nullptr, X0, nullptr, nullptr,nullptr, 128,128);
  // 3. LN1 -> bf16
  k_ln128b<<<BB*LL,128,0,stream>>>(X0, ln1_g, ln1_b, Lnb);
  // 4. in_proj (512) -> split xp(Abuf f32) / z(Zg bf16)
  k_mgemm<3><<<dim3(8,512),256,0,stream>>>(Lnb, ipw, nullptr, nullptr, Abuf, Zg, nullptr,nullptr, 512,128);
  // 5. depthwise 3x3 + silu -> Xpab bf16
  k_dwconv<<<BB*LL,256,0,stream>>>(Abuf, dw_w, dw_b, Xpab);
  // 5b. direction-ordered u copies (merged)
  k_xtm<<<dim3(128,4,2*BB),256,0,stream>>>(Xpab, Xpt0, Xpt1);
  // 6. x_proj -> DBC
  k_xdbl<<<2048,256,0,stream>>>(Xpab, x_proj_w, DBCb);
  // 7. chunked selective scan: merged main pass + chain + correction
  k_scanM<<<8192,128,0,stream>>>(DBCb, Xpt0, Xpt1, dt_proj_w, dt_proj_b, A_logs,
                                 Hbuf, Ssum, Y0,Y1,Y2,Y3);
  k_scanB<<<256,256,0,stream>>>(Ssum, Hbuf, A_logs);
  k_corr<<<8192,128,0,stream>>>(DBCb, dt_proj_w, dt_proj_b, Hbuf, Y0,Y1,Y2,Y3);
  // 8. gate
  k_gate2<<<dim3(4,64,BB),256,0,stream>>>(Y0,Y1,Y2,Y3, Xpt0, Ds, Zg, onorm_g, onorm_b);
  // 9. out_proj + residual -> X0
  k_mgemm<1><<<dim3(2,512),256,0,stream>>>(Zg, opw, nullptr, X0, X0, nullptr, nullptr,nullptr, 128,256);
  // 9b. zero padded conv buffers (P and T) — Xpab/Xpt0 regions now dead
  hipMemsetAsync(wsB + 16*MB, 0, 18*MB, stream);
  // 10. LN2 -> bf16
  k_ln128b<<<BB*LL,128,0,stream>>>(X0, ln2_g, ln2_b, Ln2b);
  // 11. MLP1 gelu -> H1 bf16
  k_mgemm<2><<<dim3(8,512),256,0,stream>>>(Ln2b, m1w, mlp_b1, nullptr, nullptr, H1, nullptr,nullptr, 512,128);
  // 12. MLP2 + bias + residual -> fused de-interleave (P bf16 padded + R f32)
  k_mgemm<4><<<dim3(2,512),256,0,stream>>>(H1, m2w, mlp_b2, X0, nullptr, nullptr, P, R, 128,512);
  // 13-14. resblocks (both images batched, img = im2*4 + b)
  k_mconv<0><<<dim3(2,64,8),256,0,stream>>>(P, rw1, bn1_g,bn1_b,bn1_m,bn1_v, nullptr, T, nullptr);
  k_mconv<1><<<dim3(2,64,8),256,0,stream>>>(T, rw2, bn2_g,bn2_b,bn2_m,bn2_v, R, nullptr, out);
}

// Round 9
// 850.034 us; speedup vs baseline: 12.5219x; 1.0475x over previous
//
#include <hip/hip_runtime.h>
#include <math.h>

// Problem constants
#define BB 4
#define CM 128      // d_model
#define DI 256      // d_inner
#define NS 16       // d_state
#define RK 8        // dt_rank
#define KD 4        // K directions
#define HH 64
#define WW 128      // interleaved width
#define LL 8192     // HH*WW
#define NC 16       // scan chunks per sequence
#define CH 512      // chunk length (NC*CH == LL)

typedef unsigned short ushortt;
typedef unsigned int uintt;
typedef __attribute__((ext_vector_type(8))) __bf16 bf16x8;
typedef __attribute__((ext_vector_type(4))) float f32x4;

__device__ __forceinline__ void lds_fence(){
  asm volatile("" ::: "memory");
  __builtin_amdgcn_sched_barrier(0);
}

__device__ __forceinline__ float sigmoidf_(float x){ return 1.f/(1.f+__expf(-x)); }
__device__ __forceinline__ float siluf_(float x){ return x*sigmoidf_(x); }
__device__ __forceinline__ float softplusf_(float x){
  float r = __logf(1.f + __expf(x));   // fast path, no libcall
  return (x > 20.f) ? x : r;
}
__device__ __forceinline__ float geluf_(float x){ return 0.5f*x*(1.f+erff(x*0.70710678118654752f)); }
__device__ __forceinline__ ushortt f2bf(float f){
  uintt u = __float_as_uint(f);
  uintt r = (u + 0x7fffu + ((u>>16)&1u)) >> 16;
  return (ushortt)r;
}
__device__ __forceinline__ float bf2f(ushortt s){
  return __uint_as_float(((uintt)s)<<16);
}
template<int CTRL>
__device__ __forceinline__ float dppadd(float x){
  int r = __builtin_amdgcn_update_dpp(0, __float_as_int(x), CTRL, 0xF, 0xF, true);
  return x + __int_as_float(r);
}
// full sum over each 16-lane row; result on all lanes
__device__ __forceinline__ float rowsum16(float x){
  x = dppadd<0x121>(x);  // row_ror:1
  x = dppadd<0x122>(x);  // row_ror:2
  x = dppadd<0x124>(x);  // row_ror:4
  x = dppadd<0x128>(x);  // row_ror:8
  return x;
}
__device__ __forceinline__ float waveReduceSum(float v){
  for (int o=32;o>0;o>>=1) v += __shfl_xor(v,o,64);
  return v;
}

// ---------------- merged weight conversions (1 launch) ----------------
__global__ void k_wall(const float* __restrict__ cw_s, ushortt* __restrict__ cw_d,
                       const float* __restrict__ ip_s, ushortt* __restrict__ ip_d,
                       const float* __restrict__ op_s, ushortt* __restrict__ op_d,
                       const float* __restrict__ m1_s, ushortt* __restrict__ m1_d,
                       const float* __restrict__ m2_s, ushortt* __restrict__ m2_d,
                       const float* __restrict__ r1_s, ushortt* __restrict__ r1_d,
                       const float* __restrict__ r2_s, ushortt* __restrict__ r2_d){
  int i = blockIdx.x*256 + threadIdx.x;
  if (i < 16384){ cw_d[i] = f2bf(cw_s[i]); return; }
  i -= 16384;
  if (i < 65536){ ip_d[i] = f2bf(ip_s[i]); return; }
  i -= 65536;
  if (i < 32768){ op_d[i] = f2bf(op_s[i]); return; }
  i -= 32768;
  if (i < 65536){ m1_d[i] = f2bf(m1_s[i]); return; }
  i -= 65536;
  if (i < 65536){ m2_d[i] = f2bf(m2_s[i]); return; }
  i -= 65536;
  if (i < 147456){ int ci=i&127, co=(i>>7)&127, tap=i>>14;
    r1_d[i]=f2bf(r1_s[(size_t)(co*128+ci)*9+tap]); return; }
  i -= 147456;
  if (i < 147456){ int ci=i&127, co=(i>>7)&127, tap=i>>14;
    r2_d[i]=f2bf(r2_s[(size_t)(co*128+ci)*9+tap]); }
}

// ---------------- CT build: interleave x1/x2 -> token-major bf16 (B*L, 128) ----------------
__global__ void k_build_ct2(const float* __restrict__ x1, const float* __restrict__ x2,
                            ushortt* __restrict__ CT){
  __shared__ ushortt Tl[64][136];
  int tid = threadIdx.x;
  int p0 = (blockIdx.x & 127) * 64;
  int b  = blockIdx.x >> 7;
  int j = tid & 63;
  int p = p0 + j; int hh = p>>7, ww = p&127, w2 = ww>>1;
  const float* src = (ww&1) ? x2 : x1;
  const float* sp = src + ((size_t)b*128*64 + hh)*64 + w2;
  for (int c0 = tid>>6; c0 < 128; c0 += 4)
    Tl[j][c0] = f2bf(sp[(size_t)c0*4096]);
  __syncthreads();
  int c = tid & 127; int rh = tid >> 7;
  for (int r = rh; r < 64; r += 2)
    CT[((size_t)b*LL + p0 + r)*128 + c] = Tl[r][c];
}

// ---------------- MFMA token GEMM ----------------
// A: [32768][K] bf16, W: [N][K] bf16; grid (N/64, 512), block 256 (4 waves).
// EPI 2: +bias,gelu -> bf16 C2 (stride 512)
// EPI 3: split n<256 -> bf16 Pp (xp), else bf16 C2 (z), both stride 256
// EPI 4: +bias+resid -> fused de-interleave: P (padded bf16) + R (f32), N=128
template<int EPI>
__global__ void k_mgemm(const ushortt* __restrict__ A, const ushortt* __restrict__ W,
                        const float* __restrict__ bias, const float* __restrict__ resid,
                        float* __restrict__ C, ushortt* __restrict__ C2,
                        ushortt* __restrict__ Pp, float* __restrict__ Rp, int N, int K){
  int n0 = blockIdx.x*64, m0 = blockIdx.y*64;
  int wv = threadIdx.x>>6, l = threadIdx.x&63;
  int ar = l&15, kg = l>>4;
  int mw = m0 + wv*16;
  f32x4 acc[4];
#pragma unroll
  for (int i=0;i<4;i++){ acc[i][0]=0.f; acc[i][1]=0.f; acc[i][2]=0.f; acc[i][3]=0.f; }
  const ushortt* Ap = A + (size_t)(mw+ar)*K + kg*8;
  const ushortt* Wp = W + (size_t)(n0+ar)*K + kg*8;
  for (int k0=0; k0<K; k0+=32){
    bf16x8 af = *(const bf16x8*)(Ap + k0);
#pragma unroll
    for (int nf=0; nf<4; ++nf){
      bf16x8 bfv = *(const bf16x8*)(Wp + (size_t)nf*16*K + k0);
      acc[nf] = __builtin_amdgcn_mfma_f32_16x16x32_bf16(af, bfv, acc[nf], 0,0,0);
    }
  }
#pragma unroll
  for (int nf=0;nf<4;nf++){
    int n = n0 + nf*16 + ar;
#pragma unroll
    for (int r=0;r<4;r++){
      int m = mw + kg*4 + r;
      float v = acc[nf][r];
      if (EPI==2){
        v += bias[n];
        C2[(size_t)m*512 + n] = f2bf(geluf_(v));
      } else if (EPI==3){
        if (n < 256) Pp[(size_t)m*256 + n] = f2bf(v);
        else         C2[(size_t)m*256 + (n-256)] = f2bf(v);
      } else { // EPI==4
        v += bias[n];
        v += resid[(size_t)m*128 + n];
        int bq = m >> 13; int pq = m & 8191; int yq = pq >> 7; int wq = pq & 127;
        int im = (wq&1)*4 + bq; int xq = wq>>1;
        Pp[(((size_t)im*66 + yq+1)*66 + xq+1)*128 + n] = f2bf(v);
        Rp[(((size_t)im*64 + yq)*64 + xq)*128 + n] = v;
      }
    }
  }
}

// ---------------- MFMA GEMM (N=128) with fused LayerNorm epilogue ----------------
// RES=0: X = A@W^T + bias; RES=1: X = A@W^T + X(old). Then O = bf16(LN(X)).
template<int RES>
__global__ void k_mgemmln(const ushortt* __restrict__ A, const ushortt* __restrict__ W,
                          const float* __restrict__ bias, float* __restrict__ X,
                          const float* __restrict__ g, const float* __restrict__ bt,
                          ushortt* __restrict__ O, int K){
  int m0 = blockIdx.x*64;
  int wv = threadIdx.x>>6, l = threadIdx.x&63;
  int ar = l&15, kg = l>>4;
  int mw = m0 + wv*16;
  f32x4 acc[8];
#pragma unroll
  for (int i=0;i<8;i++){ acc[i][0]=0.f; acc[i][1]=0.f; acc[i][2]=0.f; acc[i][3]=0.f; }
  const ushortt* Ap = A + (size_t)(mw+ar)*K + kg*8;
  const ushortt* Wp = W + (size_t)ar*K + kg*8;
  for (int k0=0; k0<K; k0+=32){
    bf16x8 af = *(const bf16x8*)(Ap + k0);
#pragma unroll
    for (int nf=0; nf<8; ++nf){
      bf16x8 bfv = *(const bf16x8*)(Wp + (size_t)nf*16*K + k0);
      acc[nf] = __builtin_amdgcn_mfma_f32_16x16x32_bf16(af, bfv, acc[nf], 0,0,0);
    }
  }
  float vv[8][4];
  float s[4] = {0,0,0,0}, s2[4] = {0,0,0,0};
#pragma unroll
  for (int nf=0;nf<8;nf++){
    int n = nf*16 + ar;
    float bv = bias ? bias[n] : 0.f;
#pragma unroll
    for (int r=0;r<4;r++){
      int m = mw + kg*4 + r;
      float v = acc[nf][r] + bv;
      if (RES) v += X[(size_t)m*128 + n];
      X[(size_t)m*128 + n] = v;
      vv[nf][r] = v;
      s[r] += v; s2[r] += v*v;
    }
  }
  float mn[4], rs[4];
#pragma unroll
  for (int r=0;r<4;r++){
    float S  = rowsum16(s[r]);
    float S2 = rowsum16(s2[r]);
    float mean = S*(1.f/128.f);
    float var  = S2*(1.f/128.f) - mean*mean;
    mn[r] = mean; rs[r] = rsqrtf(var + 1e-5f);
  }
#pragma unroll
  for (int nf=0;nf<8;nf++){
    int n = nf*16 + ar;
    float gv = g[n], bv = bt[n];
#pragma unroll
    for (int r=0;r<4;r++){
      int m = mw + kg*4 + r;
      O[(size_t)m*128 + n] = f2bf((vv[nf][r]-mn[r])*rs[r]*gv + bv);
    }
  }
}

// ---------------- Depthwise 3x3 + bias + SiLU, channel-last (B,L,256) bf16->bf16 ----------------
__global__ void k_dwconv(const ushortt* __restrict__ Xp, const float* __restrict__ w,
                         const float* __restrict__ bias, ushortt* __restrict__ O){
  int tok = blockIdx.x; int d = threadIdx.x;
  int b = tok >> 13; int p = tok & (LL-1); int hh = p>>7, ww = p&127;
  float acc = bias[d];
#pragma unroll
  for (int dy=0;dy<3;dy++){
    int yy = hh+dy-1; if (yy<0||yy>=HH) continue;
#pragma unroll
    for (int dx=0;dx<3;dx++){
      int xx = ww+dx-1; if (xx<0||xx>=WW) continue;
      acc += bf2f(Xp[((size_t)b*LL + yy*WW + xx)*256 + d]) * w[d*9 + dy*3 + dx];
    }
  }
  O[(size_t)tok*256 + d] = f2bf(siluf_(acc));
}

// ---------------- merged transposes: Xpab[b][p][d] -> Xpt0 (raster) / Xpt1 (colmajor) ----------------
__global__ void k_xtm(const ushortt* __restrict__ Xpab, ushortt* __restrict__ Xpt0,
                      ushortt* __restrict__ Xpt1){
  __shared__ ushortt Tl[64][68];
  int zb = blockIdx.z; int b = zb >> 1; int mode = zb & 1;
  int d0 = blockIdx.y*64;
  int di = threadIdx.x&63, q = threadIdx.x>>6;
  if (mode == 0){
    int p0 = blockIdx.x*64;
    for (int k2=0;k2<16;k2++){ int pi = q*16 + k2;
      Tl[pi][di] = Xpab[((size_t)b*LL + p0+pi)*256 + d0+di]; }
    __syncthreads();
    for (int k2=0;k2<16;k2++){ int dr = q*16 + k2;
      Xpt0[((size_t)(b*256 + d0+dr))*LL + p0+di] = Tl[di][dr]; }
  } else {
    int ww = blockIdx.x;
    for (int k2=0;k2<16;k2++){ int hh = q*16 + k2;
      Tl[hh][di] = Xpab[((size_t)b*LL + hh*128 + ww)*256 + d0+di]; }
    __syncthreads();
    for (int k2=0;k2<16;k2++){ int dr = q*16 + k2;
      Xpt1[((size_t)(b*256 + d0+dr))*LL + ww*64 + di] = Tl[di][dr]; }
  }
}

// ---------------- x_proj: per-token 4x40 projections, written in scan order ----------------
// dts: DBCb rows of 32B per (bk,t): 8x f32.
// B/C: BCs dwords [bk][t/16][state][t%16]: bf16 B (low), C (high).
__global__ void k_xdbl(const ushortt* __restrict__ Xpab, const float* __restrict__ xpw,
                       char* __restrict__ DBCb, char* __restrict__ BCsb){
  __shared__ float U[16][256];
  int tid = threadIdx.x;
  int blk = blockIdx.x;              // B*L/16 = 2048
  int b = blk >> 9;
  int p0 = (blk & 511) << 4;
  for (int i=tid;i<16*256;i+=256){ int tt=i>>8, d=i&255;
    U[tt][d] = bf2f(Xpab[((size_t)b*LL + p0+tt)*256 + d]); }
  __syncthreads();
  if (tid < 160){
    int k = tid/40, c = tid%40;
    const float* wr = xpw + ((size_t)k*40 + c)*256;
    float acc[16];
#pragma unroll
    for (int tt=0;tt<16;tt++) acc[tt]=0.f;
    for (int d=0;d<256;d++){
      float wv = wr[d];
#pragma unroll
      for (int tt=0;tt<16;tt++) acc[tt] += U[tt][d]*wv;
    }
    int bk = b*KD + k;
    for (int tt=0;tt<16;tt++){
      int p = p0+tt; int hh=p>>7, ww=p&127;
      int t;
      if      (k==0) t = p;
      else if (k==1) t = (ww<<6)|hh;
      else if (k==2) t = LL-1-p;
      else           t = LL-1-((ww<<6)|hh);
      if (c < 8){
        *(float*)(DBCb + ((size_t)bk*LL + t)*32 + 4*c) = acc[tt];
      } else {
        int j = (c<24) ? c-8 : c-24;
        size_t a = ((((size_t)bk*512 + (t>>4))*16 + j)*16 + (t&15))*4 + ((c<24)?0:2);
        *(ushortt*)(BCsb + a) = f2bf(acc[tt]);
      }
    }
  }
}

// ---------------- Merged scan pass: from h=0, write y_local + h_out + sum(delta) ----------------
// 128 threads = 8 groups of 16 lanes.
__global__ __launch_bounds__(128) void k_scanM(const char* __restrict__ DBCb,
                        const uintt* __restrict__ BCs,
                        const ushortt* __restrict__ Xpt0, const ushortt* __restrict__ Xpt1,
                        const float* __restrict__ dtw_all, const float* __restrict__ dtb_all,
                        const float* __restrict__ A_logs,
                        float* __restrict__ Hbuf, float* __restrict__ Ssum,
                        ushortt* __restrict__ Y0, ushortt* __restrict__ Y1,
                        ushortt* __restrict__ Y2, ushortt* __restrict__ Y3){
  __shared__ float2 sdd[8][16];
  __shared__ float yt[8][16][20];   // [grp][step][state], pad to 20 (80B rows, 16B aligned)
  int tid = threadIdx.x;
  int grp = tid >> 4, lane = tid & 15;
  int gid = blockIdx.x*8 + grp;
  int c = gid & 15;
  int bkd = gid >> 4;
  int b = bkd >> 10, k = (bkd>>8)&3, d = bkd & 255;
  int kd = k*256+d;
  int bk = b*KD + k;
  float dtw[8];
  { const float4* w4 = (const float4*)(dtw_all + (size_t)kd*8);
    float4 w0 = w4[0], w1 = w4[1];
    dtw[0]=w0.x; dtw[1]=w0.y; dtw[2]=w0.z; dtw[3]=w0.w;
    dtw[4]=w1.x; dtw[5]=w1.y; dtw[6]=w1.z; dtw[7]=w1.w; }
  float dtb  = dtb_all[kd];
  float Aval = -__expf(A_logs[(size_t)kd*16+lane]);
  const char* dbc = DBCb + (size_t)bk*LL*32;
  const uintt* bcb = BCs + ((size_t)bk*512 + (c*CH>>4))*256;
  const ushortt* Up = ((k&1)?Xpt1:Xpt0) + ((size_t)(b*256+d))*LL;
  ushortt* Yk = (k==0?Y0 : k==1?Y1 : k==2?Y2 : Y3) + ((size_t)b*256 + d)*LL;
  float h = 0.f, Sacc = 0.f;
  int t0 = c*CH;
  // prefetch block 0 dts + u
  const char* row0 = dbc + (size_t)(t0+lane)*32;
  float4 q0 = *(const float4*)row0;
  float4 q1 = *(const float4*)(row0+16);
  ushortt ur = Up[(k<2) ? (t0+lane) : (LL-1-(t0+lane))];
  for (int blk=0; blk<CH/16; ++blk){
    int tb = t0 + blk*16;
    int tme = tb + lane;
    // own-state B/C for the 16 steps of this block (contiguous 64B)
    const uint4* bcp = (const uint4*)(bcb + ((size_t)blk*16 + lane)*16);
    uint4 w0 = bcp[0], w1 = bcp[1], w2 = bcp[2], w3 = bcp[3];
    float4 c0 = q0, c1 = q1; ushortt cu = ur;
    if (blk+1 < CH/16){
      const char* rn = dbc + (size_t)(tme+16)*32;
      q0 = *(const float4*)rn;
      q1 = *(const float4*)(rn+16);
      ur = Up[(k<2) ? (tme+16) : (LL-1-(tme+16))];
    }
    float dsum = dtb + c0.x*dtw[0] + c0.y*dtw[1] + c0.z*dtw[2] + c0.w*dtw[3]
                     + c1.x*dtw[4] + c1.y*dtw[5] + c1.z*dtw[6] + c1.w*dtw[7];
    float delta = softplusf_(dsum);
    Sacc += delta;
    float u = bf2f(cu);
    sdd[grp][lane] = make_float2(delta, delta*u);
    lds_fence();             // order sdd write vs cross-lane reads below
    uintt wd[16] = {w0.x,w0.y,w0.z,w0.w, w1.x,w1.y,w1.z,w1.w,
                    w2.x,w2.y,w2.z,w2.w, w3.x,w3.y,w3.z,w3.w};
#pragma unroll
    for (int i=0;i<16;i++){
      float2 dd = sdd[grp][i];
      uintt w = wd[i];
      float Bn = __uint_as_float(w<<16);
      float Cn = __uint_as_float(w & 0xffff0000u);
      float e = __expf(dd.x * Aval);
      h = e*h + dd.y*Bn;
      yt[grp][i][lane] = h*Cn;
    }
    lds_fence();             // order yt writes vs cross-lane yt reads
    const f32x4* yr = (const f32x4*)&yt[grp][lane][0];
    f32x4 s0 = yr[0], s1 = yr[1], s2v = yr[2], s3 = yr[3];
    float acc = (s0[0]+s0[1]+s0[2]+s0[3]) + (s1[0]+s1[1]+s1[2]+s1[3])
              + (s2v[0]+s2v[1]+s2v[2]+s2v[3]) + (s3[0]+s3[1]+s3[2]+s3[3]);
    Yk[tme] = f2bf(acc);
    lds_fence();             // order yt reads vs next block's yt writes
  }
  Hbuf[(size_t)gid*16 + lane] = h;
  float Stot = rowsum16(Sacc);
  if (lane==0) Ssum[gid] = Stot;
}

// Pass B: serial over chunks; converts Hbuf (h_out) to h_start in place.
__global__ void k_scanB(const float* __restrict__ Ssum, float* __restrict__ Hbuf,
                        const float* __restrict__ A_logs){
  int idx = blockIdx.x*256 + threadIdx.x;  // bkd*16+n (65536)
  int n = idx & 15; int bkd = idx >> 4;
  int kd = ((bkd>>8)&3)*256 + (bkd&255);
  float Aval = -__expf(A_logs[(size_t)kd*16+n]);
  float h = 0.f;
  for (int c=0;c<NC;c++){
    size_t g = (size_t)bkd*NC + c;
    float hout = Hbuf[g*16+n];
    Hbuf[g*16+n] = h;
    h = __expf(Aval*Ssum[g])*h + hout;
  }
}

// Pass C': correction sweep. y(t) += sum_n C_n(t) * exp(A_n * S_incl(t)) * h0_n.
__global__ __launch_bounds__(128) void k_corr(const char* __restrict__ DBCb,
                       const uintt* __restrict__ BCs,
                       const float* __restrict__ dtw_all, const float* __restrict__ dtb_all,
                       const float* __restrict__ Hbuf,
                       ushortt* __restrict__ Y0, ushortt* __restrict__ Y1,
                       ushortt* __restrict__ Y2, ushortt* __restrict__ Y3){
  int tid = threadIdx.x;
  int grp = tid >> 4, lane = tid & 15;
  int gid = blockIdx.x*8 + grp;
  int c = gid & 15;
  if (c == 0) return;                 // h0 == 0 exactly
  int bkd = gid >> 4;
  int b = bkd >> 10, k = (bkd>>8)&3, d = bkd & 255;
  int kd = k*256+d;
  int bk = b*KD + k;
  float h0[16];
  float hmax = 0.f;
#pragma unroll
  for (int n=0;n<16;n++){
    h0[n] = Hbuf[(size_t)gid*16 + n];
    hmax = fmaxf(hmax, fabsf(h0[n]));
  }
  float Sexit = 14.f + __logf(fmaxf(hmax, 1e-30f));
  if (0.f > Sexit) return;            // h0 negligible
  float dtw[8];
  { const float4* w4 = (const float4*)(dtw_all + (size_t)kd*8);
    float4 w0 = w4[0], w1 = w4[1];
    dtw[0]=w0.x; dtw[1]=w0.y; dtw[2]=w0.z; dtw[3]=w0.w;
    dtw[4]=w1.x; dtw[5]=w1.y; dtw[6]=w1.z; dtw[7]=w1.w; }
  float dtb  = dtb_all[kd];
  const char* dbc = DBCb + (size_t)bk*LL*32;
  ushortt* Yk = (k==0?Y0 : k==1?Y1 : k==2?Y2 : Y3) + ((size_t)b*256 + d)*LL;
  float S0 = 0.f;
  int t0 = c*CH;
  for (int blk=0; blk<CH/16; ++blk){
    int tme = t0 + blk*16 + lane;
    const char* rowme = dbc + (size_t)tme*32;
    float4 q0 = *(const float4*)rowme;
    float4 q1 = *(const float4*)(rowme+16);
    float dsum = dtb + q0.x*dtw[0] + q0.y*dtw[1] + q0.z*dtw[2] + q0.w*dtw[3]
                     + q1.x*dtw[4] + q1.y*dtw[5] + q1.z*dtw[6] + q1.w*dtw[7];
    float delta = softplusf_(dsum);
    // inclusive prefix sum over the 16-lane group
    float pre = delta;
#pragma unroll
    for (int o=1;o<16;o<<=1){
      float t = __shfl_up(pre, o, 16);
      if (lane >= o) pre += t;
    }
    float S = S0 + pre;
    float E = __expf(-S);
    const uintt* cb = BCs + ((size_t)bk*512 + (tme>>4))*256 + (tme&15);
    float p = E, acc = 0.f;
#pragma unroll
    for (int n=0;n<16;n++){
      float Cn = __uint_as_float(cb[n*16] & 0xffff0000u);
      acc += Cn * h0[n] * p;
      p *= E;
    }
    float yv = bf2f(Yk[tme]);
    Yk[tme] = f2bf(yv + acc);
    S0 = __shfl(S, 15, 16);           // block total carry
    if (S0 > Sexit) break;            // uniform across group
  }
}

// ---------------- Gate: gather Y0..Y3 + u*sum(D), LN256, *silu(z) ----------------
__global__ void k_gate2(const ushortt* __restrict__ Y0, const ushortt* __restrict__ Y1,
                        const ushortt* __restrict__ Y2, const ushortt* __restrict__ Y3,
                        const ushortt* __restrict__ Xpt0, const float* __restrict__ Ds,
                        ushortt* __restrict__ Zg,
                        const float* __restrict__ g, const float* __restrict__ bt){
  __shared__ float ysum[32][257];
  __shared__ float Dl[256];
  int tid = threadIdx.x;
  int wwb = blockIdx.x;      // 0..3
  int hh  = blockIdx.y;      // 0..63
  int b   = blockIdx.z;
  if (tid < 256) Dl[tid] = Ds[tid] + Ds[256+tid] + Ds[512+tid] + Ds[768+tid];
  int ww0 = wwb*32;
  for (int it=0; it<32; ++it){
    int idx = it*256 + tid;
    int d = idx >> 5, tl = idx & 31;
    int ww = ww0 + tl;
    int p  = hh*128 + ww;
    size_t base = ((size_t)b*256 + d) << 13;
    int t1 = ww*64 + hh;
    float v = bf2f(Y0[base + p]) + bf2f(Y2[base + (LL-1) - p])
            + bf2f(Y1[base + t1]) + bf2f(Y3[base + (LL-1) - t1]);
    ysum[tl][d] = v;
  }
  __syncthreads();
  {
    int d = tid;
    if (d < 256){
      size_t ub = (((size_t)b*256 + d) << 13) + hh*128 + ww0;
      for (int tl=0; tl<32; ++tl){
        float u = bf2f(Xpt0[ub + tl]);
        ysum[tl][d] += Dl[d]*u;
      }
    }
  }
  __syncthreads();
  int wave = tid >> 6, lane = tid & 63;
  for (int tk = wave*8; tk < wave*8+8; ++tk){
    float v0 = ysum[tk][lane], v1 = ysum[tk][lane+64];
    float v2 = ysum[tk][lane+128], v3 = ysum[tk][lane+192];
    float s  = waveReduceSum(v0+v1+v2+v3);
    float s2 = waveReduceSum(v0*v0+v1*v1+v2*v2+v3*v3);
    float mean = s*(1.f/256.f);
    float var  = s2*(1.f/256.f) - mean*mean;
    float r = rsqrtf(var + 1e-5f);
    int p = hh*128 + ww0 + tk;
    size_t zb = (((size_t)b<<13) + p) << 8;
#pragma unroll
    for (int j=0;j<4;j++){
      int dd = lane + 64*j;
      float ln = (ysum[tk][dd]-mean)*r*g[dd] + bt[dd];
      float z = bf2f(Zg[zb + dd]);
      Zg[zb + dd] = f2bf(ln * siluf_(z));
    }
  }
}

// ---------------- MFMA 3x3 conv 128->128 + BN (+res) + ReLU ----------------
template<int FINAL>
__global__ void k_mconv(const ushortt* __restrict__ I, const ushortt* __restrict__ Wt,
                        const float* __restrict__ g, const float* __restrict__ bb,
                        const float* __restrict__ mn, const float* __restrict__ vv,
                        const float* __restrict__ R, ushortt* __restrict__ Op,
                        float* __restrict__ Of){
  int nh = blockIdx.x;
  int y  = blockIdx.y;
  int im = blockIdx.z;
  int wv = threadIdx.x>>6, l = threadIdx.x&63;
  int ar = l&15, kg = l>>4;
  int x0 = wv*16;
  f32x4 acc[4];
#pragma unroll
  for (int i=0;i<4;i++){ acc[i][0]=0.f; acc[i][1]=0.f; acc[i][2]=0.f; acc[i][3]=0.f; }
  const ushortt* Ibase = I + (((size_t)im*66 + y)*66 + x0 + ar)*128 + kg*8;
  const ushortt* Wbase = Wt + (size_t)(nh*64 + ar)*128 + kg*8;
#pragma unroll
  for (int tap=0; tap<9; ++tap){
    int dy = tap/3, dx = tap - dy*3;
    const ushortt* Ir = Ibase + ((size_t)dy*66 + dx)*128;
    const ushortt* Wr = Wbase + (size_t)tap*16384;
#pragma unroll
    for (int kc=0;kc<4;kc++){
      bf16x8 af = *(const bf16x8*)(Ir + kc*32);
#pragma unroll
      for (int nf=0;nf<4;nf++){
        bf16x8 bfv = *(const bf16x8*)(Wr + (size_t)nf*16*128 + kc*32);
        acc[nf] = __builtin_amdgcn_mfma_f32_16x16x32_bf16(af, bfv, acc[nf], 0,0,0);
      }
    }
  }
#pragma unroll
  for (int nf=0;nf<4;nf++){
    int co = nh*64 + nf*16 + ar;
    float s  = g[co]*rsqrtf(vv[co]+1e-5f);
    float sh = bb[co] - mn[co]*s;
#pragma unroll
    for (int r=0;r<4;r++){
      int x = x0 + kg*4 + r;
      float v = acc[nf][r]*s + sh;
      if (FINAL){
        v += R[(((size_t)im*64 + y)*64 + x)*128 + co];
        v = fmaxf(v, 0.f);
        Of[(((size_t)im*128 + co)*64 + y)*64 + x] = v;
      } else {
        v = fmaxf(v, 0.f);
        Op[(((size_t)im*66 + (y+1))*66 + (x+1))*128 + co] = f2bf(v);
      }
    }
  }
}

extern "C" void kernel_launch(void* const* d_in, const int* in_sizes, int n_in,
                              void* d_out, int out_size, void* d_ws, size_t ws_size,
                              hipStream_t stream){
  const float* x1        = (const float*)d_in[0];
  const float* x2        = (const float*)d_in[1];
  const float* conv_in_w = (const float*)d_in[2];
  const float* conv_in_b = (const float*)d_in[3];
  const float* ln1_g     = (const float*)d_in[4];
  const float* ln1_b     = (const float*)d_in[5];
  const float* in_proj_w = (const float*)d_in[6];
  const float* dw_w      = (const float*)d_in[7];
  const float* dw_b      = (const float*)d_in[8];
  const float* x_proj_w  = (const float*)d_in[9];
  const float* dt_proj_w = (const float*)d_in[10];
  const float* dt_proj_b = (const float*)d_in[11];
  const float* A_logs    = (const float*)d_in[12];
  const float* Ds        = (const float*)d_in[13];
  const float* onorm_g   = (const float*)d_in[14];
  const float* onorm_b   = (const float*)d_in[15];
  const float* out_proj_w= (const float*)d_in[16];
  const float* ln2_g     = (const float*)d_in[17];
  const float* ln2_b     = (const float*)d_in[18];
  const float* mlp_w1    = (const float*)d_in[19];
  const float* mlp_b1    = (const float*)d_in[20];
  const float* mlp_w2    = (const float*)d_in[21];
  const float* mlp_b2    = (const float*)d_in[22];
  const float* rb1_w     = (const float*)d_in[23];
  const float* bn1_g     = (const float*)d_in[24];
  const float* bn1_b     = (const float*)d_in[25];
  const float* bn1_m     = (const float*)d_in[26];
  const float* bn1_v     = (const float*)d_in[27];
  const float* rb2_w     = (const float*)d_in[28];
  const float* bn2_g     = (const float*)d_in[29];
  const float* bn2_b     = (const float*)d_in[30];
  const float* bn2_m     = (const float*)d_in[31];
  const float* bn2_v     = (const float*)d_in[32];

  float* ws = (float*)d_ws;
  char*  wsB = (char*)d_ws;
  const size_t FM = 262144;            // floats per MiB
  const size_t MB = 1048576;           // bytes per MiB
  // Workspace layout (peak 147.1 MiB, proven available):
  float*   X0   = ws;                          // 0-16    residual stream (B,L,128) f32
  ushortt* Xpab = (ushortt*)(wsB + 16*MB);     // 16-32   u post-dw-silu (B,L,256) bf16
  ushortt* Xpt0 = (ushortt*)(wsB + 32*MB);     // 32-48   u raster-order [b][d][p]
  ushortt* Xpt1 = (ushortt*)(wsB + 48*MB);     // 48-64   u colmajor-order [b][d][t1]
  char*    DBCb = wsB + 64*MB;                 // 64-68   dts rows 32B
  uintt*   BCs  = (uintt*)(wsB + 68*MB);       // 68-76   B/C dwords [bk][t/16][n][t%16]
  ushortt* Zg   = (ushortt*)(wsB + 77*MB);     // 77-93   z / gated bf16
  ushortt* Y0   = (ushortt*)(wsB + 93*MB);     // 93-109
  ushortt* Y1   = (ushortt*)(wsB + 109*MB);    // 109-125
  ushortt* Y2   = (ushortt*)(wsB + 125*MB);    // 125-141
  ushortt* Y3   = Xpab;                        // alias (Xpab dead before scanM)
  float*   Hbuf = ws + 141*FM;                 // 141-145
  float*   Ssum = ws + 145*FM;                 // 145-145.25
  // time-disjoint aliases:
  ushortt* CT   = (ushortt*)(wsB + 93*MB);     // steps 1-2 (over Y0)
  ushortt* Lnb  = (ushortt*)(wsB + 101*MB);    // steps 2-4 (over Y0 2nd half)
  ushortt* Xpb  = (ushortt*)(wsB + 109*MB);    // steps 4-5 xp pre-dw bf16 (over Y1)
  ushortt* Ln2b = (ushortt*)(wsB + 93*MB);     // steps 9-11 (Y0 dead)
  ushortt* H1   = (ushortt*)(wsB + 109*MB);    // steps 11-12 (Y1,Y2 dead)
  ushortt* P    = (ushortt*)(wsB + 16*MB);     // step 12+ padded conv input [8][66][66][128]
  ushortt* T    = (ushortt*)(wsB + 25*MB);     // conv1 out padded
  float*   R    = (float*)(wsB + 34*MB);       // 34-51 residual [8][64][64][128] f32
  // bf16 weights (persistent, never aliased):
  ushortt* cw  = (ushortt*)(wsB + 146*MB);           // 32 KB
  ushortt* ipw = (ushortt*)(wsB + 146*MB + 32*1024); // 128 KB
  ushortt* opw = (ushortt*)(wsB + 146*MB + 160*1024);// 64 KB
  ushortt* m1w = (ushortt*)(wsB + 146*MB + 224*1024);// 128 KB
  ushortt* m2w = (ushortt*)(wsB + 146*MB + 352*1024);// 128 KB
  ushortt* rw1 = (ushortt*)(wsB + 146*MB + 480*1024);// 288 KB
  ushortt* rw2 = (ushortt*)(wsB + 146*MB + 768*1024);// 288 KB
  float* out = (float*)d_out;

  // 0. all weight conversions (one launch)
  k_wall<<<2112,256,0,stream>>>(conv_in_w,cw, in_proj_w,ipw, out_proj_w,opw,
                                mlp_w1,m1w, mlp_w2,m2w, rb1_w,rw1, rb2_w,rw2);
  // 1. interleave -> CT bf16 token-major
  k_build_ct2<<<512,256,0,stream>>>(x1,x2,CT);
  // 2. conv_in 1x1 (bias) -> X0 f32 + fused LN1 -> Lnb bf16
  k_mgemmln<0><<<512,256,0,stream>>>(CT, cw, conv_in_b, X0, ln1_g, ln1_b, Lnb, 128);
  // 4. in_proj (512) -> split xp(Xpb bf16) / z(Zg bf16)
  k_mgemm<3><<<dim3(8,512),256,0,stream>>>(Lnb, ipw, nullptr, nullptr, nullptr, Zg, Xpb, nullptr, 512,128);
  // 5. depthwise 3x3 + silu -> Xpab bf16
  k_dwconv<<<BB*LL,256,0,stream>>>(Xpb, dw_w, dw_b, Xpab);
  // 5b. direction-ordered u copies (merged)
  k_xtm<<<dim3(128,4,2*BB),256,0,stream>>>(Xpab, Xpt0, Xpt1);
  // 6. x_proj -> dts (DBCb) + B/C (BCs)
  k_xdbl<<<2048,256,0,stream>>>(Xpab, x_proj_w, DBCb, (char*)BCs);
  // 7. chunked selective scan: merged main pass + chain + correction
  k_scanM<<<8192,128,0,stream>>>(DBCb, BCs, Xpt0, Xpt1, dt_proj_w, dt_proj_b, A_logs,
                                 Hbuf, Ssum, Y0,Y1,Y2,Y3);
  k_scanB<<<256,256,0,stream>>>(Ssum, Hbuf, A_logs);
  k_corr<<<8192,128,0,stream>>>(DBCb, BCs, dt_proj_w, dt_proj_b, Hbuf, Y0,Y1,Y2,Y3);
  // 8. gate
  k_gate2<<<dim3(4,64,BB),256,0,stream>>>(Y0,Y1,Y2,Y3, Xpt0, Ds, Zg, onorm_g, onorm_b);
  // 9. out_proj + residual -> X0 + fused LN2 -> Ln2b bf16
  k_mgemmln<1><<<512,256,0,stream>>>(Zg, opw, nullptr, X0, ln2_g, ln2_b, Ln2b, 256);
  // 9b. zero padded conv buffers (P and T) — Xpab/Xpt0 regions now dead
  hipMemsetAsync(wsB + 16*MB, 0, 18*MB, stream);
  // 11. MLP1 gelu -> H1 bf16
  k_mgemm<2><<<dim3(8,512),256,0,stream>>>(Ln2b, m1w, mlp_b1, nullptr, nullptr, H1, nullptr,nullptr, 512,128);
  // 12. MLP2 + bias + residual -> fused de-interleave (P bf16 padded + R f32)
  k_mgemm<4><<<dim3(2,512),256,0,stream>>>(H1, m2w, mlp_b2, X0, nullptr, nullptr, P, R, 128,512);
  // 13-14. resblocks (both images batched, img = im2*4 + b)
  k_mconv<0><<<dim3(2,64,8),256,0,stream>>>(P, rw1, bn1_g,bn1_b,bn1_m,bn1_v, nullptr, T, nullptr);
  k_mconv<1><<<dim3(2,64,8),256,0,stream>>>(T, rw2, bn2_g,bn2_b,bn2_m,bn2_v, R, nullptr, out);
}

// Round 12
// 838.806 us; speedup vs baseline: 12.6895x; 1.0134x over previous
//
#include <hip/hip_runtime.h>
#include <math.h>

// Problem constants
#define BB 4
#define CM 128      // d_model
#define DI 256      // d_inner
#define NS 16       // d_state
#define RK 8        // dt_rank
#define KD 4        // K directions
#define HH 64
#define WW 128      // interleaved width
#define LL 8192     // HH*WW
#define NC 16       // scan chunks per sequence
#define CH 512      // chunk length (NC*CH == LL)

typedef unsigned short ushortt;
typedef unsigned int uintt;
typedef __attribute__((ext_vector_type(8))) __bf16 bf16x8;
typedef __attribute__((ext_vector_type(4))) float f32x4;

__device__ __forceinline__ void lds_fence(){
  asm volatile("" ::: "memory");
  __builtin_amdgcn_sched_barrier(0);
}

__device__ __forceinline__ float sigmoidf_(float x){ return 1.f/(1.f+__expf(-x)); }
__device__ __forceinline__ float siluf_(float x){ return x*sigmoidf_(x); }
__device__ __forceinline__ float softplusf_(float x){
  float r = __logf(1.f + __expf(x));   // fast path, no libcall
  return (x > 20.f) ? x : r;
}
__device__ __forceinline__ float geluf_(float x){ return 0.5f*x*(1.f+erff(x*0.70710678118654752f)); }
__device__ __forceinline__ ushortt f2bf(float f){
  uintt u = __float_as_uint(f);
  uintt r = (u + 0x7fffu + ((u>>16)&1u)) >> 16;
  return (ushortt)r;
}
__device__ __forceinline__ float bf2f(ushortt s){
  return __uint_as_float(((uintt)s)<<16);
}
template<int CTRL>
__device__ __forceinline__ float dppadd(float x){
  int r = __builtin_amdgcn_update_dpp(0, __float_as_int(x), CTRL, 0xF, 0xF, true);
  return x + __int_as_float(r);
}
// full sum over each 16-lane row; result on all lanes
__device__ __forceinline__ float rowsum16(float x){
  x = dppadd<0x121>(x);  // row_ror:1
  x = dppadd<0x122>(x);  // row_ror:2
  x = dppadd<0x124>(x);  // row_ror:4
  x = dppadd<0x128>(x);  // row_ror:8
  return x;
}
__device__ __forceinline__ float waveReduceSum(float v){
  for (int o=32;o>0;o>>=1) v += __shfl_xor(v,o,64);
  return v;
}

// ---------------- merged weight conversions (1 launch) ----------------
__global__ void k_wall(const float* __restrict__ cw_s, ushortt* __restrict__ cw_d,
                       const float* __restrict__ ip_s, ushortt* __restrict__ ip_d,
                       const float* __restrict__ op_s, ushortt* __restrict__ op_d,
                       const float* __restrict__ m1_s, ushortt* __restrict__ m1_d,
                       const float* __restrict__ m2_s, ushortt* __restrict__ m2_d,
                       const float* __restrict__ r1_s, ushortt* __restrict__ r1_d,
                       const float* __restrict__ r2_s, ushortt* __restrict__ r2_d){
  int i = blockIdx.x*256 + threadIdx.x;
  if (i < 16384){ cw_d[i] = f2bf(cw_s[i]); return; }
  i -= 16384;
  if (i < 65536){ ip_d[i] = f2bf(ip_s[i]); return; }
  i -= 65536;
  if (i < 32768){ op_d[i] = f2bf(op_s[i]); return; }
  i -= 32768;
  if (i < 65536){ m1_d[i] = f2bf(m1_s[i]); return; }
  i -= 65536;
  if (i < 65536){ m2_d[i] = f2bf(m2_s[i]); return; }
  i -= 65536;
  if (i < 147456){ int ci=i&127, co=(i>>7)&127, tap=i>>14;
    r1_d[i]=f2bf(r1_s[(size_t)(co*128+ci)*9+tap]); return; }
  i -= 147456;
  if (i < 147456){ int ci=i&127, co=(i>>7)&127, tap=i>>14;
    r2_d[i]=f2bf(r2_s[(size_t)(co*128+ci)*9+tap]); }
}

// ---------------- CT build: interleave x1/x2 -> token-major bf16 (B*L, 128) ----------------
__global__ void k_build_ct2(const float* __restrict__ x1, const float* __restrict__ x2,
                            ushortt* __restrict__ CT){
  __shared__ ushortt Tl[64][136];
  int tid = threadIdx.x;
  int p0 = (blockIdx.x & 127) * 64;
  int b  = blockIdx.x >> 7;
  int j = tid & 63;
  int p = p0 + j; int hh = p>>7, ww = p&127, w2 = ww>>1;
  const float* src = (ww&1) ? x2 : x1;
  const float* sp = src + ((size_t)b*128*64 + hh)*64 + w2;
  for (int c0 = tid>>6; c0 < 128; c0 += 4)
    Tl[j][c0] = f2bf(sp[(size_t)c0*4096]);
  __syncthreads();
  int c = tid & 127; int rh = tid >> 7;
  for (int r = rh; r < 64; r += 2)
    CT[((size_t)b*LL + p0 + r)*128 + c] = Tl[r][c];
}

// ---------------- MFMA token GEMM ----------------
// A: [32768][K] bf16, W: [N][K] bf16; grid (N/64, 512), block 256 (4 waves).
// EPI 2: +bias,gelu -> bf16 C2 (stride 512)
// EPI 3: split n<256 -> bf16 Pp (xp), else bf16 C2 (z), both stride 256
// EPI 4: +bias+resid -> fused de-interleave: P (padded bf16) + R (f32), N=128
template<int EPI>
__global__ void k_mgemm(const ushortt* __restrict__ A, const ushortt* __restrict__ W,
                        const float* __restrict__ bias, const float* __restrict__ resid,
                        float* __restrict__ C, ushortt* __restrict__ C2,
                        ushortt* __restrict__ Pp, float* __restrict__ Rp, int N, int K){
  int n0 = blockIdx.x*64, m0 = blockIdx.y*64;
  int wv = threadIdx.x>>6, l = threadIdx.x&63;
  int ar = l&15, kg = l>>4;
  int mw = m0 + wv*16;
  f32x4 acc[4];
#pragma unroll
  for (int i=0;i<4;i++){ acc[i][0]=0.f; acc[i][1]=0.f; acc[i][2]=0.f; acc[i][3]=0.f; }
  const ushortt* Ap = A + (size_t)(mw+ar)*K + kg*8;
  const ushortt* Wp = W + (size_t)(n0+ar)*K + kg*8;
  for (int k0=0; k0<K; k0+=32){
    bf16x8 af = *(const bf16x8*)(Ap + k0);
#pragma unroll
    for (int nf=0; nf<4; ++nf){
      bf16x8 bfv = *(const bf16x8*)(Wp + (size_t)nf*16*K + k0);
      acc[nf] = __builtin_amdgcn_mfma_f32_16x16x32_bf16(af, bfv, acc[nf], 0,0,0);
    }
  }
#pragma unroll
  for (int nf=0;nf<4;nf++){
    int n = n0 + nf*16 + ar;
#pragma unroll
    for (int r=0;r<4;r++){
      int m = mw + kg*4 + r;
      float v = acc[nf][r];
      if (EPI==2){
        v += bias[n];
        C2[(size_t)m*512 + n] = f2bf(geluf_(v));
      } else if (EPI==3){
        if (n < 256) Pp[(size_t)m*256 + n] = f2bf(v);
        else         C2[(size_t)m*256 + (n-256)] = f2bf(v);
      } else { // EPI==4
        v += bias[n];
        v += resid[(size_t)m*128 + n];
        int bq = m >> 13; int pq = m & 8191; int yq = pq >> 7; int wq = pq & 127;
        int im = (wq&1)*4 + bq; int xq = wq>>1;
        Pp[(((size_t)im*66 + yq+1)*66 + xq+1)*128 + n] = f2bf(v);
        Rp[(((size_t)im*64 + yq)*64 + xq)*128 + n] = v;
      }
    }
  }
}

// ---------------- MFMA GEMM (N=128) with fused LayerNorm epilogue ----------------
// RES=0: X = A@W^T + bias; RES=1: X = A@W^T + X(old). Then O = bf16(LN(X)).
template<int RES>
__global__ void k_mgemmln(const ushortt* __restrict__ A, const ushortt* __restrict__ W,
                          const float* __restrict__ bias, float* __restrict__ X,
                          const float* __restrict__ g, const float* __restrict__ bt,
                          ushortt* __restrict__ O, int K){
  int m0 = blockIdx.x*64;
  int wv = threadIdx.x>>6, l = threadIdx.x&63;
  int ar = l&15, kg = l>>4;
  int mw = m0 + wv*16;
  f32x4 acc[8];
#pragma unroll
  for (int i=0;i<8;i++){ acc[i][0]=0.f; acc[i][1]=0.f; acc[i][2]=0.f; acc[i][3]=0.f; }
  const ushortt* Ap = A + (size_t)(mw+ar)*K + kg*8;
  const ushortt* Wp = W + (size_t)ar*K + kg*8;
  for (int k0=0; k0<K; k0+=32){
    bf16x8 af = *(const bf16x8*)(Ap + k0);
#pragma unroll
    for (int nf=0; nf<8; ++nf){
      bf16x8 bfv = *(const bf16x8*)(Wp + (size_t)nf*16*K + k0);
      acc[nf] = __builtin_amdgcn_mfma_f32_16x16x32_bf16(af, bfv, acc[nf], 0,0,0);
    }
  }
  float vv[8][4];
  float s[4] = {0,0,0,0}, s2[4] = {0,0,0,0};
#pragma unroll
  for (int nf=0;nf<8;nf++){
    int n = nf*16 + ar;
    float bv = bias ? bias[n] : 0.f;
#pragma unroll
    for (int r=0;r<4;r++){
      int m = mw + kg*4 + r;
      float v = acc[nf][r] + bv;
      if (RES) v += X[(size_t)m*128 + n];
      X[(size_t)m*128 + n] = v;
      vv[nf][r] = v;
      s[r] += v; s2[r] += v*v;
    }
  }
  float mn[4], rs[4];
#pragma unroll
  for (int r=0;r<4;r++){
    float S  = rowsum16(s[r]);
    float S2 = rowsum16(s2[r]);
    float mean = S*(1.f/128.f);
    float var  = S2*(1.f/128.f) - mean*mean;
    mn[r] = mean; rs[r] = rsqrtf(var + 1e-5f);
  }
#pragma unroll
  for (int nf=0;nf<8;nf++){
    int n = nf*16 + ar;
    float gv = g[n], bv = bt[n];
#pragma unroll
    for (int r=0;r<4;r++){
      int m = mw + kg*4 + r;
      O[(size_t)m*128 + n] = f2bf((vv[nf][r]-mn[r])*rs[r]*gv + bv);
    }
  }
}

// ---------------- Depthwise 3x3 + bias + SiLU, channel-last (B,L,256) bf16->bf16 ----------------
__global__ void k_dwconv(const ushortt* __restrict__ Xp, const float* __restrict__ w,
                         const float* __restrict__ bias, ushortt* __restrict__ O){
  int tok = blockIdx.x; int d = threadIdx.x;
  int b = tok >> 13; int p = tok & (LL-1); int hh = p>>7, ww = p&127;
  float acc = bias[d];
#pragma unroll
  for (int dy=0;dy<3;dy++){
    int yy = hh+dy-1; if (yy<0||yy>=HH) continue;
#pragma unroll
    for (int dx=0;dx<3;dx++){
      int xx = ww+dx-1; if (xx<0||xx>=WW) continue;
      acc += bf2f(Xp[((size_t)b*LL + yy*WW + xx)*256 + d]) * w[d*9 + dy*3 + dx];
    }
  }
  O[(size_t)tok*256 + d] = f2bf(siluf_(acc));
}

// ---------------- merged transposes: Xpab[b][p][d] -> Xpt0 (raster) / Xpt1 (colmajor) ----------------
__global__ void k_xtm(const ushortt* __restrict__ Xpab, ushortt* __restrict__ Xpt0,
                      ushortt* __restrict__ Xpt1){
  __shared__ ushortt Tl[64][68];
  int zb = blockIdx.z; int b = zb >> 1; int mode = zb & 1;
  int d0 = blockIdx.y*64;
  int di = threadIdx.x&63, q = threadIdx.x>>6;
  if (mode == 0){
    int p0 = blockIdx.x*64;
    for (int k2=0;k2<16;k2++){ int pi = q*16 + k2;
      Tl[pi][di] = Xpab[((size_t)b*LL + p0+pi)*256 + d0+di]; }
    __syncthreads();
    for (int k2=0;k2<16;k2++){ int dr = q*16 + k2;
      Xpt0[((size_t)(b*256 + d0+dr))*LL + p0+di] = Tl[di][dr]; }
  } else {
    int ww = blockIdx.x;
    for (int k2=0;k2<16;k2++){ int hh = q*16 + k2;
      Tl[hh][di] = Xpab[((size_t)b*LL + hh*128 + ww)*256 + d0+di]; }
    __syncthreads();
    for (int k2=0;k2<16;k2++){ int dr = q*16 + k2;
      Xpt1[((size_t)(b*256 + d0+dr))*LL + ww*64 + di] = Tl[di][dr]; }
  }
}

// ---------------- x_proj: per-token 4x40 projections, f32 weights (proven numerics) ----------------
// dts: DBCb rows of 32B per (bk,t): 8x f32.
// B/C: BCs dwords [bk][t/16][state][t%16]: bf16 B (low), C (high).
__global__ void k_xdbl(const ushortt* __restrict__ Xpab, const float* __restrict__ xpw,
                       char* __restrict__ DBCb, char* __restrict__ BCsb){
  __shared__ float U[16][256];
  int tid = threadIdx.x;
  int blk = blockIdx.x;              // B*L/16 = 2048
  int b = blk >> 9;
  int p0 = (blk & 511) << 4;
  for (int i=tid;i<16*256;i+=256){ int tt=i>>8, d=i&255;
    U[tt][d] = bf2f(Xpab[((size_t)b*LL + p0+tt)*256 + d]); }
  __syncthreads();
  if (tid < 160){
    int k = tid/40, c = tid%40;
    const float* wr = xpw + ((size_t)k*40 + c)*256;
    float acc[16];
#pragma unroll
    for (int tt=0;tt<16;tt++) acc[tt]=0.f;
    for (int d=0;d<256;d++){
      float wv = wr[d];
#pragma unroll
      for (int tt=0;tt<16;tt++) acc[tt] += U[tt][d]*wv;
    }
    int bk = b*KD + k;
    for (int tt=0;tt<16;tt++){
      int p = p0+tt; int hh=p>>7, ww=p&127;
      int t;
      if      (k==0) t = p;
      else if (k==1) t = (ww<<6)|hh;
      else if (k==2) t = LL-1-p;
      else           t = LL-1-((ww<<6)|hh);
      if (c < 8){
        *(float*)(DBCb + ((size_t)bk*LL + t)*32 + 4*c) = acc[tt];
      } else {
        int j = (c<24) ? c-8 : c-24;
        size_t a = ((((size_t)bk*512 + (t>>4))*16 + j)*16 + (t&15))*4 + ((c<24)?0:2);
        *(ushortt*)(BCsb + a) = f2bf(acc[tt]);
      }
    }
  }
}

// ---------------- Merged scan pass: from h=0, write y_local + h_out + sum(delta) ----------------
// 128 threads = 8 groups of 16 lanes.
__global__ __launch_bounds__(128) void k_scanM(const char* __restrict__ DBCb,
                        const uintt* __restrict__ BCs,
                        const ushortt* __restrict__ Xpt0, const ushortt* __restrict__ Xpt1,
                        const float* __restrict__ dtw_all, const float* __restrict__ dtb_all,
                        const float* __restrict__ A_logs,
                        float* __restrict__ Hbuf, float* __restrict__ Ssum,
                        ushortt* __restrict__ Y0, ushortt* __restrict__ Y1,
                        ushortt* __restrict__ Y2, ushortt* __restrict__ Y3){
  __shared__ float2 sdd[8][16];
  __shared__ float yt[8*328];       // group pitch 328 (==8 mod 32 banks): writes 2-way max
  int tid = threadIdx.x;
  int grp = tid >> 4, lane = tid & 15;
  float* ytg = yt + grp*328;
  int gid = blockIdx.x*8 + grp;
  int c = gid & 15;
  int bkd = gid >> 4;
  int b = bkd >> 10, k = (bkd>>8)&3, d = bkd & 255;
  int kd = k*256+d;
  int bk = b*KD + k;
  float dtw[8];
  { const float4* w4 = (const float4*)(dtw_all + (size_t)kd*8);
    float4 w0 = w4[0], w1 = w4[1];
    dtw[0]=w0.x; dtw[1]=w0.y; dtw[2]=w0.z; dtw[3]=w0.w;
    dtw[4]=w1.x; dtw[5]=w1.y; dtw[6]=w1.z; dtw[7]=w1.w; }
  float dtb  = dtb_all[kd];
  float Aval = -__expf(A_logs[(size_t)kd*16+lane]);
  const char* dbc = DBCb + (size_t)bk*LL*32;
  const uintt* bcb = BCs + ((size_t)bk*512 + (c*CH>>4))*256;
  const ushortt* Up = ((k&1)?Xpt1:Xpt0) + ((size_t)(b*256+d))*LL;
  ushortt* Yk = (k==0?Y0 : k==1?Y1 : k==2?Y2 : Y3) + ((size_t)b*256 + d)*LL;
  float h = 0.f, Sacc = 0.f;
  int t0 = c*CH;
  // prefetch block 0 dts + u
  const char* row0 = dbc + (size_t)(t0+lane)*32;
  float4 q0 = *(const float4*)row0;
  float4 q1 = *(const float4*)(row0+16);
  ushortt ur = Up[(k<2) ? (t0+lane) : (LL-1-(t0+lane))];
  for (int blk=0; blk<CH/16; ++blk){
    int tb = t0 + blk*16;
    int tme = tb + lane;
    // own-state B/C for the 16 steps of this block (contiguous 64B)
    const uint4* bcp = (const uint4*)(bcb + ((size_t)blk*16 + lane)*16);
    uint4 w0 = bcp[0], w1 = bcp[1], w2 = bcp[2], w3 = bcp[3];
    float4 c0 = q0, c1 = q1; ushortt cu = ur;
    if (blk+1 < CH/16){
      const char* rn = dbc + (size_t)(tme+16)*32;
      q0 = *(const float4*)rn;
      q1 = *(const float4*)(rn+16);
      ur = Up[(k<2) ? (tme+16) : (LL-1-(tme+16))];
    }
    float dsum = dtb + c0.x*dtw[0] + c0.y*dtw[1] + c0.z*dtw[2] + c0.w*dtw[3]
                     + c1.x*dtw[4] + c1.y*dtw[5] + c1.z*dtw[6] + c1.w*dtw[7];
    float delta = softplusf_(dsum);
    Sacc += delta;
    float u = bf2f(cu);
    sdd[grp][lane] = make_float2(delta, delta*u);
    lds_fence();             // order sdd write vs cross-lane reads below
    uintt wd[16] = {w0.x,w0.y,w0.z,w0.w, w1.x,w1.y,w1.z,w1.w,
                    w2.x,w2.y,w2.z,w2.w, w3.x,w3.y,w3.z,w3.w};
#pragma unroll
    for (int i=0;i<16;i++){
      float2 dd = sdd[grp][i];
      uintt w = wd[i];
      float Bn = __uint_as_float(w<<16);
      float Cn = __uint_as_float(w & 0xffff0000u);
      float e = __expf(dd.x * Aval);
      h = e*h + dd.y*Bn;
      ytg[i*20 + lane] = h*Cn;
    }
    lds_fence();             // order yt writes vs cross-lane yt reads
    const f32x4* yr = (const f32x4*)(ytg + lane*20);
    f32x4 s0 = yr[0], s1 = yr[1], s2v = yr[2], s3 = yr[3];
    float acc = (s0[0]+s0[1]+s0[2]+s0[3]) + (s1[0]+s1[1]+s1[2]+s1[3])
              + (s2v[0]+s2v[1]+s2v[2]+s2v[3]) + (s3[0]+s3[1]+s3[2]+s3[3]);
    Yk[tme] = f2bf(acc);
    lds_fence();             // order yt reads vs next block's yt writes
  }
  Hbuf[(size_t)gid*16 + lane] = h;
  float Stot = rowsum16(Sacc);
  if (lane==0) Ssum[gid] = Stot;
}

// Pass B: serial over chunks; converts Hbuf (h_out) to h_start in place.
__global__ void k_scanB(const float* __restrict__ Ssum, float* __restrict__ Hbuf,
                        const float* __restrict__ A_logs){
  int idx = blockIdx.x*256 + threadIdx.x;  // bkd*16+n (65536)
  int n = idx & 15; int bkd = idx >> 4;
  int kd = ((bkd>>8)&3)*256 + (bkd&255);
  float Aval = -__expf(A_logs[(size_t)kd*16+n]);
  float h = 0.f;
  for (int c=0;c<NC;c++){
    size_t g = (size_t)bkd*NC + c;
    float hout = Hbuf[g*16+n];
    Hbuf[g*16+n] = h;
    h = __expf(Aval*Ssum[g])*h + hout;
  }
}

// Pass C': correction sweep. y(t) += sum_n C_n(t) * exp(A_n * S_incl(t)) * h0_n.
__global__ __launch_bounds__(128) void k_corr(const char* __restrict__ DBCb,
                       const uintt* __restrict__ BCs,
                       const float* __restrict__ dtw_all, const float* __restrict__ dtb_all,
                       const float* __restrict__ Hbuf,
                       ushortt* __restrict__ Y0, ushortt* __restrict__ Y1,
                       ushortt* __restrict__ Y2, ushortt* __restrict__ Y3){
  int tid = threadIdx.x;
  int grp = tid >> 4, lane = tid & 15;
  int gid = blockIdx.x*8 + grp;
  int c = gid & 15;
  if (c == 0) return;                 // h0 == 0 exactly
  int bkd = gid >> 4;
  int b = bkd >> 10, k = (bkd>>8)&3, d = bkd & 255;
  int kd = k*256+d;
  int bk = b*KD + k;
  float h0[16];
  float hmax = 0.f;
#pragma unroll
  for (int n=0;n<16;n++){
    h0[n] = Hbuf[(size_t)gid*16 + n];
    hmax = fmaxf(hmax, fabsf(h0[n]));
  }
  float Sexit = 14.f + __logf(fmaxf(hmax, 1e-30f));
  if (0.f > Sexit) return;            // h0 negligible
  float dtw[8];
  { const float4* w4 = (const float4*)(dtw_all + (size_t)kd*8);
    float4 w0 = w4[0], w1 = w4[1];
    dtw[0]=w0.x; dtw[1]=w0.y; dtw[2]=w0.z; dtw[3]=w0.w;
    dtw[4]=w1.x; dtw[5]=w1.y; dtw[6]=w1.z; dtw[7]=w1.w; }
  float dtb  = dtb_all[kd];
  const char* dbc = DBCb + (size_t)bk*LL*32;
  ushortt* Yk = (k==0?Y0 : k==1?Y1 : k==2?Y2 : Y3) + ((size_t)b*256 + d)*LL;
  float S0 = 0.f;
  int t0 = c*CH;
  for (int blk=0; blk<CH/16; ++blk){
    int tme = t0 + blk*16 + lane;
    const char* rowme = dbc + (size_t)tme*32;
    float4 q0 = *(const float4*)rowme;
    float4 q1 = *(const float4*)(rowme+16);
    float dsum = dtb + q0.x*dtw[0] + q0.y*dtw[1] + q0.z*dtw[2] + q0.w*dtw[3]
                     + q1.x*dtw[4] + q1.y*dtw[5] + q1.z*dtw[6] + q1.w*dtw[7];
    float delta = softplusf_(dsum);
    // inclusive prefix sum over the 16-lane group
    float pre = delta;
#pragma unroll
    for (int o=1;o<16;o<<=1){
      float t = __shfl_up(pre, o, 16);
      if (lane >= o) pre += t;
    }
    float S = S0 + pre;
    float E = __expf(-S);
    const uintt* cb = BCs + ((size_t)bk*512 + (tme>>4))*256 + (tme&15);
    float p = E, acc = 0.f;
#pragma unroll
    for (int n=0;n<16;n++){
      float Cn = __uint_as_float(cb[n*16] & 0xffff0000u);
      acc += Cn * h0[n] * p;
      p *= E;
    }
    float yv = bf2f(Yk[tme]);
    Yk[tme] = f2bf(yv + acc);
    S0 = __shfl(S, 15, 16);           // block total carry
    if (S0 > Sexit) break;            // uniform across group
  }
}

// ---------------- Gate: gather Y0..Y3 + u*sum(D), LN256, *silu(z) ----------------
__global__ void k_gate2(const ushortt* __restrict__ Y0, const ushortt* __restrict__ Y1,
                        const ushortt* __restrict__ Y2, const ushortt* __restrict__ Y3,
                        const ushortt* __restrict__ Xpt0, const float* __restrict__ Ds,
                        ushortt* __restrict__ Zg,
                        const float* __restrict__ g, const float* __restrict__ bt){
  __shared__ float ysum[32][257];
  __shared__ float Dl[256];
  int tid = threadIdx.x;
  int wwb = blockIdx.x;      // 0..3
  int hh  = blockIdx.y;      // 0..63
  int b   = blockIdx.z;
  if (tid < 256) Dl[tid] = Ds[tid] + Ds[256+tid] + Ds[512+tid] + Ds[768+tid];
  int ww0 = wwb*32;
  for (int it=0; it<32; ++it){
    int idx = it*256 + tid;
    int d = idx >> 5, tl = idx & 31;
    int ww = ww0 + tl;
    int p  = hh*128 + ww;
    size_t base = ((size_t)b*256 + d) << 13;
    int t1 = ww*64 + hh;
    float v = bf2f(Y0[base + p]) + bf2f(Y2[base + (LL-1) - p])
            + bf2f(Y1[base + t1]) + bf2f(Y3[base + (LL-1) - t1]);
    ysum[tl][d] = v;
  }
  __syncthreads();
  {
    int d = tid;
    if (d < 256){
      size_t ub = (((size_t)b*256 + d) << 13) + hh*128 + ww0;
      for (int tl=0; tl<32; ++tl){
        float u = bf2f(Xpt0[ub + tl]);
        ysum[tl][d] += Dl[d]*u;
      }
    }
  }
  __syncthreads();
  int wave = tid >> 6, lane = tid & 63;
  for (int tk = wave*8; tk < wave*8+8; ++tk){
    float v0 = ysum[tk][lane], v1 = ysum[tk][lane+64];
    float v2 = ysum[tk][lane+128], v3 = ysum[tk][lane+192];
    float s  = waveReduceSum(v0+v1+v2+v3);
    float s2 = waveReduceSum(v0*v0+v1*v1+v2*v2+v3*v3);
    float mean = s*(1.f/256.f);
    float var  = s2*(1.f/256.f) - mean*mean;
    float r = rsqrtf(var + 1e-5f);
    int p = hh*128 + ww0 + tk;
    size_t zb = (((size_t)b<<13) + p) << 8;
#pragma unroll
    for (int j=0;j<4;j++){
      int dd = lane + 64*j;
      float ln = (ysum[tk][dd]-mean)*r*g[dd] + bt[dd];
      float z = bf2f(Zg[zb + dd]);
      Zg[zb + dd] = f2bf(ln * siluf_(z));
    }
  }
}

// ---------------- MFMA 3x3 conv 128->128(all co) + BN (+res) + ReLU ----------------
// grid (64 y, 8 img), block 256 = 4 waves (one x-quarter each), 128 co per wave.
template<int FINAL>
__global__ void k_mconv(const ushortt* __restrict__ I, const ushortt* __restrict__ Wt,
                        const float* __restrict__ g, const float* __restrict__ bb,
                        const float* __restrict__ mn, const float* __restrict__ vv,
                        const float* __restrict__ R, ushortt* __restrict__ Op,
                        float* __restrict__ Of){
  int y  = blockIdx.x;
  int im = blockIdx.y;
  int wv = threadIdx.x>>6, l = threadIdx.x&63;
  int ar = l&15, kg = l>>4;
  int x0 = wv*16;
  f32x4 acc[8];
#pragma unroll
  for (int i=0;i<8;i++){ acc[i][0]=0.f; acc[i][1]=0.f; acc[i][2]=0.f; acc[i][3]=0.f; }
  const ushortt* Ibase = I + (((size_t)im*66 + y)*66 + x0 + ar)*128 + kg*8;
  const ushortt* Wbase = Wt + (size_t)ar*128 + kg*8;
#pragma unroll
  for (int tap=0; tap<9; ++tap){
    int dy = tap/3, dx = tap - dy*3;
    const ushortt* Ir = Ibase + ((size_t)dy*66 + dx)*128;
    const ushortt* Wr = Wbase + (size_t)tap*16384;
#pragma unroll
    for (int kc=0;kc<4;kc++){
      bf16x8 af = *(const bf16x8*)(Ir + kc*32);
#pragma unroll
      for (int nf=0;nf<8;nf++){
        bf16x8 bfv = *(const bf16x8*)(Wr + (size_t)nf*16*128 + kc*32);
        acc[nf] = __builtin_amdgcn_mfma_f32_16x16x32_bf16(af, bfv, acc[nf], 0,0,0);
      }
    }
  }
#pragma unroll
  for (int nf=0;nf<8;nf++){
    int co = nf*16 + ar;
    float s  = g[co]*rsqrtf(vv[co]+1e-5f);
    float sh = bb[co] - mn[co]*s;
#pragma unroll
    for (int r=0;r<4;r++){
      int x = x0 + kg*4 + r;
      float v = acc[nf][r]*s + sh;
      if (FINAL){
        v += R[(((size_t)im*64 + y)*64 + x)*128 + co];
        v = fmaxf(v, 0.f);
        Of[(((size_t)im*128 + co)*64 + y)*64 + x] = v;
      } else {
        v = fmaxf(v, 0.f);
        Op[(((size_t)im*66 + (y+1))*66 + (x+1))*128 + co] = f2bf(v);
      }
    }
  }
}

extern "C" void kernel_launch(void* const* d_in, const int* in_sizes, int n_in,
                              void* d_out, int out_size, void* d_ws, size_t ws_size,
                              hipStream_t stream){
  const float* x1        = (const float*)d_in[0];
  const float* x2        = (const float*)d_in[1];
  const float* conv_in_w = (const float*)d_in[2];
  const float* conv_in_b = (const float*)d_in[3];
  const float* ln1_g     = (const float*)d_in[4];
  const float* ln1_b     = (const float*)d_in[5];
  const float* in_proj_w = (const float*)d_in[6];
  const float* dw_w      = (const float*)d_in[7];
  const float* dw_b      = (const float*)d_in[8];
  const float* x_proj_w  = (const float*)d_in[9];
  const float* dt_proj_w = (const float*)d_in[10];
  const float* dt_proj_b = (const float*)d_in[11];
  const float* A_logs    = (const float*)d_in[12];
  const float* Ds        = (const float*)d_in[13];
  const float* onorm_g   = (const float*)d_in[14];
  const float* onorm_b   = (const float*)d_in[15];
  const float* out_proj_w= (const float*)d_in[16];
  const float* ln2_g     = (const float*)d_in[17];
  const float* ln2_b     = (const float*)d_in[18];
  const float* mlp_w1    = (const float*)d_in[19];
  const float* mlp_b1    = (const float*)d_in[20];
  const float* mlp_w2    = (const float*)d_in[21];
  const float* mlp_b2    = (const float*)d_in[22];
  const float* rb1_w     = (const float*)d_in[23];
  const float* bn1_g     = (const float*)d_in[24];
  const float* bn1_b     = (const float*)d_in[25];
  const float* bn1_m     = (const float*)d_in[26];
  const float* bn1_v     = (const float*)d_in[27];
  const float* rb2_w     = (const float*)d_in[28];
  const float* bn2_g     = (const float*)d_in[29];
  const float* bn2_b     = (const float*)d_in[30];
  const float* bn2_m     = (const float*)d_in[31];
  const float* bn2_v     = (const float*)d_in[32];

  float* ws = (float*)d_ws;
  char*  wsB = (char*)d_ws;
  const size_t FM = 262144;            // floats per MiB
  const size_t MB = 1048576;           // bytes per MiB
  // Workspace layout (peak ~147.1 MiB, proven available):
  float*   X0   = ws;                          // 0-16    residual stream (B,L,128) f32
  ushortt* Xpab = (ushortt*)(wsB + 16*MB);     // 16-32   u post-dw-silu (B,L,256) bf16
  ushortt* Xpt0 = (ushortt*)(wsB + 32*MB);     // 32-48   u raster-order [b][d][p]
  ushortt* Xpt1 = (ushortt*)(wsB + 48*MB);     // 48-64   u colmajor-order [b][d][t1]
  char*    DBCb = wsB + 64*MB;                 // 64-68   dts rows 32B
  uintt*   BCs  = (uintt*)(wsB + 68*MB);       // 68-76   B/C dwords [bk][t/16][n][t%16]
  ushortt* Zg   = (ushortt*)(wsB + 77*MB);     // 77-93   z / gated bf16
  ushortt* Y0   = (ushortt*)(wsB + 93*MB);     // 93-109
  ushortt* Y1   = (ushortt*)(wsB + 109*MB);    // 109-125
  ushortt* Y2   = (ushortt*)(wsB + 125*MB);    // 125-141
  ushortt* Y3   = Xpab;                        // alias (Xpab dead before scanM)
  float*   Hbuf = ws + 141*FM;                 // 141-145
  float*   Ssum = ws + 145*FM;                 // 145-145.25
  // time-disjoint aliases:
  ushortt* CT   = (ushortt*)(wsB + 93*MB);     // steps 1-2 (over Y0)
  ushortt* Lnb  = (ushortt*)(wsB + 101*MB);    // steps 2-4 (over Y0 2nd half)
  ushortt* Xpb  = (ushortt*)(wsB + 109*MB);    // steps 4-5 xp pre-dw bf16 (over Y1)
  ushortt* Ln2b = (ushortt*)(wsB + 93*MB);     // steps 9-11 (Y0 dead)
  ushortt* H1   = (ushortt*)(wsB + 109*MB);    // steps 11-12 (Y1,Y2 dead)
  ushortt* P    = (ushortt*)(wsB + 16*MB);     // step 12+ padded conv input [8][66][66][128]
  ushortt* T    = (ushortt*)(wsB + 25*MB);     // conv1 out padded
  float*   R    = (float*)(wsB + 34*MB);       // 34-51 residual [8][64][64][128] f32
  // bf16 weights (persistent, never aliased):
  ushortt* cw  = (ushortt*)(wsB + 146*MB);           // 32 KB
  ushortt* ipw = (ushortt*)(wsB + 146*MB + 32*1024); // 128 KB
  ushortt* opw = (ushortt*)(wsB + 146*MB + 160*1024);// 64 KB
  ushortt* m1w = (ushortt*)(wsB + 146*MB + 224*1024);// 128 KB
  ushortt* m2w = (ushortt*)(wsB + 146*MB + 352*1024);// 128 KB
  ushortt* rw1 = (ushortt*)(wsB + 146*MB + 480*1024);// 288 KB
  ushortt* rw2 = (ushortt*)(wsB + 146*MB + 768*1024);// 288 KB
  float* out = (float*)d_out;

  // 0. all weight conversions (one launch)
  k_wall<<<2112,256,0,stream>>>(conv_in_w,cw, in_proj_w,ipw, out_proj_w,opw,
                                mlp_w1,m1w, mlp_w2,m2w, rb1_w,rw1, rb2_w,rw2);
  // 1. interleave -> CT bf16 token-major
  k_build_ct2<<<512,256,0,stream>>>(x1,x2,CT);
  // 2. conv_in 1x1 (bias) -> X0 f32 + fused LN1 -> Lnb bf16
  k_mgemmln<0><<<512,256,0,stream>>>(CT, cw, conv_in_b, X0, ln1_g, ln1_b, Lnb, 128);
  // 4. in_proj (512) -> split xp(Xpb bf16) / z(Zg bf16)
  k_mgemm<3><<<dim3(8,512),256,0,stream>>>(Lnb, ipw, nullptr, nullptr, nullptr, Zg, Xpb, nullptr, 512,128);
  // 5. depthwise 3x3 + silu -> Xpab bf16
  k_dwconv<<<BB*LL,256,0,stream>>>(Xpb, dw_w, dw_b, Xpab);
  // 5b. direction-ordered u copies (merged)
  k_xtm<<<dim3(128,4,2*BB),256,0,stream>>>(Xpab, Xpt0, Xpt1);
  // 6. x_proj (f32 weights, proven numerics) -> dts (DBCb) + B/C (BCs)
  k_xdbl<<<2048,256,0,stream>>>(Xpab, x_proj_w, DBCb, (char*)BCs);
  // 7. chunked selective scan: merged main pass + chain + correction
  k_scanM<<<8192,128,0,stream>>>(DBCb, BCs, Xpt0, Xpt1, dt_proj_w, dt_proj_b, A_logs,
                                 Hbuf, Ssum, Y0,Y1,Y2,Y3);
  k_scanB<<<256,256,0,stream>>>(Ssum, Hbuf, A_logs);
  k_corr<<<8192,128,0,stream>>>(DBCb, BCs, dt_proj_w, dt_proj_b, Hbuf, Y0,Y1,Y2,Y3);
  // 8. gate
  k_gate2<<<dim3(4,64,BB),256,0,stream>>>(Y0,Y1,Y2,Y3, Xpt0, Ds, Zg, onorm_g, onorm_b);
  // 9. out_proj + residual -> X0 + fused LN2 -> Ln2b bf16
  k_mgemmln<1><<<512,256,0,stream>>>(Zg, opw, nullptr, X0, ln2_g, ln2_b, Ln2b, 256);
  // 9b. zero padded conv buffers (P and T) — Xpab/Xpt0 regions now dead
  hipMemsetAsync(wsB + 16*MB, 0, 18*MB, stream);
  // 11. MLP1 gelu -> H1 bf16
  k_mgemm<2><<<dim3(8,512),256,0,stream>>>(Ln2b, m1w, mlp_b1, nullptr, nullptr, H1, nullptr,nullptr, 512,128);
  // 12. MLP2 + bias + residual -> fused de-interleave (P bf16 padded + R f32)
  k_mgemm<4><<<dim3(2,512),256,0,stream>>>(H1, m2w, mlp_b2, X0, nullptr, nullptr, P, R, 128,512);
  // 13-14. resblocks (both images batched, img = im2*4 + b)
  k_mconv<0><<<dim3(64,8),256,0,stream>>>(P, rw1, bn1_g,bn1_b,bn1_m,bn1_v, nullptr, T, nullptr);
  k_mconv<1><<<dim3(64,8),256,0,stream>>>(T, rw2, bn2_g,bn2_b,bn2_m,bn2_v, R, nullptr, out);
}

// Round 13
// 832.025 us; speedup vs baseline: 12.7929x; 1.0081x over previous
//
#include <hip/hip_runtime.h>
#include <math.h>

// Problem constants
#define BB 4
#define CM 128      // d_model
#define DI 256      // d_inner
#define NS 16       // d_state
#define RK 8        // dt_rank
#define KD 4        // K directions
#define HH 64
#define WW 128      // interleaved width
#define LL 8192     // HH*WW
#define NC 16       // scan chunks per sequence
#define CH 512      // chunk length (NC*CH == LL)

typedef unsigned short ushortt;
typedef unsigned int uintt;
typedef __attribute__((ext_vector_type(8))) __bf16 bf16x8;
typedef __attribute__((ext_vector_type(4))) float f32x4;

__device__ __forceinline__ void lds_fence(){
  asm volatile("" ::: "memory");
  __builtin_amdgcn_sched_barrier(0);
}

__device__ __forceinline__ float sigmoidf_(float x){ return 1.f/(1.f+__expf(-x)); }
__device__ __forceinline__ float siluf_(float x){ return x*sigmoidf_(x); }
__device__ __forceinline__ float softplusf_(float x){
  float r = __logf(1.f + __expf(x));   // fast path, no libcall
  return (x > 20.f) ? x : r;
}
__device__ __forceinline__ float geluf_(float x){ return 0.5f*x*(1.f+erff(x*0.70710678118654752f)); }
__device__ __forceinline__ ushortt f2bf(float f){
  uintt u = __float_as_uint(f);
  uintt r = (u + 0x7fffu + ((u>>16)&1u)) >> 16;
  return (ushortt)r;
}
__device__ __forceinline__ float bf2f(ushortt s){
  return __uint_as_float(((uintt)s)<<16);
}
template<int CTRL>
__device__ __forceinline__ float dppadd(float x){
  int r = __builtin_amdgcn_update_dpp(0, __float_as_int(x), CTRL, 0xF, 0xF, true);
  return x + __int_as_float(r);
}
// full sum over each 16-lane row; result on all lanes
__device__ __forceinline__ float rowsum16(float x){
  x = dppadd<0x121>(x);  // row_ror:1
  x = dppadd<0x122>(x);  // row_ror:2
  x = dppadd<0x124>(x);  // row_ror:4
  x = dppadd<0x128>(x);  // row_ror:8
  return x;
}
__device__ __forceinline__ float waveReduceSum(float v){
  for (int o=32;o>0;o>>=1) v += __shfl_xor(v,o,64);
  return v;
}

// ---------------- merged weight conversions (1 launch) ----------------
__global__ void k_wall(const float* __restrict__ cw_s, ushortt* __restrict__ cw_d,
                       const float* __restrict__ ip_s, ushortt* __restrict__ ip_d,
                       const float* __restrict__ op_s, ushortt* __restrict__ op_d,
                       const float* __restrict__ m1_s, ushortt* __restrict__ m1_d,
                       const float* __restrict__ m2_s, ushortt* __restrict__ m2_d,
                       const float* __restrict__ r1_s, ushortt* __restrict__ r1_d,
                       const float* __restrict__ r2_s, ushortt* __restrict__ r2_d,
                       const float* __restrict__ dw_s, float* __restrict__ dw_d){
  int i = blockIdx.x*256 + threadIdx.x;
  if (i < 16384){ cw_d[i] = f2bf(cw_s[i]); return; }
  i -= 16384;
  if (i < 65536){ ip_d[i] = f2bf(ip_s[i]); return; }
  i -= 65536;
  if (i < 32768){ op_d[i] = f2bf(op_s[i]); return; }
  i -= 32768;
  if (i < 65536){ m1_d[i] = f2bf(m1_s[i]); return; }
  i -= 65536;
  if (i < 65536){ m2_d[i] = f2bf(m2_s[i]); return; }
  i -= 65536;
  if (i < 147456){ int ci=i&127, co=(i>>7)&127, tap=i>>14;
    r1_d[i]=f2bf(r1_s[(size_t)(co*128+ci)*9+tap]); return; }
  i -= 147456;
  if (i < 147456){ int ci=i&127, co=(i>>7)&127, tap=i>>14;
    r2_d[i]=f2bf(r2_s[(size_t)(co*128+ci)*9+tap]); return; }
  i -= 147456;
  if (i < 2304){ int d = i & 255, tap = i >> 8;
    dw_d[i] = dw_s[d*9 + tap]; }     // exact f32 copy, [tap][d] layout
}

// ---------------- CT build: interleave x1/x2 -> token-major bf16 (B*L, 128) ----------------
__global__ void k_build_ct2(const float* __restrict__ x1, const float* __restrict__ x2,
                            ushortt* __restrict__ CT){
  __shared__ ushortt Tl[64][136];
  int tid = threadIdx.x;
  int p0 = (blockIdx.x & 127) * 64;
  int b  = blockIdx.x >> 7;
  int j = tid & 63;
  int p = p0 + j; int hh = p>>7, ww = p&127, w2 = ww>>1;
  const float* src = (ww&1) ? x2 : x1;
  const float* sp = src + ((size_t)b*128*64 + hh)*64 + w2;
  for (int c0 = tid>>6; c0 < 128; c0 += 4)
    Tl[j][c0] = f2bf(sp[(size_t)c0*4096]);
  __syncthreads();
  int c = tid & 127; int rh = tid >> 7;
  for (int r = rh; r < 64; r += 2)
    CT[((size_t)b*LL + p0 + r)*128 + c] = Tl[r][c];
}

// ---------------- MFMA token GEMM ----------------
// A: [32768][K] bf16, W: [N][K] bf16; grid (N/(NF*16), 512), block 256 (4 waves).
// EPI 2: +bias,gelu -> bf16 C2 (stride 512)
// EPI 3: split n<256 -> bf16 Pp (xp), else bf16 C2 (z), both stride 256
// EPI 4: +bias+resid -> fused de-interleave: P (padded bf16) + R (f32), N=128
template<int EPI, int NF>
__global__ void k_mgemm(const ushortt* __restrict__ A, const ushortt* __restrict__ W,
                        const float* __restrict__ bias, const float* __restrict__ resid,
                        float* __restrict__ C, ushortt* __restrict__ C2,
                        ushortt* __restrict__ Pp, float* __restrict__ Rp, int N, int K){
  int n0 = blockIdx.x*(NF*16), m0 = blockIdx.y*64;
  int wv = threadIdx.x>>6, l = threadIdx.x&63;
  int ar = l&15, kg = l>>4;
  int mw = m0 + wv*16;
  f32x4 acc[NF];
#pragma unroll
  for (int i=0;i<NF;i++){ acc[i][0]=0.f; acc[i][1]=0.f; acc[i][2]=0.f; acc[i][3]=0.f; }
  const ushortt* Ap = A + (size_t)(mw+ar)*K + kg*8;
  const ushortt* Wp = W + (size_t)(n0+ar)*K + kg*8;
  for (int k0=0; k0<K; k0+=32){
    bf16x8 af = *(const bf16x8*)(Ap + k0);
#pragma unroll
    for (int nf=0; nf<NF; ++nf){
      bf16x8 bfv = *(const bf16x8*)(Wp + (size_t)nf*16*K + k0);
      acc[nf] = __builtin_amdgcn_mfma_f32_16x16x32_bf16(af, bfv, acc[nf], 0,0,0);
    }
  }
#pragma unroll
  for (int nf=0;nf<NF;nf++){
    int n = n0 + nf*16 + ar;
#pragma unroll
    for (int r=0;r<4;r++){
      int m = mw + kg*4 + r;
      float v = acc[nf][r];
      if (EPI==2){
        v += bias[n];
        C2[(size_t)m*512 + n] = f2bf(geluf_(v));
      } else if (EPI==3){
        if (n < 256) Pp[(size_t)m*256 + n] = f2bf(v);
        else         C2[(size_t)m*256 + (n-256)] = f2bf(v);
      } else { // EPI==4
        v += bias[n];
        v += resid[(size_t)m*128 + n];
        int bq = m >> 13; int pq = m & 8191; int yq = pq >> 7; int wq = pq & 127;
        int im = (wq&1)*4 + bq; int xq = wq>>1;
        Pp[(((size_t)im*66 + yq+1)*66 + xq+1)*128 + n] = f2bf(v);
        Rp[(((size_t)im*64 + yq)*64 + xq)*128 + n] = v;
      }
    }
  }
}

// ---------------- MFMA GEMM (N=128) with fused LayerNorm epilogue ----------------
// RES=0: X = A@W^T + bias; RES=1: X = A@W^T + X(old). Then O = bf16(LN(X)).
template<int RES>
__global__ void k_mgemmln(const ushortt* __restrict__ A, const ushortt* __restrict__ W,
                          const float* __restrict__ bias, float* __restrict__ X,
                          const float* __restrict__ g, const float* __restrict__ bt,
                          ushortt* __restrict__ O, int K){
  int m0 = blockIdx.x*64;
  int wv = threadIdx.x>>6, l = threadIdx.x&63;
  int ar = l&15, kg = l>>4;
  int mw = m0 + wv*16;
  f32x4 acc[8];
#pragma unroll
  for (int i=0;i<8;i++){ acc[i][0]=0.f; acc[i][1]=0.f; acc[i][2]=0.f; acc[i][3]=0.f; }
  const ushortt* Ap = A + (size_t)(mw+ar)*K + kg*8;
  const ushortt* Wp = W + (size_t)ar*K + kg*8;
  for (int k0=0; k0<K; k0+=32){
    bf16x8 af = *(const bf16x8*)(Ap + k0);
#pragma unroll
    for (int nf=0; nf<8; ++nf){
      bf16x8 bfv = *(const bf16x8*)(Wp + (size_t)nf*16*K + k0);
      acc[nf] = __builtin_amdgcn_mfma_f32_16x16x32_bf16(af, bfv, acc[nf], 0,0,0);
    }
  }
  float vv[8][4];
  float s[4] = {0,0,0,0}, s2[4] = {0,0,0,0};
#pragma unroll
  for (int nf=0;nf<8;nf++){
    int n = nf*16 + ar;
    float bv = bias ? bias[n] : 0.f;
#pragma unroll
    for (int r=0;r<4;r++){
      int m = mw + kg*4 + r;
      float v = acc[nf][r] + bv;
      if (RES) v += X[(size_t)m*128 + n];
      X[(size_t)m*128 + n] = v;
      vv[nf][r] = v;
      s[r] += v; s2[r] += v*v;
    }
  }
  float mn[4], rs[4];
#pragma unroll
  for (int r=0;r<4;r++){
    float S  = rowsum16(s[r]);
    float S2 = rowsum16(s2[r]);
    float mean = S*(1.f/128.f);
    float var  = S2*(1.f/128.f) - mean*mean;
    mn[r] = mean; rs[r] = rsqrtf(var + 1e-5f);
  }
#pragma unroll
  for (int nf=0;nf<8;nf++){
    int n = nf*16 + ar;
    float gv = g[n], bv = bt[n];
#pragma unroll
    for (int r=0;r<4;r++){
      int m = mw + kg*4 + r;
      O[(size_t)m*128 + n] = f2bf((vv[nf][r]-mn[r])*rs[r]*gv + bv);
    }
  }
}

// ---------------- Depthwise 3x3 + bias + SiLU, channel-last (B,L,256) bf16->bf16 ----------------
// dwt: [tap][256] f32 (pre-transposed, coalesced)
__global__ void k_dwconv(const ushortt* __restrict__ Xp, const float* __restrict__ dwt,
                         const float* __restrict__ bias, ushortt* __restrict__ O){
  int tok = blockIdx.x; int d = threadIdx.x;
  int b = tok >> 13; int p = tok & (LL-1); int hh = p>>7, ww = p&127;
  float acc = bias[d];
#pragma unroll
  for (int dy=0;dy<3;dy++){
    int yy = hh+dy-1; if (yy<0||yy>=HH) continue;
#pragma unroll
    for (int dx=0;dx<3;dx++){
      int xx = ww+dx-1; if (xx<0||xx>=WW) continue;
      acc += bf2f(Xp[((size_t)b*LL + yy*WW + xx)*256 + d]) * dwt[(dy*3+dx)*256 + d];
    }
  }
  O[(size_t)tok*256 + d] = f2bf(siluf_(acc));
}

// ---------------- merged transposes: Xpab[b][p][d] -> Xpt0 (raster) / Xpt1 (colmajor) ----------------
__global__ void k_xtm(const ushortt* __restrict__ Xpab, ushortt* __restrict__ Xpt0,
                      ushortt* __restrict__ Xpt1){
  __shared__ ushortt Tl[64][68];
  int zb = blockIdx.z; int b = zb >> 1; int mode = zb & 1;
  int d0 = blockIdx.y*64;
  int di = threadIdx.x&63, q = threadIdx.x>>6;
  if (mode == 0){
    int p0 = blockIdx.x*64;
    for (int k2=0;k2<16;k2++){ int pi = q*16 + k2;
      Tl[pi][di] = Xpab[((size_t)b*LL + p0+pi)*256 + d0+di]; }
    __syncthreads();
    for (int k2=0;k2<16;k2++){ int dr = q*16 + k2;
      Xpt0[((size_t)(b*256 + d0+dr))*LL + p0+di] = Tl[di][dr]; }
  } else {
    int ww = blockIdx.x;
    for (int k2=0;k2<16;k2++){ int hh = q*16 + k2;
      Tl[hh][di] = Xpab[((size_t)b*LL + hh*128 + ww)*256 + d0+di]; }
    __syncthreads();
    for (int k2=0;k2<16;k2++){ int dr = q*16 + k2;
      Xpt1[((size_t)(b*256 + d0+dr))*LL + ww*64 + di] = Tl[di][dr]; }
  }
}

// ---------------- x_proj: per-token 4x40 projections, f32 weights (proven numerics) ----------------
// dts: DBCb rows of 32B per (bk,t): 8x f32.
// B/C: BCs dwords [bk][t/16][state][t%16]: bf16 B (low), C (high).
__global__ void k_xdbl(const ushortt* __restrict__ Xpab, const float* __restrict__ xpw,
                       char* __restrict__ DBCb, char* __restrict__ BCsb){
  __shared__ float U[16][256];
  int tid = threadIdx.x;
  int blk = blockIdx.x;              // B*L/16 = 2048
  int b = blk >> 9;
  int p0 = (blk & 511) << 4;
  for (int i=tid;i<16*256;i+=256){ int tt=i>>8, d=i&255;
    U[tt][d] = bf2f(Xpab[((size_t)b*LL + p0+tt)*256 + d]); }
  __syncthreads();
  if (tid < 160){
    int k = tid/40, c = tid%40;
    const float* wr = xpw + ((size_t)k*40 + c)*256;
    float acc[16];
#pragma unroll
    for (int tt=0;tt<16;tt++) acc[tt]=0.f;
    for (int d=0;d<256;d++){
      float wv = wr[d];
#pragma unroll
      for (int tt=0;tt<16;tt++) acc[tt] += U[tt][d]*wv;
    }
    int bk = b*KD + k;
    for (int tt=0;tt<16;tt++){
      int p = p0+tt; int hh=p>>7, ww=p&127;
      int t;
      if      (k==0) t = p;
      else if (k==1) t = (ww<<6)|hh;
      else if (k==2) t = LL-1-p;
      else           t = LL-1-((ww<<6)|hh);
      if (c < 8){
        *(float*)(DBCb + ((size_t)bk*LL + t)*32 + 4*c) = acc[tt];
      } else {
        int j = (c<24) ? c-8 : c-24;
        size_t a = ((((size_t)bk*512 + (t>>4))*16 + j)*16 + (t&15))*4 + ((c<24)?0:2);
        *(ushortt*)(BCsb + a) = f2bf(acc[tt]);
      }
    }
  }
}

// ---------------- Merged scan pass: from h=0, write y_local + h_out + sum(delta) ----------------
// 128 threads = 8 groups of 16 lanes.
__global__ __launch_bounds__(128) void k_scanM(const char* __restrict__ DBCb,
                        const uintt* __restrict__ BCs,
                        const ushortt* __restrict__ Xpt0, const ushortt* __restrict__ Xpt1,
                        const float* __restrict__ dtw_all, const float* __restrict__ dtb_all,
                        const float* __restrict__ A_logs,
                        float* __restrict__ Hbuf, float* __restrict__ Ssum,
                        ushortt* __restrict__ Y0, ushortt* __restrict__ Y1,
                        ushortt* __restrict__ Y2, ushortt* __restrict__ Y3){
  __shared__ float2 sdd[8][16];
  __shared__ float yt[8*328];       // group pitch 328
  int tid = threadIdx.x;
  int grp = tid >> 4, lane = tid & 15;
  float* ytg = yt + grp*328;
  int gid = blockIdx.x*8 + grp;
  int c = gid & 15;
  int bkd = gid >> 4;
  int b = bkd >> 10, k = (bkd>>8)&3, d = bkd & 255;
  int kd = k*256+d;
  int bk = b*KD + k;
  float dtw[8];
  { const float4* w4 = (const float4*)(dtw_all + (size_t)kd*8);
    float4 w0 = w4[0], w1 = w4[1];
    dtw[0]=w0.x; dtw[1]=w0.y; dtw[2]=w0.z; dtw[3]=w0.w;
    dtw[4]=w1.x; dtw[5]=w1.y; dtw[6]=w1.z; dtw[7]=w1.w; }
  float dtb  = dtb_all[kd];
  float Aval = -__expf(A_logs[(size_t)kd*16+lane]);
  const char* dbc = DBCb + (size_t)bk*LL*32;
  const uintt* bcb = BCs + ((size_t)bk*512 + (c*CH>>4))*256;
  const ushortt* Up = ((k&1)?Xpt1:Xpt0) + ((size_t)(b*256+d))*LL;
  ushortt* Yk = (k==0?Y0 : k==1?Y1 : k==2?Y2 : Y3) + ((size_t)b*256 + d)*LL;
  float h = 0.f, Sacc = 0.f;
  int t0 = c*CH;
  // prefetch block 0 dts + u
  const char* row0 = dbc + (size_t)(t0+lane)*32;
  float4 q0 = *(const float4*)row0;
  float4 q1 = *(const float4*)(row0+16);
  ushortt ur = Up[(k<2) ? (t0+lane) : (LL-1-(t0+lane))];
  for (int blk=0; blk<CH/16; ++blk){
    int tb = t0 + blk*16;
    int tme = tb + lane;
    const uint4* bcp = (const uint4*)(bcb + ((size_t)blk*16 + lane)*16);
    uint4 w0 = bcp[0], w1 = bcp[1], w2 = bcp[2], w3 = bcp[3];
    float4 c0 = q0, c1 = q1; ushortt cu = ur;
    if (blk+1 < CH/16){
      const char* rn = dbc + (size_t)(tme+16)*32;
      q0 = *(const float4*)rn;
      q1 = *(const float4*)(rn+16);
      ur = Up[(k<2) ? (tme+16) : (LL-1-(tme+16))];
    }
    float dsum = dtb + c0.x*dtw[0] + c0.y*dtw[1] + c0.z*dtw[2] + c0.w*dtw[3]
                     + c1.x*dtw[4] + c1.y*dtw[5] + c1.z*dtw[6] + c1.w*dtw[7];
    float delta = softplusf_(dsum);
    Sacc += delta;
    float u = bf2f(cu);
    sdd[grp][lane] = make_float2(delta, delta*u);
    lds_fence();             // order sdd write vs cross-lane reads below
    uintt wd[16] = {w0.x,w0.y,w0.z,w0.w, w1.x,w1.y,w1.z,w1.w,
                    w2.x,w2.y,w2.z,w2.w, w3.x,w3.y,w3.z,w3.w};
#pragma unroll
    for (int i=0;i<16;i++){
      float2 dd = sdd[grp][i];
      uintt w = wd[i];
      float Bn = __uint_as_float(w<<16);
      float Cn = __uint_as_float(w & 0xffff0000u);
      float e = __expf(dd.x * Aval);
      h = e*h + dd.y*Bn;
      ytg[i*20 + lane] = h*Cn;
    }
    lds_fence();             // order yt writes vs cross-lane yt reads
    const f32x4* yr = (const f32x4*)(ytg + lane*20);
    f32x4 s0 = yr[0], s1 = yr[1], s2v = yr[2], s3 = yr[3];
    float acc = (s0[0]+s0[1]+s0[2]+s0[3]) + (s1[0]+s1[1]+s1[2]+s1[3])
              + (s2v[0]+s2v[1]+s2v[2]+s2v[3]) + (s3[0]+s3[1]+s3[2]+s3[3]);
    Yk[tme] = f2bf(acc);
    lds_fence();             // order yt reads vs next block's yt writes
  }
  Hbuf[(size_t)gid*16 + lane] = h;
  float Stot = rowsum16(Sacc);
  if (lane==0) Ssum[gid] = Stot;
}

// Pass B: serial over chunks; converts Hbuf (h_out) to h_start in place.
__global__ void k_scanB(const float* __restrict__ Ssum, float* __restrict__ Hbuf,
                        const float* __restrict__ A_logs){
  int idx = blockIdx.x*256 + threadIdx.x;  // bkd*16+n (65536)
  int n = idx & 15; int bkd = idx >> 4;
  int kd = ((bkd>>8)&3)*256 + (bkd&255);
  float Aval = -__expf(A_logs[(size_t)kd*16+n]);
  float h = 0.f;
  for (int c=0;c<NC;c++){
    size_t g = (size_t)bkd*NC + c;
    float hout = Hbuf[g*16+n];
    Hbuf[g*16+n] = h;
    h = __expf(Aval*Ssum[g])*h + hout;
  }
}

// Pass C': correction sweep. y(t) += sum_n C_n(t) * exp(A_n * S_incl(t)) * h0_n.
__global__ __launch_bounds__(128) void k_corr(const char* __restrict__ DBCb,
                       const uintt* __restrict__ BCs,
                       const float* __restrict__ dtw_all, const float* __restrict__ dtb_all,
                       const float* __restrict__ Hbuf,
                       ushortt* __restrict__ Y0, ushortt* __restrict__ Y1,
                       ushortt* __restrict__ Y2, ushortt* __restrict__ Y3){
  int tid = threadIdx.x;
  int grp = tid >> 4, lane = tid & 15;
  int gid = blockIdx.x*8 + grp;
  int c = gid & 15;
  if (c == 0) return;                 // h0 == 0 exactly
  int bkd = gid >> 4;
  int b = bkd >> 10, k = (bkd>>8)&3, d = bkd & 255;
  int kd = k*256+d;
  int bk = b*KD + k;
  float h0[16];
  float hmax = 0.f;
#pragma unroll
  for (int n=0;n<16;n++){
    h0[n] = Hbuf[(size_t)gid*16 + n];
    hmax = fmaxf(hmax, fabsf(h0[n]));
  }
  float Sexit = 14.f + __logf(fmaxf(hmax, 1e-30f));
  if (0.f > Sexit) return;            // h0 negligible
  float dtw[8];
  { const float4* w4 = (const float4*)(dtw_all + (size_t)kd*8);
    float4 w0 = w4[0], w1 = w4[1];
    dtw[0]=w0.x; dtw[1]=w0.y; dtw[2]=w0.z; dtw[3]=w0.w;
    dtw[4]=w1.x; dtw[5]=w1.y; dtw[6]=w1.z; dtw[7]=w1.w; }
  float dtb  = dtb_all[kd];
  const char* dbc = DBCb + (size_t)bk*LL*32;
  ushortt* Yk = (k==0?Y0 : k==1?Y1 : k==2?Y2 : Y3) + ((size_t)b*256 + d)*LL;
  float S0 = 0.f;
  int t0 = c*CH;
  for (int blk=0; blk<CH/16; ++blk){
    int tme = t0 + blk*16 + lane;
    const char* rowme = dbc + (size_t)tme*32;
    float4 q0 = *(const float4*)rowme;
    float4 q1 = *(const float4*)(rowme+16);
    float dsum = dtb + q0.x*dtw[0] + q0.y*dtw[1] + q0.z*dtw[2] + q0.w*dtw[3]
                     + q1.x*dtw[4] + q1.y*dtw[5] + q1.z*dtw[6] + q1.w*dtw[7];
    float delta = softplusf_(dsum);
    // inclusive prefix sum over the 16-lane group
    float pre = delta;
#pragma unroll
    for (int o=1;o<16;o<<=1){
      float t = __shfl_up(pre, o, 16);
      if (lane >= o) pre += t;
    }
    float S = S0 + pre;
    float E = __expf(-S);
    const uintt* cb = BCs + ((size_t)bk*512 + (tme>>4))*256 + (tme&15);
    float p = E, acc = 0.f;
#pragma unroll
    for (int n=0;n<16;n++){
      float Cn = __uint_as_float(cb[n*16] & 0xffff0000u);
      acc += Cn * h0[n] * p;
      p *= E;
    }
    float yv = bf2f(Yk[tme]);
    Yk[tme] = f2bf(yv + acc);
    S0 = __shfl(S, 15, 16);           // block total carry
    if (S0 > Sexit) break;            // uniform across group
  }
}

// ---------------- Gate: gather Y0..Y3 + u*sum(D), LN256, *silu(z) ----------------
__global__ void k_gate2(const ushortt* __restrict__ Y0, const ushortt* __restrict__ Y1,
                        const ushortt* __restrict__ Y2, const ushortt* __restrict__ Y3,
                        const ushortt* __restrict__ Xpt0, const float* __restrict__ Ds,
                        ushortt* __restrict__ Zg,
                        const float* __restrict__ g, const float* __restrict__ bt){
  __shared__ float ysum[32][257];
  __shared__ float Dl[256];
  int tid = threadIdx.x;
  int wwb = blockIdx.x;      // 0..3
  int hh  = blockIdx.y;      // 0..63
  int b   = blockIdx.z;
  if (tid < 256) Dl[tid] = Ds[tid] + Ds[256+tid] + Ds[512+tid] + Ds[768+tid];
  int ww0 = wwb*32;
  for (int it=0; it<32; ++it){
    int idx = it*256 + tid;
    int d = idx >> 5, tl = idx & 31;
    int ww = ww0 + tl;
    int p  = hh*128 + ww;
    size_t base = ((size_t)b*256 + d) << 13;
    int t1 = ww*64 + hh;
    float v = bf2f(Y0[base + p]) + bf2f(Y2[base + (LL-1) - p])
            + bf2f(Y1[base + t1]) + bf2f(Y3[base + (LL-1) - t1]);
    ysum[tl][d] = v;
  }
  __syncthreads();
  {
    int d = tid;
    if (d < 256){
      size_t ub = (((size_t)b*256 + d) << 13) + hh*128 + ww0;
      for (int tl=0; tl<32; ++tl){
        float u = bf2f(Xpt0[ub + tl]);
        ysum[tl][d] += Dl[d]*u;
      }
    }
  }
  __syncthreads();
  int wave = tid >> 6, lane = tid & 63;
  for (int tk = wave*8; tk < wave*8+8; ++tk){
    float v0 = ysum[tk][lane], v1 = ysum[tk][lane+64];
    float v2 = ysum[tk][lane+128], v3 = ysum[tk][lane+192];
    float s  = waveReduceSum(v0+v1+v2+v3);
    float s2 = waveReduceSum(v0*v0+v1*v1+v2*v2+v3*v3);
    float mean = s*(1.f/256.f);
    float var  = s2*(1.f/256.f) - mean*mean;
    float r = rsqrtf(var + 1e-5f);
    int p = hh*128 + ww0 + tk;
    size_t zb = (((size_t)b<<13) + p) << 8;
#pragma unroll
    for (int j=0;j<4;j++){
      int dd = lane + 64*j;
      float ln = (ysum[tk][dd]-mean)*r*g[dd] + bt[dd];
      float z = bf2f(Zg[zb + dd]);
      Zg[zb + dd] = f2bf(ln * siluf_(z));
    }
  }
}

// ---------------- MFMA 3x3 conv 128->128(all co) + BN (+res) + ReLU ----------------
// grid (64 y, 8 img), block 256 = 4 waves (one x-quarter each), 128 co per wave.
template<int FINAL>
__global__ void k_mconv(const ushortt* __restrict__ I, const ushortt* __restrict__ Wt,
                        const float* __restrict__ g, const float* __restrict__ bb,
                        const float* __restrict__ mn, const float* __restrict__ vv,
                        const float* __restrict__ R, ushortt* __restrict__ Op,
                        float* __restrict__ Of){
  int y  = blockIdx.x;
  int im = blockIdx.y;
  int wv = threadIdx.x>>6, l = threadIdx.x&63;
  int ar = l&15, kg = l>>4;
  int x0 = wv*16;
  f32x4 acc[8];
#pragma unroll
  for (int i=0;i<8;i++){ acc[i][0]=0.f; acc[i][1]=0.f; acc[i][2]=0.f; acc[i][3]=0.f; }
  const ushortt* Ibase = I + (((size_t)im*66 + y)*66 + x0 + ar)*128 + kg*8;
  const ushortt* Wbase = Wt + (size_t)ar*128 + kg*8;
#pragma unroll
  for (int tap=0; tap<9; ++tap){
    int dy = tap/3, dx = tap - dy*3;
    const ushortt* Ir = Ibase + ((size_t)dy*66 + dx)*128;
    const ushortt* Wr = Wbase + (size_t)tap*16384;
#pragma unroll
    for (int kc=0;kc<4;kc++){
      bf16x8 af = *(const bf16x8*)(Ir + kc*32);
#pragma unroll
      for (int nf=0;nf<8;nf++){
        bf16x8 bfv = *(const bf16x8*)(Wr + (size_t)nf*16*128 + kc*32);
        acc[nf] = __builtin_amdgcn_mfma_f32_16x16x32_bf16(af, bfv, acc[nf], 0,0,0);
      }
    }
  }
#pragma unroll
  for (int nf=0;nf<8;nf++){
    int co = nf*16 + ar;
    float s  = g[co]*rsqrtf(vv[co]+1e-5f);
    float sh = bb[co] - mn[co]*s;
#pragma unroll
    for (int r=0;r<4;r++){
      int x = x0 + kg*4 + r;
      float v = acc[nf][r]*s + sh;
      if (FINAL){
        v += R[(((size_t)im*64 + y)*64 + x)*128 + co];
        v = fmaxf(v, 0.f);
        Of[(((size_t)im*128 + co)*64 + y)*64 + x] = v;
      } else {
        v = fmaxf(v, 0.f);
        Op[(((size_t)im*66 + (y+1))*66 + (x+1))*128 + co] = f2bf(v);
      }
    }
  }
}

extern "C" void kernel_launch(void* const* d_in, const int* in_sizes, int n_in,
                              void* d_out, int out_size, void* d_ws, size_t ws_size,
                              hipStream_t stream){
  const float* x1        = (const float*)d_in[0];
  const float* x2        = (const float*)d_in[1];
  const float* conv_in_w = (const float*)d_in[2];
  const float* conv_in_b = (const float*)d_in[3];
  const float* ln1_g     = (const float*)d_in[4];
  const float* ln1_b     = (const float*)d_in[5];
  const float* in_proj_w = (const float*)d_in[6];
  const float* dw_w      = (const float*)d_in[7];
  const float* dw_b      = (const float*)d_in[8];
  const float* x_proj_w  = (const float*)d_in[9];
  const float* dt_proj_w = (const float*)d_in[10];
  const float* dt_proj_b = (const float*)d_in[11];
  const float* A_logs    = (const float*)d_in[12];
  const float* Ds        = (const float*)d_in[13];
  const float* onorm_g   = (const float*)d_in[14];
  const float* onorm_b   = (const float*)d_in[15];
  const float* out_proj_w= (const float*)d_in[16];
  const float* ln2_g     = (const float*)d_in[17];
  const float* ln2_b     = (const float*)d_in[18];
  const float* mlp_w1    = (const float*)d_in[19];
  const float* mlp_b1    = (const float*)d_in[20];
  const float* mlp_w2    = (const float*)d_in[21];
  const float* mlp_b2    = (const float*)d_in[22];
  const float* rb1_w     = (const float*)d_in[23];
  const float* bn1_g     = (const float*)d_in[24];
  const float* bn1_b     = (const float*)d_in[25];
  const float* bn1_m     = (const float*)d_in[26];
  const float* bn1_v     = (const float*)d_in[27];
  const float* rb2_w     = (const float*)d_in[28];
  const float* bn2_g     = (const float*)d_in[29];
  const float* bn2_b     = (const float*)d_in[30];
  const float* bn2_m     = (const float*)d_in[31];
  const float* bn2_v     = (const float*)d_in[32];

  float* ws = (float*)d_ws;
  char*  wsB = (char*)d_ws;
  const size_t FM = 262144;            // floats per MiB
  const size_t MB = 1048576;           // bytes per MiB
  // Workspace layout (peak ~147.1 MiB, proven available):
  float*   X0   = ws;                          // 0-16    residual stream (B,L,128) f32
  ushortt* Xpab = (ushortt*)(wsB + 16*MB);     // 16-32   u post-dw-silu (B,L,256) bf16
  ushortt* Xpt0 = (ushortt*)(wsB + 32*MB);     // 32-48   u raster-order [b][d][p]
  ushortt* Xpt1 = (ushortt*)(wsB + 48*MB);     // 48-64   u colmajor-order [b][d][t1]
  char*    DBCb = wsB + 64*MB;                 // 64-68   dts rows 32B
  uintt*   BCs  = (uintt*)(wsB + 68*MB);       // 68-76   B/C dwords [bk][t/16][n][t%16]
  ushortt* Zg   = (ushortt*)(wsB + 77*MB);     // 77-93   z / gated bf16
  ushortt* Y0   = (ushortt*)(wsB + 93*MB);     // 93-109
  ushortt* Y1   = (ushortt*)(wsB + 109*MB);    // 109-125
  ushortt* Y2   = (ushortt*)(wsB + 125*MB);    // 125-141
  ushortt* Y3   = Xpab;                        // alias (Xpab dead before scanM)
  float*   Hbuf = ws + 141*FM;                 // 141-145
  float*   Ssum = ws + 145*FM;                 // 145-145.25
  // time-disjoint aliases:
  ushortt* CT   = (ushortt*)(wsB + 93*MB);     // steps 1-2 (over Y0)
  ushortt* Lnb  = (ushortt*)(wsB + 101*MB);    // steps 2-4 (over Y0 2nd half)
  ushortt* Xpb  = (ushortt*)(wsB + 109*MB);    // steps 4-5 xp pre-dw bf16 (over Y1)
  ushortt* Ln2b = (ushortt*)(wsB + 93*MB);     // steps 9-11 (Y0 dead)
  ushortt* H1   = (ushortt*)(wsB + 109*MB);    // steps 11-12 (Y1,Y2 dead)
  ushortt* P    = (ushortt*)(wsB + 16*MB);     // step 12+ padded conv input [8][66][66][128]
  ushortt* T    = (ushortt*)(wsB + 25*MB);     // conv1 out padded
  float*   R    = (float*)(wsB + 34*MB);       // 34-51 residual [8][64][64][128] f32
  // bf16 weights (persistent, never aliased):
  ushortt* cw  = (ushortt*)(wsB + 146*MB);           // 32 KB
  ushortt* ipw = (ushortt*)(wsB + 146*MB + 32*1024); // 128 KB
  ushortt* opw = (ushortt*)(wsB + 146*MB + 160*1024);// 64 KB
  ushortt* m1w = (ushortt*)(wsB + 146*MB + 224*1024);// 128 KB
  ushortt* m2w = (ushortt*)(wsB + 146*MB + 352*1024);// 128 KB
  ushortt* rw1 = (ushortt*)(wsB + 146*MB + 480*1024);// 288 KB
  ushortt* rw2 = (ushortt*)(wsB + 146*MB + 768*1024);// 288 KB
  float*   dwt = (float*)(wsB + 146*MB + 1056*1024); // 9 KB [tap][256] f32
  float* out = (float*)d_out;

  // 0. all weight conversions (one launch)
  k_wall<<<2121,256,0,stream>>>(conv_in_w,cw, in_proj_w,ipw, out_proj_w,opw,
                                mlp_w1,m1w, mlp_w2,m2w, rb1_w,rw1, rb2_w,rw2,
                                dw_w, dwt);
  // 1. interleave -> CT bf16 token-major
  k_build_ct2<<<512,256,0,stream>>>(x1,x2,CT);
  // 2. conv_in 1x1 (bias) -> X0 f32 + fused LN1 -> Lnb bf16
  k_mgemmln<0><<<512,256,0,stream>>>(CT, cw, conv_in_b, X0, ln1_g, ln1_b, Lnb, 128);
  // 4. in_proj (512) -> split xp(Xpb bf16) / z(Zg bf16); wide blocks (A read x2)
  k_mgemm<3,16><<<dim3(2,512),256,0,stream>>>(Lnb, ipw, nullptr, nullptr, nullptr, Zg, Xpb, nullptr, 512,128);
  // 5. depthwise 3x3 + silu -> Xpab bf16 (transposed weights)
  k_dwconv<<<BB*LL,256,0,stream>>>(Xpb, dwt, dw_b, Xpab);
  // 5b. direction-ordered u copies (merged)
  k_xtm<<<dim3(128,4,2*BB),256,0,stream>>>(Xpab, Xpt0, Xpt1);
  // 6. x_proj (f32 weights, proven numerics) -> dts (DBCb) + B/C (BCs)
  k_xdbl<<<2048,256,0,stream>>>(Xpab, x_proj_w, DBCb, (char*)BCs);
  // 7. chunked selective scan: merged main pass + chain + correction
  k_scanM<<<8192,128,0,stream>>>(DBCb, BCs, Xpt0, Xpt1, dt_proj_w, dt_proj_b, A_logs,
                                 Hbuf, Ssum, Y0,Y1,Y2,Y3);
  k_scanB<<<256,256,0,stream>>>(Ssum, Hbuf, A_logs);
  k_corr<<<8192,128,0,stream>>>(DBCb, BCs, dt_proj_w, dt_proj_b, Hbuf, Y0,Y1,Y2,Y3);
  // 8. gate
  k_gate2<<<dim3(4,64,BB),256,0,stream>>>(Y0,Y1,Y2,Y3, Xpt0, Ds, Zg, onorm_g, onorm_b);
  // 9. out_proj + residual -> X0 + fused LN2 -> Ln2b bf16
  k_mgemmln<1><<<512,256,0,stream>>>(Zg, opw, nullptr, X0, ln2_g, ln2_b, Ln2b, 256);
  // 9b. zero padded conv buffers (P and T) — Xpab/Xpt0 regions now dead
  hipMemsetAsync(wsB + 16*MB, 0, 18*MB, stream);
  // 11. MLP1 gelu -> H1 bf16; wide blocks
  k_mgemm<2,16><<<dim3(2,512),256,0,stream>>>(Ln2b, m1w, mlp_b1, nullptr, nullptr, H1, nullptr,nullptr, 512,128);
  // 12. MLP2 + bias + residual -> fused de-interleave (P bf16 padded + R f32); wide blocks
  k_mgemm<4,8><<<dim3(1,512),256,0,stream>>>(H1, m2w, mlp_b2, X0, nullptr, nullptr, P, R, 128,512);
  // 13-14. resblocks (both images batched, img = im2*4 + b)
  k_mconv<0><<<dim3(64,8),256,0,stream>>>(P, rw1, bn1_g,bn1_b,bn1_m,bn1_v, nullptr, T, nullptr);
  k_mconv<1><<<dim3(64,8),256,0,stream>>>(T, rw2, bn2_g,bn2_b,bn2_m,bn2_v, R, nullptr, out);
}

// Round 14
// 763.799 us; speedup vs baseline: 13.9356x; 1.0893x over previous
//
#include <hip/hip_runtime.h>
#include <math.h>

// Problem constants
#define BB 4
#define CM 128      // d_model
#define DI 256      // d_inner
#define NS 16       // d_state
#define RK 8        // dt_rank
#define KD 4        // K directions
#define HH 64
#define WW 128      // interleaved width
#define LL 8192     // HH*WW
#define NC 16       // scan chunks per sequence
#define CH 512      // chunk length (NC*CH == LL)

typedef unsigned short ushortt;
typedef unsigned int uintt;
typedef __attribute__((ext_vector_type(8))) __bf16 bf16x8;
typedef __attribute__((ext_vector_type(4))) float f32x4;

// Compiler memory-order fence: LDS ops cannot cross (asm memory clobber).
// sched_barrier removed: scheduler may interleave VALU, memory order preserved.
__device__ __forceinline__ void lds_fence(){
  asm volatile("" ::: "memory");
}

__device__ __forceinline__ float sigmoidf_(float x){ return 1.f/(1.f+__expf(-x)); }
__device__ __forceinline__ float siluf_(float x){ return x*sigmoidf_(x); }
__device__ __forceinline__ float softplusf_(float x){
  float r = __logf(1.f + __expf(x));   // fast path, no libcall
  return (x > 20.f) ? x : r;
}
__device__ __forceinline__ float geluf_(float x){ return 0.5f*x*(1.f+erff(x*0.70710678118654752f)); }
__device__ __forceinline__ ushortt f2bf(float f){
  uintt u = __float_as_uint(f);
  uintt r = (u + 0x7fffu + ((u>>16)&1u)) >> 16;
  return (ushortt)r;
}
__device__ __forceinline__ float bf2f(ushortt s){
  return __uint_as_float(((uintt)s)<<16);
}
template<int CTRL>
__device__ __forceinline__ float dppadd(float x){
  int r = __builtin_amdgcn_update_dpp(0, __float_as_int(x), CTRL, 0xF, 0xF, true);
  return x + __int_as_float(r);
}
// full sum over each 16-lane row; result on all lanes
__device__ __forceinline__ float rowsum16(float x){
  x = dppadd<0x121>(x);  // row_ror:1
  x = dppadd<0x122>(x);  // row_ror:2
  x = dppadd<0x124>(x);  // row_ror:4
  x = dppadd<0x128>(x);  // row_ror:8
  return x;
}
__device__ __forceinline__ float waveReduceSum(float v){
  for (int o=32;o>0;o>>=1) v += __shfl_xor(v,o,64);
  return v;
}

// ---------------- merged weight conversions (1 launch) ----------------
// xp packing (320 rows x 256): rows 0-31 dts hi (k*8+c), rows 32-63 dts lo,
// rows 64+q*64+s (q=dir, s<32: BC hi of j=s; s>=32: BC lo of j=s-32), j<16=B, j>=16=C.
__global__ void k_wall(const float* __restrict__ cw_s, ushortt* __restrict__ cw_d,
                       const float* __restrict__ ip_s, ushortt* __restrict__ ip_d,
                       const float* __restrict__ op_s, ushortt* __restrict__ op_d,
                       const float* __restrict__ m1_s, ushortt* __restrict__ m1_d,
                       const float* __restrict__ m2_s, ushortt* __restrict__ m2_d,
                       const float* __restrict__ r1_s, ushortt* __restrict__ r1_d,
                       const float* __restrict__ r2_s, ushortt* __restrict__ r2_d,
                       const float* __restrict__ dw_s, float* __restrict__ dw_d,
                       const float* __restrict__ xp_s, ushortt* __restrict__ xp_d){
  int i = blockIdx.x*256 + threadIdx.x;
  if (i < 16384){ cw_d[i] = f2bf(cw_s[i]); return; }
  i -= 16384;
  if (i < 65536){ ip_d[i] = f2bf(ip_s[i]); return; }
  i -= 65536;
  if (i < 32768){ op_d[i] = f2bf(op_s[i]); return; }
  i -= 32768;
  if (i < 65536){ m1_d[i] = f2bf(m1_s[i]); return; }
  i -= 65536;
  if (i < 65536){ m2_d[i] = f2bf(m2_s[i]); return; }
  i -= 65536;
  if (i < 147456){ int ci=i&127, co=(i>>7)&127, tap=i>>14;
    r1_d[i]=f2bf(r1_s[(size_t)(co*128+ci)*9+tap]); return; }
  i -= 147456;
  if (i < 147456){ int ci=i&127, co=(i>>7)&127, tap=i>>14;
    r2_d[i]=f2bf(r2_s[(size_t)(co*128+ci)*9+tap]); return; }
  i -= 147456;
  if (i < 2304){ int d = i & 255, tap = i >> 8;
    dw_d[i] = dw_s[d*9 + tap]; return; }   // exact f32 copy, [tap][d]
  i -= 2304;
  if (i < 81920){
    int d = i & 255, row = i >> 8;         // row 0..319
    float v; int lo;
    if (row < 64){
      int rr = row & 31; int k = rr>>3, c = rr&7;
      v = xp_s[((size_t)(k*40+c))*256 + d];
      lo = (row >= 32);
    } else {
      int rr = row - 64; int q = rr>>6, s = rr&63;
      int j = s & 31;
      v = xp_s[((size_t)(q*40+8+j))*256 + d];
      lo = (s >= 32);
    }
    xp_d[i] = lo ? f2bf(v - bf2f(f2bf(v))) : f2bf(v);
  }
}

// ---------------- CT build: interleave x1/x2 -> token-major bf16 (B*L, 128) ----------------
__global__ void k_build_ct2(const float* __restrict__ x1, const float* __restrict__ x2,
                            ushortt* __restrict__ CT){
  __shared__ ushortt Tl[64][136];
  int tid = threadIdx.x;
  int p0 = (blockIdx.x & 127) * 64;
  int b  = blockIdx.x >> 7;
  int j = tid & 63;
  int p = p0 + j; int hh = p>>7, ww = p&127, w2 = ww>>1;
  const float* src = (ww&1) ? x2 : x1;
  const float* sp = src + ((size_t)b*128*64 + hh)*64 + w2;
  for (int c0 = tid>>6; c0 < 128; c0 += 4)
    Tl[j][c0] = f2bf(sp[(size_t)c0*4096]);
  __syncthreads();
  int c = tid & 127; int rh = tid >> 7;
  for (int r = rh; r < 64; r += 2)
    CT[((size_t)b*LL + p0 + r)*128 + c] = Tl[r][c];
}

// ---------------- MFMA token GEMM ----------------
// A: [32768][K] bf16, W: [N][K] bf16; grid (N/(NF*16), 512), block 256 (4 waves).
// EPI 2: +bias,gelu -> bf16 C2 (stride 512)
// EPI 3: split n<256 -> bf16 Pp (xp), else bf16 C2 (z), both stride 256
// EPI 4: +bias+resid -> fused de-interleave: P (padded bf16) + R (f32), N=128
template<int EPI, int NF>
__global__ void k_mgemm(const ushortt* __restrict__ A, const ushortt* __restrict__ W,
                        const float* __restrict__ bias, const float* __restrict__ resid,
                        float* __restrict__ C, ushortt* __restrict__ C2,
                        ushortt* __restrict__ Pp, float* __restrict__ Rp, int N, int K){
  int n0 = blockIdx.x*(NF*16), m0 = blockIdx.y*64;
  int wv = threadIdx.x>>6, l = threadIdx.x&63;
  int ar = l&15, kg = l>>4;
  int mw = m0 + wv*16;
  f32x4 acc[NF];
#pragma unroll
  for (int i=0;i<NF;i++){ acc[i][0]=0.f; acc[i][1]=0.f; acc[i][2]=0.f; acc[i][3]=0.f; }
  const ushortt* Ap = A + (size_t)(mw+ar)*K + kg*8;
  const ushortt* Wp = W + (size_t)(n0+ar)*K + kg*8;
  for (int k0=0; k0<K; k0+=32){
    bf16x8 af = *(const bf16x8*)(Ap + k0);
#pragma unroll
    for (int nf=0; nf<NF; ++nf){
      bf16x8 bfv = *(const bf16x8*)(Wp + (size_t)nf*16*K + k0);
      acc[nf] = __builtin_amdgcn_mfma_f32_16x16x32_bf16(af, bfv, acc[nf], 0,0,0);
    }
  }
#pragma unroll
  for (int nf=0;nf<NF;nf++){
    int n = n0 + nf*16 + ar;
#pragma unroll
    for (int r=0;r<4;r++){
      int m = mw + kg*4 + r;
      float v = acc[nf][r];
      if (EPI==2){
        v += bias[n];
        C2[(size_t)m*512 + n] = f2bf(geluf_(v));
      } else if (EPI==3){
        if (n < 256) Pp[(size_t)m*256 + n] = f2bf(v);
        else         C2[(size_t)m*256 + (n-256)] = f2bf(v);
      } else { // EPI==4
        v += bias[n];
        v += resid[(size_t)m*128 + n];
        int bq = m >> 13; int pq = m & 8191; int yq = pq >> 7; int wq = pq & 127;
        int im = (wq&1)*4 + bq; int xq = wq>>1;
        Pp[(((size_t)im*66 + yq+1)*66 + xq+1)*128 + n] = f2bf(v);
        Rp[(((size_t)im*64 + yq)*64 + xq)*128 + n] = v;
      }
    }
  }
}

// ---------------- MFMA GEMM (N=128) with fused LayerNorm epilogue ----------------
// RES=0: X = A@W^T + bias; RES=1: X = A@W^T + X(old). Then O = bf16(LN(X)).
template<int RES>
__global__ void k_mgemmln(const ushortt* __restrict__ A, const ushortt* __restrict__ W,
                          const float* __restrict__ bias, float* __restrict__ X,
                          const float* __restrict__ g, const float* __restrict__ bt,
                          ushortt* __restrict__ O, int K){
  int m0 = blockIdx.x*64;
  int wv = threadIdx.x>>6, l = threadIdx.x&63;
  int ar = l&15, kg = l>>4;
  int mw = m0 + wv*16;
  f32x4 acc[8];
#pragma unroll
  for (int i=0;i<8;i++){ acc[i][0]=0.f; acc[i][1]=0.f; acc[i][2]=0.f; acc[i][3]=0.f; }
  const ushortt* Ap = A + (size_t)(mw+ar)*K + kg*8;
  const ushortt* Wp = W + (size_t)ar*K + kg*8;
  for (int k0=0; k0<K; k0+=32){
    bf16x8 af = *(const bf16x8*)(Ap + k0);
#pragma unroll
    for (int nf=0; nf<8; ++nf){
      bf16x8 bfv = *(const bf16x8*)(Wp + (size_t)nf*16*K + k0);
      acc[nf] = __builtin_amdgcn_mfma_f32_16x16x32_bf16(af, bfv, acc[nf], 0,0,0);
    }
  }
  float vv[8][4];
  float s[4] = {0,0,0,0}, s2[4] = {0,0,0,0};
#pragma unroll
  for (int nf=0;nf<8;nf++){
    int n = nf*16 + ar;
    float bv = bias ? bias[n] : 0.f;
#pragma unroll
    for (int r=0;r<4;r++){
      int m = mw + kg*4 + r;
      float v = acc[nf][r] + bv;
      if (RES) v += X[(size_t)m*128 + n];
      X[(size_t)m*128 + n] = v;
      vv[nf][r] = v;
      s[r] += v; s2[r] += v*v;
    }
  }
  float mn[4], rs[4];
#pragma unroll
  for (int r=0;r<4;r++){
    float S  = rowsum16(s[r]);
    float S2 = rowsum16(s2[r]);
    float mean = S*(1.f/128.f);
    float var  = S2*(1.f/128.f) - mean*mean;
    mn[r] = mean; rs[r] = rsqrtf(var + 1e-5f);
  }
#pragma unroll
  for (int nf=0;nf<8;nf++){
    int n = nf*16 + ar;
    float gv = g[n], bv = bt[n];
#pragma unroll
    for (int r=0;r<4;r++){
      int m = mw + kg*4 + r;
      O[(size_t)m*128 + n] = f2bf((vv[nf][r]-mn[r])*rs[r]*gv + bv);
    }
  }
}

// ---------------- Depthwise 3x3 + bias + SiLU, channel-last (B,L,256) bf16->bf16 ----------------
// dwt: [tap][256] f32 (pre-transposed, coalesced)
__global__ void k_dwconv(const ushortt* __restrict__ Xp, const float* __restrict__ dwt,
                         const float* __restrict__ bias, ushortt* __restrict__ O){
  int tok = blockIdx.x; int d = threadIdx.x;
  int b = tok >> 13; int p = tok & (LL-1); int hh = p>>7, ww = p&127;
  float acc = bias[d];
#pragma unroll
  for (int dy=0;dy<3;dy++){
    int yy = hh+dy-1; if (yy<0||yy>=HH) continue;
#pragma unroll
    for (int dx=0;dx<3;dx++){
      int xx = ww+dx-1; if (xx<0||xx>=WW) continue;
      acc += bf2f(Xp[((size_t)b*LL + yy*WW + xx)*256 + d]) * dwt[(dy*3+dx)*256 + d];
    }
  }
  O[(size_t)tok*256 + d] = f2bf(siluf_(acc));
}

// ---------------- merged transposes: Xpab[b][p][d] -> Xpt0 (raster) / Xpt1 (colmajor) ----------------
__global__ void k_xtm(const ushortt* __restrict__ Xpab, ushortt* __restrict__ Xpt0,
                      ushortt* __restrict__ Xpt1){
  __shared__ ushortt Tl[64][68];
  int zb = blockIdx.z; int b = zb >> 1; int mode = zb & 1;
  int d0 = blockIdx.y*64;
  int di = threadIdx.x&63, q = threadIdx.x>>6;
  if (mode == 0){
    int p0 = blockIdx.x*64;
    for (int k2=0;k2<16;k2++){ int pi = q*16 + k2;
      Tl[pi][di] = Xpab[((size_t)b*LL + p0+pi)*256 + d0+di]; }
    __syncthreads();
    for (int k2=0;k2<16;k2++){ int dr = q*16 + k2;
      Xpt0[((size_t)(b*256 + d0+dr))*LL + p0+di] = Tl[di][dr]; }
  } else {
    int ww = blockIdx.x;
    for (int k2=0;k2<16;k2++){ int hh = q*16 + k2;
      Tl[hh][di] = Xpab[((size_t)b*LL + hh*128 + ww)*256 + d0+di]; }
    __syncthreads();
    for (int k2=0;k2<16;k2++){ int dr = q*16 + k2;
      Xpt1[((size_t)(b*256 + d0+dr))*LL + ww*64 + di] = Tl[di][dr]; }
  }
}

// ---------------- x_proj as MFMA GEMM, hi/lo weights (f32-equivalent numerics) ----------------
// A: Xpab [32768][256] bf16; W: xpw packed 320 rows (see k_wall).
// grid (5, 512): block 0 = dts (hi+lo), blocks 1-4 = B/C per direction (hi+lo).
__global__ void k_xproj(const ushortt* __restrict__ A, const ushortt* __restrict__ W,
                        float* __restrict__ DBCf, char* __restrict__ BCsb){
  int n0 = blockIdx.x*64, m0 = blockIdx.y*64;
  int wv = threadIdx.x>>6, l = threadIdx.x&63;
  int ar = l&15, kg = l>>4;
  int mw = m0 + wv*16;
  f32x4 acc[4];
#pragma unroll
  for (int i=0;i<4;i++){ acc[i][0]=0.f; acc[i][1]=0.f; acc[i][2]=0.f; acc[i][3]=0.f; }
  const ushortt* Ap = A + (size_t)(mw+ar)*256 + kg*8;
  const ushortt* Wp = W + (size_t)(n0+ar)*256 + kg*8;
#pragma unroll
  for (int k0=0; k0<256; k0+=32){
    bf16x8 af = *(const bf16x8*)(Ap + k0);
#pragma unroll
    for (int nf=0; nf<4; ++nf){
      bf16x8 bfv = *(const bf16x8*)(Wp + (size_t)nf*16*256 + k0);
      acc[nf] = __builtin_amdgcn_mfma_f32_16x16x32_bf16(af, bfv, acc[nf], 0,0,0);
    }
  }
  if (blockIdx.x == 0){
    // dts: fragments 0-1 = hi rows, 2-3 = lo rows (same lane)
#pragma unroll
    for (int nf=0;nf<2;nf++){
      int n = nf*16 + ar;          // 0..31
      int kq = n>>3, cq = n&7;
#pragma unroll
      for (int r=0;r<4;r++){
        int m = mw + kg*4 + r;
        int b = m >> 13, p = m & 8191;
        int hh = p>>7, ww = p&127;
        int tc = (ww<<6)|hh;
        int t = (kq==0)? p : (kq==1)? tc : (kq==2)? (8191-p) : (8191-tc);
        int bk = b*KD + kq;
        DBCf[((size_t)bk*LL + t)*8 + cq] = acc[nf][r] + acc[nf+2][r];
      }
    }
  } else {
    int q = blockIdx.x - 1;        // direction
#pragma unroll
    for (int nf=0;nf<2;nf++){
      int st = ar;
      int hi = (nf==1) ? 2 : 0;    // nf=0 -> B (low half), nf=1 -> C (high half)
#pragma unroll
      for (int r=0;r<4;r++){
        int m = mw + kg*4 + r;
        int b = m >> 13, p = m & 8191;
        int hh = p>>7, ww = p&127;
        int tc = (ww<<6)|hh;
        int t = (q==0)? p : (q==1)? tc : (q==2)? (8191-p) : (8191-tc);
        int bk = b*KD + q;
        float v = acc[nf][r] + acc[nf+2][r];
        size_t a = ((((size_t)bk*512 + (t>>4))*16 + st)*16 + (t&15))*4 + hi;
        *(ushortt*)(BCsb + a) = f2bf(v);
      }
    }
  }
}

// ---------------- Merged scan pass: from h=0, write y_local + h_out + sum(delta) ----------------
// 128 threads = 8 groups of 16 lanes.
__global__ __launch_bounds__(128) void k_scanM(const char* __restrict__ DBCb,
                        const uintt* __restrict__ BCs,
                        const ushortt* __restrict__ Xpt0, const ushortt* __restrict__ Xpt1,
                        const float* __restrict__ dtw_all, const float* __restrict__ dtb_all,
                        const float* __restrict__ A_logs,
                        float* __restrict__ Hbuf, float* __restrict__ Ssum,
                        ushortt* __restrict__ Y0, ushortt* __restrict__ Y1,
                        ushortt* __restrict__ Y2, ushortt* __restrict__ Y3){
  __shared__ float2 sdd[8][16];
  __shared__ float yt[8*328];       // group pitch 328
  int tid = threadIdx.x;
  int grp = tid >> 4, lane = tid & 15;
  float* ytg = yt + grp*328;
  int gid = blockIdx.x*8 + grp;
  int c = gid & 15;
  int bkd = gid >> 4;
  int b = bkd >> 10, k = (bkd>>8)&3, d = bkd & 255;
  int kd = k*256+d;
  int bk = b*KD + k;
  float dtw[8];
  { const float4* w4 = (const float4*)(dtw_all + (size_t)kd*8);
    float4 w0 = w4[0], w1 = w4[1];
    dtw[0]=w0.x; dtw[1]=w0.y; dtw[2]=w0.z; dtw[3]=w0.w;
    dtw[4]=w1.x; dtw[5]=w1.y; dtw[6]=w1.z; dtw[7]=w1.w; }
  float dtb  = dtb_all[kd];
  float Aval = -__expf(A_logs[(size_t)kd*16+lane]);
  const char* dbc = DBCb + (size_t)bk*LL*32;
  const uintt* bcb = BCs + ((size_t)bk*512 + (c*CH>>4))*256;
  const ushortt* Up = ((k&1)?Xpt1:Xpt0) + ((size_t)(b*256+d))*LL;
  ushortt* Yk = (k==0?Y0 : k==1?Y1 : k==2?Y2 : Y3) + ((size_t)b*256 + d)*LL;
  float h = 0.f, Sacc = 0.f;
  int t0 = c*CH;
  // prefetch block 0 dts + u
  const char* row0 = dbc + (size_t)(t0+lane)*32;
  float4 q0 = *(const float4*)row0;
  float4 q1 = *(const float4*)(row0+16);
  ushortt ur = Up[(k<2) ? (t0+lane) : (LL-1-(t0+lane))];
  for (int blk=0; blk<CH/16; ++blk){
    int tb = t0 + blk*16;
    int tme = tb + lane;
    const uint4* bcp = (const uint4*)(bcb + ((size_t)blk*16 + lane)*16);
    uint4 w0 = bcp[0], w1 = bcp[1], w2 = bcp[2], w3 = bcp[3];
    float4 c0 = q0, c1 = q1; ushortt cu = ur;
    if (blk+1 < CH/16){
      const char* rn = dbc + (size_t)(tme+16)*32;
      q0 = *(const float4*)rn;
      q1 = *(const float4*)(rn+16);
      ur = Up[(k<2) ? (tme+16) : (LL-1-(tme+16))];
    }
    float dsum = dtb + c0.x*dtw[0] + c0.y*dtw[1] + c0.z*dtw[2] + c0.w*dtw[3]
                     + c1.x*dtw[4] + c1.y*dtw[5] + c1.z*dtw[6] + c1.w*dtw[7];
    float delta = softplusf_(dsum);
    Sacc += delta;
    float u = bf2f(cu);
    sdd[grp][lane] = make_float2(delta, delta*u);
    lds_fence();             // order sdd write vs cross-lane reads below
    uintt wd[16] = {w0.x,w0.y,w0.z,w0.w, w1.x,w1.y,w1.z,w1.w,
                    w2.x,w2.y,w2.z,w2.w, w3.x,w3.y,w3.z,w3.w};
#pragma unroll
    for (int i=0;i<16;i++){
      float2 dd = sdd[grp][i];
      uintt w = wd[i];
      float Bn = __uint_as_float(w<<16);
      float Cn = __uint_as_float(w & 0xffff0000u);
      float e = __expf(dd.x * Aval);
      h = e*h + dd.y*Bn;
      ytg[i*20 + lane] = h*Cn;
    }
    lds_fence();             // order yt writes vs cross-lane yt reads
    const f32x4* yr = (const f32x4*)(ytg + lane*20);
    f32x4 s0 = yr[0], s1 = yr[1], s2v = yr[2], s3 = yr[3];
    float acc = (s0[0]+s0[1]+s0[2]+s0[3]) + (s1[0]+s1[1]+s1[2]+s1[3])
              + (s2v[0]+s2v[1]+s2v[2]+s2v[3]) + (s3[0]+s3[1]+s3[2]+s3[3]);
    Yk[tme] = f2bf(acc);
    lds_fence();             // order yt reads vs next block's yt writes
  }
  Hbuf[(size_t)gid*16 + lane] = h;
  float Stot = rowsum16(Sacc);
  if (lane==0) Ssum[gid] = Stot;
}

// Pass B: serial over chunks; converts Hbuf (h_out) to h_start in place.
__global__ void k_scanB(const float* __restrict__ Ssum, float* __restrict__ Hbuf,
                        const float* __restrict__ A_logs){
  int idx = blockIdx.x*256 + threadIdx.x;  // bkd*16+n (65536)
  int n = idx & 15; int bkd = idx >> 4;
  int kd = ((bkd>>8)&3)*256 + (bkd&255);
  float Aval = -__expf(A_logs[(size_t)kd*16+n]);
  float h = 0.f;
  for (int c=0;c<NC;c++){
    size_t g = (size_t)bkd*NC + c;
    float hout = Hbuf[g*16+n];
    Hbuf[g*16+n] = h;
    h = __expf(Aval*Ssum[g])*h + hout;
  }
}

// Pass C': correction sweep. y(t) += sum_n C_n(t) * exp(A_n * S_incl(t)) * h0_n.
__global__ __launch_bounds__(128) void k_corr(const char* __restrict__ DBCb,
                       const uintt* __restrict__ BCs,
                       const float* __restrict__ dtw_all, const float* __restrict__ dtb_all,
                       const float* __restrict__ Hbuf,
                       ushortt* __restrict__ Y0, ushortt* __restrict__ Y1,
                       ushortt* __restrict__ Y2, ushortt* __restrict__ Y3){
  int tid = threadIdx.x;
  int grp = tid >> 4, lane = tid & 15;
  int gid = blockIdx.x*8 + grp;
  int c = gid & 15;
  if (c == 0) return;                 // h0 == 0 exactly
  int bkd = gid >> 4;
  int b = bkd >> 10, k = (bkd>>8)&3, d = bkd & 255;
  int kd = k*256+d;
  int bk = b*KD + k;
  float h0[16];
  float hmax = 0.f;
#pragma unroll
  for (int n=0;n<16;n++){
    h0[n] = Hbuf[(size_t)gid*16 + n];
    hmax = fmaxf(hmax, fabsf(h0[n]));
  }
  float Sexit = 14.f + __logf(fmaxf(hmax, 1e-30f));
  if (0.f > Sexit) return;            // h0 negligible
  float dtw[8];
  { const float4* w4 = (const float4*)(dtw_all + (size_t)kd*8);
    float4 w0 = w4[0], w1 = w4[1];
    dtw[0]=w0.x; dtw[1]=w0.y; dtw[2]=w0.z; dtw[3]=w0.w;
    dtw[4]=w1.x; dtw[5]=w1.y; dtw[6]=w1.z; dtw[7]=w1.w; }
  float dtb  = dtb_all[kd];
  const char* dbc = DBCb + (size_t)bk*LL*32;
  ushortt* Yk = (k==0?Y0 : k==1?Y1 : k==2?Y2 : Y3) + ((size_t)b*256 + d)*LL;
  float S0 = 0.f;
  int t0 = c*CH;
  for (int blk=0; blk<CH/16; ++blk){
    int tme = t0 + blk*16 + lane;
    const char* rowme = dbc + (size_t)tme*32;
    float4 q0 = *(const float4*)rowme;
    float4 q1 = *(const float4*)(rowme+16);
    float dsum = dtb + q0.x*dtw[0] + q0.y*dtw[1] + q0.z*dtw[2] + q0.w*dtw[3]
                     + q1.x*dtw[4] + q1.y*dtw[5] + q1.z*dtw[6] + q1.w*dtw[7];
    float delta = softplusf_(dsum);
    // inclusive prefix sum over the 16-lane group
    float pre = delta;
#pragma unroll
    for (int o=1;o<16;o<<=1){
      float t = __shfl_up(pre, o, 16);
      if (lane >= o) pre += t;
    }
    float S = S0 + pre;
    float E = __expf(-S);
    const uintt* cb = BCs + ((size_t)bk*512 + (tme>>4))*256 + (tme&15);
    float p = E, acc = 0.f;
#pragma unroll
    for (int n=0;n<16;n++){
      float Cn = __uint_as_float(cb[n*16] & 0xffff0000u);
      acc += Cn * h0[n] * p;
      p *= E;
    }
    float yv = bf2f(Yk[tme]);
    Yk[tme] = f2bf(yv + acc);
    S0 = __shfl(S, 15, 16);           // block total carry
    if (S0 > Sexit) break;            // uniform across group
  }
}

// ---------------- Gate: gather Y0..Y3 + u*sum(D), LN256, *silu(z) ----------------
__global__ void k_gate2(const ushortt* __restrict__ Y0, const ushortt* __restrict__ Y1,
                        const ushortt* __restrict__ Y2, const ushortt* __restrict__ Y3,
                        const ushortt* __restrict__ Xpt0, const float* __restrict__ Ds,
                        ushortt* __restrict__ Zg,
                        const float* __restrict__ g, const float* __restrict__ bt){
  __shared__ float ysum[32][257];
  __shared__ float Dl[256];
  int tid = threadIdx.x;
  int wwb = blockIdx.x;      // 0..3
  int hh  = blockIdx.y;      // 0..63
  int b   = blockIdx.z;
  if (tid < 256) Dl[tid] = Ds[tid] + Ds[256+tid] + Ds[512+tid] + Ds[768+tid];
  int ww0 = wwb*32;
  for (int it=0; it<32; ++it){
    int idx = it*256 + tid;
    int d = idx >> 5, tl = idx & 31;
    int ww = ww0 + tl;
    int p  = hh*128 + ww;
    size_t base = ((size_t)b*256 + d) << 13;
    int t1 = ww*64 + hh;
    float v = bf2f(Y0[base + p]) + bf2f(Y2[base + (LL-1) - p])
            + bf2f(Y1[base + t1]) + bf2f(Y3[base + (LL-1) - t1]);
    ysum[tl][d] = v;
  }
  __syncthreads();
  {
    int d = tid;
    if (d < 256){
      size_t ub = (((size_t)b*256 + d) << 13) + hh*128 + ww0;
      const uint4* up = (const uint4*)(Xpt0 + ub);   // 64B aligned
      uint4 u0 = up[0], u1 = up[1], u2 = up[2], u3 = up[3];
      uintt uw[16] = {u0.x,u0.y,u0.z,u0.w, u1.x,u1.y,u1.z,u1.w,
                      u2.x,u2.y,u2.z,u2.w, u3.x,u3.y,u3.z,u3.w};
      float Dd = Dl[d];
#pragma unroll
      for (int qd=0; qd<16; ++qd){
        float ulo = __uint_as_float(uw[qd]<<16);
        float uhi = __uint_as_float(uw[qd] & 0xffff0000u);
        ysum[2*qd][d]   += Dd*ulo;
        ysum[2*qd+1][d] += Dd*uhi;
      }
    }
  }
  __syncthreads();
  int wave = tid >> 6, lane = tid & 63;
  for (int tk = wave*8; tk < wave*8+8; ++tk){
    float v0 = ysum[tk][lane], v1 = ysum[tk][lane+64];
    float v2 = ysum[tk][lane+128], v3 = ysum[tk][lane+192];
    float s  = waveReduceSum(v0+v1+v2+v3);
    float s2 = waveReduceSum(v0*v0+v1*v1+v2*v2+v3*v3);
    float mean = s*(1.f/256.f);
    float var  = s2*(1.f/256.f) - mean*mean;
    float r = rsqrtf(var + 1e-5f);
    int p = hh*128 + ww0 + tk;
    size_t zb = (((size_t)b<<13) + p) << 8;
#pragma unroll
    for (int j=0;j<4;j++){
      int dd = lane + 64*j;
      float ln = (ysum[tk][dd]-mean)*r*g[dd] + bt[dd];
      float z = bf2f(Zg[zb + dd]);
      Zg[zb + dd] = f2bf(ln * siluf_(z));
    }
  }
}

// ---------------- MFMA 3x3 conv 128->128(all co) + BN (+res) + ReLU ----------------
// grid (64 y, 8 img), block 256 = 4 waves (one x-quarter each), 128 co per wave.
template<int FINAL>
__global__ void k_mconv(const ushortt* __restrict__ I, const ushortt* __restrict__ Wt,
                        const float* __restrict__ g, const float* __restrict__ bb,
                        const float* __restrict__ mn, const float* __restrict__ vv,
                        const float* __restrict__ R, ushortt* __restrict__ Op,
                        float* __restrict__ Of){
  int y  = blockIdx.x;
  int im = blockIdx.y;
  int wv = threadIdx.x>>6, l = threadIdx.x&63;
  int ar = l&15, kg = l>>4;
  int x0 = wv*16;
  f32x4 acc[8];
#pragma unroll
  for (int i=0;i<8;i++){ acc[i][0]=0.f; acc[i][1]=0.f; acc[i][2]=0.f; acc[i][3]=0.f; }
  const ushortt* Ibase = I + (((size_t)im*66 + y)*66 + x0 + ar)*128 + kg*8;
  const ushortt* Wbase = Wt + (size_t)ar*128 + kg*8;
#pragma unroll
  for (int tap=0; tap<9; ++tap){
    int dy = tap/3, dx = tap - dy*3;
    const ushortt* Ir = Ibase + ((size_t)dy*66 + dx)*128;
    const ushortt* Wr = Wbase + (size_t)tap*16384;
#pragma unroll
    for (int kc=0;kc<4;kc++){
      bf16x8 af = *(const bf16x8*)(Ir + kc*32);
#pragma unroll
      for (int nf=0;nf<8;nf++){
        bf16x8 bfv = *(const bf16x8*)(Wr + (size_t)nf*16*128 + kc*32);
        acc[nf] = __builtin_amdgcn_mfma_f32_16x16x32_bf16(af, bfv, acc[nf], 0,0,0);
      }
    }
  }
#pragma unroll
  for (int nf=0;nf<8;nf++){
    int co = nf*16 + ar;
    float s  = g[co]*rsqrtf(vv[co]+1e-5f);
    float sh = bb[co] - mn[co]*s;
#pragma unroll
    for (int r=0;r<4;r++){
      int x = x0 + kg*4 + r;
      float v = acc[nf][r]*s + sh;
      if (FINAL){
        v += R[(((size_t)im*64 + y)*64 + x)*128 + co];
        v = fmaxf(v, 0.f);
        Of[(((size_t)im*128 + co)*64 + y)*64 + x] = v;
      } else {
        v = fmaxf(v, 0.f);
        Op[(((size_t)im*66 + (y+1))*66 + (x+1))*128 + co] = f2bf(v);
      }
    }
  }
}

extern "C" void kernel_launch(void* const* d_in, const int* in_sizes, int n_in,
                              void* d_out, int out_size, void* d_ws, size_t ws_size,
                              hipStream_t stream){
  const float* x1        = (const float*)d_in[0];
  const float* x2        = (const float*)d_in[1];
  const float* conv_in_w = (const float*)d_in[2];
  const float* conv_in_b = (const float*)d_in[3];
  const float* ln1_g     = (const float*)d_in[4];
  const float* ln1_b     = (const float*)d_in[5];
  const float* in_proj_w = (const float*)d_in[6];
  const float* dw_w      = (const float*)d_in[7];
  const float* dw_b      = (const float*)d_in[8];
  const float* x_proj_w  = (const float*)d_in[9];
  const float* dt_proj_w = (const float*)d_in[10];
  const float* dt_proj_b = (const float*)d_in[11];
  const float* A_logs    = (const float*)d_in[12];
  const float* Ds        = (const float*)d_in[13];
  const float* onorm_g   = (const float*)d_in[14];
  const float* onorm_b   = (const float*)d_in[15];
  const float* out_proj_w= (const float*)d_in[16];
  const float* ln2_g     = (const float*)d_in[17];
  const float* ln2_b     = (const float*)d_in[18];
  const float* mlp_w1    = (const float*)d_in[19];
  const float* mlp_b1    = (const float*)d_in[20];
  const float* mlp_w2    = (const float*)d_in[21];
  const float* mlp_b2    = (const float*)d_in[22];
  const float* rb1_w     = (const float*)d_in[23];
  const float* bn1_g     = (const float*)d_in[24];
  const float* bn1_b     = (const float*)d_in[25];
  const float* bn1_m     = (const float*)d_in[26];
  const float* bn1_v     = (const float*)d_in[27];
  const float* rb2_w     = (const float*)d_in[28];
  const float* bn2_g     = (const float*)d_in[29];
  const float* bn2_b     = (const float*)d_in[30];
  const float* bn2_m     = (const float*)d_in[31];
  const float* bn2_v     = (const float*)d_in[32];

  float* ws = (float*)d_ws;
  char*  wsB = (char*)d_ws;
  const size_t FM = 262144;            // floats per MiB
  const size_t MB = 1048576;           // bytes per MiB
  // Workspace layout (peak ~147.2 MiB):
  float*   X0   = ws;                          // 0-16    residual stream (B,L,128) f32
  ushortt* Xpab = (ushortt*)(wsB + 16*MB);     // 16-32   u post-dw-silu (B,L,256) bf16
  ushortt* Xpt0 = (ushortt*)(wsB + 32*MB);     // 32-48   u raster-order [b][d][p]
  ushortt* Xpt1 = (ushortt*)(wsB + 48*MB);     // 48-64   u colmajor-order [b][d][t1]
  char*    DBCb = wsB + 64*MB;                 // 64-68   dts rows 32B
  uintt*   BCs  = (uintt*)(wsB + 68*MB);       // 68-76   B/C dwords [bk][t/16][n][t%16]
  ushortt* Zg   = (ushortt*)(wsB + 77*MB);     // 77-93   z / gated bf16
  ushortt* Y0   = (ushortt*)(wsB + 93*MB);     // 93-109
  ushortt* Y1   = (ushortt*)(wsB + 109*MB);    // 109-125
  ushortt* Y2   = (ushortt*)(wsB + 125*MB);    // 125-141
  ushortt* Y3   = Xpab;                        // alias (Xpab dead before scanM)
  float*   Hbuf = ws + 141*FM;                 // 141-145
  float*   Ssum = ws + 145*FM;                 // 145-145.25
  // time-disjoint aliases:
  ushortt* CT   = (ushortt*)(wsB + 93*MB);     // steps 1-2 (over Y0)
  ushortt* Lnb  = (ushortt*)(wsB + 101*MB);    // steps 2-4 (over Y0 2nd half)
  ushortt* Xpb  = (ushortt*)(wsB + 109*MB);    // steps 4-5 xp pre-dw bf16 (over Y1)
  ushortt* Ln2b = (ushortt*)(wsB + 93*MB);     // steps 9-11 (Y0 dead)
  ushortt* H1   = (ushortt*)(wsB + 109*MB);    // steps 11-12 (Y1,Y2 dead)
  ushortt* P    = (ushortt*)(wsB + 16*MB);     // step 12+ padded conv input [8][66][66][128]
  ushortt* T    = (ushortt*)(wsB + 25*MB);     // conv1 out padded
  float*   R    = (float*)(wsB + 34*MB);       // 34-51 residual [8][64][64][128] f32
  // bf16 weights (persistent, never aliased):
  ushortt* cw  = (ushortt*)(wsB + 146*MB);            // 32 KB
  ushortt* ipw = (ushortt*)(wsB + 146*MB + 32*1024);  // 128 KB
  ushortt* opw = (ushortt*)(wsB + 146*MB + 160*1024); // 64 KB
  ushortt* m1w = (ushortt*)(wsB + 146*MB + 224*1024); // 128 KB
  ushortt* m2w = (ushortt*)(wsB + 146*MB + 352*1024); // 128 KB
  ushortt* rw1 = (ushortt*)(wsB + 146*MB + 480*1024); // 288 KB
  ushortt* rw2 = (ushortt*)(wsB + 146*MB + 768*1024); // 288 KB
  ushortt* xpw = (ushortt*)(wsB + 146*MB + 1056*1024);// 160 KB (320x256 bf16)
  float*   dwt = (float*)(wsB + 146*MB + 1216*1024);  // 9 KB [tap][256] f32
  float* out = (float*)d_out;

  // 0. all weight conversions (one launch)
  k_wall<<<2441,256,0,stream>>>(conv_in_w,cw, in_proj_w,ipw, out_proj_w,opw,
                                mlp_w1,m1w, mlp_w2,m2w, rb1_w,rw1, rb2_w,rw2,
                                dw_w, dwt, x_proj_w, xpw);
  // 1. interleave -> CT bf16 token-major
  k_build_ct2<<<512,256,0,stream>>>(x1,x2,CT);
  // 2. conv_in 1x1 (bias) -> X0 f32 + fused LN1 -> Lnb bf16
  k_mgemmln<0><<<512,256,0,stream>>>(CT, cw, conv_in_b, X0, ln1_g, ln1_b, Lnb, 128);
  // 4. in_proj (512) -> split xp(Xpb bf16) / z(Zg bf16); wide blocks
  k_mgemm<3,16><<<dim3(2,512),256,0,stream>>>(Lnb, ipw, nullptr, nullptr, nullptr, Zg, Xpb, nullptr, 512,128);
  // 5. depthwise 3x3 + silu -> Xpab bf16 (transposed weights)
  k_dwconv<<<BB*LL,256,0,stream>>>(Xpb, dwt, dw_b, Xpab);
  // 5b. direction-ordered u copies (merged)
  k_xtm<<<dim3(128,4,2*BB),256,0,stream>>>(Xpab, Xpt0, Xpt1);
  // 6. x_proj MFMA GEMM (hi/lo weights, f32-equivalent) -> dts (DBCb) + B/C (BCs)
  k_xproj<<<dim3(5,512),256,0,stream>>>(Xpab, xpw, (float*)DBCb, (char*)BCs);
  // 7. chunked selective scan: merged main pass + chain + correction
  k_scanM<<<8192,128,0,stream>>>(DBCb, BCs, Xpt0, Xpt1, dt_proj_w, dt_proj_b, A_logs,
                                 Hbuf, Ssum, Y0,Y1,Y2,Y3);
  k_scanB<<<256,256,0,stream>>>(Ssum, Hbuf, A_logs);
  k_corr<<<8192,128,0,stream>>>(DBCb, BCs, dt_proj_w, dt_proj_b, Hbuf, Y0,Y1,Y2,Y3);
  // 8. gate
  k_gate2<<<dim3(4,64,BB),256,0,stream>>>(Y0,Y1,Y2,Y3, Xpt0, Ds, Zg, onorm_g, onorm_b);
  // 9. out_proj + residual -> X0 + fused LN2 -> Ln2b bf16
  k_mgemmln<1><<<512,256,0,stream>>>(Zg, opw, nullptr, X0, ln2_g, ln2_b, Ln2b, 256);
  // 9b. zero padded conv buffers (P and T) — Xpab/Xpt0 regions now dead
  hipMemsetAsync(wsB + 16*MB, 0, 18*MB, stream);
  // 11. MLP1 gelu -> H1 bf16; wide blocks
  k_mgemm<2,16><<<dim3(2,512),256,0,stream>>>(Ln2b, m1w, mlp_b1, nullptr, nullptr, H1, nullptr,nullptr, 512,128);
  // 12. MLP2 + bias + residual -> fused de-interleave (P bf16 padded + R f32); wide blocks
  k_mgemm<4,8><<<dim3(1,512),256,0,stream>>>(H1, m2w, mlp_b2, X0, nullptr, nullptr, P, R, 128,512);
  // 13-14. resblocks (both images batched, img = im2*4 + b)
  k_mconv<0><<<dim3(64,8),256,0,stream>>>(P, rw1, bn1_g,bn1_b,bn1_m,bn1_v, nullptr, T, nullptr);
  k_mconv<1><<<dim3(64,8),256,0,stream>>>(T, rw2, bn2_g,bn2_b,bn2_m,bn2_v, R, nullptr, out);
}

// Round 15
// 724.577 us; speedup vs baseline: 14.6900x; 1.0541x over previous
//
#include <hip/hip_runtime.h>
#include <math.h>

// Problem constants
#define BB 4
#define CM 128      // d_model
#define DI 256      // d_inner
#define NS 16       // d_state
#define RK 8        // dt_rank
#define KD 4        // K directions
#define HH 64
#define WW 128      // interleaved width
#define LL 8192     // HH*WW
#define NC 8        // scan chunks per sequence
#define CH 1024     // chunk length (NC*CH == LL)

typedef unsigned short ushortt;
typedef unsigned int uintt;
typedef __attribute__((ext_vector_type(8))) __bf16 bf16x8;
typedef __attribute__((ext_vector_type(4))) float f32x4;

// Compiler memory-order fence: LDS ops cannot cross (asm memory clobber).
__device__ __forceinline__ void lds_fence(){
  asm volatile("" ::: "memory");
}

__device__ __forceinline__ float sigmoidf_(float x){ return 1.f/(1.f+__expf(-x)); }
__device__ __forceinline__ float siluf_(float x){ return x*sigmoidf_(x); }
__device__ __forceinline__ float softplusf_(float x){
  float r = __logf(1.f + __expf(x));   // fast path, no libcall
  return (x > 20.f) ? x : r;
}
__device__ __forceinline__ float geluf_(float x){ return 0.5f*x*(1.f+erff(x*0.70710678118654752f)); }
__device__ __forceinline__ ushortt f2bf(float f){
  uintt u = __float_as_uint(f);
  uintt r = (u + 0x7fffu + ((u>>16)&1u)) >> 16;
  return (ushortt)r;
}
__device__ __forceinline__ float bf2f(ushortt s){
  return __uint_as_float(((uintt)s)<<16);
}
template<int CTRL>
__device__ __forceinline__ float dppadd(float x){
  int r = __builtin_amdgcn_update_dpp(0, __float_as_int(x), CTRL, 0xF, 0xF, true);
  return x + __int_as_float(r);
}
// full sum over each 16-lane row; result on all lanes
__device__ __forceinline__ float rowsum16(float x){
  x = dppadd<0x121>(x);  // row_ror:1
  x = dppadd<0x122>(x);  // row_ror:2
  x = dppadd<0x124>(x);  // row_ror:4
  x = dppadd<0x128>(x);  // row_ror:8
  return x;
}
__device__ __forceinline__ float waveReduceSum(float v){
  for (int o=32;o>0;o>>=1) v += __shfl_xor(v,o,64);
  return v;
}

// ---------------- merged weight conversions (1 launch) ----------------
// xp packing (320 rows x 256): rows 0-31 dts hi (k*8+c), rows 32-63 dts lo,
// rows 64+q*64+s (q=dir, s<32: BC hi of j=s; s>=32: BC lo of j=s-32), j<16=B, j>=16=C.
__global__ void k_wall(const float* __restrict__ cw_s, ushortt* __restrict__ cw_d,
                       const float* __restrict__ ip_s, ushortt* __restrict__ ip_d,
                       const float* __restrict__ op_s, ushortt* __restrict__ op_d,
                       const float* __restrict__ m1_s, ushortt* __restrict__ m1_d,
                       const float* __restrict__ m2_s, ushortt* __restrict__ m2_d,
                       const float* __restrict__ r1_s, ushortt* __restrict__ r1_d,
                       const float* __restrict__ r2_s, ushortt* __restrict__ r2_d,
                       const float* __restrict__ dw_s, float* __restrict__ dw_d,
                       const float* __restrict__ xp_s, ushortt* __restrict__ xp_d){
  int i = blockIdx.x*256 + threadIdx.x;
  if (i < 16384){ cw_d[i] = f2bf(cw_s[i]); return; }
  i -= 16384;
  if (i < 65536){ ip_d[i] = f2bf(ip_s[i]); return; }
  i -= 65536;
  if (i < 32768){ op_d[i] = f2bf(op_s[i]); return; }
  i -= 32768;
  if (i < 65536){ m1_d[i] = f2bf(m1_s[i]); return; }
  i -= 65536;
  if (i < 65536){ m2_d[i] = f2bf(m2_s[i]); return; }
  i -= 65536;
  if (i < 147456){ int ci=i&127, co=(i>>7)&127, tap=i>>14;
    r1_d[i]=f2bf(r1_s[(size_t)(co*128+ci)*9+tap]); return; }
  i -= 147456;
  if (i < 147456){ int ci=i&127, co=(i>>7)&127, tap=i>>14;
    r2_d[i]=f2bf(r2_s[(size_t)(co*128+ci)*9+tap]); return; }
  i -= 147456;
  if (i < 2304){ int d = i & 255, tap = i >> 8;
    dw_d[i] = dw_s[d*9 + tap]; return; }   // exact f32 copy, [tap][d]
  i -= 2304;
  if (i < 81920){
    int d = i & 255, row = i >> 8;         // row 0..319
    float v; int lo;
    if (row < 64){
      int rr = row & 31; int k = rr>>3, c = rr&7;
      v = xp_s[((size_t)(k*40+c))*256 + d];
      lo = (row >= 32);
    } else {
      int rr = row - 64; int q = rr>>6, s = rr&63;
      int j = s & 31;
      v = xp_s[((size_t)(q*40+8+j))*256 + d];
      lo = (s >= 32);
    }
    xp_d[i] = lo ? f2bf(v - bf2f(f2bf(v))) : f2bf(v);
  }
}

// ---------------- CT build: interleave x1/x2 -> token-major bf16 (B*L, 128) ----------------
__global__ void k_build_ct2(const float* __restrict__ x1, const float* __restrict__ x2,
                            ushortt* __restrict__ CT){
  __shared__ ushortt Tl[64][136];
  int tid = threadIdx.x;
  int p0 = (blockIdx.x & 127) * 64;
  int b  = blockIdx.x >> 7;
  int j = tid & 63;
  int p = p0 + j; int hh = p>>7, ww = p&127, w2 = ww>>1;
  const float* src = (ww&1) ? x2 : x1;
  const float* sp = src + ((size_t)b*128*64 + hh)*64 + w2;
  for (int c0 = tid>>6; c0 < 128; c0 += 4)
    Tl[j][c0] = f2bf(sp[(size_t)c0*4096]);
  __syncthreads();
  int c = tid & 127; int rh = tid >> 7;
  for (int r = rh; r < 64; r += 2)
    CT[((size_t)b*LL + p0 + r)*128 + c] = Tl[r][c];
}

// ---------------- MFMA token GEMM ----------------
template<int EPI, int NF>
__global__ void k_mgemm(const ushortt* __restrict__ A, const ushortt* __restrict__ W,
                        const float* __restrict__ bias, const float* __restrict__ resid,
                        float* __restrict__ C, ushortt* __restrict__ C2,
                        ushortt* __restrict__ Pp, float* __restrict__ Rp, int N, int K){
  int n0 = blockIdx.x*(NF*16), m0 = blockIdx.y*64;
  int wv = threadIdx.x>>6, l = threadIdx.x&63;
  int ar = l&15, kg = l>>4;
  int mw = m0 + wv*16;
  f32x4 acc[NF];
#pragma unroll
  for (int i=0;i<NF;i++){ acc[i][0]=0.f; acc[i][1]=0.f; acc[i][2]=0.f; acc[i][3]=0.f; }
  const ushortt* Ap = A + (size_t)(mw+ar)*K + kg*8;
  const ushortt* Wp = W + (size_t)(n0+ar)*K + kg*8;
  for (int k0=0; k0<K; k0+=32){
    bf16x8 af = *(const bf16x8*)(Ap + k0);
#pragma unroll
    for (int nf=0; nf<NF; ++nf){
      bf16x8 bfv = *(const bf16x8*)(Wp + (size_t)nf*16*K + k0);
      acc[nf] = __builtin_amdgcn_mfma_f32_16x16x32_bf16(af, bfv, acc[nf], 0,0,0);
    }
  }
#pragma unroll
  for (int nf=0;nf<NF;nf++){
    int n = n0 + nf*16 + ar;
#pragma unroll
    for (int r=0;r<4;r++){
      int m = mw + kg*4 + r;
      float v = acc[nf][r];
      if (EPI==2){
        v += bias[n];
        C2[(size_t)m*512 + n] = f2bf(geluf_(v));
      } else if (EPI==3){
        if (n < 256) Pp[(size_t)m*256 + n] = f2bf(v);
        else         C2[(size_t)m*256 + (n-256)] = f2bf(v);
      } else { // EPI==4
        v += bias[n];
        v += resid[(size_t)m*128 + n];
        int bq = m >> 13; int pq = m & 8191; int yq = pq >> 7; int wq = pq & 127;
        int im = (wq&1)*4 + bq; int xq = wq>>1;
        Pp[(((size_t)im*66 + yq+1)*66 + xq+1)*128 + n] = f2bf(v);
        Rp[(((size_t)im*64 + yq)*64 + xq)*128 + n] = v;
      }
    }
  }
}

// ---------------- MFMA GEMM (N=128) with fused LayerNorm epilogue ----------------
template<int RES>
__global__ void k_mgemmln(const ushortt* __restrict__ A, const ushortt* __restrict__ W,
                          const float* __restrict__ bias, float* __restrict__ X,
                          const float* __restrict__ g, const float* __restrict__ bt,
                          ushortt* __restrict__ O, int K){
  int m0 = blockIdx.x*64;
  int wv = threadIdx.x>>6, l = threadIdx.x&63;
  int ar = l&15, kg = l>>4;
  int mw = m0 + wv*16;
  f32x4 acc[8];
#pragma unroll
  for (int i=0;i<8;i++){ acc[i][0]=0.f; acc[i][1]=0.f; acc[i][2]=0.f; acc[i][3]=0.f; }
  const ushortt* Ap = A + (size_t)(mw+ar)*K + kg*8;
  const ushortt* Wp = W + (size_t)ar*K + kg*8;
  for (int k0=0; k0<K; k0+=32){
    bf16x8 af = *(const bf16x8*)(Ap + k0);
#pragma unroll
    for (int nf=0; nf<8; ++nf){
      bf16x8 bfv = *(const bf16x8*)(Wp + (size_t)nf*16*K + k0);
      acc[nf] = __builtin_amdgcn_mfma_f32_16x16x32_bf16(af, bfv, acc[nf], 0,0,0);
    }
  }
  float vv[8][4];
  float s[4] = {0,0,0,0}, s2[4] = {0,0,0,0};
#pragma unroll
  for (int nf=0;nf<8;nf++){
    int n = nf*16 + ar;
    float bv = bias ? bias[n] : 0.f;
#pragma unroll
    for (int r=0;r<4;r++){
      int m = mw + kg*4 + r;
      float v = acc[nf][r] + bv;
      if (RES) v += X[(size_t)m*128 + n];
      X[(size_t)m*128 + n] = v;
      vv[nf][r] = v;
      s[r] += v; s2[r] += v*v;
    }
  }
  float mn[4], rs[4];
#pragma unroll
  for (int r=0;r<4;r++){
    float S  = rowsum16(s[r]);
    float S2 = rowsum16(s2[r]);
    float mean = S*(1.f/128.f);
    float var  = S2*(1.f/128.f) - mean*mean;
    mn[r] = mean; rs[r] = rsqrtf(var + 1e-5f);
  }
#pragma unroll
  for (int nf=0;nf<8;nf++){
    int n = nf*16 + ar;
    float gv = g[n], bv = bt[n];
#pragma unroll
    for (int r=0;r<4;r++){
      int m = mw + kg*4 + r;
      O[(size_t)m*128 + n] = f2bf((vv[nf][r]-mn[r])*rs[r]*gv + bv);
    }
  }
}

// ---------------- Depthwise 3x3 + bias + SiLU, tiled 16-token strip ----------------
// grid (8 strips, 64 hh, 4 b), block 256 (one d-column per thread).
__global__ void k_dwconv(const ushortt* __restrict__ Xp, const float* __restrict__ dwt,
                         const float* __restrict__ bias, ushortt* __restrict__ O){
  __shared__ ushortt S[3][18][256];   // 27.6 KB
  int tid = threadIdx.x;
  int ws0 = blockIdx.x*16;
  int hh  = blockIdx.y;
  int b   = blockIdx.z;
  // stage halo tile: 54 rows (dy,j) x 256 d, 8-bf16 vectors
  for (int v = tid; v < 1728; v += 256){
    int d0 = (v & 31)*8;
    int r  = v >> 5;            // 0..53
    int dy = r/18, j = r - dy*18;
    int yy = hh + dy - 1, xx = ws0 + j - 1;
    uint4 val = make_uint4(0,0,0,0);
    if (yy>=0 && yy<HH && xx>=0 && xx<WW)
      val = *(const uint4*)(Xp + ((size_t)b*LL + yy*WW + xx)*256 + d0);
    *(uint4*)(&S[dy][j][d0]) = val;
  }
  __syncthreads();
  int d = tid;
  float w[9];
#pragma unroll
  for (int t=0;t<9;t++) w[t] = dwt[t*256+d];
  float bv = bias[d];
  float a0=bf2f(S[0][0][d]), a1=bf2f(S[1][0][d]), a2=bf2f(S[2][0][d]);
  float b0=bf2f(S[0][1][d]), b1=bf2f(S[1][1][d]), b2=bf2f(S[2][1][d]);
  for (int j=0;j<16;j++){
    float c0=bf2f(S[0][j+2][d]), c1=bf2f(S[1][j+2][d]), c2=bf2f(S[2][j+2][d]);
    float acc = bv;
    acc += a0*w[0] + b0*w[1] + c0*w[2];
    acc += a1*w[3] + b1*w[4] + c1*w[5];
    acc += a2*w[6] + b2*w[7] + c2*w[8];
    O[((size_t)b*LL + hh*WW + ws0 + j)*256 + d] = f2bf(siluf_(acc));
    a0=b0; a1=b1; a2=b2; b0=c0; b1=c1; b2=c2;
  }
}

// ---------------- merged transposes: Xpab[b][p][d] -> Xpt0 (raster) / Xpt1 (colmajor) ----------------
__global__ void k_xtm(const ushortt* __restrict__ Xpab, ushortt* __restrict__ Xpt0,
                      ushortt* __restrict__ Xpt1){
  __shared__ ushortt Tl[64][68];
  int zb = blockIdx.z; int b = zb >> 1; int mode = zb & 1;
  int d0 = blockIdx.y*64;
  int di = threadIdx.x&63, q = threadIdx.x>>6;
  if (mode == 0){
    int p0 = blockIdx.x*64;
    for (int k2=0;k2<16;k2++){ int pi = q*16 + k2;
      Tl[pi][di] = Xpab[((size_t)b*LL + p0+pi)*256 + d0+di]; }
    __syncthreads();
    for (int k2=0;k2<16;k2++){ int dr = q*16 + k2;
      Xpt0[((size_t)(b*256 + d0+dr))*LL + p0+di] = Tl[di][dr]; }
  } else {
    int ww = blockIdx.x;
    for (int k2=0;k2<16;k2++){ int hh = q*16 + k2;
      Tl[hh][di] = Xpab[((size_t)b*LL + hh*128 + ww)*256 + d0+di]; }
    __syncthreads();
    for (int k2=0;k2<16;k2++){ int dr = q*16 + k2;
      Xpt1[((size_t)(b*256 + d0+dr))*LL + ww*64 + di] = Tl[di][dr]; }
  }
}

// ---------------- x_proj as MFMA GEMM, hi/lo weights (f32-equivalent numerics) ----------------
__global__ void k_xproj(const ushortt* __restrict__ A, const ushortt* __restrict__ W,
                        float* __restrict__ DBCf, char* __restrict__ BCsb){
  int n0 = blockIdx.x*64, m0 = blockIdx.y*64;
  int wv = threadIdx.x>>6, l = threadIdx.x&63;
  int ar = l&15, kg = l>>4;
  int mw = m0 + wv*16;
  f32x4 acc[4];
#pragma unroll
  for (int i=0;i<4;i++){ acc[i][0]=0.f; acc[i][1]=0.f; acc[i][2]=0.f; acc[i][3]=0.f; }
  const ushortt* Ap = A + (size_t)(mw+ar)*256 + kg*8;
  const ushortt* Wp = W + (size_t)(n0+ar)*256 + kg*8;
#pragma unroll
  for (int k0=0; k0<256; k0+=32){
    bf16x8 af = *(const bf16x8*)(Ap + k0);
#pragma unroll
    for (int nf=0; nf<4; ++nf){
      bf16x8 bfv = *(const bf16x8*)(Wp + (size_t)nf*16*256 + k0);
      acc[nf] = __builtin_amdgcn_mfma_f32_16x16x32_bf16(af, bfv, acc[nf], 0,0,0);
    }
  }
  if (blockIdx.x == 0){
#pragma unroll
    for (int nf=0;nf<2;nf++){
      int n = nf*16 + ar;          // 0..31
      int kq = n>>3, cq = n&7;
#pragma unroll
      for (int r=0;r<4;r++){
        int m = mw + kg*4 + r;
        int b = m >> 13, p = m & 8191;
        int hh = p>>7, ww = p&127;
        int tc = (ww<<6)|hh;
        int t = (kq==0)? p : (kq==1)? tc : (kq==2)? (8191-p) : (8191-tc);
        int bk = b*KD + kq;
        DBCf[((size_t)bk*LL + t)*8 + cq] = acc[nf][r] + acc[nf+2][r];
      }
    }
  } else {
    int q = blockIdx.x - 1;        // direction
#pragma unroll
    for (int nf=0;nf<2;nf++){
      int st = ar;
      int hi = (nf==1) ? 2 : 0;    // nf=0 -> B (low half), nf=1 -> C (high half)
#pragma unroll
      for (int r=0;r<4;r++){
        int m = mw + kg*4 + r;
        int b = m >> 13, p = m & 8191;
        int hh = p>>7, ww = p&127;
        int tc = (ww<<6)|hh;
        int t = (q==0)? p : (q==1)? tc : (q==2)? (8191-p) : (8191-tc);
        int bk = b*KD + q;
        float v = acc[nf][r] + acc[nf+2][r];
        size_t a = ((((size_t)bk*512 + (t>>4))*16 + st)*16 + (t&15))*4 + hi;
        *(ushortt*)(BCsb + a) = f2bf(v);
      }
    }
  }
}

// ---------------- Merged scan pass: from h=0, write y_local + h_out + sum(delta) ----------------
// 128 threads = 8 groups of 16 lanes.
__global__ __launch_bounds__(128) void k_scanM(const char* __restrict__ DBCb,
                        const uintt* __restrict__ BCs,
                        const ushortt* __restrict__ Xpt0, const ushortt* __restrict__ Xpt1,
                        const float* __restrict__ dtw_all, const float* __restrict__ dtb_all,
                        const float* __restrict__ A_logs,
                        float* __restrict__ Hbuf, float* __restrict__ Ssum,
                        ushortt* __restrict__ Y0, ushortt* __restrict__ Y1,
                        ushortt* __restrict__ Y2, ushortt* __restrict__ Y3){
  __shared__ float2 sdd[8][16];
  __shared__ float yt[8*328];       // group pitch 328
  int tid = threadIdx.x;
  int grp = tid >> 4, lane = tid & 15;
  float* ytg = yt + grp*328;
  int gid = blockIdx.x*8 + grp;
  int c = gid & (NC-1);
  int bkd = gid / NC;
  int b = bkd >> 10, k = (bkd>>8)&3, d = bkd & 255;
  int kd = k*256+d;
  int bk = b*KD + k;
  float dtw[8];
  { const float4* w4 = (const float4*)(dtw_all + (size_t)kd*8);
    float4 w0 = w4[0], w1 = w4[1];
    dtw[0]=w0.x; dtw[1]=w0.y; dtw[2]=w0.z; dtw[3]=w0.w;
    dtw[4]=w1.x; dtw[5]=w1.y; dtw[6]=w1.z; dtw[7]=w1.w; }
  float dtb  = dtb_all[kd];
  float Aval = -__expf(A_logs[(size_t)kd*16+lane]);
  const char* dbc = DBCb + (size_t)bk*LL*32;
  const uintt* bcb = BCs + ((size_t)bk*512 + (c*CH>>4))*256;
  const ushortt* Up = ((k&1)?Xpt1:Xpt0) + ((size_t)(b*256+d))*LL;
  ushortt* Yk = (k==0?Y0 : k==1?Y1 : k==2?Y2 : Y3) + ((size_t)b*256 + d)*LL;
  float h = 0.f, Sacc = 0.f;
  int t0 = c*CH;
  // prefetch block 0 dts + u
  const char* row0 = dbc + (size_t)(t0+lane)*32;
  float4 q0 = *(const float4*)row0;
  float4 q1 = *(const float4*)(row0+16);
  ushortt ur = Up[(k<2) ? (t0+lane) : (LL-1-(t0+lane))];
  for (int blk=0; blk<CH/16; ++blk){
    int tb = t0 + blk*16;
    int tme = tb + lane;
    const uint4* bcp = (const uint4*)(bcb + ((size_t)blk*16 + lane)*16);
    uint4 w0 = bcp[0], w1 = bcp[1], w2 = bcp[2], w3 = bcp[3];
    float4 c0 = q0, c1 = q1; ushortt cu = ur;
    if (blk+1 < CH/16){
      const char* rn = dbc + (size_t)(tme+16)*32;
      q0 = *(const float4*)rn;
      q1 = *(const float4*)(rn+16);
      ur = Up[(k<2) ? (tme+16) : (LL-1-(tme+16))];
    }
    float dsum = dtb + c0.x*dtw[0] + c0.y*dtw[1] + c0.z*dtw[2] + c0.w*dtw[3]
                     + c1.x*dtw[4] + c1.y*dtw[5] + c1.z*dtw[6] + c1.w*dtw[7];
    float delta = softplusf_(dsum);
    Sacc += delta;
    float u = bf2f(cu);
    sdd[grp][lane] = make_float2(delta, delta*u);
    lds_fence();             // order sdd write vs cross-lane reads below
    uintt wd[16] = {w0.x,w0.y,w0.z,w0.w, w1.x,w1.y,w1.z,w1.w,
                    w2.x,w2.y,w2.z,w2.w, w3.x,w3.y,w3.z,w3.w};
#pragma unroll
    for (int i=0;i<16;i++){
      float2 dd = sdd[grp][i];
      uintt w = wd[i];
      float Bn = __uint_as_float(w<<16);
      float Cn = __uint_as_float(w & 0xffff0000u);
      float e = __expf(dd.x * Aval);
      h = e*h + dd.y*Bn;
      ytg[i*20 + lane] = h*Cn;
    }
    lds_fence();             // order yt writes vs cross-lane yt reads
    const f32x4* yr = (const f32x4*)(ytg + lane*20);
    f32x4 s0 = yr[0], s1 = yr[1], s2v = yr[2], s3 = yr[3];
    float acc = (s0[0]+s0[1]+s0[2]+s0[3]) + (s1[0]+s1[1]+s1[2]+s1[3])
              + (s2v[0]+s2v[1]+s2v[2]+s2v[3]) + (s3[0]+s3[1]+s3[2]+s3[3]);
    Yk[tme] = f2bf(acc);
    lds_fence();             // order yt reads vs next block's yt writes
  }
  Hbuf[(size_t)gid*16 + lane] = h;
  float Stot = rowsum16(Sacc);
  if (lane==0) Ssum[gid] = Stot;
}

// Pass B: serial over chunks; converts Hbuf (h_out) to h_start in place.
__global__ void k_scanB(const float* __restrict__ Ssum, float* __restrict__ Hbuf,
                        const float* __restrict__ A_logs){
  int idx = blockIdx.x*256 + threadIdx.x;  // bkd*16+n (65536)
  int n = idx & 15; int bkd = idx >> 4;
  int kd = ((bkd>>8)&3)*256 + (bkd&255);
  float Aval = -__expf(A_logs[(size_t)kd*16+n]);
  float h = 0.f;
  for (int c=0;c<NC;c++){
    size_t g = (size_t)bkd*NC + c;
    float hout = Hbuf[g*16+n];
    Hbuf[g*16+n] = h;
    h = __expf(Aval*Ssum[g])*h + hout;
  }
}

// Pass C': correction sweep. y(t) += sum_n C_n(t) * exp(A_n * S_incl(t)) * h0_n.
__global__ __launch_bounds__(128) void k_corr(const char* __restrict__ DBCb,
                       const uintt* __restrict__ BCs,
                       const float* __restrict__ dtw_all, const float* __restrict__ dtb_all,
                       const float* __restrict__ Hbuf,
                       ushortt* __restrict__ Y0, ushortt* __restrict__ Y1,
                       ushortt* __restrict__ Y2, ushortt* __restrict__ Y3){
  int tid = threadIdx.x;
  int grp = tid >> 4, lane = tid & 15;
  int gid = blockIdx.x*8 + grp;
  int c = gid & (NC-1);
  if (c == 0) return;                 // h0 == 0 exactly
  int bkd = gid / NC;
  int b = bkd >> 10, k = (bkd>>8)&3, d = bkd & 255;
  int kd = k*256+d;
  int bk = b*KD + k;
  float h0[16];
  float hmax = 0.f;
#pragma unroll
  for (int n=0;n<16;n++){
    h0[n] = Hbuf[(size_t)gid*16 + n];
    hmax = fmaxf(hmax, fabsf(h0[n]));
  }
  float Sexit = 14.f + __logf(fmaxf(hmax, 1e-30f));
  if (0.f > Sexit) return;            // h0 negligible
  float dtw[8];
  { const float4* w4 = (const float4*)(dtw_all + (size_t)kd*8);
    float4 w0 = w4[0], w1 = w4[1];
    dtw[0]=w0.x; dtw[1]=w0.y; dtw[2]=w0.z; dtw[3]=w0.w;
    dtw[4]=w1.x; dtw[5]=w1.y; dtw[6]=w1.z; dtw[7]=w1.w; }
  float dtb  = dtb_all[kd];
  const char* dbc = DBCb + (size_t)bk*LL*32;
  ushortt* Yk = (k==0?Y0 : k==1?Y1 : k==2?Y2 : Y3) + ((size_t)b*256 + d)*LL;
  float S0 = 0.f;
  int t0 = c*CH;
  for (int blk=0; blk<CH/16; ++blk){
    int tme = t0 + blk*16 + lane;
    const char* rowme = dbc + (size_t)tme*32;
    float4 q0 = *(const float4*)rowme;
    float4 q1 = *(const float4*)(rowme+16);
    float dsum = dtb + q0.x*dtw[0] + q0.y*dtw[1] + q0.z*dtw[2] + q0.w*dtw[3]
                     + q1.x*dtw[4] + q1.y*dtw[5] + q1.z*dtw[6] + q1.w*dtw[7];
    float delta = softplusf_(dsum);
    // inclusive prefix sum over the 16-lane group
    float pre = delta;
#pragma unroll
    for (int o=1;o<16;o<<=1){
      float t = __shfl_up(pre, o, 16);
      if (lane >= o) pre += t;
    }
    float S = S0 + pre;
    float E = __expf(-S);
    const uintt* cb = BCs + ((size_t)bk*512 + (tme>>4))*256 + (tme&15);
    float p = E, acc = 0.f;
#pragma unroll
    for (int n=0;n<16;n++){
      float Cn = __uint_as_float(cb[n*16] & 0xffff0000u);
      acc += Cn * h0[n] * p;
      p *= E;
    }
    float yv = bf2f(Yk[tme]);
    Yk[tme] = f2bf(yv + acc);
    S0 = __shfl(S, 15, 16);           // block total carry
    if (S0 > Sexit) break;            // uniform across group
  }
}

// ---------------- Gate: gather Y0..Y3 + u*sum(D), LN256, *silu(z) ----------------
__global__ void k_gate2(const ushortt* __restrict__ Y0, const ushortt* __restrict__ Y1,
                        const ushortt* __restrict__ Y2, const ushortt* __restrict__ Y3,
                        const ushortt* __restrict__ Xpt0, const float* __restrict__ Ds,
                        ushortt* __restrict__ Zg,
                        const float* __restrict__ g, const float* __restrict__ bt){
  __shared__ float ysum[32][257];
  __shared__ float Dl[256];
  int tid = threadIdx.x;
  int wwb = blockIdx.x;      // 0..3
  int hh  = blockIdx.y;      // 0..63
  int b   = blockIdx.z;
  if (tid < 256) Dl[tid] = Ds[tid] + Ds[256+tid] + Ds[512+tid] + Ds[768+tid];
  int ww0 = wwb*32;
  for (int it=0; it<32; ++it){
    int idx = it*256 + tid;
    int d = idx >> 5, tl = idx & 31;
    int ww = ww0 + tl;
    int p  = hh*128 + ww;
    size_t base = ((size_t)b*256 + d) << 13;
    int t1 = ww*64 + hh;
    float v = bf2f(Y0[base + p]) + bf2f(Y2[base + (LL-1) - p])
            + bf2f(Y1[base + t1]) + bf2f(Y3[base + (LL-1) - t1]);
    ysum[tl][d] = v;
  }
  __syncthreads();
  {
    int d = tid;
    if (d < 256){
      size_t ub = (((size_t)b*256 + d) << 13) + hh*128 + ww0;
      const uint4* up = (const uint4*)(Xpt0 + ub);   // 64B aligned
      uint4 u0 = up[0], u1 = up[1], u2 = up[2], u3 = up[3];
      uintt uw[16] = {u0.x,u0.y,u0.z,u0.w, u1.x,u1.y,u1.z,u1.w,
                      u2.x,u2.y,u2.z,u2.w, u3.x,u3.y,u3.z,u3.w};
      float Dd = Dl[d];
#pragma unroll
      for (int qd=0; qd<16; ++qd){
        float ulo = __uint_as_float(uw[qd]<<16);
        float uhi = __uint_as_float(uw[qd] & 0xffff0000u);
        ysum[2*qd][d]   += Dd*ulo;
        ysum[2*qd+1][d] += Dd*uhi;
      }
    }
  }
  __syncthreads();
  int wave = tid >> 6, lane = tid & 63;
  for (int tk = wave*8; tk < wave*8+8; ++tk){
    float v0 = ysum[tk][lane], v1 = ysum[tk][lane+64];
    float v2 = ysum[tk][lane+128], v3 = ysum[tk][lane+192];
    float s  = waveReduceSum(v0+v1+v2+v3);
    float s2 = waveReduceSum(v0*v0+v1*v1+v2*v2+v3*v3);
    float mean = s*(1.f/256.f);
    float var  = s2*(1.f/256.f) - mean*mean;
    float r = rsqrtf(var + 1e-5f);
    int p = hh*128 + ww0 + tk;
    size_t zb = (((size_t)b<<13) + p) << 8;
#pragma unroll
    for (int j=0;j<4;j++){
      int dd = lane + 64*j;
      float ln = (ysum[tk][dd]-mean)*r*g[dd] + bt[dd];
      float z = bf2f(Zg[zb + dd]);
      Zg[zb + dd] = f2bf(ln * siluf_(z));
    }
  }
}

// ---------------- MFMA 3x3 conv 128->128(all co) + BN (+res) + ReLU ----------------
template<int FINAL>
__global__ void k_mconv(const ushortt* __restrict__ I, const ushortt* __restrict__ Wt,
                        const float* __restrict__ g, const float* __restrict__ bb,
                        const float* __restrict__ mn, const float* __restrict__ vv,
                        const float* __restrict__ R, ushortt* __restrict__ Op,
                        float* __restrict__ Of){
  int y  = blockIdx.x;
  int im = blockIdx.y;
  int wv = threadIdx.x>>6, l = threadIdx.x&63;
  int ar = l&15, kg = l>>4;
  int x0 = wv*16;
  f32x4 acc[8];
#pragma unroll
  for (int i=0;i<8;i++){ acc[i][0]=0.f; acc[i][1]=0.f; acc[i][2]=0.f; acc[i][3]=0.f; }
  const ushortt* Ibase = I + (((size_t)im*66 + y)*66 + x0 + ar)*128 + kg*8;
  const ushortt* Wbase = Wt + (size_t)ar*128 + kg*8;
#pragma unroll
  for (int tap=0; tap<9; ++tap){
    int dy = tap/3, dx = tap - dy*3;
    const ushortt* Ir = Ibase + ((size_t)dy*66 + dx)*128;
    const ushortt* Wr = Wbase + (size_t)tap*16384;
#pragma unroll
    for (int kc=0;kc<4;kc++){
      bf16x8 af = *(const bf16x8*)(Ir + kc*32);
#pragma unroll
      for (int nf=0;nf<8;nf++){
        bf16x8 bfv = *(const bf16x8*)(Wr + (size_t)nf*16*128 + kc*32);
        acc[nf] = __builtin_amdgcn_mfma_f32_16x16x32_bf16(af, bfv, acc[nf], 0,0,0);
      }
    }
  }
#pragma unroll
  for (int nf=0;nf<8;nf++){
    int co = nf*16 + ar;
    float s  = g[co]*rsqrtf(vv[co]+1e-5f);
    float sh = bb[co] - mn[co]*s;
#pragma unroll
    for (int r=0;r<4;r++){
      int x = x0 + kg*4 + r;
      float v = acc[nf][r]*s + sh;
      if (FINAL){
        v += R[(((size_t)im*64 + y)*64 + x)*128 + co];
        v = fmaxf(v, 0.f);
        Of[(((size_t)im*128 + co)*64 + y)*64 + x] = v;
      } else {
        v = fmaxf(v, 0.f);
        Op[(((size_t)im*66 + (y+1))*66 + (x+1))*128 + co] = f2bf(v);
      }
    }
  }
}

extern "C" void kernel_launch(void* const* d_in, const int* in_sizes, int n_in,
                              void* d_out, int out_size, void* d_ws, size_t ws_size,
                              hipStream_t stream){
  const float* x1        = (const float*)d_in[0];
  const float* x2        = (const float*)d_in[1];
  const float* conv_in_w = (const float*)d_in[2];
  const float* conv_in_b = (const float*)d_in[3];
  const float* ln1_g     = (const float*)d_in[4];
  const float* ln1_b     = (const float*)d_in[5];
  const float* in_proj_w = (const float*)d_in[6];
  const float* dw_w      = (const float*)d_in[7];
  const float* dw_b      = (const float*)d_in[8];
  const float* x_proj_w  = (const float*)d_in[9];
  const float* dt_proj_w = (const float*)d_in[10];
  const float* dt_proj_b = (const float*)d_in[11];
  const float* A_logs    = (const float*)d_in[12];
  const float* Ds        = (const float*)d_in[13];
  const float* onorm_g   = (const float*)d_in[14];
  const float* onorm_b   = (const float*)d_in[15];
  const float* out_proj_w= (const float*)d_in[16];
  const float* ln2_g     = (const float*)d_in[17];
  const float* ln2_b     = (const float*)d_in[18];
  const float* mlp_w1    = (const float*)d_in[19];
  const float* mlp_b1    = (const float*)d_in[20];
  const float* mlp_w2    = (const float*)d_in[21];
  const float* mlp_b2    = (const float*)d_in[22];
  const float* rb1_w     = (const float*)d_in[23];
  const float* bn1_g     = (const float*)d_in[24];
  const float* bn1_b     = (const float*)d_in[25];
  const float* bn1_m     = (const float*)d_in[26];
  const float* bn1_v     = (const float*)d_in[27];
  const float* rb2_w     = (const float*)d_in[28];
  const float* bn2_g     = (const float*)d_in[29];
  const float* bn2_b     = (const float*)d_in[30];
  const float* bn2_m     = (const float*)d_in[31];
  const float* bn2_v     = (const float*)d_in[32];

  float* ws = (float*)d_ws;
  char*  wsB = (char*)d_ws;
  const size_t FM = 262144;            // floats per MiB
  const size_t MB = 1048576;           // bytes per MiB
  // Workspace layout (peak ~147.2 MiB):
  float*   X0   = ws;                          // 0-16    residual stream (B,L,128) f32
  ushortt* Xpab = (ushortt*)(wsB + 16*MB);     // 16-32   u post-dw-silu (B,L,256) bf16
  ushortt* Xpt0 = (ushortt*)(wsB + 32*MB);     // 32-48   u raster-order [b][d][p]
  ushortt* Xpt1 = (ushortt*)(wsB + 48*MB);     // 48-64   u colmajor-order [b][d][t1]
  char*    DBCb = wsB + 64*MB;                 // 64-68   dts rows 32B
  uintt*   BCs  = (uintt*)(wsB + 68*MB);       // 68-76   B/C dwords [bk][t/16][n][t%16]
  ushortt* Zg   = (ushortt*)(wsB + 77*MB);     // 77-93   z / gated bf16
  ushortt* Y0   = (ushortt*)(wsB + 93*MB);     // 93-109
  ushortt* Y1   = (ushortt*)(wsB + 109*MB);    // 109-125
  ushortt* Y2   = (ushortt*)(wsB + 125*MB);    // 125-141
  ushortt* Y3   = Xpab;                        // alias (Xpab dead before scanM)
  float*   Hbuf = ws + 141*FM;                 // 141-143 (32768*16 f32)
  float*   Ssum = ws + 145*FM;                 // 145-145.125
  // time-disjoint aliases:
  ushortt* CT   = (ushortt*)(wsB + 93*MB);     // steps 1-2 (over Y0)
  ushortt* Lnb  = (ushortt*)(wsB + 101*MB);    // steps 2-4 (over Y0 2nd half)
  ushortt* Xpb  = (ushortt*)(wsB + 109*MB);    // steps 4-5 xp pre-dw bf16 (over Y1)
  ushortt* Ln2b = (ushortt*)(wsB + 93*MB);     // steps 9-11 (Y0 dead)
  ushortt* H1   = (ushortt*)(wsB + 109*MB);    // steps 11-12 (Y1,Y2 dead)
  ushortt* P    = (ushortt*)(wsB + 16*MB);     // step 12+ padded conv input [8][66][66][128]
  ushortt* T    = (ushortt*)(wsB + 25*MB);     // conv1 out padded
  float*   R    = (float*)(wsB + 34*MB);       // 34-51 residual [8][64][64][128] f32
  // bf16 weights (persistent, never aliased):
  ushortt* cw  = (ushortt*)(wsB + 146*MB);            // 32 KB
  ushortt* ipw = (ushortt*)(wsB + 146*MB + 32*1024);  // 128 KB
  ushortt* opw = (ushortt*)(wsB + 146*MB + 160*1024); // 64 KB
  ushortt* m1w = (ushortt*)(wsB + 146*MB + 224*1024); // 128 KB
  ushortt* m2w = (ushortt*)(wsB + 146*MB + 352*1024); // 128 KB
  ushortt* rw1 = (ushortt*)(wsB + 146*MB + 480*1024); // 288 KB
  ushortt* rw2 = (ushortt*)(wsB + 146*MB + 768*1024); // 288 KB
  ushortt* xpw = (ushortt*)(wsB + 146*MB + 1056*1024);// 160 KB (320x256 bf16)
  float*   dwt = (float*)(wsB + 146*MB + 1216*1024);  // 9 KB [tap][256] f32
  float* out = (float*)d_out;

  // 0. all weight conversions (one launch)
  k_wall<<<2441,256,0,stream>>>(conv_in_w,cw, in_proj_w,ipw, out_proj_w,opw,
                                mlp_w1,m1w, mlp_w2,m2w, rb1_w,rw1, rb2_w,rw2,
                                dw_w, dwt, x_proj_w, xpw);
  // 1. interleave -> CT bf16 token-major
  k_build_ct2<<<512,256,0,stream>>>(x1,x2,CT);
  // 2. conv_in 1x1 (bias) -> X0 f32 + fused LN1 -> Lnb bf16
  k_mgemmln<0><<<512,256,0,stream>>>(CT, cw, conv_in_b, X0, ln1_g, ln1_b, Lnb, 128);
  // 4. in_proj (512) -> split xp(Xpb bf16) / z(Zg bf16); wide blocks
  k_mgemm<3,16><<<dim3(2,512),256,0,stream>>>(Lnb, ipw, nullptr, nullptr, nullptr, Zg, Xpb, nullptr, 512,128);
  // 5. depthwise 3x3 + silu -> Xpab bf16 (tiled, LDS-staged)
  k_dwconv<<<dim3(8,64,BB),256,0,stream>>>(Xpb, dwt, dw_b, Xpab);
  // 5b. direction-ordered u copies (merged)
  k_xtm<<<dim3(128,4,2*BB),256,0,stream>>>(Xpab, Xpt0, Xpt1);
  // 6. x_proj MFMA GEMM (hi/lo weights, f32-equivalent) -> dts (DBCb) + B/C (BCs)
  k_xproj<<<dim3(5,512),256,0,stream>>>(Xpab, xpw, (float*)DBCb, (char*)BCs);
  // 7. chunked selective scan: merged main pass + chain + correction (NC=8)
  k_scanM<<<4096,128,0,stream>>>(DBCb, BCs, Xpt0, Xpt1, dt_proj_w, dt_proj_b, A_logs,
                                 Hbuf, Ssum, Y0,Y1,Y2,Y3);
  k_scanB<<<256,256,0,stream>>>(Ssum, Hbuf, A_logs);
  k_corr<<<4096,128,0,stream>>>(DBCb, BCs, dt_proj_w, dt_proj_b, Hbuf, Y0,Y1,Y2,Y3);
  // 8. gate
  k_gate2<<<dim3(4,64,BB),256,0,stream>>>(Y0,Y1,Y2,Y3, Xpt0, Ds, Zg, onorm_g, onorm_b);
  // 9. out_proj + residual -> X0 + fused LN2 -> Ln2b bf16
  k_mgemmln<1><<<512,256,0,stream>>>(Zg, opw, nullptr, X0, ln2_g, ln2_b, Ln2b, 256);
  // 9b. zero padded conv buffers (P and T) — Xpab/Xpt0 regions now dead
  hipMemsetAsync(wsB + 16*MB, 0, 18*MB, stream);
  // 11. MLP1 gelu -> H1 bf16; wide blocks
  k_mgemm<2,16><<<dim3(2,512),256,0,stream>>>(Ln2b, m1w, mlp_b1, nullptr, nullptr, H1, nullptr,nullptr, 512,128);
  // 12. MLP2 + bias + residual -> fused de-interleave (P bf16 padded + R f32); wide blocks
  k_mgemm<4,8><<<dim3(1,512),256,0,stream>>>(H1, m2w, mlp_b2, X0, nullptr, nullptr, P, R, 128,512);
  // 13-14. resblocks (both images batched, img = im2*4 + b)
  k_mconv<0><<<dim3(64,8),256,0,stream>>>(P, rw1, bn1_g,bn1_b,bn1_m,bn1_v, nullptr, T, nullptr);
  k_mconv<1><<<dim3(64,8),256,0,stream>>>(T, rw2, bn2_g,bn2_b,bn2_m,bn2_v, R, nullptr, out);
}

// Round 16
// 722.202 us; speedup vs baseline: 14.7383x; 1.0033x over previous
//
#include <hip/hip_runtime.h>
#include <math.h>

// Problem constants
#define BB 4
#define CM 128      // d_model
#define DI 256      // d_inner
#define NS 16       // d_state
#define RK 8        // dt_rank
#define KD 4        // K directions
#define HH 64
#define WW 128      // interleaved width
#define LL 8192     // HH*WW
#define NC 8        // scan chunks per sequence
#define CH 1024     // chunk length (NC*CH == LL)

typedef unsigned short ushortt;
typedef unsigned int uintt;
typedef __attribute__((ext_vector_type(8))) __bf16 bf16x8;
typedef __attribute__((ext_vector_type(4))) float f32x4;

// Compiler memory-order fence: LDS ops cannot cross (asm memory clobber).
__device__ __forceinline__ void lds_fence(){
  asm volatile("" ::: "memory");
}

__device__ __forceinline__ float sigmoidf_(float x){ return 1.f/(1.f+__expf(-x)); }
__device__ __forceinline__ float siluf_(float x){ return x*sigmoidf_(x); }
__device__ __forceinline__ float softplusf_(float x){
  float r = __logf(1.f + __expf(x));   // fast path, no libcall
  return (x > 20.f) ? x : r;
}
__device__ __forceinline__ float geluf_(float x){ return 0.5f*x*(1.f+erff(x*0.70710678118654752f)); }
__device__ __forceinline__ ushortt f2bf(float f){
  uintt u = __float_as_uint(f);
  uintt r = (u + 0x7fffu + ((u>>16)&1u)) >> 16;
  return (ushortt)r;
}
__device__ __forceinline__ float bf2f(ushortt s){
  return __uint_as_float(((uintt)s)<<16);
}
template<int CTRL>
__device__ __forceinline__ float dppadd(float x){
  int r = __builtin_amdgcn_update_dpp(0, __float_as_int(x), CTRL, 0xF, 0xF, true);
  return x + __int_as_float(r);
}
// full sum over each 16-lane row; result on all lanes
__device__ __forceinline__ float rowsum16(float x){
  x = dppadd<0x121>(x);  // row_ror:1
  x = dppadd<0x122>(x);  // row_ror:2
  x = dppadd<0x124>(x);  // row_ror:4
  x = dppadd<0x128>(x);  // row_ror:8
  return x;
}
__device__ __forceinline__ float waveReduceSum(float v){
  for (int o=32;o>0;o>>=1) v += __shfl_xor(v,o,64);
  return v;
}

// ---------------- merged weight conversions (1 launch) ----------------
// xp packing (320 rows x 256): rows 0-31 dts hi (k*8+c), rows 32-63 dts lo,
// rows 64+q*64+s (q=dir, s<32: BC hi of j=s; s>=32: BC lo of j=s-32), j<16=B, j>=16=C.
__global__ void k_wall(const float* __restrict__ cw_s, ushortt* __restrict__ cw_d,
                       const float* __restrict__ ip_s, ushortt* __restrict__ ip_d,
                       const float* __restrict__ op_s, ushortt* __restrict__ op_d,
                       const float* __restrict__ m1_s, ushortt* __restrict__ m1_d,
                       const float* __restrict__ m2_s, ushortt* __restrict__ m2_d,
                       const float* __restrict__ r1_s, ushortt* __restrict__ r1_d,
                       const float* __restrict__ r2_s, ushortt* __restrict__ r2_d,
                       const float* __restrict__ dw_s, float* __restrict__ dw_d,
                       const float* __restrict__ xp_s, ushortt* __restrict__ xp_d){
  int i = blockIdx.x*256 + threadIdx.x;
  if (i < 16384){ cw_d[i] = f2bf(cw_s[i]); return; }
  i -= 16384;
  if (i < 65536){ ip_d[i] = f2bf(ip_s[i]); return; }
  i -= 65536;
  if (i < 32768){ op_d[i] = f2bf(op_s[i]); return; }
  i -= 32768;
  if (i < 65536){ m1_d[i] = f2bf(m1_s[i]); return; }
  i -= 65536;
  if (i < 65536){ m2_d[i] = f2bf(m2_s[i]); return; }
  i -= 65536;
  if (i < 147456){ int ci=i&127, co=(i>>7)&127, tap=i>>14;
    r1_d[i]=f2bf(r1_s[(size_t)(co*128+ci)*9+tap]); return; }
  i -= 147456;
  if (i < 147456){ int ci=i&127, co=(i>>7)&127, tap=i>>14;
    r2_d[i]=f2bf(r2_s[(size_t)(co*128+ci)*9+tap]); return; }
  i -= 147456;
  if (i < 2304){ int d = i & 255, tap = i >> 8;
    dw_d[i] = dw_s[d*9 + tap]; return; }   // exact f32 copy, [tap][d]
  i -= 2304;
  if (i < 81920){
    int d = i & 255, row = i >> 8;         // row 0..319
    float v; int lo;
    if (row < 64){
      int rr = row & 31; int k = rr>>3, c = rr&7;
      v = xp_s[((size_t)(k*40+c))*256 + d];
      lo = (row >= 32);
    } else {
      int rr = row - 64; int q = rr>>6, s = rr&63;
      int j = s & 31;
      v = xp_s[((size_t)(q*40+8+j))*256 + d];
      lo = (s >= 32);
    }
    xp_d[i] = lo ? f2bf(v - bf2f(f2bf(v))) : f2bf(v);
  }
}

// ---------------- CT build: interleave x1/x2 -> token-major bf16 (B*L, 128) ----------------
__global__ void k_build_ct2(const float* __restrict__ x1, const float* __restrict__ x2,
                            ushortt* __restrict__ CT){
  __shared__ ushortt Tl[64][136];
  int tid = threadIdx.x;
  int p0 = (blockIdx.x & 127) * 64;
  int b  = blockIdx.x >> 7;
  int j = tid & 63;
  int p = p0 + j; int hh = p>>7, ww = p&127, w2 = ww>>1;
  const float* src = (ww&1) ? x2 : x1;
  const float* sp = src + ((size_t)b*128*64 + hh)*64 + w2;
  for (int c0 = tid>>6; c0 < 128; c0 += 4)
    Tl[j][c0] = f2bf(sp[(size_t)c0*4096]);
  __syncthreads();
  int c = tid & 127; int rh = tid >> 7;
  for (int r = rh; r < 64; r += 2)
    CT[((size_t)b*LL + p0 + r)*128 + c] = Tl[r][c];
}

// ---------------- MFMA token GEMM ----------------
template<int EPI, int NF>
__global__ void k_mgemm(const ushortt* __restrict__ A, const ushortt* __restrict__ W,
                        const float* __restrict__ bias, const float* __restrict__ resid,
                        float* __restrict__ C, ushortt* __restrict__ C2,
                        ushortt* __restrict__ Pp, float* __restrict__ Rp, int N, int K){
  int n0 = blockIdx.x*(NF*16), m0 = blockIdx.y*64;
  int wv = threadIdx.x>>6, l = threadIdx.x&63;
  int ar = l&15, kg = l>>4;
  int mw = m0 + wv*16;
  f32x4 acc[NF];
#pragma unroll
  for (int i=0;i<NF;i++){ acc[i][0]=0.f; acc[i][1]=0.f; acc[i][2]=0.f; acc[i][3]=0.f; }
  const ushortt* Ap = A + (size_t)(mw+ar)*K + kg*8;
  const ushortt* Wp = W + (size_t)(n0+ar)*K + kg*8;
  for (int k0=0; k0<K; k0+=32){
    bf16x8 af = *(const bf16x8*)(Ap + k0);
#pragma unroll
    for (int nf=0; nf<NF; ++nf){
      bf16x8 bfv = *(const bf16x8*)(Wp + (size_t)nf*16*K + k0);
      acc[nf] = __builtin_amdgcn_mfma_f32_16x16x32_bf16(af, bfv, acc[nf], 0,0,0);
    }
  }
#pragma unroll
  for (int nf=0;nf<NF;nf++){
    int n = n0 + nf*16 + ar;
#pragma unroll
    for (int r=0;r<4;r++){
      int m = mw + kg*4 + r;
      float v = acc[nf][r];
      if (EPI==2){
        v += bias[n];
        C2[(size_t)m*512 + n] = f2bf(geluf_(v));
      } else if (EPI==3){
        if (n < 256) Pp[(size_t)m*256 + n] = f2bf(v);
        else         C2[(size_t)m*256 + (n-256)] = f2bf(v);
      } else { // EPI==4
        v += bias[n];
        v += resid[(size_t)m*128 + n];
        int bq = m >> 13; int pq = m & 8191; int yq = pq >> 7; int wq = pq & 127;
        int im = (wq&1)*4 + bq; int xq = wq>>1;
        Pp[(((size_t)im*66 + yq+1)*66 + xq+1)*128 + n] = f2bf(v);
        Rp[(((size_t)im*64 + yq)*64 + xq)*128 + n] = v;
      }
    }
  }
}

// ---------------- MFMA GEMM (N=128) with fused LayerNorm epilogue ----------------
template<int RES>
__global__ void k_mgemmln(const ushortt* __restrict__ A, const ushortt* __restrict__ W,
                          const float* __restrict__ bias, float* __restrict__ X,
                          const float* __restrict__ g, const float* __restrict__ bt,
                          ushortt* __restrict__ O, int K){
  int m0 = blockIdx.x*64;
  int wv = threadIdx.x>>6, l = threadIdx.x&63;
  int ar = l&15, kg = l>>4;
  int mw = m0 + wv*16;
  f32x4 acc[8];
#pragma unroll
  for (int i=0;i<8;i++){ acc[i][0]=0.f; acc[i][1]=0.f; acc[i][2]=0.f; acc[i][3]=0.f; }
  const ushortt* Ap = A + (size_t)(mw+ar)*K + kg*8;
  const ushortt* Wp = W + (size_t)ar*K + kg*8;
  for (int k0=0; k0<K; k0+=32){
    bf16x8 af = *(const bf16x8*)(Ap + k0);
#pragma unroll
    for (int nf=0; nf<8; ++nf){
      bf16x8 bfv = *(const bf16x8*)(Wp + (size_t)nf*16*K + k0);
      acc[nf] = __builtin_amdgcn_mfma_f32_16x16x32_bf16(af, bfv, acc[nf], 0,0,0);
    }
  }
  float vv[8][4];
  float s[4] = {0,0,0,0}, s2[4] = {0,0,0,0};
#pragma unroll
  for (int nf=0;nf<8;nf++){
    int n = nf*16 + ar;
    float bv = bias ? bias[n] : 0.f;
#pragma unroll
    for (int r=0;r<4;r++){
      int m = mw + kg*4 + r;
      float v = acc[nf][r] + bv;
      if (RES) v += X[(size_t)m*128 + n];
      X[(size_t)m*128 + n] = v;
      vv[nf][r] = v;
      s[r] += v; s2[r] += v*v;
    }
  }
  float mn[4], rs[4];
#pragma unroll
  for (int r=0;r<4;r++){
    float S  = rowsum16(s[r]);
    float S2 = rowsum16(s2[r]);
    float mean = S*(1.f/128.f);
    float var  = S2*(1.f/128.f) - mean*mean;
    mn[r] = mean; rs[r] = rsqrtf(var + 1e-5f);
  }
#pragma unroll
  for (int nf=0;nf<8;nf++){
    int n = nf*16 + ar;
    float gv = g[n], bv = bt[n];
#pragma unroll
    for (int r=0;r<4;r++){
      int m = mw + kg*4 + r;
      O[(size_t)m*128 + n] = f2bf((vv[nf][r]-mn[r])*rs[r]*gv + bv);
    }
  }
}

// ---------------- Depthwise 3x3 + bias + SiLU, tiled; emits Xpab AND Xpt0 ----------------
// grid (8 strips, 64 hh, 4 b), block 256 (one d-column per thread).
__global__ void k_dwconv(const ushortt* __restrict__ Xp, const float* __restrict__ dwt,
                         const float* __restrict__ bias, ushortt* __restrict__ O,
                         ushortt* __restrict__ Xpt0){
  __shared__ ushortt S[3][18][256];   // 27.6 KB
  int tid = threadIdx.x;
  int ws0 = blockIdx.x*16;
  int hh  = blockIdx.y;
  int b   = blockIdx.z;
  // stage halo tile: 54 rows (dy,j) x 256 d, 8-bf16 vectors
  for (int v = tid; v < 1728; v += 256){
    int d0 = (v & 31)*8;
    int r  = v >> 5;            // 0..53
    int dy = r/18, j = r - dy*18;
    int yy = hh + dy - 1, xx = ws0 + j - 1;
    uint4 val = make_uint4(0,0,0,0);
    if (yy>=0 && yy<HH && xx>=0 && xx<WW)
      val = *(const uint4*)(Xp + ((size_t)b*LL + yy*WW + xx)*256 + d0);
    *(uint4*)(&S[dy][j][d0]) = val;
  }
  __syncthreads();
  int d = tid;
  float w[9];
#pragma unroll
  for (int t=0;t<9;t++) w[t] = dwt[t*256+d];
  float bv = bias[d];
  ushortt outs[16];
  float a0=bf2f(S[0][0][d]), a1=bf2f(S[1][0][d]), a2=bf2f(S[2][0][d]);
  float b0=bf2f(S[0][1][d]), b1=bf2f(S[1][1][d]), b2=bf2f(S[2][1][d]);
  for (int j=0;j<16;j++){
    float c0=bf2f(S[0][j+2][d]), c1=bf2f(S[1][j+2][d]), c2=bf2f(S[2][j+2][d]);
    float acc = bv;
    acc += a0*w[0] + b0*w[1] + c0*w[2];
    acc += a1*w[3] + b1*w[4] + c1*w[5];
    acc += a2*w[6] + b2*w[7] + c2*w[8];
    ushortt ov = f2bf(siluf_(acc));
    outs[j] = ov;
    O[((size_t)b*LL + hh*WW + ws0 + j)*256 + d] = ov;
    a0=b0; a1=b1; a2=b2; b0=c0; b1=c1; b2=c2;
  }
  // contiguous 32B row of Xpt0[b][d][p0..p0+15]
  uintt pk[8];
#pragma unroll
  for (int q=0;q<8;q++) pk[q] = (uintt)outs[2*q] | ((uintt)outs[2*q+1]<<16);
  ushortt* dst = Xpt0 + ((size_t)(b*256+d))*LL + hh*WW + ws0;
  *(uint4*)dst       = make_uint4(pk[0],pk[1],pk[2],pk[3]);
  *(uint4*)(dst + 8) = make_uint4(pk[4],pk[5],pk[6],pk[7]);
}

// ---------------- transpose: Xpab[b][p][d] -> Xpt1 (colmajor t1 = ww*64+hh) ----------------
__global__ void k_xtm(const ushortt* __restrict__ Xpab, ushortt* __restrict__ Xpt1){
  __shared__ ushortt Tl[64][68];
  int b = blockIdx.z;
  int d0 = blockIdx.y*64;
  int ww = blockIdx.x;
  int di = threadIdx.x&63, q = threadIdx.x>>6;
  for (int k2=0;k2<16;k2++){ int hh = q*16 + k2;
    Tl[hh][di] = Xpab[((size_t)b*LL + hh*128 + ww)*256 + d0+di]; }
  __syncthreads();
  for (int k2=0;k2<16;k2++){ int dr = q*16 + k2;
    Xpt1[((size_t)(b*256 + d0+dr))*LL + ww*64 + di] = Tl[di][dr]; }
}

// ---------------- x_proj as MFMA GEMM, hi/lo weights (f32-equivalent numerics) ----------------
__global__ void k_xproj(const ushortt* __restrict__ A, const ushortt* __restrict__ W,
                        float* __restrict__ DBCf, char* __restrict__ BCsb){
  int n0 = blockIdx.x*64, m0 = blockIdx.y*64;
  int wv = threadIdx.x>>6, l = threadIdx.x&63;
  int ar = l&15, kg = l>>4;
  int mw = m0 + wv*16;
  f32x4 acc[4];
#pragma unroll
  for (int i=0;i<4;i++){ acc[i][0]=0.f; acc[i][1]=0.f; acc[i][2]=0.f; acc[i][3]=0.f; }
  const ushortt* Ap = A + (size_t)(mw+ar)*256 + kg*8;
  const ushortt* Wp = W + (size_t)(n0+ar)*256 + kg*8;
#pragma unroll
  for (int k0=0; k0<256; k0+=32){
    bf16x8 af = *(const bf16x8*)(Ap + k0);
#pragma unroll
    for (int nf=0; nf<4; ++nf){
      bf16x8 bfv = *(const bf16x8*)(Wp + (size_t)nf*16*256 + k0);
      acc[nf] = __builtin_amdgcn_mfma_f32_16x16x32_bf16(af, bfv, acc[nf], 0,0,0);
    }
  }
  if (blockIdx.x == 0){
#pragma unroll
    for (int nf=0;nf<2;nf++){
      int n = nf*16 + ar;          // 0..31
      int kq = n>>3, cq = n&7;
#pragma unroll
      for (int r=0;r<4;r++){
        int m = mw + kg*4 + r;
        int b = m >> 13, p = m & 8191;
        int hh = p>>7, ww = p&127;
        int tc = (ww<<6)|hh;
        int t = (kq==0)? p : (kq==1)? tc : (kq==2)? (8191-p) : (8191-tc);
        int bk = b*KD + kq;
        DBCf[((size_t)bk*LL + t)*8 + cq] = acc[nf][r] + acc[nf+2][r];
      }
    }
  } else {
    int q = blockIdx.x - 1;        // direction
#pragma unroll
    for (int nf=0;nf<2;nf++){
      int st = ar;
      int hi = (nf==1) ? 2 : 0;    // nf=0 -> B (low half), nf=1 -> C (high half)
#pragma unroll
      for (int r=0;r<4;r++){
        int m = mw + kg*4 + r;
        int b = m >> 13, p = m & 8191;
        int hh = p>>7, ww = p&127;
        int tc = (ww<<6)|hh;
        int t = (q==0)? p : (q==1)? tc : (q==2)? (8191-p) : (8191-tc);
        int bk = b*KD + q;
        float v = acc[nf][r] + acc[nf+2][r];
        size_t a = ((((size_t)bk*512 + (t>>4))*16 + st)*16 + (t&15))*4 + hi;
        *(ushortt*)(BCsb + a) = f2bf(v);
      }
    }
  }
}

// ---------------- Merged scan pass: from h=0, write y_local + h_out + sum(delta) ----------------
// 128 threads = 8 groups of 16 lanes.
__global__ __launch_bounds__(128) void k_scanM(const char* __restrict__ DBCb,
                        const uintt* __restrict__ BCs,
                        const ushortt* __restrict__ Xpt0, const ushortt* __restrict__ Xpt1,
                        const float* __restrict__ dtw_all, const float* __restrict__ dtb_all,
                        const float* __restrict__ A_logs,
                        float* __restrict__ Hbuf, float* __restrict__ Ssum,
                        ushortt* __restrict__ Y0, ushortt* __restrict__ Y1,
                        ushortt* __restrict__ Y2, ushortt* __restrict__ Y3){
  __shared__ float2 sdd[8][16];
  __shared__ float yt[8*328];       // group pitch 328
  int tid = threadIdx.x;
  int grp = tid >> 4, lane = tid & 15;
  float* ytg = yt + grp*328;
  int gid = blockIdx.x*8 + grp;
  int c = gid & (NC-1);
  int bkd = gid / NC;
  int b = bkd >> 10, k = (bkd>>8)&3, d = bkd & 255;
  int kd = k*256+d;
  int bk = b*KD + k;
  float dtw[8];
  { const float4* w4 = (const float4*)(dtw_all + (size_t)kd*8);
    float4 w0 = w4[0], w1 = w4[1];
    dtw[0]=w0.x; dtw[1]=w0.y; dtw[2]=w0.z; dtw[3]=w0.w;
    dtw[4]=w1.x; dtw[5]=w1.y; dtw[6]=w1.z; dtw[7]=w1.w; }
  float dtb  = dtb_all[kd];
  float Aval = -__expf(A_logs[(size_t)kd*16+lane]);
  const char* dbc = DBCb + (size_t)bk*LL*32;
  const uintt* bcb = BCs + ((size_t)bk*512 + (c*CH>>4))*256;
  const ushortt* Up = ((k&1)?Xpt1:Xpt0) + ((size_t)(b*256+d))*LL;
  ushortt* Yk = (k==0?Y0 : k==1?Y1 : k==2?Y2 : Y3) + ((size_t)b*256 + d)*LL;
  float h = 0.f, Sacc = 0.f;
  int t0 = c*CH;
  // prefetch block 0 dts + u
  const char* row0 = dbc + (size_t)(t0+lane)*32;
  float4 q0 = *(const float4*)row0;
  float4 q1 = *(const float4*)(row0+16);
  ushortt ur = Up[(k<2) ? (t0+lane) : (LL-1-(t0+lane))];
  for (int blk=0; blk<CH/16; ++blk){
    int tb = t0 + blk*16;
    int tme = tb + lane;
    const uint4* bcp = (const uint4*)(bcb + ((size_t)blk*16 + lane)*16);
    uint4 w0 = bcp[0], w1 = bcp[1], w2 = bcp[2], w3 = bcp[3];
    float4 c0 = q0, c1 = q1; ushortt cu = ur;
    if (blk+1 < CH/16){
      const char* rn = dbc + (size_t)(tme+16)*32;
      q0 = *(const float4*)rn;
      q1 = *(const float4*)(rn+16);
      ur = Up[(k<2) ? (tme+16) : (LL-1-(tme+16))];
    }
    float dsum = dtb + c0.x*dtw[0] + c0.y*dtw[1] + c0.z*dtw[2] + c0.w*dtw[3]
                     + c1.x*dtw[4] + c1.y*dtw[5] + c1.z*dtw[6] + c1.w*dtw[7];
    float delta = softplusf_(dsum);
    Sacc += delta;
    float u = bf2f(cu);
    sdd[grp][lane] = make_float2(delta, delta*u);
    lds_fence();             // order sdd write vs cross-lane reads below
    uintt wd[16] = {w0.x,w0.y,w0.z,w0.w, w1.x,w1.y,w1.z,w1.w,
                    w2.x,w2.y,w2.z,w2.w, w3.x,w3.y,w3.z,w3.w};
#pragma unroll
    for (int i=0;i<16;i++){
      float2 dd = sdd[grp][i];
      uintt w = wd[i];
      float Bn = __uint_as_float(w<<16);
      float Cn = __uint_as_float(w & 0xffff0000u);
      float e = __expf(dd.x * Aval);
      h = e*h + dd.y*Bn;
      ytg[i*20 + lane] = h*Cn;
    }
    lds_fence();             // order yt writes vs cross-lane yt reads
    const f32x4* yr = (const f32x4*)(ytg + lane*20);
    f32x4 s0 = yr[0], s1 = yr[1], s2v = yr[2], s3 = yr[3];
    float acc = (s0[0]+s0[1]+s0[2]+s0[3]) + (s1[0]+s1[1]+s1[2]+s1[3])
              + (s2v[0]+s2v[1]+s2v[2]+s2v[3]) + (s3[0]+s3[1]+s3[2]+s3[3]);
    Yk[tme] = f2bf(acc);
    lds_fence();             // order yt reads vs next block's yt writes
  }
  Hbuf[(size_t)gid*16 + lane] = h;
  float Stot = rowsum16(Sacc);
  if (lane==0) Ssum[gid] = Stot;
}

// Pass C': correction sweep with inline h_start chain (scanB fused).
// y(t) += sum_n C_n(t) * exp(A_n * S_incl(t)) * h0_n.
__global__ __launch_bounds__(128) void k_corr(const char* __restrict__ DBCb,
                       const uintt* __restrict__ BCs,
                       const float* __restrict__ dtw_all, const float* __restrict__ dtb_all,
                       const float* __restrict__ A_logs,
                       const float* __restrict__ Hbuf, const float* __restrict__ Ssum,
                       ushortt* __restrict__ Y0, ushortt* __restrict__ Y1,
                       ushortt* __restrict__ Y2, ushortt* __restrict__ Y3){
  __shared__ float hs[8][16];
  int tid = threadIdx.x;
  int grp = tid >> 4, lane = tid & 15;
  int gid = blockIdx.x*8 + grp;
  int c = gid & (NC-1);
  if (c == 0) return;                 // h0 == 0 exactly
  int bkd = gid / NC;
  int b = bkd >> 10, k = (bkd>>8)&3, d = bkd & 255;
  int kd = k*256+d;
  int bk = b*KD + k;
  // lane n computes h_start[n] via scanB's recurrence (bit-identical order)
  {
    float Avn = -__expf(A_logs[(size_t)kd*16+lane]);
    float h = 0.f;
    for (int j=0; j<c; ++j){
      size_t gj = (size_t)bkd*NC + j;
      h = __expf(Avn*Ssum[gj])*h + Hbuf[gj*16 + lane];
    }
    hs[grp][lane] = h;
  }
  lds_fence();
  float h0[16];
  float hmax = 0.f;
#pragma unroll
  for (int n=0;n<16;n++){
    h0[n] = hs[grp][n];
    hmax = fmaxf(hmax, fabsf(h0[n]));
  }
  float Sexit = 14.f + __logf(fmaxf(hmax, 1e-30f));
  if (0.f > Sexit) return;            // h0 negligible
  float dtw[8];
  { const float4* w4 = (const float4*)(dtw_all + (size_t)kd*8);
    float4 w0 = w4[0], w1 = w4[1];
    dtw[0]=w0.x; dtw[1]=w0.y; dtw[2]=w0.z; dtw[3]=w0.w;
    dtw[4]=w1.x; dtw[5]=w1.y; dtw[6]=w1.z; dtw[7]=w1.w; }
  float dtb  = dtb_all[kd];
  const char* dbc = DBCb + (size_t)bk*LL*32;
  ushortt* Yk = (k==0?Y0 : k==1?Y1 : k==2?Y2 : Y3) + ((size_t)b*256 + d)*LL;
  float S0 = 0.f;
  int t0 = c*CH;
  for (int blk=0; blk<CH/16; ++blk){
    int tme = t0 + blk*16 + lane;
    const char* rowme = dbc + (size_t)tme*32;
    float4 q0 = *(const float4*)rowme;
    float4 q1 = *(const float4*)(rowme+16);
    float dsum = dtb + q0.x*dtw[0] + q0.y*dtw[1] + q0.z*dtw[2] + q0.w*dtw[3]
                     + q1.x*dtw[4] + q1.y*dtw[5] + q1.z*dtw[6] + q1.w*dtw[7];
    float delta = softplusf_(dsum);
    // inclusive prefix sum over the 16-lane group
    float pre = delta;
#pragma unroll
    for (int o=1;o<16;o<<=1){
      float t = __shfl_up(pre, o, 16);
      if (lane >= o) pre += t;
    }
    float S = S0 + pre;
    float E = __expf(-S);
    const uintt* cb = BCs + ((size_t)bk*512 + (tme>>4))*256 + (tme&15);
    float p = E, acc = 0.f;
#pragma unroll
    for (int n=0;n<16;n++){
      float Cn = __uint_as_float(cb[n*16] & 0xffff0000u);
      acc += Cn * h0[n] * p;
      p *= E;
    }
    float yv = bf2f(Yk[tme]);
    Yk[tme] = f2bf(yv + acc);
    S0 = __shfl(S, 15, 16);           // block total carry
    if (S0 > Sexit) break;            // uniform across group
  }
}

// ---------------- Gate: gather Y0..Y3 + u*sum(D), LN256, *silu(z) ----------------
__global__ void k_gate2(const ushortt* __restrict__ Y0, const ushortt* __restrict__ Y1,
                        const ushortt* __restrict__ Y2, const ushortt* __restrict__ Y3,
                        const ushortt* __restrict__ Xpt0, const float* __restrict__ Ds,
                        ushortt* __restrict__ Zg,
                        const float* __restrict__ g, const float* __restrict__ bt){
  __shared__ float ysum[32][257];
  __shared__ float Dl[256];
  int tid = threadIdx.x;
  int wwb = blockIdx.x;      // 0..3
  int hh  = blockIdx.y;      // 0..63
  int b   = blockIdx.z;
  if (tid < 256) Dl[tid] = Ds[tid] + Ds[256+tid] + Ds[512+tid] + Ds[768+tid];
  int ww0 = wwb*32;
  for (int it=0; it<32; ++it){
    int idx = it*256 + tid;
    int d = idx >> 5, tl = idx & 31;
    int ww = ww0 + tl;
    int p  = hh*128 + ww;
    size_t base = ((size_t)b*256 + d) << 13;
    int t1 = ww*64 + hh;
    float v = bf2f(Y0[base + p]) + bf2f(Y2[base + (LL-1) - p])
            + bf2f(Y1[base + t1]) + bf2f(Y3[base + (LL-1) - t1]);
    ysum[tl][d] = v;
  }
  __syncthreads();
  {
    int d = tid;
    if (d < 256){
      size_t ub = (((size_t)b*256 + d) << 13) + hh*128 + ww0;
      const uint4* up = (const uint4*)(Xpt0 + ub);   // 64B aligned
      uint4 u0 = up[0], u1 = up[1], u2 = up[2], u3 = up[3];
      uintt uw[16] = {u0.x,u0.y,u0.z,u0.w, u1.x,u1.y,u1.z,u1.w,
                      u2.x,u2.y,u2.z,u2.w, u3.x,u3.y,u3.z,u3.w};
      float Dd = Dl[d];
#pragma unroll
      for (int qd=0; qd<16; ++qd){
        float ulo = __uint_as_float(uw[qd]<<16);
        float uhi = __uint_as_float(uw[qd] & 0xffff0000u);
        ysum[2*qd][d]   += Dd*ulo;
        ysum[2*qd+1][d] += Dd*uhi;
      }
    }
  }
  __syncthreads();
  int wave = tid >> 6, lane = tid & 63;
  for (int tk = wave*8; tk < wave*8+8; ++tk){
    float v0 = ysum[tk][lane], v1 = ysum[tk][lane+64];
    float v2 = ysum[tk][lane+128], v3 = ysum[tk][lane+192];
    float s  = waveReduceSum(v0+v1+v2+v3);
    float s2 = waveReduceSum(v0*v0+v1*v1+v2*v2+v3*v3);
    float mean = s*(1.f/256.f);
    float var  = s2*(1.f/256.f) - mean*mean;
    float r = rsqrtf(var + 1e-5f);
    int p = hh*128 + ww0 + tk;
    size_t zb = (((size_t)b<<13) + p) << 8;
#pragma unroll
    for (int j=0;j<4;j++){
      int dd = lane + 64*j;
      float ln = (ysum[tk][dd]-mean)*r*g[dd] + bt[dd];
      float z = bf2f(Zg[zb + dd]);
      Zg[zb + dd] = f2bf(ln * siluf_(z));
    }
  }
}

// ---------------- MFMA 3x3 conv 128->128(all co) + BN (+res) + ReLU ----------------
template<int FINAL>
__global__ void k_mconv(const ushortt* __restrict__ I, const ushortt* __restrict__ Wt,
                        const float* __restrict__ g, const float* __restrict__ bb,
                        const float* __restrict__ mn, const float* __restrict__ vv,
                        const float* __restrict__ R, ushortt* __restrict__ Op,
                        float* __restrict__ Of){
  int y  = blockIdx.x;
  int im = blockIdx.y;
  int wv = threadIdx.x>>6, l = threadIdx.x&63;
  int ar = l&15, kg = l>>4;
  int x0 = wv*16;
  f32x4 acc[8];
#pragma unroll
  for (int i=0;i<8;i++){ acc[i][0]=0.f; acc[i][1]=0.f; acc[i][2]=0.f; acc[i][3]=0.f; }
  const ushortt* Ibase = I + (((size_t)im*66 + y)*66 + x0 + ar)*128 + kg*8;
  const ushortt* Wbase = Wt + (size_t)ar*128 + kg*8;
#pragma unroll
  for (int tap=0; tap<9; ++tap){
    int dy = tap/3, dx = tap - dy*3;
    const ushortt* Ir = Ibase + ((size_t)dy*66 + dx)*128;
    const ushortt* Wr = Wbase + (size_t)tap*16384;
#pragma unroll
    for (int kc=0;kc<4;kc++){
      bf16x8 af = *(const bf16x8*)(Ir + kc*32);
#pragma unroll
      for (int nf=0;nf<8;nf++){
        bf16x8 bfv = *(const bf16x8*)(Wr + (size_t)nf*16*128 + kc*32);
        acc[nf] = __builtin_amdgcn_mfma_f32_16x16x32_bf16(af, bfv, acc[nf], 0,0,0);
      }
    }
  }
#pragma unroll
  for (int nf=0;nf<8;nf++){
    int co = nf*16 + ar;
    float s  = g[co]*rsqrtf(vv[co]+1e-5f);
    float sh = bb[co] - mn[co]*s;
#pragma unroll
    for (int r=0;r<4;r++){
      int x = x0 + kg*4 + r;
      float v = acc[nf][r]*s + sh;
      if (FINAL){
        v += R[(((size_t)im*64 + y)*64 + x)*128 + co];
        v = fmaxf(v, 0.f);
        Of[(((size_t)im*128 + co)*64 + y)*64 + x] = v;
      } else {
        v = fmaxf(v, 0.f);
        Op[(((size_t)im*66 + (y+1))*66 + (x+1))*128 + co] = f2bf(v);
      }
    }
  }
}

extern "C" void kernel_launch(void* const* d_in, const int* in_sizes, int n_in,
                              void* d_out, int out_size, void* d_ws, size_t ws_size,
                              hipStream_t stream){
  const float* x1        = (const float*)d_in[0];
  const float* x2        = (const float*)d_in[1];
  const float* conv_in_w = (const float*)d_in[2];
  const float* conv_in_b = (const float*)d_in[3];
  const float* ln1_g     = (const float*)d_in[4];
  const float* ln1_b     = (const float*)d_in[5];
  const float* in_proj_w = (const float*)d_in[6];
  const float* dw_w      = (const float*)d_in[7];
  const float* dw_b      = (const float*)d_in[8];
  const float* x_proj_w  = (const float*)d_in[9];
  const float* dt_proj_w = (const float*)d_in[10];
  const float* dt_proj_b = (const float*)d_in[11];
  const float* A_logs    = (const float*)d_in[12];
  const float* Ds        = (const float*)d_in[13];
  const float* onorm_g   = (const float*)d_in[14];
  const float* onorm_b   = (const float*)d_in[15];
  const float* out_proj_w= (const float*)d_in[16];
  const float* ln2_g     = (const float*)d_in[17];
  const float* ln2_b     = (const float*)d_in[18];
  const float* mlp_w1    = (const float*)d_in[19];
  const float* mlp_b1    = (const float*)d_in[20];
  const float* mlp_w2    = (const float*)d_in[21];
  const float* mlp_b2    = (const float*)d_in[22];
  const float* rb1_w     = (const float*)d_in[23];
  const float* bn1_g     = (const float*)d_in[24];
  const float* bn1_b     = (const float*)d_in[25];
  const float* bn1_m     = (const float*)d_in[26];
  const float* bn1_v     = (const float*)d_in[27];
  const float* rb2_w     = (const float*)d_in[28];
  const float* bn2_g     = (const float*)d_in[29];
  const float* bn2_b     = (const float*)d_in[30];
  const float* bn2_m     = (const float*)d_in[31];
  const float* bn2_v     = (const float*)d_in[32];

  float* ws = (float*)d_ws;
  char*  wsB = (char*)d_ws;
  const size_t FM = 262144;            // floats per MiB
  const size_t MB = 1048576;           // bytes per MiB
  // Workspace layout (peak ~147.2 MiB):
  float*   X0   = ws;                          // 0-16    residual stream (B,L,128) f32
  ushortt* Xpab = (ushortt*)(wsB + 16*MB);     // 16-32   u post-dw-silu (B,L,256) bf16
  ushortt* Xpt0 = (ushortt*)(wsB + 32*MB);     // 32-48   u raster-order [b][d][p]
  ushortt* Xpt1 = (ushortt*)(wsB + 48*MB);     // 48-64   u colmajor-order [b][d][t1]
  char*    DBCb = wsB + 64*MB;                 // 64-68   dts rows 32B
  uintt*   BCs  = (uintt*)(wsB + 68*MB);       // 68-76   B/C dwords [bk][t/16][n][t%16]
  ushortt* Zg   = (ushortt*)(wsB + 77*MB);     // 77-93   z / gated bf16
  ushortt* Y0   = (ushortt*)(wsB + 93*MB);     // 93-109
  ushortt* Y1   = (ushortt*)(wsB + 109*MB);    // 109-125
  ushortt* Y2   = (ushortt*)(wsB + 125*MB);    // 125-141
  ushortt* Y3   = Xpab;                        // alias (Xpab dead before scanM)
  float*   Hbuf = ws + 141*FM;                 // 141-143 (32768*16 f32)
  float*   Ssum = ws + 145*FM;                 // 145-145.125
  // time-disjoint aliases:
  ushortt* CT   = (ushortt*)(wsB + 93*MB);     // steps 1-2 (over Y0)
  ushortt* Lnb  = (ushortt*)(wsB + 101*MB);    // steps 2-4 (over Y0 2nd half)
  ushortt* Xpb  = (ushortt*)(wsB + 109*MB);    // steps 4-5 xp pre-dw bf16 (over Y1)
  ushortt* Ln2b = (ushortt*)(wsB + 93*MB);     // steps 9-11 (Y0 dead)
  ushortt* H1   = (ushortt*)(wsB + 109*MB);    // steps 11-12 (Y1,Y2 dead)
  ushortt* P    = (ushortt*)(wsB + 16*MB);     // step 12+ padded conv input [8][66][66][128]
  ushortt* T    = (ushortt*)(wsB + 25*MB);     // conv1 out padded
  float*   R    = (float*)(wsB + 34*MB);       // 34-51 residual [8][64][64][128] f32
  // bf16 weights (persistent, never aliased):
  ushortt* cw  = (ushortt*)(wsB + 146*MB);            // 32 KB
  ushortt* ipw = (ushortt*)(wsB + 146*MB + 32*1024);  // 128 KB
  ushortt* opw = (ushortt*)(wsB + 146*MB + 160*1024); // 64 KB
  ushortt* m1w = (ushortt*)(wsB + 146*MB + 224*1024); // 128 KB
  ushortt* m2w = (ushortt*)(wsB + 146*MB + 352*1024); // 128 KB
  ushortt* rw1 = (ushortt*)(wsB + 146*MB + 480*1024); // 288 KB
  ushortt* rw2 = (ushortt*)(wsB + 146*MB + 768*1024); // 288 KB
  ushortt* xpw = (ushortt*)(wsB + 146*MB + 1056*1024);// 160 KB (320x256 bf16)
  float*   dwt = (float*)(wsB + 146*MB + 1216*1024);  // 9 KB [tap][256] f32
  float* out = (float*)d_out;

  // 0. all weight conversions (one launch)
  k_wall<<<2441,256,0,stream>>>(conv_in_w,cw, in_proj_w,ipw, out_proj_w,opw,
                                mlp_w1,m1w, mlp_w2,m2w, rb1_w,rw1, rb2_w,rw2,
                                dw_w, dwt, x_proj_w, xpw);
  // 1. interleave -> CT bf16 token-major
  k_build_ct2<<<512,256,0,stream>>>(x1,x2,CT);
  // 2. conv_in 1x1 (bias) -> X0 f32 + fused LN1 -> Lnb bf16
  k_mgemmln<0><<<512,256,0,stream>>>(CT, cw, conv_in_b, X0, ln1_g, ln1_b, Lnb, 128);
  // 4. in_proj (512) -> split xp(Xpb bf16) / z(Zg bf16); wide blocks
  k_mgemm<3,16><<<dim3(2,512),256,0,stream>>>(Lnb, ipw, nullptr, nullptr, nullptr, Zg, Xpb, nullptr, 512,128);
  // 5. depthwise 3x3 + silu -> Xpab bf16 + Xpt0 (fused transpose)
  k_dwconv<<<dim3(8,64,BB),256,0,stream>>>(Xpb, dwt, dw_b, Xpab, Xpt0);
  // 5b. colmajor u copy only
  k_xtm<<<dim3(128,4,BB),256,0,stream>>>(Xpab, Xpt1);
  // 6. x_proj MFMA GEMM (hi/lo weights, f32-equivalent) -> dts (DBCb) + B/C (BCs)
  k_xproj<<<dim3(5,512),256,0,stream>>>(Xpab, xpw, (float*)DBCb, (char*)BCs);
  // 7. chunked selective scan: merged main pass + correction (scanB inlined)
  k_scanM<<<4096,128,0,stream>>>(DBCb, BCs, Xpt0, Xpt1, dt_proj_w, dt_proj_b, A_logs,
                                 Hbuf, Ssum, Y0,Y1,Y2,Y3);
  k_corr<<<4096,128,0,stream>>>(DBCb, BCs, dt_proj_w, dt_proj_b, A_logs, Hbuf, Ssum,
                                Y0,Y1,Y2,Y3);
  // 8. gate
  k_gate2<<<dim3(4,64,BB),256,0,stream>>>(Y0,Y1,Y2,Y3, Xpt0, Ds, Zg, onorm_g, onorm_b);
  // 9. out_proj + residual -> X0 + fused LN2 -> Ln2b bf16
  k_mgemmln<1><<<512,256,0,stream>>>(Zg, opw, nullptr, X0, ln2_g, ln2_b, Ln2b, 256);
  // 9b. zero padded conv buffers (P and T) — Xpab/Xpt0 regions now dead
  hipMemsetAsync(wsB + 16*MB, 0, 18*MB, stream);
  // 11. MLP1 gelu -> H1 bf16; wide blocks
  k_mgemm<2,16><<<dim3(2,512),256,0,stream>>>(Ln2b, m1w, mlp_b1, nullptr, nullptr, H1, nullptr,nullptr, 512,128);
  // 12. MLP2 + bias + residual -> fused de-interleave (P bf16 padded + R f32); wide blocks
  k_mgemm<4,8><<<dim3(1,512),256,0,stream>>>(H1, m2w, mlp_b2, X0, nullptr, nullptr, P, R, 128,512);
  // 13-14. resblocks (both images batched, img = im2*4 + b)
  k_mconv<0><<<dim3(64,8),256,0,stream>>>(P, rw1, bn1_g,bn1_b,bn1_m,bn1_v, nullptr, T, nullptr);
  k_mconv<1><<<dim3(64,8),256,0,stream>>>(T, rw2, bn2_g,bn2_b,bn2_m,bn2_v, R, nullptr, out);
}

// Round 17
// 719.930 us; speedup vs baseline: 14.7848x; 1.0032x over previous
//
#include <hip/hip_runtime.h>
#include <math.h>

// Problem constants
#define BB 4
#define CM 128      // d_model
#define DI 256      // d_inner
#define NS 16       // d_state
#define RK 8        // dt_rank
#define KD 4        // K directions
#define HH 64
#define WW 128      // interleaved width
#define LL 8192     // HH*WW
#define NC 8        // scan chunks per sequence
#define CH 1024     // chunk length (NC*CH == LL)

typedef unsigned short ushortt;
typedef unsigned int uintt;
typedef __attribute__((ext_vector_type(8))) __bf16 bf16x8;
typedef __attribute__((ext_vector_type(4))) float f32x4;

// Compiler memory-order fence: LDS ops cannot cross (asm memory clobber).
__device__ __forceinline__ void lds_fence(){
  asm volatile("" ::: "memory");
}

__device__ __forceinline__ float sigmoidf_(float x){ return 1.f/(1.f+__expf(-x)); }
__device__ __forceinline__ float siluf_(float x){ return x*sigmoidf_(x); }
__device__ __forceinline__ float softplusf_(float x){
  float r = __logf(1.f + __expf(x));   // fast path, no libcall
  return (x > 20.f) ? x : r;
}
__device__ __forceinline__ float geluf_(float x){ return 0.5f*x*(1.f+erff(x*0.70710678118654752f)); }
__device__ __forceinline__ ushortt f2bf(float f){
  uintt u = __float_as_uint(f);
  uintt r = (u + 0x7fffu + ((u>>16)&1u)) >> 16;
  return (ushortt)r;
}
__device__ __forceinline__ float bf2f(ushortt s){
  return __uint_as_float(((uintt)s)<<16);
}
template<int CTRL>
__device__ __forceinline__ float dppadd(float x){
  int r = __builtin_amdgcn_update_dpp(0, __float_as_int(x), CTRL, 0xF, 0xF, true);
  return x + __int_as_float(r);
}
// full sum over each 16-lane row; result on all lanes
__device__ __forceinline__ float rowsum16(float x){
  x = dppadd<0x121>(x);  // row_ror:1
  x = dppadd<0x122>(x);  // row_ror:2
  x = dppadd<0x124>(x);  // row_ror:4
  x = dppadd<0x128>(x);  // row_ror:8
  return x;
}
__device__ __forceinline__ float waveReduceSum(float v){
  for (int o=32;o>0;o>>=1) v += __shfl_xor(v,o,64);
  return v;
}

// ---------------- merged weight conversions (1 launch) ----------------
// xp packing (320 rows x 256), 10 units of {16 hi rows + 16 lo rows}:
//   u0: dts k=0,1 (r16 = k*8+c, k in {0,1}); u1: dts k=2,3
//   u2+e (e=0..7): e>>1 = direction q, e&1 = 0->B / 1->C, r16 = state
__global__ void k_wall(const float* __restrict__ cw_s, ushortt* __restrict__ cw_d,
                       const float* __restrict__ ip_s, ushortt* __restrict__ ip_d,
                       const float* __restrict__ op_s, ushortt* __restrict__ op_d,
                       const float* __restrict__ m1_s, ushortt* __restrict__ m1_d,
                       const float* __restrict__ m2_s, ushortt* __restrict__ m2_d,
                       const float* __restrict__ r1_s, ushortt* __restrict__ r1_d,
                       const float* __restrict__ r2_s, ushortt* __restrict__ r2_d,
                       const float* __restrict__ dw_s, float* __restrict__ dw_d,
                       const float* __restrict__ xp_s, ushortt* __restrict__ xp_d){
  int i = blockIdx.x*256 + threadIdx.x;
  if (i < 16384){ cw_d[i] = f2bf(cw_s[i]); return; }
  i -= 16384;
  if (i < 65536){ ip_d[i] = f2bf(ip_s[i]); return; }
  i -= 65536;
  if (i < 32768){ op_d[i] = f2bf(op_s[i]); return; }
  i -= 32768;
  if (i < 65536){ m1_d[i] = f2bf(m1_s[i]); return; }
  i -= 65536;
  if (i < 65536){ m2_d[i] = f2bf(m2_s[i]); return; }
  i -= 65536;
  if (i < 147456){ int ci=i&127, co=(i>>7)&127, tap=i>>14;
    r1_d[i]=f2bf(r1_s[(size_t)(co*128+ci)*9+tap]); return; }
  i -= 147456;
  if (i < 147456){ int ci=i&127, co=(i>>7)&127, tap=i>>14;
    r2_d[i]=f2bf(r2_s[(size_t)(co*128+ci)*9+tap]); return; }
  i -= 147456;
  if (i < 2304){ int d = i & 255, tap = i >> 8;
    dw_d[i] = dw_s[d*9 + tap]; return; }   // exact f32 copy, [tap][d]
  i -= 2304;
  if (i < 81920){
    int d = i & 255, row = i >> 8;         // row 0..319
    int u = row >> 5, rem = row & 31;
    int lo = rem >> 4, r16 = rem & 15;
    float v;
    if (u < 2){
      int k = u*2 + (r16>>3), c = r16&7;
      v = xp_s[((size_t)(k*40+c))*256 + d];
    } else {
      int e = u-2; int q = e>>1; int j = (e&1)*16 + r16;
      v = xp_s[((size_t)(q*40+8+j))*256 + d];
    }
    xp_d[i] = lo ? f2bf(v - bf2f(f2bf(v))) : f2bf(v);
  }
}

// ---------------- zero padding rings of P and T ----------------
__global__ void k_bz(ushortt* __restrict__ P, ushortt* __restrict__ T){
  int i = blockIdx.x*256 + threadIdx.x;     // < 2*8*260*128 = 532480
  if (i >= 532480) return;
  int d = i & 127; int r = (i >> 7) % 260; int im = (i >> 7) / 260;
  ushortt* buf = (im >= 8) ? T : P;
  im &= 7;
  int y, x;
  if (r < 66){ y = 0; x = r; }
  else if (r < 132){ y = 65; x = r-66; }
  else { int rr = r-132; y = 1 + (rr>>1); x = (rr&1)?65:0; }
  buf[(((size_t)im*66 + y)*66 + x)*128 + d] = 0;
}

// ---------------- CT build: interleave x1/x2 -> token-major bf16 (B*L, 128) ----------------
__global__ void k_build_ct2(const float* __restrict__ x1, const float* __restrict__ x2,
                            ushortt* __restrict__ CT){
  __shared__ ushortt Tl[64][136];
  int tid = threadIdx.x;
  int p0 = (blockIdx.x & 127) * 64;
  int b  = blockIdx.x >> 7;
  int j = tid & 63;
  int p = p0 + j; int hh = p>>7, ww = p&127, w2 = ww>>1;
  const float* src = (ww&1) ? x2 : x1;
  const float* sp = src + ((size_t)b*128*64 + hh)*64 + w2;
  for (int c0 = tid>>6; c0 < 128; c0 += 4)
    Tl[j][c0] = f2bf(sp[(size_t)c0*4096]);
  __syncthreads();
  int c = tid & 127; int rh = tid >> 7;
  for (int r = rh; r < 64; r += 2)
    CT[((size_t)b*LL + p0 + r)*128 + c] = Tl[r][c];
}

// ---------------- MFMA token GEMM ----------------
template<int EPI, int NF>
__global__ void k_mgemm(const ushortt* __restrict__ A, const ushortt* __restrict__ W,
                        const float* __restrict__ bias, const float* __restrict__ resid,
                        float* __restrict__ C, ushortt* __restrict__ C2,
                        ushortt* __restrict__ Pp, float* __restrict__ Rp, int N, int K){
  int n0 = blockIdx.x*(NF*16), m0 = blockIdx.y*64;
  int wv = threadIdx.x>>6, l = threadIdx.x&63;
  int ar = l&15, kg = l>>4;
  int mw = m0 + wv*16;
  f32x4 acc[NF];
#pragma unroll
  for (int i=0;i<NF;i++){ acc[i][0]=0.f; acc[i][1]=0.f; acc[i][2]=0.f; acc[i][3]=0.f; }
  const ushortt* Ap = A + (size_t)(mw+ar)*K + kg*8;
  const ushortt* Wp = W + (size_t)(n0+ar)*K + kg*8;
  for (int k0=0; k0<K; k0+=32){
    bf16x8 af = *(const bf16x8*)(Ap + k0);
#pragma unroll
    for (int nf=0; nf<NF; ++nf){
      bf16x8 bfv = *(const bf16x8*)(Wp + (size_t)nf*16*K + k0);
      acc[nf] = __builtin_amdgcn_mfma_f32_16x16x32_bf16(af, bfv, acc[nf], 0,0,0);
    }
  }
#pragma unroll
  for (int nf=0;nf<NF;nf++){
    int n = n0 + nf*16 + ar;
#pragma unroll
    for (int r=0;r<4;r++){
      int m = mw + kg*4 + r;
      float v = acc[nf][r];
      if (EPI==2){
        v += bias[n];
        C2[(size_t)m*512 + n] = f2bf(geluf_(v));
      } else if (EPI==3){
        if (n < 256) Pp[(size_t)m*256 + n] = f2bf(v);
        else         C2[(size_t)m*256 + (n-256)] = f2bf(v);
      } else { // EPI==4
        v += bias[n];
        v += resid[(size_t)m*128 + n];
        int bq = m >> 13; int pq = m & 8191; int yq = pq >> 7; int wq = pq & 127;
        int im = (wq&1)*4 + bq; int xq = wq>>1;
        Pp[(((size_t)im*66 + yq+1)*66 + xq+1)*128 + n] = f2bf(v);
        Rp[(((size_t)im*64 + yq)*64 + xq)*128 + n] = v;
      }
    }
  }
}

// ---------------- MFMA GEMM (N=128) with fused LayerNorm epilogue ----------------
template<int RES>
__global__ void k_mgemmln(const ushortt* __restrict__ A, const ushortt* __restrict__ W,
                          const float* __restrict__ bias, float* __restrict__ X,
                          const float* __restrict__ g, const float* __restrict__ bt,
                          ushortt* __restrict__ O, int K){
  int m0 = blockIdx.x*64;
  int wv = threadIdx.x>>6, l = threadIdx.x&63;
  int ar = l&15, kg = l>>4;
  int mw = m0 + wv*16;
  f32x4 acc[8];
#pragma unroll
  for (int i=0;i<8;i++){ acc[i][0]=0.f; acc[i][1]=0.f; acc[i][2]=0.f; acc[i][3]=0.f; }
  const ushortt* Ap = A + (size_t)(mw+ar)*K + kg*8;
  const ushortt* Wp = W + (size_t)ar*K + kg*8;
  for (int k0=0; k0<K; k0+=32){
    bf16x8 af = *(const bf16x8*)(Ap + k0);
#pragma unroll
    for (int nf=0; nf<8; ++nf){
      bf16x8 bfv = *(const bf16x8*)(Wp + (size_t)nf*16*K + k0);
      acc[nf] = __builtin_amdgcn_mfma_f32_16x16x32_bf16(af, bfv, acc[nf], 0,0,0);
    }
  }
  float vv[8][4];
  float s[4] = {0,0,0,0}, s2[4] = {0,0,0,0};
#pragma unroll
  for (int nf=0;nf<8;nf++){
    int n = nf*16 + ar;
    float bv = bias ? bias[n] : 0.f;
#pragma unroll
    for (int r=0;r<4;r++){
      int m = mw + kg*4 + r;
      float v = acc[nf][r] + bv;
      if (RES) v += X[(size_t)m*128 + n];
      X[(size_t)m*128 + n] = v;
      vv[nf][r] = v;
      s[r] += v; s2[r] += v*v;
    }
  }
  float mn[4], rs[4];
#pragma unroll
  for (int r=0;r<4;r++){
    float S  = rowsum16(s[r]);
    float S2 = rowsum16(s2[r]);
    float mean = S*(1.f/128.f);
    float var  = S2*(1.f/128.f) - mean*mean;
    mn[r] = mean; rs[r] = rsqrtf(var + 1e-5f);
  }
#pragma unroll
  for (int nf=0;nf<8;nf++){
    int n = nf*16 + ar;
    float gv = g[n], bv = bt[n];
#pragma unroll
    for (int r=0;r<4;r++){
      int m = mw + kg*4 + r;
      O[(size_t)m*128 + n] = f2bf((vv[nf][r]-mn[r])*rs[r]*gv + bv);
    }
  }
}

// ---------------- Depthwise 3x3 + bias + SiLU, tiled; emits Xpab AND Xpt0 ----------------
// grid (8 strips, 64 hh, 4 b), block 256 (one d-column per thread).
__global__ void k_dwconv(const ushortt* __restrict__ Xp, const float* __restrict__ dwt,
                         const float* __restrict__ bias, ushortt* __restrict__ O,
                         ushortt* __restrict__ Xpt0){
  __shared__ ushortt S[3][18][256];   // 27.6 KB
  int tid = threadIdx.x;
  int ws0 = blockIdx.x*16;
  int hh  = blockIdx.y;
  int b   = blockIdx.z;
  // stage halo tile: 54 rows (dy,j) x 256 d, 8-bf16 vectors
  for (int v = tid; v < 1728; v += 256){
    int d0 = (v & 31)*8;
    int r  = v >> 5;            // 0..53
    int dy = r/18, j = r - dy*18;
    int yy = hh + dy - 1, xx = ws0 + j - 1;
    uint4 val = make_uint4(0,0,0,0);
    if (yy>=0 && yy<HH && xx>=0 && xx<WW)
      val = *(const uint4*)(Xp + ((size_t)b*LL + yy*WW + xx)*256 + d0);
    *(uint4*)(&S[dy][j][d0]) = val;
  }
  __syncthreads();
  int d = tid;
  float w[9];
#pragma unroll
  for (int t=0;t<9;t++) w[t] = dwt[t*256+d];
  float bv = bias[d];
  ushortt outs[16];
  float a0=bf2f(S[0][0][d]), a1=bf2f(S[1][0][d]), a2=bf2f(S[2][0][d]);
  float b0=bf2f(S[0][1][d]), b1=bf2f(S[1][1][d]), b2=bf2f(S[2][1][d]);
  for (int j=0;j<16;j++){
    float c0=bf2f(S[0][j+2][d]), c1=bf2f(S[1][j+2][d]), c2=bf2f(S[2][j+2][d]);
    float acc = bv;
    acc += a0*w[0] + b0*w[1] + c0*w[2];
    acc += a1*w[3] + b1*w[4] + c1*w[5];
    acc += a2*w[6] + b2*w[7] + c2*w[8];
    ushortt ov = f2bf(siluf_(acc));
    outs[j] = ov;
    O[((size_t)b*LL + hh*WW + ws0 + j)*256 + d] = ov;
    a0=b0; a1=b1; a2=b2; b0=c0; b1=c1; b2=c2;
  }
  // contiguous 32B row of Xpt0[b][d][p0..p0+15]
  uintt pk[8];
#pragma unroll
  for (int q=0;q<8;q++) pk[q] = (uintt)outs[2*q] | ((uintt)outs[2*q+1]<<16);
  ushortt* dst = Xpt0 + ((size_t)(b*256+d))*LL + hh*WW + ws0;
  *(uint4*)dst       = make_uint4(pk[0],pk[1],pk[2],pk[3]);
  *(uint4*)(dst + 8) = make_uint4(pk[4],pk[5],pk[6],pk[7]);
}

// ---------------- transpose: Xpab[b][p][d] -> Xpt1 (colmajor t1 = ww*64+hh) ----------------
__global__ void k_xtm(const ushortt* __restrict__ Xpab, ushortt* __restrict__ Xpt1){
  __shared__ ushortt Tl[64][68];
  int b = blockIdx.z;
  int d0 = blockIdx.y*64;
  int ww = blockIdx.x;
  int di = threadIdx.x&63, q = threadIdx.x>>6;
  for (int k2=0;k2<16;k2++){ int hh = q*16 + k2;
    Tl[hh][di] = Xpab[((size_t)b*LL + hh*128 + ww)*256 + d0+di]; }
  __syncthreads();
  for (int k2=0;k2<16;k2++){ int dr = q*16 + k2;
    Xpt1[((size_t)(b*256 + d0+dr))*LL + ww*64 + di] = Tl[di][dr]; }
}

// ---------------- x_proj as MFMA GEMM, hi/lo unit pairs; A read 2x total ----------------
// grid (2, 512): n0 = blockIdx.x*160, NF=10 fragments (5 hi/lo pairs).
__global__ void k_xproj(const ushortt* __restrict__ A, const ushortt* __restrict__ W,
                        float* __restrict__ DBCf, char* __restrict__ BCsb){
  int n0 = blockIdx.x*160, m0 = blockIdx.y*64;
  int wv = threadIdx.x>>6, l = threadIdx.x&63;
  int ar = l&15, kg = l>>4;
  int mw = m0 + wv*16;
  f32x4 acc[10];
#pragma unroll
  for (int i=0;i<10;i++){ acc[i][0]=0.f; acc[i][1]=0.f; acc[i][2]=0.f; acc[i][3]=0.f; }
  const ushortt* Ap = A + (size_t)(mw+ar)*256 + kg*8;
  const ushortt* Wp = W + (size_t)(n0+ar)*256 + kg*8;
  for (int k0=0; k0<256; k0+=32){
    bf16x8 af = *(const bf16x8*)(Ap + k0);
#pragma unroll
    for (int nf=0; nf<10; ++nf){
      bf16x8 bfv = *(const bf16x8*)(Wp + (size_t)nf*16*256 + k0);
      acc[nf] = __builtin_amdgcn_mfma_f32_16x16x32_bf16(af, bfv, acc[nf], 0,0,0);
    }
  }
#pragma unroll
  for (int nf=0; nf<10; nf+=2){     // even = hi, odd = lo partner
    int u = (n0 + nf*16) >> 5;      // unit 0..9
#pragma unroll
    for (int r=0;r<4;r++){
      int m = mw + kg*4 + r;
      int b = m >> 13, p = m & 8191;
      int hh = p>>7, ww = p&127;
      int tc = (ww<<6)|hh;
      float v = acc[nf][r] + acc[nf+1][r];
      if (u < 2){
        int kq = u*2 + (ar>>3), cq = ar&7;
        int t = (kq==0)? p : (kq==1)? tc : (kq==2)? (8191-p) : (8191-tc);
        int bk = b*KD + kq;
        DBCf[((size_t)bk*LL + t)*8 + cq] = v;
      } else {
        int e = u-2; int q = e>>1; int isC = e&1;
        int t = (q==0)? p : (q==1)? tc : (q==2)? (8191-p) : (8191-tc);
        int bk = b*KD + q;
        size_t a = ((((size_t)bk*512 + (t>>4))*16 + ar)*16 + (t&15))*4 + (isC?2:0);
        *(ushortt*)(BCsb + a) = f2bf(v);
      }
    }
  }
}

// ---------------- Merged scan pass: from h=0, write y_local + h_out + sum(delta) ----------------
// 128 threads = 8 groups of 16 lanes.
__global__ __launch_bounds__(128) void k_scanM(const char* __restrict__ DBCb,
                        const uintt* __restrict__ BCs,
                        const ushortt* __restrict__ Xpt0, const ushortt* __restrict__ Xpt1,
                        const float* __restrict__ dtw_all, const float* __restrict__ dtb_all,
                        const float* __restrict__ A_logs,
                        float* __restrict__ Hbuf, float* __restrict__ Ssum,
                        ushortt* __restrict__ Y0, ushortt* __restrict__ Y1,
                        ushortt* __restrict__ Y2, ushortt* __restrict__ Y3){
  __shared__ float2 sdd[8][16];
  __shared__ float yt[8*328];       // group pitch 328
  int tid = threadIdx.x;
  int grp = tid >> 4, lane = tid & 15;
  float* ytg = yt + grp*328;
  int gid = blockIdx.x*8 + grp;
  int c = gid & (NC-1);
  int bkd = gid / NC;
  int b = bkd >> 10, k = (bkd>>8)&3, d = bkd & 255;
  int kd = k*256+d;
  int bk = b*KD + k;
  float dtw[8];
  { const float4* w4 = (const float4*)(dtw_all + (size_t)kd*8);
    float4 w0 = w4[0], w1 = w4[1];
    dtw[0]=w0.x; dtw[1]=w0.y; dtw[2]=w0.z; dtw[3]=w0.w;
    dtw[4]=w1.x; dtw[5]=w1.y; dtw[6]=w1.z; dtw[7]=w1.w; }
  float dtb  = dtb_all[kd];
  float Aval = -__expf(A_logs[(size_t)kd*16+lane]);
  const char* dbc = DBCb + (size_t)bk*LL*32;
  const uintt* bcb = BCs + ((size_t)bk*512 + (c*CH>>4))*256;
  const ushortt* Up = ((k&1)?Xpt1:Xpt0) + ((size_t)(b*256+d))*LL;
  ushortt* Yk = (k==0?Y0 : k==1?Y1 : k==2?Y2 : Y3) + ((size_t)b*256 + d)*LL;
  float h = 0.f, Sacc = 0.f;
  int t0 = c*CH;
  // prefetch block 0 dts + u
  const char* row0 = dbc + (size_t)(t0+lane)*32;
  float4 q0 = *(const float4*)row0;
  float4 q1 = *(const float4*)(row0+16);
  ushortt ur = Up[(k<2) ? (t0+lane) : (LL-1-(t0+lane))];
  for (int blk=0; blk<CH/16; ++blk){
    int tb = t0 + blk*16;
    int tme = tb + lane;
    const uint4* bcp = (const uint4*)(bcb + ((size_t)blk*16 + lane)*16);
    uint4 w0 = bcp[0], w1 = bcp[1], w2 = bcp[2], w3 = bcp[3];
    float4 c0 = q0, c1 = q1; ushortt cu = ur;
    if (blk+1 < CH/16){
      const char* rn = dbc + (size_t)(tme+16)*32;
      q0 = *(const float4*)rn;
      q1 = *(const float4*)(rn+16);
      ur = Up[(k<2) ? (tme+16) : (LL-1-(tme+16))];
    }
    float dsum = dtb + c0.x*dtw[0] + c0.y*dtw[1] + c0.z*dtw[2] + c0.w*dtw[3]
                     + c1.x*dtw[4] + c1.y*dtw[5] + c1.z*dtw[6] + c1.w*dtw[7];
    float delta = softplusf_(dsum);
    Sacc += delta;
    float u = bf2f(cu);
    sdd[grp][lane] = make_float2(delta, delta*u);
    lds_fence();             // order sdd write vs cross-lane reads below
    uintt wd[16] = {w0.x,w0.y,w0.z,w0.w, w1.x,w1.y,w1.z,w1.w,
                    w2.x,w2.y,w2.z,w2.w, w3.x,w3.y,w3.z,w3.w};
#pragma unroll
    for (int i=0;i<16;i++){
      float2 dd = sdd[grp][i];
      uintt w = wd[i];
      float Bn = __uint_as_float(w<<16);
      float Cn = __uint_as_float(w & 0xffff0000u);
      float e = __expf(dd.x * Aval);
      h = e*h + dd.y*Bn;
      ytg[i*20 + lane] = h*Cn;
    }
    lds_fence();             // order yt writes vs cross-lane yt reads
    const f32x4* yr = (const f32x4*)(ytg + lane*20);
    f32x4 s0 = yr[0], s1 = yr[1], s2v = yr[2], s3 = yr[3];
    float acc = (s0[0]+s0[1]+s0[2]+s0[3]) + (s1[0]+s1[1]+s1[2]+s1[3])
              + (s2v[0]+s2v[1]+s2v[2]+s2v[3]) + (s3[0]+s3[1]+s3[2]+s3[3]);
    Yk[tme] = f2bf(acc);
    lds_fence();             // order yt reads vs next block's yt writes
  }
  Hbuf[(size_t)gid*16 + lane] = h;
  float Stot = rowsum16(Sacc);
  if (lane==0) Ssum[gid] = Stot;
}

// Pass C': correction sweep with inline h_start chain (scanB fused).
__global__ __launch_bounds__(128) void k_corr(const char* __restrict__ DBCb,
                       const uintt* __restrict__ BCs,
                       const float* __restrict__ dtw_all, const float* __restrict__ dtb_all,
                       const float* __restrict__ A_logs,
                       const float* __restrict__ Hbuf, const float* __restrict__ Ssum,
                       ushortt* __restrict__ Y0, ushortt* __restrict__ Y1,
                       ushortt* __restrict__ Y2, ushortt* __restrict__ Y3){
  __shared__ float hs[8][16];
  int tid = threadIdx.x;
  int grp = tid >> 4, lane = tid & 15;
  int gid = blockIdx.x*8 + grp;
  int c = gid & (NC-1);
  if (c == 0) return;                 // h0 == 0 exactly
  int bkd = gid / NC;
  int b = bkd >> 10, k = (bkd>>8)&3, d = bkd & 255;
  int kd = k*256+d;
  int bk = b*KD + k;
  // lane n computes h_start[n] via scanB's recurrence (bit-identical order)
  {
    float Avn = -__expf(A_logs[(size_t)kd*16+lane]);
    float h = 0.f;
    for (int j=0; j<c; ++j){
      size_t gj = (size_t)bkd*NC + j;
      h = __expf(Avn*Ssum[gj])*h + Hbuf[gj*16 + lane];
    }
    hs[grp][lane] = h;
  }
  lds_fence();
  float h0[16];
  float hmax = 0.f;
#pragma unroll
  for (int n=0;n<16;n++){
    h0[n] = hs[grp][n];
    hmax = fmaxf(hmax, fabsf(h0[n]));
  }
  float Sexit = 14.f + __logf(fmaxf(hmax, 1e-30f));
  if (0.f > Sexit) return;            // h0 negligible
  float dtw[8];
  { const float4* w4 = (const float4*)(dtw_all + (size_t)kd*8);
    float4 w0 = w4[0], w1 = w4[1];
    dtw[0]=w0.x; dtw[1]=w0.y; dtw[2]=w0.z; dtw[3]=w0.w;
    dtw[4]=w1.x; dtw[5]=w1.y; dtw[6]=w1.z; dtw[7]=w1.w; }
  float dtb  = dtb_all[kd];
  const char* dbc = DBCb + (size_t)bk*LL*32;
  ushortt* Yk = (k==0?Y0 : k==1?Y1 : k==2?Y2 : Y3) + ((size_t)b*256 + d)*LL;
  float S0 = 0.f;
  int t0 = c*CH;
  for (int blk=0; blk<CH/16; ++blk){
    int tme = t0 + blk*16 + lane;
    const char* rowme = dbc + (size_t)tme*32;
    float4 q0 = *(const float4*)rowme;
    float4 q1 = *(const float4*)(rowme+16);
    float dsum = dtb + q0.x*dtw[0] + q0.y*dtw[1] + q0.z*dtw[2] + q0.w*dtw[3]
                     + q1.x*dtw[4] + q1.y*dtw[5] + q1.z*dtw[6] + q1.w*dtw[7];
    float delta = softplusf_(dsum);
    // inclusive prefix sum over the 16-lane group
    float pre = delta;
#pragma unroll
    for (int o=1;o<16;o<<=1){
      float t = __shfl_up(pre, o, 16);
      if (lane >= o) pre += t;
    }
    float S = S0 + pre;
    float E = __expf(-S);
    const uintt* cb = BCs + ((size_t)bk*512 + (tme>>4))*256 + (tme&15);
    float p = E, acc = 0.f;
#pragma unroll
    for (int n=0;n<16;n++){
      float Cn = __uint_as_float(cb[n*16] & 0xffff0000u);
      acc += Cn * h0[n] * p;
      p *= E;
    }
    float yv = bf2f(Yk[tme]);
    Yk[tme] = f2bf(yv + acc);
    S0 = __shfl(S, 15, 16);           // block total carry
    if (S0 > Sexit) break;            // uniform across group
  }
}

// ---------------- Gate: gather Y0..Y3 + u*sum(D), LN256, *silu(z) ----------------
__global__ void k_gate2(const ushortt* __restrict__ Y0, const ushortt* __restrict__ Y1,
                        const ushortt* __restrict__ Y2, const ushortt* __restrict__ Y3,
                        const ushortt* __restrict__ Xpt0, const float* __restrict__ Ds,
                        ushortt* __restrict__ Zg,
                        const float* __restrict__ g, const float* __restrict__ bt){
  __shared__ float ysum[32][257];
  __shared__ float Dl[256];
  int tid = threadIdx.x;
  int wwb = blockIdx.x;      // 0..3
  int hh  = blockIdx.y;      // 0..63
  int b   = blockIdx.z;
  if (tid < 256) Dl[tid] = Ds[tid] + Ds[256+tid] + Ds[512+tid] + Ds[768+tid];
  int ww0 = wwb*32;
  for (int it=0; it<32; ++it){
    int idx = it*256 + tid;
    int d = idx >> 5, tl = idx & 31;
    int ww = ww0 + tl;
    int p  = hh*128 + ww;
    size_t base = ((size_t)b*256 + d) << 13;
    int t1 = ww*64 + hh;
    float v = bf2f(Y0[base + p]) + bf2f(Y2[base + (LL-1) - p])
            + bf2f(Y1[base + t1]) + bf2f(Y3[base + (LL-1) - t1]);
    ysum[tl][d] = v;
  }
  __syncthreads();
  {
    int d = tid;
    if (d < 256){
      size_t ub = (((size_t)b*256 + d) << 13) + hh*128 + ww0;
      const uint4* up = (const uint4*)(Xpt0 + ub);   // 64B aligned
      uint4 u0 = up[0], u1 = up[1], u2 = up[2], u3 = up[3];
      uintt uw[16] = {u0.x,u0.y,u0.z,u0.w, u1.x,u1.y,u1.z,u1.w,
                      u2.x,u2.y,u2.z,u2.w, u3.x,u3.y,u3.z,u3.w};
      float Dd = Dl[d];
#pragma unroll
      for (int qd=0; qd<16; ++qd){
        float ulo = __uint_as_float(uw[qd]<<16);
        float uhi = __uint_as_float(uw[qd] & 0xffff0000u);
        ysum[2*qd][d]   += Dd*ulo;
        ysum[2*qd+1][d] += Dd*uhi;
      }
    }
  }
  __syncthreads();
  int wave = tid >> 6, lane = tid & 63;
  for (int tk = wave*8; tk < wave*8+8; ++tk){
    float v0 = ysum[tk][lane], v1 = ysum[tk][lane+64];
    float v2 = ysum[tk][lane+128], v3 = ysum[tk][lane+192];
    float s  = waveReduceSum(v0+v1+v2+v3);
    float s2 = waveReduceSum(v0*v0+v1*v1+v2*v2+v3*v3);
    float mean = s*(1.f/256.f);
    float var  = s2*(1.f/256.f) - mean*mean;
    float r = rsqrtf(var + 1e-5f);
    int p = hh*128 + ww0 + tk;
    size_t zb = (((size_t)b<<13) + p) << 8;
#pragma unroll
    for (int j=0;j<4;j++){
      int dd = lane + 64*j;
      float ln = (ysum[tk][dd]-mean)*r*g[dd] + bt[dd];
      float z = bf2f(Zg[zb + dd]);
      Zg[zb + dd] = f2bf(ln * siluf_(z));
    }
  }
}

// ---------------- MFMA 3x3 conv 128->128(all co) + BN (+res) + ReLU ----------------
template<int FINAL>
__global__ void k_mconv(const ushortt* __restrict__ I, const ushortt* __restrict__ Wt,
                        const float* __restrict__ g, const float* __restrict__ bb,
                        const float* __restrict__ mn, const float* __restrict__ vv,
                        const float* __restrict__ R, ushortt* __restrict__ Op,
                        float* __restrict__ Of){
  int y  = blockIdx.x;
  int im = blockIdx.y;
  int wv = threadIdx.x>>6, l = threadIdx.x&63;
  int ar = l&15, kg = l>>4;
  int x0 = wv*16;
  f32x4 acc[8];
#pragma unroll
  for (int i=0;i<8;i++){ acc[i][0]=0.f; acc[i][1]=0.f; acc[i][2]=0.f; acc[i][3]=0.f; }
  const ushortt* Ibase = I + (((size_t)im*66 + y)*66 + x0 + ar)*128 + kg*8;
  const ushortt* Wbase = Wt + (size_t)ar*128 + kg*8;
#pragma unroll
  for (int tap=0; tap<9; ++tap){
    int dy = tap/3, dx = tap - dy*3;
    const ushortt* Ir = Ibase + ((size_t)dy*66 + dx)*128;
    const ushortt* Wr = Wbase + (size_t)tap*16384;
#pragma unroll
    for (int kc=0;kc<4;kc++){
      bf16x8 af = *(const bf16x8*)(Ir + kc*32);
#pragma unroll
      for (int nf=0;nf<8;nf++){
        bf16x8 bfv = *(const bf16x8*)(Wr + (size_t)nf*16*128 + kc*32);
        acc[nf] = __builtin_amdgcn_mfma_f32_16x16x32_bf16(af, bfv, acc[nf], 0,0,0);
      }
    }
  }
#pragma unroll
  for (int nf=0;nf<8;nf++){
    int co = nf*16 + ar;
    float s  = g[co]*rsqrtf(vv[co]+1e-5f);
    float sh = bb[co] - mn[co]*s;
#pragma unroll
    for (int r=0;r<4;r++){
      int x = x0 + kg*4 + r;
      float v = acc[nf][r]*s + sh;
      if (FINAL){
        v += R[(((size_t)im*64 + y)*64 + x)*128 + co];
        v = fmaxf(v, 0.f);
        Of[(((size_t)im*128 + co)*64 + y)*64 + x] = v;
      } else {
        v = fmaxf(v, 0.f);
        Op[(((size_t)im*66 + (y+1))*66 + (x+1))*128 + co] = f2bf(v);
      }
    }
  }
}

extern "C" void kernel_launch(void* const* d_in, const int* in_sizes, int n_in,
                              void* d_out, int out_size, void* d_ws, size_t ws_size,
                              hipStream_t stream){
  const float* x1        = (const float*)d_in[0];
  const float* x2        = (const float*)d_in[1];
  const float* conv_in_w = (const float*)d_in[2];
  const float* conv_in_b = (const float*)d_in[3];
  const float* ln1_g     = (const float*)d_in[4];
  const float* ln1_b     = (const float*)d_in[5];
  const float* in_proj_w = (const float*)d_in[6];
  const float* dw_w      = (const float*)d_in[7];
  const float* dw_b      = (const float*)d_in[8];
  const float* x_proj_w  = (const float*)d_in[9];
  const float* dt_proj_w = (const float*)d_in[10];
  const float* dt_proj_b = (const float*)d_in[11];
  const float* A_logs    = (const float*)d_in[12];
  const float* Ds        = (const float*)d_in[13];
  const float* onorm_g   = (const float*)d_in[14];
  const float* onorm_b   = (const float*)d_in[15];
  const float* out_proj_w= (const float*)d_in[16];
  const float* ln2_g     = (const float*)d_in[17];
  const float* ln2_b     = (const float*)d_in[18];
  const float* mlp_w1    = (const float*)d_in[19];
  const float* mlp_b1    = (const float*)d_in[20];
  const float* mlp_w2    = (const float*)d_in[21];
  const float* mlp_b2    = (const float*)d_in[22];
  const float* rb1_w     = (const float*)d_in[23];
  const float* bn1_g     = (const float*)d_in[24];
  const float* bn1_b     = (const float*)d_in[25];
  const float* bn1_m     = (const float*)d_in[26];
  const float* bn1_v     = (const float*)d_in[27];
  const float* rb2_w     = (const float*)d_in[28];
  const float* bn2_g     = (const float*)d_in[29];
  const float* bn2_b     = (const float*)d_in[30];
  const float* bn2_m     = (const float*)d_in[31];
  const float* bn2_v     = (const float*)d_in[32];

  float* ws = (float*)d_ws;
  char*  wsB = (char*)d_ws;
  const size_t FM = 262144;            // floats per MiB
  const size_t MB = 1048576;           // bytes per MiB
  // Workspace layout (peak ~147.2 MiB):
  float*   X0   = ws;                          // 0-16    residual stream (B,L,128) f32
  ushortt* Xpab = (ushortt*)(wsB + 16*MB);     // 16-32   u post-dw-silu (B,L,256) bf16
  ushortt* Xpt0 = (ushortt*)(wsB + 32*MB);     // 32-48   u raster-order [b][d][p]
  ushortt* Xpt1 = (ushortt*)(wsB + 48*MB);     // 48-64   u colmajor-order [b][d][t1]
  char*    DBCb = wsB + 64*MB;                 // 64-68   dts rows 32B
  uintt*   BCs  = (uintt*)(wsB + 68*MB);       // 68-76   B/C dwords [bk][t/16][n][t%16]
  ushortt* Zg   = (ushortt*)(wsB + 77*MB);     // 77-93   z / gated bf16
  ushortt* Y0   = (ushortt*)(wsB + 93*MB);     // 93-109
  ushortt* Y1   = (ushortt*)(wsB + 109*MB);    // 109-125
  ushortt* Y2   = (ushortt*)(wsB + 125*MB);    // 125-141
  ushortt* Y3   = Xpab;                        // alias (Xpab dead before scanM)
  float*   Hbuf = ws + 141*FM;                 // 141-143 (32768*16 f32)
  float*   Ssum = ws + 145*FM;                 // 145-145.125
  // time-disjoint aliases:
  ushortt* CT   = (ushortt*)(wsB + 93*MB);     // steps 1-2 (over Y0)
  ushortt* Lnb  = (ushortt*)(wsB + 101*MB);    // steps 2-4 (over Y0 2nd half)
  ushortt* Xpb  = (ushortt*)(wsB + 109*MB);    // steps 4-5 xp pre-dw bf16 (over Y1)
  ushortt* Ln2b = (ushortt*)(wsB + 93*MB);     // steps 9-11 (Y0 dead)
  ushortt* H1   = (ushortt*)(wsB + 109*MB);    // steps 11-12 (Y1,Y2 dead)
  ushortt* P    = (ushortt*)(wsB + 16*MB);     // step 12+ padded conv input [8][66][66][128]
  ushortt* T    = (ushortt*)(wsB + 25*MB);     // conv1 out padded
  float*   R    = (float*)(wsB + 34*MB);       // 34-51 residual [8][64][64][128] f32
  // bf16 weights (persistent, never aliased):
  ushortt* cw  = (ushortt*)(wsB + 146*MB);            // 32 KB
  ushortt* ipw = (ushortt*)(wsB + 146*MB + 32*1024);  // 128 KB
  ushortt* opw = (ushortt*)(wsB + 146*MB + 160*1024); // 64 KB
  ushortt* m1w = (ushortt*)(wsB + 146*MB + 224*1024); // 128 KB
  ushortt* m2w = (ushortt*)(wsB + 146*MB + 352*1024); // 128 KB
  ushortt* rw1 = (ushortt*)(wsB + 146*MB + 480*1024); // 288 KB
  ushortt* rw2 = (ushortt*)(wsB + 146*MB + 768*1024); // 288 KB
  ushortt* xpw = (ushortt*)(wsB + 146*MB + 1056*1024);// 160 KB (320x256 bf16)
  float*   dwt = (float*)(wsB + 146*MB + 1216*1024);  // 9 KB [tap][256] f32
  float* out = (float*)d_out;

  // 0. all weight conversions (one launch)
  k_wall<<<2441,256,0,stream>>>(conv_in_w,cw, in_proj_w,ipw, out_proj_w,opw,
                                mlp_w1,m1w, mlp_w2,m2w, rb1_w,rw1, rb2_w,rw2,
                                dw_w, dwt, x_proj_w, xpw);
  // 1. interleave -> CT bf16 token-major
  k_build_ct2<<<512,256,0,stream>>>(x1,x2,CT);
  // 2. conv_in 1x1 (bias) -> X0 f32 + fused LN1 -> Lnb bf16
  k_mgemmln<0><<<512,256,0,stream>>>(CT, cw, conv_in_b, X0, ln1_g, ln1_b, Lnb, 128);
  // 4. in_proj (512) -> split xp(Xpb bf16) / z(Zg bf16); wide blocks
  k_mgemm<3,16><<<dim3(2,512),256,0,stream>>>(Lnb, ipw, nullptr, nullptr, nullptr, Zg, Xpb, nullptr, 512,128);
  // 5. depthwise 3x3 + silu -> Xpab bf16 + Xpt0 (fused transpose)
  k_dwconv<<<dim3(8,64,BB),256,0,stream>>>(Xpb, dwt, dw_b, Xpab, Xpt0);
  // 5b. colmajor u copy only
  k_xtm<<<dim3(128,4,BB),256,0,stream>>>(Xpab, Xpt1);
  // 6. x_proj MFMA GEMM (hi/lo unit pairs; A read 2x) -> dts (DBCb) + B/C (BCs)
  k_xproj<<<dim3(2,512),256,0,stream>>>(Xpab, xpw, (float*)DBCb, (char*)BCs);
  // 7. chunked selective scan: merged main pass + correction (scanB inlined)
  k_scanM<<<4096,128,0,stream>>>(DBCb, BCs, Xpt0, Xpt1, dt_proj_w, dt_proj_b, A_logs,
                                 Hbuf, Ssum, Y0,Y1,Y2,Y3);
  k_corr<<<4096,128,0,stream>>>(DBCb, BCs, dt_proj_w, dt_proj_b, A_logs, Hbuf, Ssum,
                                Y0,Y1,Y2,Y3);
  // 8. gate
  k_gate2<<<dim3(4,64,BB),256,0,stream>>>(Y0,Y1,Y2,Y3, Xpt0, Ds, Zg, onorm_g, onorm_b);
  // 9. out_proj + residual -> X0 + fused LN2 -> Ln2b bf16
  k_mgemmln<1><<<512,256,0,stream>>>(Zg, opw, nullptr, X0, ln2_g, ln2_b, Ln2b, 256);
  // 9b. zero only the padding rings of P and T (Xpab/Xpt0 regions now dead)
  k_bz<<<2080,256,0,stream>>>(P, T);
  // 11. MLP1 gelu -> H1 bf16; wide blocks
  k_mgemm<2,16><<<dim3(2,512),256,0,stream>>>(Ln2b, m1w, mlp_b1, nullptr, nullptr, H1, nullptr,nullptr, 512,128);
  // 12. MLP2 + bias + residual -> fused de-interleave (P bf16 padded + R f32); wide blocks
  k_mgemm<4,8><<<dim3(1,512),256,0,stream>>>(H1, m2w, mlp_b2, X0, nullptr, nullptr, P, R, 128,512);
  // 13-14. resblocks (both images batched, img = im2*4 + b)
  k_mconv<0><<<dim3(64,8),256,0,stream>>>(P, rw1, bn1_g,bn1_b,bn1_m,bn1_v, nullptr, T, nullptr);
  k_mconv<1><<<dim3(64,8),256,0,stream>>>(T, rw2, bn2_g,bn2_b,bn2_m,bn2_v, R, nullptr, out);
}